// Round 6
// baseline (2198.318 us; speedup 1.0000x reference)
//
#include <hip/hip_runtime.h>
#include <hip/hip_bf16.h>
#include <math.h>

#define BB 16
#define TT 256
#define DIN 384
#define DD 512
#define LL 6
#define HH 8
#define PP 64
#define SS 10
#define BT (BB*TT)   // 4096

enum { ACT_NONE=0, ACT_RELU=1, ACT_TANH=2, ACT_SILU=3 };

typedef __attribute__((ext_vector_type(8))) short bf16x8;
typedef __attribute__((ext_vector_type(4))) float f32x4;
typedef __hip_bfloat16 bh16;

typedef const __attribute__((address_space(1))) void gvoid_t;
typedef __attribute__((address_space(3))) void lvoid_t;
__device__ __forceinline__ void gload16(const void* g, void* l) {
    __builtin_amdgcn_global_load_lds((gvoid_t*)g, (lvoid_t*)l, 16, 0, 0);
}

// =====================================================================================
// Generic bf16 MFMA GEMM: C = act(A @ Bt^T + bias)  (Bt stored [N][K])
// BM=128, BN=64, BK=64; 4 waves 2x2, wave tile 64x32 (4x2 frags of 16x16).
// Optional batch dim z: z1=z>>zshift, z0=z&zmask; element-offsets per z1/z0.
// shift: A-row for output row r is (r-shift), valid iff (r%256)>=shift (else zero-page).
// ccdil: fused 3-tap causal conv over packed K=1536 (A lda=512, row-aliased):
//   tap = kt/8; mask threshold (2-tap)*ccdil; address shift mask+tap so that
//   (grow-addr_sh)*512 + tap*512 + c == (grow-mask_sh)*512 + c  (the desired tap row).
// Outputs: Cf fp32 (accum optional) and/or Cb bf16, both ldc.
__global__ __launch_bounds__(256) void mgemm_kernel(
    const bh16* __restrict__ A, int lda,
    const bh16* __restrict__ Bt, int ldb,
    const float* __restrict__ bias,
    float* __restrict__ Cf, bh16* __restrict__ Cb, int ldc,
    int N, int K, int shift, int accum, int act,
    int zmask, int zshift,
    long aS1, long aS0, long bS1, long bS0, long cS1, long cS0,
    int ccdil,
    const bh16* __restrict__ zp)
{
    __shared__ bf16x8 As[128*8];   // 16KB: [row][8 chunks], chunk XOR-swizzled by row&7
    __shared__ bf16x8 Bs[64*8];    // 8KB

    int z = blockIdx.z;
    long z1 = (long)(z >> zshift), z0 = (long)(z & zmask);
    A  += z1*aS1 + z0*aS0;
    Bt += z1*bS1 + z0*bS0;
    long coff = z1*cS1 + z0*cS0;

    const int tid  = threadIdx.x;
    const int lane = tid & 63, w = tid >> 6;
    const int wm = w >> 1, wn = w & 1;
    const int row0 = blockIdx.y * 128, col0 = blockIdx.x * 64;

    f32x4 acc[4][2];
    #pragma unroll
    for (int i = 0; i < 4; ++i)
        #pragma unroll
        for (int j = 0; j < 2; ++j) acc[i][j] = (f32x4){0.f,0.f,0.f,0.f};

    const int nkt = K >> 6;
    for (int kt = 0; kt < nkt; ++kt) {
        int k0 = kt << 6;
        int mask_sh, addr_sh;
        if (ccdil) {
            int tap = kt >> 3;
            mask_sh = (2 - tap) * ccdil;
            addr_sh = mask_sh + tap;      // compensates k0 row-aliasing (lda=512, k0 carries tap*512)
        } else {
            mask_sh = shift; addr_sh = shift;
        }
        // stage A: 1024 16B-chunks, 4 instr/wave
        #pragma unroll
        for (int j = 0; j < 4; ++j) {
            int c = ((w*4 + j) << 6) + lane;
            int row = c >> 3, chk = c & 7;
            int schk = chk ^ (row & 7);
            int grow = row0 + row;
            const bh16* src = ((grow & 255) >= mask_sh)
                ? (A + (size_t)(grow - addr_sh)*lda + k0 + schk*8) : zp;
            gload16(src, &As[(w*4 + j) * 64]);
        }
        // stage B: 512 chunks, 2 instr/wave
        #pragma unroll
        for (int j = 0; j < 2; ++j) {
            int c = ((w*2 + j) << 6) + lane;
            int row = c >> 3, chk = c & 7;
            int schk = chk ^ (row & 7);
            int gcol = col0 + row;
            const bh16* src = (gcol < N)
                ? (Bt + (size_t)gcol*ldb + k0 + schk*8) : zp;
            gload16(src, &Bs[(w*2 + j) * 64]);
        }
        asm volatile("s_waitcnt vmcnt(0)" ::: "memory");
        __syncthreads();

        bf16x8 a[4][2], b[2][2];
        #pragma unroll
        for (int fm = 0; fm < 4; ++fm) {
            int row = wm*64 + fm*16 + (lane & 15);
            #pragma unroll
            for (int ks = 0; ks < 2; ++ks)
                a[fm][ks] = As[row*8 + ((ks*4 + (lane>>4)) ^ (row & 7))];
        }
        #pragma unroll
        for (int fn = 0; fn < 2; ++fn) {
            int col = wn*32 + fn*16 + (lane & 15);
            #pragma unroll
            for (int ks = 0; ks < 2; ++ks)
                b[fn][ks] = Bs[col*8 + ((ks*4 + (lane>>4)) ^ (col & 7))];
        }
        #pragma unroll
        for (int ks = 0; ks < 2; ++ks)
            #pragma unroll
            for (int fm = 0; fm < 4; ++fm)
                #pragma unroll
                for (int fn = 0; fn < 2; ++fn)
                    acc[fm][fn] = __builtin_amdgcn_mfma_f32_16x16x32_bf16(
                        a[fm][ks], b[fn][ks], acc[fm][fn], 0, 0, 0);
        __syncthreads();
    }

    // epilogue: D[row][col], col=lane&15, row=(lane>>4)*4+r
    #pragma unroll
    for (int fm = 0; fm < 4; ++fm) {
        #pragma unroll
        for (int fn = 0; fn < 2; ++fn) {
            int gc = col0 + wn*32 + fn*16 + (lane & 15);
            float bs = bias ? bias[gc] : 0.f;
            #pragma unroll
            for (int r = 0; r < 4; ++r) {
                int gr = row0 + wm*64 + fm*16 + (lane>>4)*4 + r;
                float v = acc[fm][fn][r] + bs;
                if (act == ACT_RELU) v = fmaxf(v, 0.f);
                size_t o = (size_t)gr*ldc + gc + coff;
                if (Cf) { if (accum) Cf[o] += v; else Cf[o] = v; }
                if (Cb) Cb[o] = __float2bfloat16(v);
            }
        }
    }
}

// =====================================================================================
// Small-M (M=16) MFMA GEMM, one wave = 16x16xK tile, no LDS.
__global__ __launch_bounds__(256) void hgemm16_kernel(
    const bh16* __restrict__ A, int lda, long aZ,
    const bh16* __restrict__ Bt, int ldb,
    const float* __restrict__ bias,
    const float* __restrict__ pre,
    float* __restrict__ Of, bh16* __restrict__ Ob, long oZ,
    int N, int K, int act,
    float* __restrict__ curf, bh16* __restrict__ curb,
    const float* __restrict__ scaleptr)
{
    const int z = blockIdx.z;
    A += (long)z * aZ;
    const int lane = threadIdx.x & 63, w = threadIdx.x >> 6;
    const int col0 = blockIdx.x * 64 + w * 16;
    const int ar = lane & 15;
    const int koff = (lane >> 4) * 8;
    const bh16* arow = A + (size_t)ar * lda + koff;
    const bh16* brow = Bt + (size_t)(col0 + ar) * ldb + koff;
    f32x4 acc = {0.f, 0.f, 0.f, 0.f};
    const int nkt = K >> 5;
    for (int kt0 = 0; kt0 < nkt; kt0 += 8) {
        bf16x8 av[8], bv[8];
        #pragma unroll
        for (int j = 0; j < 8; ++j) {
            av[j] = *(const bf16x8*)(arow + (size_t)(kt0 + j) * 32);
            bv[j] = *(const bf16x8*)(brow + (size_t)(kt0 + j) * 32);
        }
        #pragma unroll
        for (int j = 0; j < 8; ++j)
            acc = __builtin_amdgcn_mfma_f32_16x16x32_bf16(av[j], bv[j], acc, 0, 0, 0);
    }
    const int col = col0 + ar;
    float bs = bias ? bias[col] : 0.f;
    float sc = scaleptr ? *scaleptr : 0.f;
    #pragma unroll
    for (int r = 0; r < 4; ++r) {
        int row = (lane >> 4) * 4 + r;
        float v = acc[r] + bs;
        if (pre) v += pre[(size_t)row * N + col];
        if (act == ACT_SILU)      v = v / (1.f + expf(-v));
        else if (act == ACT_TANH) v = tanhf(v);
        if (curf) {
            size_t o = (size_t)row * 512 + col;
            float nc = curf[o] - v * sc;
            curf[o] = nc;
            curb[o] = __float2bfloat16(nc);
        } else {
            size_t o = (size_t)z * oZ + (size_t)row * N + col;
            if (Of) Of[o] = v;
            if (Ob) Ob[o] = __float2bfloat16(v);
        }
    }
}

// ---------------- per-head squared norms from packed qkv (lda=1536) ----------------
__global__ __launch_bounds__(256) void sqnorm2_kernel(const bh16* __restrict__ qkv,
                                                      float* __restrict__ qn, float* __restrict__ kn)
{
    int lane = threadIdx.x & 63, wid = threadIdx.x >> 6;
    int row = blockIdx.x * 4 + wid;            // over B*H*T
    const bh16* src = qkv + (blockIdx.y ? 512 : 0);
    float* dst = blockIdx.y ? kn : qn;
    int t = row & 255; int bh = row >> 8; int b = bh >> 3, hh = bh & 7;
    float v = __bfloat162float(src[((size_t)b * TT + t) * 1536 + hh * 64 + lane]);
    float s = v * v;
    #pragma unroll
    for (int off = 32; off; off >>= 1) s += __shfl_xor(s, off);
    if (lane == 0) dst[row] = s;
}

// ---------------- hyperbolic distance + softmax: fp32 logits in, bf16 probs out ----------------
__global__ __launch_bounds__(256) void attn_softmax_kernel(const float* __restrict__ at, bh16* __restrict__ pb,
                                                           const float* __restrict__ qn,
                                                           const float* __restrict__ kn,
                                                           const float* __restrict__ curv)
{
    int lane = threadIdx.x & 63, wid = threadIdx.x >> 6;
    int row = blockIdx.x * 4 + wid;            // over B*H*T
    int i = row & 255; int bh = row >> 8; int hh = bh & 7;
    float c = fabsf(curv[hh]) + 1e-8f;
    float inv_sqrt_c = 1.f / sqrtf(c);
    float qni = qn[row];
    const float* srow = at + (size_t)bh * TT * TT + (size_t)i * TT;
    bh16* prow = pb + (size_t)bh * TT * TT + (size_t)i * TT;
    const float* knr = kn + (size_t)bh * TT;
    float logit[4];
    float mx = -1e30f;
    #pragma unroll
    for (int u = 0; u < 4; ++u) {
        int j = lane + u * 64;
        float s = srow[j];
        float knj = knr[j];
        float d2 = fmaxf(qni + knj - 2.f * s, 0.f);
        float denom = fmaxf((1.f - c * qni) * (1.f - c * knj), 1e-5f);
        float arg = fmaxf(1.f + (2.f * c * d2) / denom, 1.00001f);
        float dist = logf(arg + sqrtf((arg - 1.f) * (arg + 1.f))) * inv_sqrt_c;
        logit[u] = -dist;
        mx = fmaxf(mx, logit[u]);
    }
    #pragma unroll
    for (int off = 32; off; off >>= 1) mx = fmaxf(mx, __shfl_xor(mx, off));
    float e[4]; float sum = 0.f;
    #pragma unroll
    for (int u = 0; u < 4; ++u) { e[u] = expf(logit[u] - mx); sum += e[u]; }
    #pragma unroll
    for (int off = 32; off; off >>= 1) sum += __shfl_xor(sum, off);
    float inv = 1.f / sum;
    #pragma unroll
    for (int u = 0; u < 4; ++u) prow[lane + u * 64] = __float2bfloat16(e[u] * inv);
}

// ---------------- V transpose per (b,h): packed qkv (v at +1024, lda=1536) -> vt[bh][d][t] ----------------
__global__ __launch_bounds__(256) void vtrans_kernel(const bh16* __restrict__ vb, bh16* __restrict__ vt)
{
    int bh = blockIdx.y, b = bh >> 3, hh = bh & 7;
    int t0 = blockIdx.x * 64;
    __shared__ bh16 tile[64][65];
    for (int e = threadIdx.x; e < 4096; e += 256) {
        int r = e >> 6, c = e & 63;
        tile[r][c] = vb[((size_t)(b*256 + t0 + r))*1536 + hh*64 + c];
    }
    __syncthreads();
    for (int e = threadIdx.x; e < 4096; e += 256) {
        int d = e >> 6, t2 = e & 63;
        vt[((size_t)bh*64 + d)*256 + t0 + t2] = tile[t2][d];
    }
}

// ---------------- wavelet filter softmax ----------------
__global__ __launch_bounds__(256) void filt_softmax_kernel(const float* __restrict__ w0, const float* __restrict__ w1,
                                                           const float* __restrict__ w2, const float* __restrict__ w3,
                                                           float* __restrict__ filt)
{
    int idx = blockIdx.x * 256 + threadIdx.x;
    if (idx >= 4 * DD) return;
    int d = idx & 511, i = idx >> 9;
    const float* w = (i == 0) ? w0 : (i == 1) ? w1 : (i == 2) ? w2 : w3;
    int K = 4 << i;
    int fb = (i == 0) ? 0 : (i == 1) ? 2048 : (i == 2) ? 6144 : 14336;
    const float* row = w + (size_t)d * K;
    float mx = -1e30f;
    for (int k = 0; k < K; ++k) mx = fmaxf(mx, row[k]);
    float s = 0.f;
    for (int k = 0; k < K; ++k) s += expf(row[k] - mx);
    float inv = 1.f / s;
    float* fo = filt + fb + (size_t)d * K;
    for (int k = 0; k < K; ++k) fo[k] = expf(row[k] - mx) * inv;
}

// ---------------- fused wavelet: dec (LDS) + linear interp -> comb bf16 ----------------
// grid: (dblk 0..3, scale 0..3, b 0..15), 256 threads.
__global__ __launch_bounds__(256) void wave_kernel(const float* __restrict__ h,
                                                   const float* __restrict__ filt,
                                                   bh16* __restrict__ comb)
{
    __shared__ float dtile[128*128];   // [j][d0], 64KB (Ti<=128)
    __shared__ float flds[32*128];     // [k][d0] transposed, 16KB (K<=32)
    const int dblk = blockIdx.x;
    const int i    = blockIdx.y;
    const int b    = blockIdx.z;
    const int K = 4 << i, stride = 2 << i, Ti = 128 >> i;
    const int fbarr[4] = {0, 2048, 6144, 14336};
    const int fb = fbarr[i];
    const int tid = threadIdx.x;
    // preload filter transposed (conflict-free reads in phase 1)
    for (int e = tid; e < K * 128; e += 256) {
        int k = e >> 7, d0 = e & 127;
        flds[k * 128 + d0] = filt[fb + (size_t)(dblk * 128 + d0) * K + k];
    }
    __syncthreads();
    // phase 1: decimated causal depthwise conv into LDS
    for (int e = tid; e < Ti * 128; e += 256) {
        int j = e >> 7, d0 = e & 127;
        int d = dblk * 128 + d0;
        int tbase = j * stride - (K - 1);
        float acc = 0.f;
        for (int k = 0; k < K; ++k) {
            int t = tbase + k;
            if (t >= 0) acc += h[((size_t)b * TT + t) * DD + d] * flds[k * 128 + d0];
        }
        dtile[j * 128 + d0] = acc;
    }
    __syncthreads();
    // phase 2: linear interp Ti -> 256, write comb[b][t][i*512 + d]
    float scale = (float)Ti * (1.f / 256.f);
    for (int e = tid; e < 256 * 128; e += 256) {
        int t = e >> 7, d0 = e & 127;
        float pos = ((float)t + 0.5f) * scale - 0.5f;
        pos = fminf(fmaxf(pos, 0.f), (float)(Ti - 1));
        int lo = (int)floorf(pos);
        int hi = min(lo + 1, Ti - 1);
        float w = pos - (float)lo;
        float v = dtile[lo * 128 + d0] * (1.f - w) + dtile[hi * 128 + d0] * w;
        comb[((size_t)b * TT + t) * 2048 + i * 512 + dblk * 128 + d0] = __float2bfloat16(v);
    }
}

// ---------------- boundary loss: 32 blocks, one atomic per block ----------------
__global__ __launch_bounds__(256) void bd_loss_kernel(const float* __restrict__ tfb, const float* __restrict__ bdw,
                                                      const float* __restrict__ bdb, float* __restrict__ loss)
{
    __shared__ float wsum[4];
    int lane = threadIdx.x & 63, wid = threadIdx.x >> 6;
    float w = bdw[lane * 2] - bdw[lane * 2 + 1];
    float bconst = (bdb[0] - bdb[1]) + 0.1f;
    float acc = 0.f;
    for (int row = blockIdx.x * 4 + wid; row < BT; row += 128) {
        float vv = tfb[(size_t)row * PP + lane] * w;
        #pragma unroll
        for (int off = 32; off; off >>= 1) vv += __shfl_xor(vv, off);
        if (lane == 0) acc += fmaxf(vv + bconst, 0.f);
    }
    if (lane == 0) wsum[wid] = acc;
    __syncthreads();
    if (threadIdx.x == 0) {
        atomicAdd(loss, (wsum[0] + wsum[1] + wsum[2] + wsum[3]) * (1.f / 4096.f));
    }
}

// ---------------- h = layernorm(s + h)*g + b, dual fp32+bf16 out ----------------
__global__ __launch_bounds__(256) void add_ln_kernel(const float* __restrict__ s, float* __restrict__ h,
                                                     bh16* __restrict__ hb,
                                                     const float* __restrict__ g, const float* __restrict__ be)
{
    int lane = threadIdx.x & 63, wid = threadIdx.x >> 6;
    size_t row = (size_t)blockIdx.x * 4 + wid;
    const float* sr = s + row * DD;
    float* hr = h + row * DD;
    bh16* hbr = hb + row * DD;
    float xv[8]; float sum = 0.f;
    #pragma unroll
    for (int u = 0; u < 8; ++u) { int c = lane + u * 64; xv[u] = sr[c] + hr[c]; sum += xv[u]; }
    #pragma unroll
    for (int off = 32; off; off >>= 1) sum += __shfl_xor(sum, off);
    float mu = sum * (1.f / 512.f);
    float sq = 0.f;
    #pragma unroll
    for (int u = 0; u < 8; ++u) { float d = xv[u] - mu; sq += d * d; }
    #pragma unroll
    for (int off = 32; off; off >>= 1) sq += __shfl_xor(sq, off);
    float rstd = 1.f / sqrtf(sq * (1.f / 512.f) + 1e-5f);
    #pragma unroll
    for (int u = 0; u < 8; ++u) {
        int c = lane + u * 64;
        float v = (xv[u] - mu) * rstd * g[c] + be[c];
        hr[c] = v;
        hbr[c] = __float2bfloat16(v);
    }
}

// ---------------- weight transpose-convert: [l-sel][K][N] f32 -> out + l*lstride, [N][K] bf16 ----------------
__global__ __launch_bounds__(256) void wtrans_kernel(const float* __restrict__ W, bh16* __restrict__ Wt,
                                                     int K, int N, long lstride)
{
    int l = blockIdx.z;
    const float* Wl = W + (size_t)l * K * N;
    bh16* Wo = Wt + (size_t)l * lstride;
    __shared__ float tile[32][33];
    int n0 = blockIdx.x * 32, k0 = blockIdx.y * 32;
    int lx = threadIdx.x & 31, ly = threadIdx.x >> 5;
    #pragma unroll
    for (int j = 0; j < 4; ++j) {
        int kk = ly + j * 8;
        tile[kk][lx] = Wl[(size_t)(k0 + kk) * N + n0 + lx];
    }
    __syncthreads();
    #pragma unroll
    for (int j = 0; j < 4; ++j) {
        int nr = ly + j * 8;
        Wo[(size_t)(n0 + nr) * K + k0 + lx] = __float2bfloat16(tile[lx][nr]);
    }
}

// ---------------- cc_w [L][O][I][3] f32 -> ccT [L][O][tap*512+I] bf16 (tap-major K for fused conv GEMM) ----------------
__global__ __launch_bounds__(256) void ccconv_kernel(const float* __restrict__ ccw, bh16* __restrict__ ccT)
{
    size_t idx = (size_t)blockIdx.x * 256 + threadIdx.x;   // 6*512*1536
    int i = idx & 511; size_t rem = idx >> 9;
    int tap = (int)(rem % 3); rem /= 3;
    int o = (int)(rem & 511); int l = (int)(rem >> 9);
    ccT[idx] = __float2bfloat16(ccw[(((size_t)l*512 + o)*512 + i)*3 + tap]);
}

// ---------------- qkv bias concat: [L][1536] ----------------
__global__ __launch_bounds__(256) void qkvbias_kernel(const float* __restrict__ qb_, const float* __restrict__ kb_,
                                                      const float* __restrict__ vb_, float* __restrict__ ob)
{
    int idx = blockIdx.x * 256 + threadIdx.x;   // 6*1536
    if (idx >= 6 * 1536) return;
    int l = idx / 1536, n = idx % 1536;
    float v = (n < 512) ? qb_[l*512 + n] : (n < 1024) ? kb_[l*512 + n - 512] : vb_[l*512 + n - 1024];
    ob[idx] = v;
}

// ---------------- x f32 -> bf16 ----------------
__global__ __launch_bounds__(256) void convx_kernel(const float* __restrict__ x, bh16* __restrict__ xb)
{
    size_t idx = (size_t)blockIdx.x * 256 + threadIdx.x;
    xb[idx] = __float2bfloat16(x[idx]);
}

// ---------------- E matrix: row (t,b) = [sched[t]*noise[t,b,:] | temb[t]] (bf16, 160x1024) ----------------
__global__ __launch_bounds__(256) void build_E_kernel(const float* __restrict__ noise, const float* __restrict__ sched,
                                                      bh16* __restrict__ E)
{
    int idx = blockIdx.x * 256 + threadIdx.x;   // 10*16*1024
    if (idx >= SS * BB * 1024) return;
    int k = idx & 1023; int rem = idx >> 10; int b = rem & 15; int t = rem >> 4;
    float v;
    if (k < 512) {
        v = sched[t] * noise[((size_t)t * BB + b) * 512 + k];
    } else {
        int j = k - 512;
        const float kfac = -9.210340371976184f / 255.f;   // -ln(10000)/255
        v = (j < 256) ? sinf((float)t * expf((float)j * kfac))
                      : cosf((float)t * expf((float)(j - 256) * kfac));
    }
    E[idx] = __float2bfloat16(v);
}

// ---------------- head helpers ----------------
__global__ void init_kernel(bh16* zp, float* loss)
{
    int t = threadIdx.x;
    if (t < 64) zp[t] = __float2bfloat16(0.f);
    if (t == 64) *loss = 0.f;
}

__global__ __launch_bounds__(256) void build_cat16_kernel(const float* __restrict__ h, bh16* __restrict__ catb)
{
    int idx = blockIdx.x * 256 + threadIdx.x;   // 16*1024
    if (idx >= BB * 1024) return;
    int k = idx & 1023, b = idx >> 10;
    float v = (k < 512) ? h[((size_t)b * TT + 255) * DD + k]
                        : h[((size_t)b * TT + 254) * DD + (k - 512)];
    catb[idx] = __float2bfloat16(v);
}

__global__ __launch_bounds__(256) void cur_init2_kernel(const float* __restrict__ h, const float* __restrict__ mix,
                                                        float* __restrict__ curf, bh16* __restrict__ curb)
{
    int idx = blockIdx.x * 256 + threadIdx.x;   // 16*512
    if (idx >= BB * DD) return;
    int c = idx & 511, b = idx >> 9;
    float v = h[((size_t)b * TT + 255) * DD + c] + mix[idx];
    curf[idx] = v;
    curb[idx] = __float2bfloat16(v);
}

__global__ void fail_kernel(float* p) { p[0] = 1e30f; }

// =====================================================================================
extern "C" void kernel_launch(void* const* d_in, const int* in_sizes, int n_in,
                              void* d_out, int out_size, void* d_ws, size_t ws_size,
                              hipStream_t stream)
{
    const float* x      = (const float*)d_in[0];
    const float* in_w   = (const float*)d_in[1];
    const float* in_b   = (const float*)d_in[2];
    const float* gq_w   = (const float*)d_in[3];
    const float* gq_b   = (const float*)d_in[4];
    const float* gk_w   = (const float*)d_in[5];
    const float* gk_b   = (const float*)d_in[6];
    const float* gv_w   = (const float*)d_in[7];
    const float* gv_b   = (const float*)d_in[8];
    const float* go_w   = (const float*)d_in[9];
    const float* go_b   = (const float*)d_in[10];
    const float* curv   = (const float*)d_in[11];
    const float* wav0   = (const float*)d_in[12];
    const float* wav1   = (const float*)d_in[13];
    const float* wav2   = (const float*)d_in[14];
    const float* wav3   = (const float*)d_in[15];
    const float* wrec_w = (const float*)d_in[16];
    const float* wrec_b = (const float*)d_in[17];
    const float* te1_w  = (const float*)d_in[18];
    const float* te1_b  = (const float*)d_in[19];
    const float* te2_w  = (const float*)d_in[20];
    const float* te2_b  = (const float*)d_in[21];
    const float* td1_w  = (const float*)d_in[22];
    const float* td1_b  = (const float*)d_in[23];
    const float* td2_w  = (const float*)d_in[24];
    const float* td2_b  = (const float*)d_in[25];
    const float* bd_w   = (const float*)d_in[26];
    const float* bd_b   = (const float*)d_in[27];
    const float* cc_w   = (const float*)d_in[28];
    const float* cc_b   = (const float*)d_in[29];
    const float* ln_g   = (const float*)d_in[30];
    const float* ln_b   = (const float*)d_in[31];
    const float* mm1_w  = (const float*)d_in[32];
    const float* mm1_b  = (const float*)d_in[33];
    const float* mm2_w  = (const float*)d_in[34];
    const float* mm2_b  = (const float*)d_in[35];
    const float* dn1_w  = (const float*)d_in[36];
    const float* dn1_b  = (const float*)d_in[37];
    const float* dn2_w  = (const float*)d_in[38];
    const float* dn2_b  = (const float*)d_in[39];
    const float* dn3_w  = (const float*)d_in[40];
    const float* dn3_b  = (const float*)d_in[41];
    const float* out_w  = (const float*)d_in[42];
    const float* out_b  = (const float*)d_in[43];
    const float* nsched = (const float*)d_in[44];
    const float* noise  = (const float*)d_in[45];
    float* out = (float*)d_out;
    float* ws  = (float*)d_ws;

    // ---- fp32 workspace layout (float offsets) ----
    const size_t o_h   = 0;          // 2097152
    const size_t o_dec = 2097152;    // 2097152 (pre1 for head: 81920)
    const size_t o_s   = 4194304;    // 2097152
    const size_t o_tf  = 6291456;    // 262144
    const size_t o_qn  = 6553600;    // 32768
    const size_t o_kn  = 6586368;    // 32768
    const size_t o_at  = 6619136;    // 8388608
    const size_t o_fl  = 15007744;   // 30720
    const size_t o_mix = 15038464;   // 8192
    const size_t o_cur = 15046656;   // 8192
    const size_t o_qkb = 15054848;   // 9216 (qkv bias [6][1536])
    const size_t FP32_TOTAL = 15095808;
    // ---- bf16 region (element offsets from bp) ----
    const size_t b_xb   = 0;          // 1572864
    const size_t b_hb   = 1572864;    // 2097152
    const size_t b_qkv  = 3670016;    // 6291456: packed qkv [4096][1536]
    const size_t b_vt   = 9961472;    // 2097152
    const size_t b_pb   = 12058624;   // 8388608 (head scratch aliases here after layers)
    const size_t b_gmb  = 20447232;   // 2097152
    const size_t b_tdb  = 22544384;   // 2097152
    const size_t b_t1b  = 24641536;   // 262144
    const size_t b_tfb  = 24903680;   // 262144
    const size_t b_zp   = 25165824;   // 512
    const size_t b_inwT = 25166336;   // 196608
    const size_t b_qkvT = 25362944;   // 4718592: [6][1536][512]
    const size_t b_goT  = 30081536;   // 1572864
    const size_t b_wrT  = 31654400;   // 6291456
    const size_t b_td1T = 37945856;   // 196608
    const size_t b_td2T = 38142464;   // 1572864
    const size_t b_te1T = 39715328;   // 196608
    const size_t b_te2T = 39911936;   // 24576
    const size_t b_ccT  = 39936512;   // 4718592: [6][512][1536]
    const size_t BF16_TOTAL = 44655104;
    const size_t TOTAL_BYTES = FP32_TOTAL * 4 + BF16_TOTAL * 2;
    if (ws_size < TOTAL_BYTES) { fail_kernel<<<1, 1, 0, stream>>>(out); return; }

    float* h_   = ws + o_h;
    float* dec_ = ws + o_dec;
    float* s_   = ws + o_s;
    float* tf_  = ws + o_tf;
    float* qn_  = ws + o_qn;
    float* kn_  = ws + o_kn;
    float* at_  = ws + o_at;
    float* fl_  = ws + o_fl;
    float* mixb = ws + o_mix;
    float* curf = ws + o_cur;
    float* qkvbias = ws + o_qkb;
    bh16* bp   = (bh16*)(ws + FP32_TOTAL);
    bh16* xb   = bp + b_xb;
    bh16* hb   = bp + b_hb;
    bh16* qkvb = bp + b_qkv;
    bh16* vt   = bp + b_vt;
    bh16* pb   = bp + b_pb;
    bh16* gmb  = bp + b_gmb;
    bh16* tdb  = bp + b_tdb;
    bh16* t1b  = bp + b_t1b;
    bh16* tfb  = bp + b_tfb;
    bh16* zp   = bp + b_zp;
    bh16* inwT = bp + b_inwT;
    bh16* qkvT = bp + b_qkvT;
    bh16* goT  = bp + b_goT;
    bh16* wrT  = bp + b_wrT;
    bh16* td1T = bp + b_td1T;
    bh16* td2T = bp + b_td2T;
    bh16* te1T = bp + b_te1T;
    bh16* te2T = bp + b_te2T;
    bh16* ccT  = bp + b_ccT;
    bh16* combb = (bh16*)at_;   // aliases at_ after softmax consumed it

    // head bf16 scratch: aliased into pb region (dead after layer loop)
    bh16* dn1T  = pb;             // 524288
    bh16* dn2T  = pb + 524288;    // 262144
    bh16* dn3T  = pb + 786432;    // 262144
    bh16* mm1T  = pb + 1048576;   // 524288
    bh16* mm2T  = pb + 1572864;   // 262144
    bh16* outT  = pb + 1835008;   // 196608
    bh16* E16   = pb + 2031616;   // 163840
    bh16* cat16 = pb + 2195456;   // 16384
    bh16* tmb16 = pb + 2211840;   // 8192
    bh16* cur16 = pb + 2220032;   // 8192
    bh16* d1b16 = pb + 2228224;   // 8192
    bh16* d2b16 = pb + 2236416;   // 8192
    float* pre1 = dec_;           // 81920 f32, aliases dec_ after layers

    auto mg = [&](const bh16* A, int lda, const bh16* Bt, int ldb,
                  const float* bias, float* Cf, bh16* Cb, int ldc,
                  int M, int N, int K, int shift, int accum, int act,
                  int nb, int zmask, int zshift,
                  long aS1, long aS0, long bS1, long bS0, long cS1, long cS0, int ccdil) {
        dim3 g(N / 64, M / 128, nb);
        mgemm_kernel<<<g, 256, 0, stream>>>(A, lda, Bt, ldb, bias, Cf, Cb, ldc, N, K,
                                            shift, accum, act, zmask, zshift,
                                            aS1, aS0, bS1, bS0, cS1, cS0, ccdil, zp);
    };
    auto mgp = [&](const bh16* A, int lda, const bh16* Bt, int ldb,
                   const float* bias, float* Cf, bh16* Cb, int ldc,
                   int M, int N, int K, int shift, int accum, int act) {
        mg(A, lda, Bt, ldb, bias, Cf, Cb, ldc, M, N, K, shift, accum, act, 1, 0, 0, 0, 0, 0, 0, 0, 0, 0);
    };
    auto hg = [&](const bh16* A, int lda, long aZ, const bh16* Bt, int ldb,
                  const float* bias, const float* pre, float* Of, bh16* Ob, long oZ,
                  int N, int K, int act, float* cf, bh16* cb, const float* sp, int nz) {
        hgemm16_kernel<<<dim3(N / 64, 1, nz), 256, 0, stream>>>(
            A, lda, aZ, Bt, ldb, bias, pre, Of, Ob, oZ, N, K, act, cf, cb, sp);
    };

    // ---- setup: zero page/loss, converts ----
    init_kernel<<<1, 128, 0, stream>>>(zp, out + BB * DIN);
    convx_kernel<<<BT * DIN / 256, 256, 0, stream>>>(x, xb);
    wtrans_kernel<<<dim3(DD/32, DIN/32, 1), 256, 0, stream>>>(in_w, inwT, DIN, DD, (long)DIN*DD);
    // packed qkvT: rows 0-511 q, 512-1023 k, 1024-1535 v; l-stride 786432
    wtrans_kernel<<<dim3(16, 16, 6), 256, 0, stream>>>(gq_w, qkvT,          DD, DD, 786432L);
    wtrans_kernel<<<dim3(16, 16, 6), 256, 0, stream>>>(gk_w, qkvT + 262144, DD, DD, 786432L);
    wtrans_kernel<<<dim3(16, 16, 6), 256, 0, stream>>>(gv_w, qkvT + 524288, DD, DD, 786432L);
    qkvbias_kernel<<<36, 256, 0, stream>>>(gq_b, gk_b, gv_b, qkvbias);
    wtrans_kernel<<<dim3(16, 16, 6), 256, 0, stream>>>(go_w, goT, DD, DD, (long)DD*DD);
    wtrans_kernel<<<dim3(16, 64, 6), 256, 0, stream>>>(wrec_w, wrT, 2048, DD, 2048L*DD);
    wtrans_kernel<<<dim3(16, 2, 6), 256, 0, stream>>>(td1_w, td1T, PP, DD, (long)PP*DD);
    wtrans_kernel<<<dim3(16, 16, 6), 256, 0, stream>>>(td2_w, td2T, DD, DD, (long)DD*DD);
    wtrans_kernel<<<dim3(2, 16, 6), 256, 0, stream>>>(te1_w, te1T, DD, PP, (long)DD*PP);
    wtrans_kernel<<<dim3(2, 2, 6), 256, 0, stream>>>(te2_w, te2T, PP, PP, (long)PP*PP);
    ccconv_kernel<<<18432, 256, 0, stream>>>(cc_w, ccT);

    // h = x @ in_w + in_b  (fp32 + bf16)
    mgp(xb, DIN, inwT, DIN, in_b, h_, hb, DD, BT, DD, DIN, 0, 0, ACT_NONE);

    for (int l = 0; l < LL; ++l) {
        // fused q|k|v projection: N=1536, packed output [BT][1536]
        mgp(hb, DD, qkvT + (size_t)l*786432, DD, qkvbias + (size_t)l*1536,
            nullptr, qkvb, 1536, BT, 1536, DD, 0, 0, ACT_NONE);
        // attention
        sqnorm2_kernel<<<dim3(8192, 2), 256, 0, stream>>>(qkvb, qn_, kn_);
        mg(qkvb, 1536, qkvb + 512, 1536, nullptr, at_, nullptr, TT, TT, TT, 64, 0, 0, ACT_NONE,
           128, 7, 3, 393216, 64, 393216, 64, 524288, 65536, 0);
        attn_softmax_kernel<<<8192, 256, 0, stream>>>(at_, pb, qn_, kn_, curv + (size_t)l*HH);
        vtrans_kernel<<<dim3(4, 128), 256, 0, stream>>>(qkvb + 1024, vt);
        mg(pb, TT, vt, TT, nullptr, nullptr, gmb, DD, TT, 64, TT, 0, 0, ACT_NONE,
           128, 7, 3, 524288, 65536, 131072, 16384, 131072, 64, 0);
        mgp(gmb, DD, goT + (size_t)l*262144, DD, go_b + (size_t)l*DD, s_, nullptr, DD, BT, DD, DD, 0, 0, ACT_NONE);
        // wavelet branch (fused dec+interp; comb aliases at_ which softmax already consumed)
        filt_softmax_kernel<<<8, 256, 0, stream>>>(wav0 + (size_t)l*DD*4, wav1 + (size_t)l*DD*8,
                                                   wav2 + (size_t)l*DD*16, wav3 + (size_t)l*DD*32, fl_);
        wave_kernel<<<dim3(4, 4, 16), 256, 0, stream>>>(h_, fl_, combb);
        mgp(combb, 2048, wrT + (size_t)l*1048576, 2048, wrec_b + (size_t)l*DD, s_, nullptr, DD, BT, DD, 2048, 0, 1, ACT_NONE);
        // topo branch
        mgp(hb, DD, te1T + (size_t)l*32768, DD, te1_b + (size_t)l*PP, nullptr, t1b, PP, BT, PP, DD, 0, 0, ACT_RELU);
        mgp(t1b, PP, te2T + (size_t)l*4096, PP, te2_b + (size_t)l*PP, tf_, tfb, PP, BT, PP, PP, 0, 0, ACT_NONE);
        bd_loss_kernel<<<32, 256, 0, stream>>>(tf_, bd_w + (size_t)l*PP*2, bd_b + (size_t)l*2, out + BB*DIN);
        mgp(tfb, PP, td1T + (size_t)l*32768, PP, td1_b + (size_t)l*DD, nullptr, tdb, DD, BT, DD, PP, 0, 0, ACT_RELU);
        mgp(tdb, DD, td2T + (size_t)l*262144, DD, td2_b + (size_t)l*DD, s_, nullptr, DD, BT, DD, DD, 0, 1, ACT_NONE);
        // fused causal dilated conv: single K=1536 GEMM, per-K-tile shift schedule
        int dil = 1 << l;
        mg(hb, DD, ccT + (size_t)l*786432, 1536, cc_b + (size_t)l*DD,
           s_, nullptr, DD, BT, DD, 1536, 0, 1, ACT_NONE, 1, 0, 0, 0, 0, 0, 0, 0, 0, dil);
        // h = LN(s + h)
        add_ln_kernel<<<BT/4, 256, 0, stream>>>(s_, h_, hb, ln_g, ln_b);
    }

    // ---- head: convert weights (into dead pb region), precompute E/pre1 ----
    wtrans_kernel<<<dim3(16, 32, 1), 256, 0, stream>>>(dn1_w, dn1T, 1024, 512, 0L);
    wtrans_kernel<<<dim3(16, 16, 1), 256, 0, stream>>>(dn2_w, dn2T, 512, 512, 0L);
    wtrans_kernel<<<dim3(16, 16, 1), 256, 0, stream>>>(dn3_w, dn3T, 512, 512, 0L);
    wtrans_kernel<<<dim3(16, 32, 1), 256, 0, stream>>>(mm1_w, mm1T, 1024, 512, 0L);
    wtrans_kernel<<<dim3(16, 16, 1), 256, 0, stream>>>(mm2_w, mm2T, 512, 512, 0L);
    wtrans_kernel<<<dim3(12, 16, 1), 256, 0, stream>>>(out_w, outT, 512, 384, 0L);
    build_E_kernel<<<640, 256, 0, stream>>>(noise, nsched, E16);
    // pre1[t] = E_t @ dn1_w + dn1_b   (z-batched over t)
    hg(E16, 1024, 16*1024, dn1T, 1024, dn1_b, nullptr, pre1, nullptr, 8192,
       512, 1024, ACT_NONE, nullptr, nullptr, nullptr, SS);
    // mix head
    build_cat16_kernel<<<64, 256, 0, stream>>>(h_, cat16);
    hg(cat16, 1024, 0, mm1T, 1024, mm1_b, nullptr, nullptr, tmb16, 0,
       512, 1024, ACT_TANH, nullptr, nullptr, nullptr, 1);
    hg(tmb16, 512, 0, mm2T, 512, mm2_b, nullptr, mixb, nullptr, 0,
       512, 512, ACT_NONE, nullptr, nullptr, nullptr, 1);
    cur_init2_kernel<<<32, 256, 0, stream>>>(h_, mixb, curf, cur16);
    // diffusion chain: 3 launches per step
    for (int t = 0; t < SS; ++t) {
        hg(cur16, 512, 0, dn1T, 1024, nullptr, pre1 + (size_t)t*8192, nullptr, d1b16, 0,
           512, 512, ACT_SILU, nullptr, nullptr, nullptr, 1);
        hg(d1b16, 512, 0, dn2T, 512, dn2_b, nullptr, nullptr, d2b16, 0,
           512, 512, ACT_SILU, nullptr, nullptr, nullptr, 1);
        hg(d2b16, 512, 0, dn3T, 512, dn3_b, nullptr, nullptr, nullptr, 0,
           512, 512, ACT_NONE, curf, cur16, nsched + t, 1);
    }
    // pred = cur @ out_w + out_b
    hg(cur16, 512, 0, outT, 512, out_b, nullptr, out, nullptr, 0,
       384, 512, ACT_NONE, nullptr, nullptr, nullptr, 1);
}

// Round 7
// 2154.260 us; speedup vs baseline: 1.0205x; 1.0205x over previous
//
#include <hip/hip_runtime.h>
#include <hip/hip_bf16.h>
#include <math.h>

#define BB 16
#define TT 256
#define DIN 384
#define DD 512
#define LL 6
#define HH 8
#define PP 64
#define SS 10
#define BT (BB*TT)   // 4096

enum { ACT_NONE=0, ACT_RELU=1, ACT_TANH=2, ACT_SILU=3 };

typedef __attribute__((ext_vector_type(8))) short bf16x8;
typedef __attribute__((ext_vector_type(4))) float f32x4;
typedef __hip_bfloat16 bh16;

typedef const __attribute__((address_space(1))) void gvoid_t;
typedef __attribute__((address_space(3))) void lvoid_t;
__device__ __forceinline__ void gload16(const void* g, void* l) {
    __builtin_amdgcn_global_load_lds((gvoid_t*)g, (lvoid_t*)l, 16, 0, 0);
}

__device__ __forceinline__ float b2f(unsigned short u) {
    return __uint_as_float(((unsigned int)u) << 16);
}

// =====================================================================================
// Generic bf16 MFMA GEMM: C = act(A @ Bt^T + bias)  (Bt stored [N][K])
// BM=128, BN=64, BK=64; 4 waves 2x2, wave tile 64x32 (4x2 frags of 16x16).
// Optional batch dim z; shift row-masking; ccdil fused 3-tap causal conv (see r5 notes).
__global__ __launch_bounds__(256) void mgemm_kernel(
    const bh16* __restrict__ A, int lda,
    const bh16* __restrict__ Bt, int ldb,
    const float* __restrict__ bias,
    float* __restrict__ Cf, bh16* __restrict__ Cb, int ldc,
    int N, int K, int shift, int accum, int act,
    int zmask, int zshift,
    long aS1, long aS0, long bS1, long bS0, long cS1, long cS0,
    int ccdil,
    const bh16* __restrict__ zp)
{
    __shared__ bf16x8 As[128*8];   // 16KB: [row][8 chunks], chunk XOR-swizzled by row&7
    __shared__ bf16x8 Bs[64*8];    // 8KB

    int z = blockIdx.z;
    long z1 = (long)(z >> zshift), z0 = (long)(z & zmask);
    A  += z1*aS1 + z0*aS0;
    Bt += z1*bS1 + z0*bS0;
    long coff = z1*cS1 + z0*cS0;

    const int tid  = threadIdx.x;
    const int lane = tid & 63, w = tid >> 6;
    const int wm = w >> 1, wn = w & 1;
    const int row0 = blockIdx.y * 128, col0 = blockIdx.x * 64;

    f32x4 acc[4][2];
    #pragma unroll
    for (int i = 0; i < 4; ++i)
        #pragma unroll
        for (int j = 0; j < 2; ++j) acc[i][j] = (f32x4){0.f,0.f,0.f,0.f};

    const int nkt = K >> 6;
    for (int kt = 0; kt < nkt; ++kt) {
        int k0 = kt << 6;
        int mask_sh, addr_sh;
        if (ccdil) {
            int tap = kt >> 3;
            mask_sh = (2 - tap) * ccdil;
            addr_sh = mask_sh + tap;      // compensates k0 row-aliasing (lda=512, k0 carries tap*512)
        } else {
            mask_sh = shift; addr_sh = shift;
        }
        // stage A: 1024 16B-chunks, 4 instr/wave
        #pragma unroll
        for (int j = 0; j < 4; ++j) {
            int c = ((w*4 + j) << 6) + lane;
            int row = c >> 3, chk = c & 7;
            int schk = chk ^ (row & 7);
            int grow = row0 + row;
            const bh16* src = ((grow & 255) >= mask_sh)
                ? (A + (size_t)(grow - addr_sh)*lda + k0 + schk*8) : zp;
            gload16(src, &As[(w*4 + j) * 64]);
        }
        // stage B: 512 chunks, 2 instr/wave
        #pragma unroll
        for (int j = 0; j < 2; ++j) {
            int c = ((w*2 + j) << 6) + lane;
            int row = c >> 3, chk = c & 7;
            int schk = chk ^ (row & 7);
            int gcol = col0 + row;
            const bh16* src = (gcol < N)
                ? (Bt + (size_t)gcol*ldb + k0 + schk*8) : zp;
            gload16(src, &Bs[(w*2 + j) * 64]);
        }
        asm volatile("s_waitcnt vmcnt(0)" ::: "memory");
        __syncthreads();

        bf16x8 a[4][2], b[2][2];
        #pragma unroll
        for (int fm = 0; fm < 4; ++fm) {
            int row = wm*64 + fm*16 + (lane & 15);
            #pragma unroll
            for (int ks = 0; ks < 2; ++ks)
                a[fm][ks] = As[row*8 + ((ks*4 + (lane>>4)) ^ (row & 7))];
        }
        #pragma unroll
        for (int fn = 0; fn < 2; ++fn) {
            int col = wn*32 + fn*16 + (lane & 15);
            #pragma unroll
            for (int ks = 0; ks < 2; ++ks)
                b[fn][ks] = Bs[col*8 + ((ks*4 + (lane>>4)) ^ (col & 7))];
        }
        #pragma unroll
        for (int ks = 0; ks < 2; ++ks)
            #pragma unroll
            for (int fm = 0; fm < 4; ++fm)
                #pragma unroll
                for (int fn = 0; fn < 2; ++fn)
                    acc[fm][fn] = __builtin_amdgcn_mfma_f32_16x16x32_bf16(
                        a[fm][ks], b[fn][ks], acc[fm][fn], 0, 0, 0);
        __syncthreads();
    }

    // epilogue: D[row][col], col=lane&15, row=(lane>>4)*4+r
    #pragma unroll
    for (int fm = 0; fm < 4; ++fm) {
        #pragma unroll
        for (int fn = 0; fn < 2; ++fn) {
            int gc = col0 + wn*32 + fn*16 + (lane & 15);
            float bs = bias ? bias[gc] : 0.f;
            #pragma unroll
            for (int r = 0; r < 4; ++r) {
                int gr = row0 + wm*64 + fm*16 + (lane>>4)*4 + r;
                float v = acc[fm][fn][r] + bs;
                if (act == ACT_RELU) v = fmaxf(v, 0.f);
                size_t o = (size_t)gr*ldc + gc + coff;
                if (Cf) { if (accum) Cf[o] += v; else Cf[o] = v; }
                if (Cb) Cb[o] = __float2bfloat16(v);
            }
        }
    }
}

// =====================================================================================
// Small-M (M=16) MFMA GEMM, one wave = 16x16xK tile, no LDS.
__global__ __launch_bounds__(256) void hgemm16_kernel(
    const bh16* __restrict__ A, int lda, long aZ,
    const bh16* __restrict__ Bt, int ldb,
    const float* __restrict__ bias,
    const float* __restrict__ pre,
    float* __restrict__ Of, bh16* __restrict__ Ob, long oZ,
    int N, int K, int act,
    float* __restrict__ curf, bh16* __restrict__ curb,
    const float* __restrict__ scaleptr)
{
    const int z = blockIdx.z;
    A += (long)z * aZ;
    const int lane = threadIdx.x & 63, w = threadIdx.x >> 6;
    const int col0 = blockIdx.x * 64 + w * 16;
    const int ar = lane & 15;
    const int koff = (lane >> 4) * 8;
    const bh16* arow = A + (size_t)ar * lda + koff;
    const bh16* brow = Bt + (size_t)(col0 + ar) * ldb + koff;
    f32x4 acc = {0.f, 0.f, 0.f, 0.f};
    const int nkt = K >> 5;
    for (int kt0 = 0; kt0 < nkt; kt0 += 8) {
        bf16x8 av[8], bv[8];
        #pragma unroll
        for (int j = 0; j < 8; ++j) {
            av[j] = *(const bf16x8*)(arow + (size_t)(kt0 + j) * 32);
            bv[j] = *(const bf16x8*)(brow + (size_t)(kt0 + j) * 32);
        }
        #pragma unroll
        for (int j = 0; j < 8; ++j)
            acc = __builtin_amdgcn_mfma_f32_16x16x32_bf16(av[j], bv[j], acc, 0, 0, 0);
    }
    const int col = col0 + ar;
    float bs = bias ? bias[col] : 0.f;
    float sc = scaleptr ? *scaleptr : 0.f;
    #pragma unroll
    for (int r = 0; r < 4; ++r) {
        int row = (lane >> 4) * 4 + r;
        float v = acc[r] + bs;
        if (pre) v += pre[(size_t)row * N + col];
        if (act == ACT_SILU)      v = v / (1.f + expf(-v));
        else if (act == ACT_TANH) v = tanhf(v);
        if (curf) {
            size_t o = (size_t)row * 512 + col;
            float nc = curf[o] - v * sc;
            curf[o] = nc;
            curb[o] = __float2bfloat16(nc);
        } else {
            size_t o = (size_t)z * oZ + (size_t)row * N + col;
            if (Of) Of[o] = v;
            if (Ob) Ob[o] = __float2bfloat16(v);
        }
    }
}

// ---------------- per-head squared norms from packed qkv (lda=1536) ----------------
__global__ __launch_bounds__(256) void sqnorm2_kernel(const bh16* __restrict__ qkv,
                                                      float* __restrict__ qn, float* __restrict__ kn)
{
    int lane = threadIdx.x & 63, wid = threadIdx.x >> 6;
    int row = blockIdx.x * 4 + wid;            // over B*H*T
    const bh16* src = qkv + (blockIdx.y ? 512 : 0);
    float* dst = blockIdx.y ? kn : qn;
    int t = row & 255; int bh = row >> 8; int b = bh >> 3, hh = bh & 7;
    float v = __bfloat162float(src[((size_t)b * TT + t) * 1536 + hh * 64 + lane]);
    float s = v * v;
    #pragma unroll
    for (int off = 32; off; off >>= 1) s += __shfl_xor(s, off);
    if (lane == 0) dst[row] = s;
}

// ---------------- hyperbolic distance + softmax: fp32 logits in, bf16 probs out ----------------
__global__ __launch_bounds__(256) void attn_softmax_kernel(const float* __restrict__ at, bh16* __restrict__ pb,
                                                           const float* __restrict__ qn,
                                                           const float* __restrict__ kn,
                                                           const float* __restrict__ curv)
{
    int lane = threadIdx.x & 63, wid = threadIdx.x >> 6;
    int row = blockIdx.x * 4 + wid;            // over B*H*T
    int i = row & 255; int bh = row >> 8; int hh = bh & 7;
    float c = fabsf(curv[hh]) + 1e-8f;
    float inv_sqrt_c = 1.f / sqrtf(c);
    float qni = qn[row];
    const float* srow = at + (size_t)bh * TT * TT + (size_t)i * TT;
    bh16* prow = pb + (size_t)bh * TT * TT + (size_t)i * TT;
    const float* knr = kn + (size_t)bh * TT;
    float logit[4];
    float mx = -1e30f;
    #pragma unroll
    for (int u = 0; u < 4; ++u) {
        int j = lane + u * 64;
        float s = srow[j];
        float knj = knr[j];
        float d2 = fmaxf(qni + knj - 2.f * s, 0.f);
        float denom = fmaxf((1.f - c * qni) * (1.f - c * knj), 1e-5f);
        float arg = fmaxf(1.f + (2.f * c * d2) / denom, 1.00001f);
        float dist = logf(arg + sqrtf((arg - 1.f) * (arg + 1.f))) * inv_sqrt_c;
        logit[u] = -dist;
        mx = fmaxf(mx, logit[u]);
    }
    #pragma unroll
    for (int off = 32; off; off >>= 1) mx = fmaxf(mx, __shfl_xor(mx, off));
    float e[4]; float sum = 0.f;
    #pragma unroll
    for (int u = 0; u < 4; ++u) { e[u] = expf(logit[u] - mx); sum += e[u]; }
    #pragma unroll
    for (int off = 32; off; off >>= 1) sum += __shfl_xor(sum, off);
    float inv = 1.f / sum;
    #pragma unroll
    for (int u = 0; u < 4; ++u) prow[lane + u * 64] = __float2bfloat16(e[u] * inv);
}

// ---------------- V transpose per (b,h): packed qkv (v at +1024, lda=1536) -> vt[bh][d][t] ----------------
__global__ __launch_bounds__(256) void vtrans_kernel(const bh16* __restrict__ vb, bh16* __restrict__ vt)
{
    int bh = blockIdx.y, b = bh >> 3, hh = bh & 7;
    int t0 = blockIdx.x * 64;
    __shared__ bh16 tile[64][65];
    for (int e = threadIdx.x; e < 4096; e += 256) {
        int r = e >> 6, c = e & 63;
        tile[r][c] = vb[((size_t)(b*256 + t0 + r))*1536 + hh*64 + c];
    }
    __syncthreads();
    for (int e = threadIdx.x; e < 4096; e += 256) {
        int d = e >> 6, t2 = e & 63;
        vt[((size_t)bh*64 + d)*256 + t0 + t2] = tile[t2][d];
    }
}

// ---------------- wavelet filter softmax -> TRANSPOSED layout fT[i][k][512] ----------------
__global__ __launch_bounds__(256) void filt_softmax_kernel(const float* __restrict__ w0, const float* __restrict__ w1,
                                                           const float* __restrict__ w2, const float* __restrict__ w3,
                                                           float* __restrict__ filt)
{
    int idx = blockIdx.x * 256 + threadIdx.x;
    if (idx >= 4 * DD) return;
    int d = idx & 511, i = idx >> 9;
    const float* w = (i == 0) ? w0 : (i == 1) ? w1 : (i == 2) ? w2 : w3;
    int K = 4 << i;
    int fb = (i == 0) ? 0 : (i == 1) ? 2048 : (i == 2) ? 6144 : 14336;
    const float* row = w + (size_t)d * K;
    float mx = -1e30f;
    for (int k = 0; k < K; ++k) mx = fmaxf(mx, row[k]);
    float s = 0.f;
    for (int k = 0; k < K; ++k) s += expf(row[k] - mx);
    float inv = 1.f / s;
    float* fo = filt + fb;
    for (int k = 0; k < K; ++k) fo[k * 512 + d] = expf(row[k] - mx) * inv;   // [k][d]
}

// ---------------- direct wavelet: comb[b,t,i,d] = sum_k ((1-w)h[tlo+k] + w h[thi+k]) f[k][d] ----------------
template<int I>
__device__ __forceinline__ void wave_scale(const bh16* __restrict__ hb, const float* __restrict__ filtT,
                                           bh16* __restrict__ comb, int lidx)
{
    const int K = 4 << I, stride = 2 << I, Ti = 128 >> I;
    const int fb = (I == 0) ? 0 : (I == 1) ? 2048 : (I == 2) ? 6144 : 14336;
    int d4 = lidx & 127; int rem = lidx >> 7; int t = rem & 255; int b = rem >> 8;
    int d = d4 << 2;
    float pos = ((float)t + 0.5f) * ((float)Ti / 256.f) - 0.5f;
    pos = fminf(fmaxf(pos, 0.f), (float)(Ti - 1));
    int lo = (int)pos;                       // pos >= 0, floor == trunc
    int hi = min(lo + 1, Ti - 1);
    float w = pos - (float)lo;
    float wl = 1.f - w, wh = w;
    int tlo = lo * stride - (K - 1);
    int thi = hi * stride - (K - 1);
    const float* fT = filtT + fb + d;
    const bh16* hrow = hb + (size_t)b * (TT * DD) + d;
    float a0 = 0.f, a1 = 0.f, a2 = 0.f, a3 = 0.f;
    #pragma unroll 8
    for (int k = 0; k < K; ++k) {
        f32x4 f = *(const f32x4*)(fT + k * 512);
        int ta = tlo + k, tb = thi + k;
        ushort4 ul = (ta >= 0) ? *(const ushort4*)(hrow + (size_t)ta * DD) : (ushort4){0, 0, 0, 0};
        ushort4 uh = (tb >= 0) ? *(const ushort4*)(hrow + (size_t)tb * DD) : (ushort4){0, 0, 0, 0};
        a0 += (wl * b2f(ul.x) + wh * b2f(uh.x)) * f.x;
        a1 += (wl * b2f(ul.y) + wh * b2f(uh.y)) * f.y;
        a2 += (wl * b2f(ul.z) + wh * b2f(uh.z)) * f.z;
        a3 += (wl * b2f(ul.w) + wh * b2f(uh.w)) * f.w;
    }
    bh16* op = comb + ((size_t)b * TT + t) * 2048 + I * 512 + d;
    ushort4 ov;
    ov.x = __bfloat16_as_ushort(__float2bfloat16(a0));
    ov.y = __bfloat16_as_ushort(__float2bfloat16(a1));
    ov.z = __bfloat16_as_ushort(__float2bfloat16(a2));
    ov.w = __bfloat16_as_ushort(__float2bfloat16(a3));
    *(ushort4*)op = ov;
}

__global__ __launch_bounds__(256) void wave2_kernel(const bh16* __restrict__ hb,
                                                    const float* __restrict__ filtT,
                                                    bh16* __restrict__ comb)
{
    int gid = blockIdx.x * 256 + threadIdx.x;   // 4 * 524288
    int scale = gid >> 19;
    int lidx = gid & 524287;
    switch (scale) {
        case 0: wave_scale<0>(hb, filtT, comb, lidx); break;
        case 1: wave_scale<1>(hb, filtT, comb, lidx); break;
        case 2: wave_scale<2>(hb, filtT, comb, lidx); break;
        default: wave_scale<3>(hb, filtT, comb, lidx); break;
    }
}

// ---------------- boundary loss: 32 blocks, one atomic per block ----------------
__global__ __launch_bounds__(256) void bd_loss_kernel(const float* __restrict__ tfb, const float* __restrict__ bdw,
                                                      const float* __restrict__ bdb, float* __restrict__ loss)
{
    __shared__ float wsum[4];
    int lane = threadIdx.x & 63, wid = threadIdx.x >> 6;
    float w = bdw[lane * 2] - bdw[lane * 2 + 1];
    float bconst = (bdb[0] - bdb[1]) + 0.1f;
    float acc = 0.f;
    for (int row = blockIdx.x * 4 + wid; row < BT; row += 128) {
        float vv = tfb[(size_t)row * PP + lane] * w;
        #pragma unroll
        for (int off = 32; off; off >>= 1) vv += __shfl_xor(vv, off);
        if (lane == 0) acc += fmaxf(vv + bconst, 0.f);
    }
    if (lane == 0) wsum[wid] = acc;
    __syncthreads();
    if (threadIdx.x == 0) {
        atomicAdd(loss, (wsum[0] + wsum[1] + wsum[2] + wsum[3]) * (1.f / 4096.f));
    }
}

// ---------------- h = layernorm(s + h)*g + b, dual fp32+bf16 out ----------------
__global__ __launch_bounds__(256) void add_ln_kernel(const float* __restrict__ s, float* __restrict__ h,
                                                     bh16* __restrict__ hb,
                                                     const float* __restrict__ g, const float* __restrict__ be)
{
    int lane = threadIdx.x & 63, wid = threadIdx.x >> 6;
    size_t row = (size_t)blockIdx.x * 4 + wid;
    const float* sr = s + row * DD;
    float* hr = h + row * DD;
    bh16* hbr = hb + row * DD;
    float xv[8]; float sum = 0.f;
    #pragma unroll
    for (int u = 0; u < 8; ++u) { int c = lane + u * 64; xv[u] = sr[c] + hr[c]; sum += xv[u]; }
    #pragma unroll
    for (int off = 32; off; off >>= 1) sum += __shfl_xor(sum, off);
    float mu = sum * (1.f / 512.f);
    float sq = 0.f;
    #pragma unroll
    for (int u = 0; u < 8; ++u) { float d = xv[u] - mu; sq += d * d; }
    #pragma unroll
    for (int off = 32; off; off >>= 1) sq += __shfl_xor(sq, off);
    float rstd = 1.f / sqrtf(sq * (1.f / 512.f) + 1e-5f);
    #pragma unroll
    for (int u = 0; u < 8; ++u) {
        int c = lane + u * 64;
        float v = (xv[u] - mu) * rstd * g[c] + be[c];
        hr[c] = v;
        hbr[c] = __float2bfloat16(v);
    }
}

// ---------------- weight transpose-convert: [l-sel][K][N] f32 -> out + l*lstride, [N][K] bf16 ----------------
__global__ __launch_bounds__(256) void wtrans_kernel(const float* __restrict__ W, bh16* __restrict__ Wt,
                                                     int K, int N, long lstride)
{
    int l = blockIdx.z;
    const float* Wl = W + (size_t)l * K * N;
    bh16* Wo = Wt + (size_t)l * lstride;
    __shared__ float tile[32][33];
    int n0 = blockIdx.x * 32, k0 = blockIdx.y * 32;
    int lx = threadIdx.x & 31, ly = threadIdx.x >> 5;
    #pragma unroll
    for (int j = 0; j < 4; ++j) {
        int kk = ly + j * 8;
        tile[kk][lx] = Wl[(size_t)(k0 + kk) * N + n0 + lx];
    }
    __syncthreads();
    #pragma unroll
    for (int j = 0; j < 4; ++j) {
        int nr = ly + j * 8;
        Wo[(size_t)(n0 + nr) * K + k0 + lx] = __float2bfloat16(tile[lx][nr]);
    }
}

// ---------------- cc_w [L][O][I][3] f32 -> ccT [L][O][tap*512+I] bf16 (tap-major K for fused conv GEMM) ----------------
__global__ __launch_bounds__(256) void ccconv_kernel(const float* __restrict__ ccw, bh16* __restrict__ ccT)
{
    size_t idx = (size_t)blockIdx.x * 256 + threadIdx.x;   // 6*512*1536
    int i = idx & 511; size_t rem = idx >> 9;
    int tap = (int)(rem % 3); rem /= 3;
    int o = (int)(rem & 511); int l = (int)(rem >> 9);
    ccT[idx] = __float2bfloat16(ccw[(((size_t)l*512 + o)*512 + i)*3 + tap]);
}

// ---------------- qkv bias concat: [L][1536] ----------------
__global__ __launch_bounds__(256) void qkvbias_kernel(const float* __restrict__ qb_, const float* __restrict__ kb_,
                                                      const float* __restrict__ vb_, float* __restrict__ ob)
{
    int idx = blockIdx.x * 256 + threadIdx.x;   // 6*1536
    if (idx >= 6 * 1536) return;
    int l = idx / 1536, n = idx % 1536;
    float v = (n < 512) ? qb_[l*512 + n] : (n < 1024) ? kb_[l*512 + n - 512] : vb_[l*512 + n - 1024];
    ob[idx] = v;
}

// ---------------- x f32 -> bf16 ----------------
__global__ __launch_bounds__(256) void convx_kernel(const float* __restrict__ x, bh16* __restrict__ xb)
{
    size_t idx = (size_t)blockIdx.x * 256 + threadIdx.x;
    xb[idx] = __float2bfloat16(x[idx]);
}

// ---------------- E matrix: row (t,b) = [sched[t]*noise[t,b,:] | temb[t]] (bf16, 160x1024) ----------------
__global__ __launch_bounds__(256) void build_E_kernel(const float* __restrict__ noise, const float* __restrict__ sched,
                                                      bh16* __restrict__ E)
{
    int idx = blockIdx.x * 256 + threadIdx.x;   // 10*16*1024
    if (idx >= SS * BB * 1024) return;
    int k = idx & 1023; int rem = idx >> 10; int b = rem & 15; int t = rem >> 4;
    float v;
    if (k < 512) {
        v = sched[t] * noise[((size_t)t * BB + b) * 512 + k];
    } else {
        int j = k - 512;
        const float kfac = -9.210340371976184f / 255.f;   // -ln(10000)/255
        v = (j < 256) ? sinf((float)t * expf((float)j * kfac))
                      : cosf((float)t * expf((float)(j - 256) * kfac));
    }
    E[idx] = __float2bfloat16(v);
}

// ---------------- head helpers ----------------
__global__ void init_kernel(bh16* zp, float* loss)
{
    int t = threadIdx.x;
    if (t < 64) zp[t] = __float2bfloat16(0.f);
    if (t == 64) *loss = 0.f;
}

__global__ __launch_bounds__(256) void build_cat16_kernel(const float* __restrict__ h, bh16* __restrict__ catb)
{
    int idx = blockIdx.x * 256 + threadIdx.x;   // 16*1024
    if (idx >= BB * 1024) return;
    int k = idx & 1023, b = idx >> 10;
    float v = (k < 512) ? h[((size_t)b * TT + 255) * DD + k]
                        : h[((size_t)b * TT + 254) * DD + (k - 512)];
    catb[idx] = __float2bfloat16(v);
}

__global__ __launch_bounds__(256) void cur_init2_kernel(const float* __restrict__ h, const float* __restrict__ mix,
                                                        float* __restrict__ curf, bh16* __restrict__ curb)
{
    int idx = blockIdx.x * 256 + threadIdx.x;   // 16*512
    if (idx >= BB * DD) return;
    int c = idx & 511, b = idx >> 9;
    float v = h[((size_t)b * TT + 255) * DD + c] + mix[idx];
    curf[idx] = v;
    curb[idx] = __float2bfloat16(v);
}

__global__ void fail_kernel(float* p) { p[0] = 1e30f; }

// =====================================================================================
extern "C" void kernel_launch(void* const* d_in, const int* in_sizes, int n_in,
                              void* d_out, int out_size, void* d_ws, size_t ws_size,
                              hipStream_t stream)
{
    const float* x      = (const float*)d_in[0];
    const float* in_w   = (const float*)d_in[1];
    const float* in_b   = (const float*)d_in[2];
    const float* gq_w   = (const float*)d_in[3];
    const float* gq_b   = (const float*)d_in[4];
    const float* gk_w   = (const float*)d_in[5];
    const float* gk_b   = (const float*)d_in[6];
    const float* gv_w   = (const float*)d_in[7];
    const float* gv_b   = (const float*)d_in[8];
    const float* go_w   = (const float*)d_in[9];
    const float* go_b   = (const float*)d_in[10];
    const float* curv   = (const float*)d_in[11];
    const float* wav0   = (const float*)d_in[12];
    const float* wav1   = (const float*)d_in[13];
    const float* wav2   = (const float*)d_in[14];
    const float* wav3   = (const float*)d_in[15];
    const float* wrec_w = (const float*)d_in[16];
    const float* wrec_b = (const float*)d_in[17];
    const float* te1_w  = (const float*)d_in[18];
    const float* te1_b  = (const float*)d_in[19];
    const float* te2_w  = (const float*)d_in[20];
    const float* te2_b  = (const float*)d_in[21];
    const float* td1_w  = (const float*)d_in[22];
    const float* td1_b  = (const float*)d_in[23];
    const float* td2_w  = (const float*)d_in[24];
    const float* td2_b  = (const float*)d_in[25];
    const float* bd_w   = (const float*)d_in[26];
    const float* bd_b   = (const float*)d_in[27];
    const float* cc_w   = (const float*)d_in[28];
    const float* cc_b   = (const float*)d_in[29];
    const float* ln_g   = (const float*)d_in[30];
    const float* ln_b   = (const float*)d_in[31];
    const float* mm1_w  = (const float*)d_in[32];
    const float* mm1_b  = (const float*)d_in[33];
    const float* mm2_w  = (const float*)d_in[34];
    const float* mm2_b  = (const float*)d_in[35];
    const float* dn1_w  = (const float*)d_in[36];
    const float* dn1_b  = (const float*)d_in[37];
    const float* dn2_w  = (const float*)d_in[38];
    const float* dn2_b  = (const float*)d_in[39];
    const float* dn3_w  = (const float*)d_in[40];
    const float* dn3_b  = (const float*)d_in[41];
    const float* out_w  = (const float*)d_in[42];
    const float* out_b  = (const float*)d_in[43];
    const float* nsched = (const float*)d_in[44];
    const float* noise  = (const float*)d_in[45];
    float* out = (float*)d_out;
    float* ws  = (float*)d_ws;

    // ---- fp32 workspace layout (float offsets) ----
    const size_t o_h   = 0;          // 2097152
    const size_t o_dec = 2097152;    // 2097152 (pre1 for head: 81920)
    const size_t o_s   = 4194304;    // 2097152
    const size_t o_tf  = 6291456;    // 262144
    const size_t o_qn  = 6553600;    // 32768
    const size_t o_kn  = 6586368;    // 32768
    const size_t o_at  = 6619136;    // 8388608
    const size_t o_fl  = 15007744;   // 30720
    const size_t o_mix = 15038464;   // 8192
    const size_t o_cur = 15046656;   // 8192
    const size_t o_qkb = 15054848;   // 9216 (qkv bias [6][1536])
    const size_t FP32_TOTAL = 15095808;
    // ---- bf16 region (element offsets from bp) ----
    const size_t b_xb   = 0;          // 1572864
    const size_t b_hb   = 1572864;    // 2097152
    const size_t b_qkv  = 3670016;    // 6291456: packed qkv [4096][1536]
    const size_t b_vt   = 9961472;    // 2097152
    const size_t b_pb   = 12058624;   // 8388608 (head scratch aliases here after layers)
    const size_t b_gmb  = 20447232;   // 2097152
    const size_t b_tdb  = 22544384;   // 2097152
    const size_t b_t1b  = 24641536;   // 262144
    const size_t b_tfb  = 24903680;   // 262144
    const size_t b_zp   = 25165824;   // 512
    const size_t b_inwT = 25166336;   // 196608
    const size_t b_qkvT = 25362944;   // 4718592: [6][1536][512]
    const size_t b_goT  = 30081536;   // 1572864
    const size_t b_wrT  = 31654400;   // 6291456
    const size_t b_td1T = 37945856;   // 196608
    const size_t b_td2T = 38142464;   // 1572864
    const size_t b_te1T = 39715328;   // 196608
    const size_t b_te2T = 39911936;   // 24576
    const size_t b_ccT  = 39936512;   // 4718592: [6][512][1536]
    const size_t BF16_TOTAL = 44655104;
    const size_t TOTAL_BYTES = FP32_TOTAL * 4 + BF16_TOTAL * 2;
    if (ws_size < TOTAL_BYTES) { fail_kernel<<<1, 1, 0, stream>>>(out); return; }

    float* h_   = ws + o_h;
    float* dec_ = ws + o_dec;
    float* s_   = ws + o_s;
    float* tf_  = ws + o_tf;
    float* qn_  = ws + o_qn;
    float* kn_  = ws + o_kn;
    float* at_  = ws + o_at;
    float* fl_  = ws + o_fl;
    float* mixb = ws + o_mix;
    float* curf = ws + o_cur;
    float* qkvbias = ws + o_qkb;
    bh16* bp   = (bh16*)(ws + FP32_TOTAL);
    bh16* xb   = bp + b_xb;
    bh16* hb   = bp + b_hb;
    bh16* qkvb = bp + b_qkv;
    bh16* vt   = bp + b_vt;
    bh16* pb   = bp + b_pb;
    bh16* gmb  = bp + b_gmb;
    bh16* tdb  = bp + b_tdb;
    bh16* t1b  = bp + b_t1b;
    bh16* tfb  = bp + b_tfb;
    bh16* zp   = bp + b_zp;
    bh16* inwT = bp + b_inwT;
    bh16* qkvT = bp + b_qkvT;
    bh16* goT  = bp + b_goT;
    bh16* wrT  = bp + b_wrT;
    bh16* td1T = bp + b_td1T;
    bh16* td2T = bp + b_td2T;
    bh16* te1T = bp + b_te1T;
    bh16* te2T = bp + b_te2T;
    bh16* ccT  = bp + b_ccT;
    bh16* combb = (bh16*)at_;   // aliases at_ after softmax consumed it

    // head bf16 scratch: aliased into pb region (dead after layer loop)
    bh16* dn1T  = pb;             // 524288
    bh16* dn2T  = pb + 524288;    // 262144
    bh16* dn3T  = pb + 786432;    // 262144
    bh16* mm1T  = pb + 1048576;   // 524288
    bh16* mm2T  = pb + 1572864;   // 262144
    bh16* outT  = pb + 1835008;   // 196608
    bh16* E16   = pb + 2031616;   // 163840
    bh16* cat16 = pb + 2195456;   // 16384
    bh16* tmb16 = pb + 2211840;   // 8192
    bh16* cur16 = pb + 2220032;   // 8192
    bh16* d1b16 = pb + 2228224;   // 8192
    bh16* d2b16 = pb + 2236416;   // 8192
    float* pre1 = dec_;           // 81920 f32, aliases dec_ after layers

    auto mg = [&](const bh16* A, int lda, const bh16* Bt, int ldb,
                  const float* bias, float* Cf, bh16* Cb, int ldc,
                  int M, int N, int K, int shift, int accum, int act,
                  int nb, int zmask, int zshift,
                  long aS1, long aS0, long bS1, long bS0, long cS1, long cS0, int ccdil) {
        dim3 g(N / 64, M / 128, nb);
        mgemm_kernel<<<g, 256, 0, stream>>>(A, lda, Bt, ldb, bias, Cf, Cb, ldc, N, K,
                                            shift, accum, act, zmask, zshift,
                                            aS1, aS0, bS1, bS0, cS1, cS0, ccdil, zp);
    };
    auto mgp = [&](const bh16* A, int lda, const bh16* Bt, int ldb,
                   const float* bias, float* Cf, bh16* Cb, int ldc,
                   int M, int N, int K, int shift, int accum, int act) {
        mg(A, lda, Bt, ldb, bias, Cf, Cb, ldc, M, N, K, shift, accum, act, 1, 0, 0, 0, 0, 0, 0, 0, 0, 0);
    };
    auto hg = [&](const bh16* A, int lda, long aZ, const bh16* Bt, int ldb,
                  const float* bias, const float* pre, float* Of, bh16* Ob, long oZ,
                  int N, int K, int act, float* cf, bh16* cb, const float* sp, int nz) {
        hgemm16_kernel<<<dim3(N / 64, 1, nz), 256, 0, stream>>>(
            A, lda, aZ, Bt, ldb, bias, pre, Of, Ob, oZ, N, K, act, cf, cb, sp);
    };

    // ---- setup: zero page/loss, converts ----
    init_kernel<<<1, 128, 0, stream>>>(zp, out + BB * DIN);
    convx_kernel<<<BT * DIN / 256, 256, 0, stream>>>(x, xb);
    wtrans_kernel<<<dim3(DD/32, DIN/32, 1), 256, 0, stream>>>(in_w, inwT, DIN, DD, (long)DIN*DD);
    // packed qkvT: rows 0-511 q, 512-1023 k, 1024-1535 v; l-stride 786432
    wtrans_kernel<<<dim3(16, 16, 6), 256, 0, stream>>>(gq_w, qkvT,          DD, DD, 786432L);
    wtrans_kernel<<<dim3(16, 16, 6), 256, 0, stream>>>(gk_w, qkvT + 262144, DD, DD, 786432L);
    wtrans_kernel<<<dim3(16, 16, 6), 256, 0, stream>>>(gv_w, qkvT + 524288, DD, DD, 786432L);
    qkvbias_kernel<<<36, 256, 0, stream>>>(gq_b, gk_b, gv_b, qkvbias);
    wtrans_kernel<<<dim3(16, 16, 6), 256, 0, stream>>>(go_w, goT, DD, DD, (long)DD*DD);
    wtrans_kernel<<<dim3(16, 64, 6), 256, 0, stream>>>(wrec_w, wrT, 2048, DD, 2048L*DD);
    wtrans_kernel<<<dim3(16, 2, 6), 256, 0, stream>>>(td1_w, td1T, PP, DD, (long)PP*DD);
    wtrans_kernel<<<dim3(16, 16, 6), 256, 0, stream>>>(td2_w, td2T, DD, DD, (long)DD*DD);
    wtrans_kernel<<<dim3(2, 16, 6), 256, 0, stream>>>(te1_w, te1T, DD, PP, (long)DD*PP);
    wtrans_kernel<<<dim3(2, 2, 6), 256, 0, stream>>>(te2_w, te2T, PP, PP, (long)PP*PP);
    ccconv_kernel<<<18432, 256, 0, stream>>>(cc_w, ccT);

    // h = x @ in_w + in_b  (fp32 + bf16)
    mgp(xb, DIN, inwT, DIN, in_b, h_, hb, DD, BT, DD, DIN, 0, 0, ACT_NONE);

    for (int l = 0; l < LL; ++l) {
        // fused q|k|v projection: N=1536, packed output [BT][1536]
        mgp(hb, DD, qkvT + (size_t)l*786432, DD, qkvbias + (size_t)l*1536,
            nullptr, qkvb, 1536, BT, 1536, DD, 0, 0, ACT_NONE);
        // attention
        sqnorm2_kernel<<<dim3(8192, 2), 256, 0, stream>>>(qkvb, qn_, kn_);
        mg(qkvb, 1536, qkvb + 512, 1536, nullptr, at_, nullptr, TT, TT, TT, 64, 0, 0, ACT_NONE,
           128, 7, 3, 393216, 64, 393216, 64, 524288, 65536, 0);
        attn_softmax_kernel<<<8192, 256, 0, stream>>>(at_, pb, qn_, kn_, curv + (size_t)l*HH);
        vtrans_kernel<<<dim3(4, 128), 256, 0, stream>>>(qkvb + 1024, vt);
        mg(pb, TT, vt, TT, nullptr, nullptr, gmb, DD, TT, 64, TT, 0, 0, ACT_NONE,
           128, 7, 3, 524288, 65536, 131072, 16384, 131072, 64, 0);
        mgp(gmb, DD, goT + (size_t)l*262144, DD, go_b + (size_t)l*DD, s_, nullptr, DD, BT, DD, DD, 0, 0, ACT_NONE);
        // wavelet branch: direct streaming kernel (comb aliases at_, softmax already consumed it)
        filt_softmax_kernel<<<8, 256, 0, stream>>>(wav0 + (size_t)l*DD*4, wav1 + (size_t)l*DD*8,
                                                   wav2 + (size_t)l*DD*16, wav3 + (size_t)l*DD*32, fl_);
        wave2_kernel<<<8192, 256, 0, stream>>>(hb, fl_, combb);
        mgp(combb, 2048, wrT + (size_t)l*1048576, 2048, wrec_b + (size_t)l*DD, s_, nullptr, DD, BT, DD, 2048, 0, 1, ACT_NONE);
        // topo branch
        mgp(hb, DD, te1T + (size_t)l*32768, DD, te1_b + (size_t)l*PP, nullptr, t1b, PP, BT, PP, DD, 0, 0, ACT_RELU);
        mgp(t1b, PP, te2T + (size_t)l*4096, PP, te2_b + (size_t)l*PP, tf_, tfb, PP, BT, PP, PP, 0, 0, ACT_NONE);
        bd_loss_kernel<<<32, 256, 0, stream>>>(tf_, bd_w + (size_t)l*PP*2, bd_b + (size_t)l*2, out + BB*DIN);
        mgp(tfb, PP, td1T + (size_t)l*32768, PP, td1_b + (size_t)l*DD, nullptr, tdb, DD, BT, DD, PP, 0, 0, ACT_RELU);
        mgp(tdb, DD, td2T + (size_t)l*262144, DD, td2_b + (size_t)l*DD, s_, nullptr, DD, BT, DD, DD, 0, 1, ACT_NONE);
        // fused causal dilated conv: single K=1536 GEMM, per-K-tile shift schedule
        int dil = 1 << l;
        mg(hb, DD, ccT + (size_t)l*786432, 1536, cc_b + (size_t)l*DD,
           s_, nullptr, DD, BT, DD, 1536, 0, 1, ACT_NONE, 1, 0, 0, 0, 0, 0, 0, 0, 0, dil);
        // h = LN(s + h)
        add_ln_kernel<<<BT/4, 256, 0, stream>>>(s_, h_, hb, ln_g, ln_b);
    }

    // ---- head: convert weights (into dead pb region), precompute E/pre1 ----
    wtrans_kernel<<<dim3(16, 32, 1), 256, 0, stream>>>(dn1_w, dn1T, 1024, 512, 0L);
    wtrans_kernel<<<dim3(16, 16, 1), 256, 0, stream>>>(dn2_w, dn2T, 512, 512, 0L);
    wtrans_kernel<<<dim3(16, 16, 1), 256, 0, stream>>>(dn3_w, dn3T, 512, 512, 0L);
    wtrans_kernel<<<dim3(16, 32, 1), 256, 0, stream>>>(mm1_w, mm1T, 1024, 512, 0L);
    wtrans_kernel<<<dim3(16, 16, 1), 256, 0, stream>>>(mm2_w, mm2T, 512, 512, 0L);
    wtrans_kernel<<<dim3(12, 16, 1), 256, 0, stream>>>(out_w, outT, 512, 384, 0L);
    build_E_kernel<<<640, 256, 0, stream>>>(noise, nsched, E16);
    // pre1[t] = E_t @ dn1_w + dn1_b   (z-batched over t)
    hg(E16, 1024, 16*1024, dn1T, 1024, dn1_b, nullptr, pre1, nullptr, 8192,
       512, 1024, ACT_NONE, nullptr, nullptr, nullptr, SS);
    // mix head
    build_cat16_kernel<<<64, 256, 0, stream>>>(h_, cat16);
    hg(cat16, 1024, 0, mm1T, 1024, mm1_b, nullptr, nullptr, tmb16, 0,
       512, 1024, ACT_TANH, nullptr, nullptr, nullptr, 1);
    hg(tmb16, 512, 0, mm2T, 512, mm2_b, nullptr, mixb, nullptr, 0,
       512, 512, ACT_NONE, nullptr, nullptr, nullptr, 1);
    cur_init2_kernel<<<32, 256, 0, stream>>>(h_, mixb, curf, cur16);
    // diffusion chain: 3 launches per step
    for (int t = 0; t < SS; ++t) {
        hg(cur16, 512, 0, dn1T, 1024, nullptr, pre1 + (size_t)t*8192, nullptr, d1b16, 0,
           512, 512, ACT_SILU, nullptr, nullptr, nullptr, 1);
        hg(d1b16, 512, 0, dn2T, 512, dn2_b, nullptr, nullptr, d2b16, 0,
           512, 512, ACT_SILU, nullptr, nullptr, nullptr, 1);
        hg(d2b16, 512, 0, dn3T, 512, dn3_b, nullptr, nullptr, nullptr, 0,
           512, 512, ACT_NONE, curf, cur16, nsched + t, 1);
    }
    // pred = cur @ out_w + out_b
    hg(cur16, 512, 0, outT, 512, out_b, nullptr, out, nullptr, 0,
       384, 512, ACT_NONE, nullptr, nullptr, nullptr, 1);
}

// Round 8
// 2140.545 us; speedup vs baseline: 1.0270x; 1.0064x over previous
//
#include <hip/hip_runtime.h>
#include <hip/hip_bf16.h>
#include <math.h>

#define BB 16
#define TT 256
#define DIN 384
#define DD 512
#define LL 6
#define HH 8
#define PP 64
#define SS 10
#define BT (BB*TT)   // 4096

enum { ACT_NONE=0, ACT_RELU=1, ACT_TANH=2, ACT_SILU=3 };

typedef __attribute__((ext_vector_type(8))) short bf16x8;
typedef __attribute__((ext_vector_type(8))) unsigned short u16x8;
typedef __attribute__((ext_vector_type(4))) float f32x4;
typedef __hip_bfloat16 bh16;

typedef const __attribute__((address_space(1))) void gvoid_t;
typedef __attribute__((address_space(3))) void lvoid_t;
__device__ __forceinline__ void gload16(const void* g, void* l) {
    __builtin_amdgcn_global_load_lds((gvoid_t*)g, (lvoid_t*)l, 16, 0, 0);
}

__device__ __forceinline__ float b2f(unsigned short u) {
    return __uint_as_float(((unsigned int)u) << 16);
}

// =====================================================================================
// Generic bf16 MFMA GEMM: C = act(A @ Bt^T + bias)  (Bt stored [N][K])
// BM=128, BN=64, BK=64; 4 waves 2x2, wave tile 64x32 (4x2 frags of 16x16).
// Optional batch dim z; shift row-masking; ccdil fused 3-tap causal conv (see r5 notes).
__global__ __launch_bounds__(256) void mgemm_kernel(
    const bh16* __restrict__ A, int lda,
    const bh16* __restrict__ Bt, int ldb,
    const float* __restrict__ bias,
    float* __restrict__ Cf, bh16* __restrict__ Cb, int ldc,
    int N, int K, int shift, int accum, int act,
    int zmask, int zshift,
    long aS1, long aS0, long bS1, long bS0, long cS1, long cS0,
    int ccdil,
    const bh16* __restrict__ zp)
{
    __shared__ bf16x8 As[128*8];   // 16KB: [row][8 chunks], chunk XOR-swizzled by row&7
    __shared__ bf16x8 Bs[64*8];    // 8KB

    int z = blockIdx.z;
    long z1 = (long)(z >> zshift), z0 = (long)(z & zmask);
    A  += z1*aS1 + z0*aS0;
    Bt += z1*bS1 + z0*bS0;
    long coff = z1*cS1 + z0*cS0;

    const int tid  = threadIdx.x;
    const int lane = tid & 63, w = tid >> 6;
    const int wm = w >> 1, wn = w & 1;
    const int row0 = blockIdx.y * 128, col0 = blockIdx.x * 64;

    f32x4 acc[4][2];
    #pragma unroll
    for (int i = 0; i < 4; ++i)
        #pragma unroll
        for (int j = 0; j < 2; ++j) acc[i][j] = (f32x4){0.f,0.f,0.f,0.f};

    const int nkt = K >> 6;
    for (int kt = 0; kt < nkt; ++kt) {
        int k0 = kt << 6;
        int mask_sh, addr_sh;
        if (ccdil) {
            int tap = kt >> 3;
            mask_sh = (2 - tap) * ccdil;
            addr_sh = mask_sh + tap;      // compensates k0 row-aliasing (lda=512, k0 carries tap*512)
        } else {
            mask_sh = shift; addr_sh = shift;
        }
        // stage A: 1024 16B-chunks, 4 instr/wave
        #pragma unroll
        for (int j = 0; j < 4; ++j) {
            int c = ((w*4 + j) << 6) + lane;
            int row = c >> 3, chk = c & 7;
            int schk = chk ^ (row & 7);
            int grow = row0 + row;
            const bh16* src = ((grow & 255) >= mask_sh)
                ? (A + (size_t)(grow - addr_sh)*lda + k0 + schk*8) : zp;
            gload16(src, &As[(w*4 + j) * 64]);
        }
        // stage B: 512 chunks, 2 instr/wave
        #pragma unroll
        for (int j = 0; j < 2; ++j) {
            int c = ((w*2 + j) << 6) + lane;
            int row = c >> 3, chk = c & 7;
            int schk = chk ^ (row & 7);
            int gcol = col0 + row;
            const bh16* src = (gcol < N)
                ? (Bt + (size_t)gcol*ldb + k0 + schk*8) : zp;
            gload16(src, &Bs[(w*2 + j) * 64]);
        }
        asm volatile("s_waitcnt vmcnt(0)" ::: "memory");
        __syncthreads();

        bf16x8 a[4][2], b[2][2];
        #pragma unroll
        for (int fm = 0; fm < 4; ++fm) {
            int row = wm*64 + fm*16 + (lane & 15);
            #pragma unroll
            for (int ks = 0; ks < 2; ++ks)
                a[fm][ks] = As[row*8 + ((ks*4 + (lane>>4)) ^ (row & 7))];
        }
        #pragma unroll
        for (int fn = 0; fn < 2; ++fn) {
            int col = wn*32 + fn*16 + (lane & 15);
            #pragma unroll
            for (int ks = 0; ks < 2; ++ks)
                b[fn][ks] = Bs[col*8 + ((ks*4 + (lane>>4)) ^ (col & 7))];
        }
        #pragma unroll
        for (int ks = 0; ks < 2; ++ks)
            #pragma unroll
            for (int fm = 0; fm < 4; ++fm)
                #pragma unroll
                for (int fn = 0; fn < 2; ++fn)
                    acc[fm][fn] = __builtin_amdgcn_mfma_f32_16x16x32_bf16(
                        a[fm][ks], b[fn][ks], acc[fm][fn], 0, 0, 0);
        __syncthreads();
    }

    // epilogue: D[row][col], col=lane&15, row=(lane>>4)*4+r
    #pragma unroll
    for (int fm = 0; fm < 4; ++fm) {
        #pragma unroll
        for (int fn = 0; fn < 2; ++fn) {
            int gc = col0 + wn*32 + fn*16 + (lane & 15);
            float bs = bias ? bias[gc] : 0.f;
            #pragma unroll
            for (int r = 0; r < 4; ++r) {
                int gr = row0 + wm*64 + fm*16 + (lane>>4)*4 + r;
                float v = acc[fm][fn][r] + bs;
                if (act == ACT_RELU) v = fmaxf(v, 0.f);
                size_t o = (size_t)gr*ldc + gc + coff;
                if (Cf) { if (accum) Cf[o] += v; else Cf[o] = v; }
                if (Cb) Cb[o] = __float2bfloat16(v);
            }
        }
    }
}

// =====================================================================================
// Small-M (M=16) MFMA GEMM, one wave = 16x16xK tile, no LDS.
__global__ __launch_bounds__(256) void hgemm16_kernel(
    const bh16* __restrict__ A, int lda, long aZ,
    const bh16* __restrict__ Bt, int ldb,
    const float* __restrict__ bias,
    const float* __restrict__ pre,
    float* __restrict__ Of, bh16* __restrict__ Ob, long oZ,
    int N, int K, int act,
    float* __restrict__ curf, bh16* __restrict__ curb,
    const float* __restrict__ scaleptr)
{
    const int z = blockIdx.z;
    A += (long)z * aZ;
    const int lane = threadIdx.x & 63, w = threadIdx.x >> 6;
    const int col0 = blockIdx.x * 64 + w * 16;
    const int ar = lane & 15;
    const int koff = (lane >> 4) * 8;
    const bh16* arow = A + (size_t)ar * lda + koff;
    const bh16* brow = Bt + (size_t)(col0 + ar) * ldb + koff;
    f32x4 acc = {0.f, 0.f, 0.f, 0.f};
    const int nkt = K >> 5;
    for (int kt0 = 0; kt0 < nkt; kt0 += 8) {
        bf16x8 av[8], bv[8];
        #pragma unroll
        for (int j = 0; j < 8; ++j) {
            av[j] = *(const bf16x8*)(arow + (size_t)(kt0 + j) * 32);
            bv[j] = *(const bf16x8*)(brow + (size_t)(kt0 + j) * 32);
        }
        #pragma unroll
        for (int j = 0; j < 8; ++j)
            acc = __builtin_amdgcn_mfma_f32_16x16x32_bf16(av[j], bv[j], acc, 0, 0, 0);
    }
    const int col = col0 + ar;
    float bs = bias ? bias[col] : 0.f;
    float sc = scaleptr ? *scaleptr : 0.f;
    #pragma unroll
    for (int r = 0; r < 4; ++r) {
        int row = (lane >> 4) * 4 + r;
        float v = acc[r] + bs;
        if (pre) v += pre[(size_t)row * N + col];
        if (act == ACT_SILU)      v = v / (1.f + expf(-v));
        else if (act == ACT_TANH) v = tanhf(v);
        if (curf) {
            size_t o = (size_t)row * 512 + col;
            float nc = curf[o] - v * sc;
            curf[o] = nc;
            curb[o] = __float2bfloat16(nc);
        } else {
            size_t o = (size_t)z * oZ + (size_t)row * N + col;
            if (Of) Of[o] = v;
            if (Ob) Ob[o] = __float2bfloat16(v);
        }
    }
}

// ---------------- per-head squared norms from packed qkv (lda=1536) ----------------
__global__ __launch_bounds__(256) void sqnorm2_kernel(const bh16* __restrict__ qkv,
                                                      float* __restrict__ qn, float* __restrict__ kn)
{
    int lane = threadIdx.x & 63, wid = threadIdx.x >> 6;
    int row = blockIdx.x * 4 + wid;            // over B*H*T
    const bh16* src = qkv + (blockIdx.y ? 512 : 0);
    float* dst = blockIdx.y ? kn : qn;
    int t = row & 255; int bh = row >> 8; int b = bh >> 3, hh = bh & 7;
    float v = __bfloat162float(src[((size_t)b * TT + t) * 1536 + hh * 64 + lane]);
    float s = v * v;
    #pragma unroll
    for (int off = 32; off; off >>= 1) s += __shfl_xor(s, off);
    if (lane == 0) dst[row] = s;
}

// ---------------- hyperbolic distance + softmax: fp32 logits in, bf16 probs out ----------------
__global__ __launch_bounds__(256) void attn_softmax_kernel(const float* __restrict__ at, bh16* __restrict__ pb,
                                                           const float* __restrict__ qn,
                                                           const float* __restrict__ kn,
                                                           const float* __restrict__ curv)
{
    int lane = threadIdx.x & 63, wid = threadIdx.x >> 6;
    int row = blockIdx.x * 4 + wid;            // over B*H*T
    int i = row & 255; int bh = row >> 8; int hh = bh & 7;
    float c = fabsf(curv[hh]) + 1e-8f;
    float inv_sqrt_c = 1.f / sqrtf(c);
    float qni = qn[row];
    const float* srow = at + (size_t)bh * TT * TT + (size_t)i * TT;
    bh16* prow = pb + (size_t)bh * TT * TT + (size_t)i * TT;
    const float* knr = kn + (size_t)bh * TT;
    float logit[4];
    float mx = -1e30f;
    #pragma unroll
    for (int u = 0; u < 4; ++u) {
        int j = lane + u * 64;
        float s = srow[j];
        float knj = knr[j];
        float d2 = fmaxf(qni + knj - 2.f * s, 0.f);
        float denom = fmaxf((1.f - c * qni) * (1.f - c * knj), 1e-5f);
        float arg = fmaxf(1.f + (2.f * c * d2) / denom, 1.00001f);
        float dist = logf(arg + sqrtf((arg - 1.f) * (arg + 1.f))) * inv_sqrt_c;
        logit[u] = -dist;
        mx = fmaxf(mx, logit[u]);
    }
    #pragma unroll
    for (int off = 32; off; off >>= 1) mx = fmaxf(mx, __shfl_xor(mx, off));
    float e[4]; float sum = 0.f;
    #pragma unroll
    for (int u = 0; u < 4; ++u) { e[u] = expf(logit[u] - mx); sum += e[u]; }
    #pragma unroll
    for (int off = 32; off; off >>= 1) sum += __shfl_xor(sum, off);
    float inv = 1.f / sum;
    #pragma unroll
    for (int u = 0; u < 4; ++u) prow[lane + u * 64] = __float2bfloat16(e[u] * inv);
}

// ---------------- V transpose per (b,h): packed qkv (v at +1024, lda=1536) -> vt[bh][d][t] ----------------
__global__ __launch_bounds__(256) void vtrans_kernel(const bh16* __restrict__ vb, bh16* __restrict__ vt)
{
    int bh = blockIdx.y, b = bh >> 3, hh = bh & 7;
    int t0 = blockIdx.x * 64;
    __shared__ bh16 tile[64][65];
    for (int e = threadIdx.x; e < 4096; e += 256) {
        int r = e >> 6, c = e & 63;
        tile[r][c] = vb[((size_t)(b*256 + t0 + r))*1536 + hh*64 + c];
    }
    __syncthreads();
    for (int e = threadIdx.x; e < 4096; e += 256) {
        int d = e >> 6, t2 = e & 63;
        vt[((size_t)bh*64 + d)*256 + t0 + t2] = tile[t2][d];
    }
}

// ---------------- wavelet filter softmax -> TRANSPOSED layout fT[i][k][512] ----------------
__global__ __launch_bounds__(256) void filt_softmax_kernel(const float* __restrict__ w0, const float* __restrict__ w1,
                                                           const float* __restrict__ w2, const float* __restrict__ w3,
                                                           float* __restrict__ filt)
{
    int idx = blockIdx.x * 256 + threadIdx.x;
    if (idx >= 4 * DD) return;
    int d = idx & 511, i = idx >> 9;
    const float* w = (i == 0) ? w0 : (i == 1) ? w1 : (i == 2) ? w2 : w3;
    int K = 4 << i;
    int fb = (i == 0) ? 0 : (i == 1) ? 2048 : (i == 2) ? 6144 : 14336;
    const float* row = w + (size_t)d * K;
    float mx = -1e30f;
    for (int k = 0; k < K; ++k) mx = fmaxf(mx, row[k]);
    float s = 0.f;
    for (int k = 0; k < K; ++k) s += expf(row[k] - mx);
    float inv = 1.f / s;
    float* fo = filt + fb;
    for (int k = 0; k < K; ++k) fo[k * 512 + d] = expf(row[k] - mx) * inv;   // [k][d]
}

// ---------------- direct wavelet, merged coefficient stream, 8 ch/thread ----------------
// comb[b,t,I,d] = sum_{r=0}^{KE-1} h[b, tbase+r, d] * coef[r,d]
//   coef[r,d] = (r<K)*wl*f[r,d] + (r>=stride)*wh*f[r-stride,d], gated by (tbase+r>=0)
//   (hi==lo clamp case has wh==0, so delta=stride is always valid)
template<int I>
__device__ __forceinline__ void wave_scale8(const bh16* __restrict__ hb, const float* __restrict__ filtT,
                                            bh16* __restrict__ comb, int lidx)
{
    const int K = 4 << I, stride = 2 << I, Ti = 128 >> I, KE = K + stride;
    const int fb = (I == 0) ? 0 : (I == 1) ? 2048 : (I == 2) ? 6144 : 14336;
    int d8 = lidx & 63; int rem = lidx >> 6; int t = rem & 255; int b = rem >> 8;
    int d = d8 << 3;
    float pos = ((float)t + 0.5f) * ((float)Ti / 256.f) - 0.5f;
    pos = fminf(fmaxf(pos, 0.f), (float)(Ti - 1));
    int lo = (int)pos;                       // pos >= 0, floor == trunc
    float w = pos - (float)lo;
    float wl = 1.f - w, wh = w;              // if lo clamps to Ti-1, wh == 0
    int tbase = lo * stride - (K - 1);
    const float* fT = filtT + fb + d;
    const bh16* hrow = hb + (size_t)b * (TT * DD) + d;
    float a[8] = {0.f, 0.f, 0.f, 0.f, 0.f, 0.f, 0.f, 0.f};
    #pragma unroll
    for (int r = 0; r < KE; ++r) {
        int tr = tbase + r;
        int trc = (tr < 0) ? 0 : tr;
        float gate = (tr >= 0) ? 1.f : 0.f;
        u16x8 hv = *(const u16x8*)(hrow + (size_t)trc * DD);
        float wle = (r < K) ? wl * gate : 0.f;          // r<K is compile-time (full unroll)
        float whe = (r >= stride) ? wh * gate : 0.f;    // r>=stride compile-time
        #pragma unroll
        for (int j = 0; j < 8; ++j) {
            float c = 0.f;
            if (r < K)       c += wle * fT[r * 512 + j];
            if (r >= stride) c += whe * fT[(r - stride) * 512 + j];
            a[j] += c * b2f(hv[j]);
        }
    }
    bh16* op = comb + ((size_t)b * TT + t) * 2048 + I * 512 + d;
    u16x8 ov;
    #pragma unroll
    for (int j = 0; j < 8; ++j) ov[j] = __bfloat16_as_ushort(__float2bfloat16(a[j]));
    *(u16x8*)op = ov;
}

__global__ __launch_bounds__(256) void wave3_kernel(const bh16* __restrict__ hb,
                                                    const float* __restrict__ filtT,
                                                    bh16* __restrict__ comb)
{
    int gid = blockIdx.x * 256 + threadIdx.x;   // 4 * 262144
    int scale = gid >> 18;
    int lidx = gid & 262143;
    switch (scale) {
        case 0: wave_scale8<0>(hb, filtT, comb, lidx); break;
        case 1: wave_scale8<1>(hb, filtT, comb, lidx); break;
        case 2: wave_scale8<2>(hb, filtT, comb, lidx); break;
        default: wave_scale8<3>(hb, filtT, comb, lidx); break;
    }
}

// ---------------- boundary loss: 32 blocks, one atomic per block ----------------
__global__ __launch_bounds__(256) void bd_loss_kernel(const float* __restrict__ tfb, const float* __restrict__ bdw,
                                                      const float* __restrict__ bdb, float* __restrict__ loss)
{
    __shared__ float wsum[4];
    int lane = threadIdx.x & 63, wid = threadIdx.x >> 6;
    float w = bdw[lane * 2] - bdw[lane * 2 + 1];
    float bconst = (bdb[0] - bdb[1]) + 0.1f;
    float acc = 0.f;
    for (int row = blockIdx.x * 4 + wid; row < BT; row += 128) {
        float vv = tfb[(size_t)row * PP + lane] * w;
        #pragma unroll
        for (int off = 32; off; off >>= 1) vv += __shfl_xor(vv, off);
        if (lane == 0) acc += fmaxf(vv + bconst, 0.f);
    }
    if (lane == 0) wsum[wid] = acc;
    __syncthreads();
    if (threadIdx.x == 0) {
        atomicAdd(loss, (wsum[0] + wsum[1] + wsum[2] + wsum[3]) * (1.f / 4096.f));
    }
}

// ---------------- h = layernorm(s + h)*g + b, dual fp32+bf16 out ----------------
__global__ __launch_bounds__(256) void add_ln_kernel(const float* __restrict__ s, float* __restrict__ h,
                                                     bh16* __restrict__ hb,
                                                     const float* __restrict__ g, const float* __restrict__ be)
{
    int lane = threadIdx.x & 63, wid = threadIdx.x >> 6;
    size_t row = (size_t)blockIdx.x * 4 + wid;
    const float* sr = s + row * DD;
    float* hr = h + row * DD;
    bh16* hbr = hb + row * DD;
    float xv[8]; float sum = 0.f;
    #pragma unroll
    for (int u = 0; u < 8; ++u) { int c = lane + u * 64; xv[u] = sr[c] + hr[c]; sum += xv[u]; }
    #pragma unroll
    for (int off = 32; off; off >>= 1) sum += __shfl_xor(sum, off);
    float mu = sum * (1.f / 512.f);
    float sq = 0.f;
    #pragma unroll
    for (int u = 0; u < 8; ++u) { float d = xv[u] - mu; sq += d * d; }
    #pragma unroll
    for (int off = 32; off; off >>= 1) sq += __shfl_xor(sq, off);
    float rstd = 1.f / sqrtf(sq * (1.f / 512.f) + 1e-5f);
    #pragma unroll
    for (int u = 0; u < 8; ++u) {
        int c = lane + u * 64;
        float v = (xv[u] - mu) * rstd * g[c] + be[c];
        hr[c] = v;
        hbr[c] = __float2bfloat16(v);
    }
}

// ---------------- weight transpose-convert: [l-sel][K][N] f32 -> out + l*lstride, [N][K] bf16 ----------------
__global__ __launch_bounds__(256) void wtrans_kernel(const float* __restrict__ W, bh16* __restrict__ Wt,
                                                     int K, int N, long lstride)
{
    int l = blockIdx.z;
    const float* Wl = W + (size_t)l * K * N;
    bh16* Wo = Wt + (size_t)l * lstride;
    __shared__ float tile[32][33];
    int n0 = blockIdx.x * 32, k0 = blockIdx.y * 32;
    int lx = threadIdx.x & 31, ly = threadIdx.x >> 5;
    #pragma unroll
    for (int j = 0; j < 4; ++j) {
        int kk = ly + j * 8;
        tile[kk][lx] = Wl[(size_t)(k0 + kk) * N + n0 + lx];
    }
    __syncthreads();
    #pragma unroll
    for (int j = 0; j < 4; ++j) {
        int nr = ly + j * 8;
        Wo[(size_t)(n0 + nr) * K + k0 + lx] = __float2bfloat16(tile[lx][nr]);
    }
}

// ---------------- cc_w [L][O][I][3] f32 -> ccT [L][O][tap*512+I] bf16 (tap-major K for fused conv GEMM) ----------------
__global__ __launch_bounds__(256) void ccconv_kernel(const float* __restrict__ ccw, bh16* __restrict__ ccT)
{
    size_t idx = (size_t)blockIdx.x * 256 + threadIdx.x;   // 6*512*1536
    int i = idx & 511; size_t rem = idx >> 9;
    int tap = (int)(rem % 3); rem /= 3;
    int o = (int)(rem & 511); int l = (int)(rem >> 9);
    ccT[idx] = __float2bfloat16(ccw[(((size_t)l*512 + o)*512 + i)*3 + tap]);
}

// ---------------- qkv bias concat: [L][1536] ----------------
__global__ __launch_bounds__(256) void qkvbias_kernel(const float* __restrict__ qb_, const float* __restrict__ kb_,
                                                      const float* __restrict__ vb_, float* __restrict__ ob)
{
    int idx = blockIdx.x * 256 + threadIdx.x;   // 6*1536
    if (idx >= 6 * 1536) return;
    int l = idx / 1536, n = idx % 1536;
    float v = (n < 512) ? qb_[l*512 + n] : (n < 1024) ? kb_[l*512 + n - 512] : vb_[l*512 + n - 1024];
    ob[idx] = v;
}

// ---------------- x f32 -> bf16 ----------------
__global__ __launch_bounds__(256) void convx_kernel(const float* __restrict__ x, bh16* __restrict__ xb)
{
    size_t idx = (size_t)blockIdx.x * 256 + threadIdx.x;
    xb[idx] = __float2bfloat16(x[idx]);
}

// ---------------- E matrix: row (t,b) = [sched[t]*noise[t,b,:] | temb[t]] (bf16, 160x1024) ----------------
__global__ __launch_bounds__(256) void build_E_kernel(const float* __restrict__ noise, const float* __restrict__ sched,
                                                      bh16* __restrict__ E)
{
    int idx = blockIdx.x * 256 + threadIdx.x;   // 10*16*1024
    if (idx >= SS * BB * 1024) return;
    int k = idx & 1023; int rem = idx >> 10; int b = rem & 15; int t = rem >> 4;
    float v;
    if (k < 512) {
        v = sched[t] * noise[((size_t)t * BB + b) * 512 + k];
    } else {
        int j = k - 512;
        const float kfac = -9.210340371976184f / 255.f;   // -ln(10000)/255
        v = (j < 256) ? sinf((float)t * expf((float)j * kfac))
                      : cosf((float)t * expf((float)(j - 256) * kfac));
    }
    E[idx] = __float2bfloat16(v);
}

// ---------------- head helpers ----------------
__global__ void init_kernel(bh16* zp, float* loss)
{
    int t = threadIdx.x;
    if (t < 64) zp[t] = __float2bfloat16(0.f);
    if (t == 64) *loss = 0.f;
}

__global__ __launch_bounds__(256) void build_cat16_kernel(const float* __restrict__ h, bh16* __restrict__ catb)
{
    int idx = blockIdx.x * 256 + threadIdx.x;   // 16*1024
    if (idx >= BB * 1024) return;
    int k = idx & 1023, b = idx >> 10;
    float v = (k < 512) ? h[((size_t)b * TT + 255) * DD + k]
                        : h[((size_t)b * TT + 254) * DD + (k - 512)];
    catb[idx] = __float2bfloat16(v);
}

__global__ __launch_bounds__(256) void cur_init2_kernel(const float* __restrict__ h, const float* __restrict__ mix,
                                                        float* __restrict__ curf, bh16* __restrict__ curb)
{
    int idx = blockIdx.x * 256 + threadIdx.x;   // 16*512
    if (idx >= BB * DD) return;
    int c = idx & 511, b = idx >> 9;
    float v = h[((size_t)b * TT + 255) * DD + c] + mix[idx];
    curf[idx] = v;
    curb[idx] = __float2bfloat16(v);
}

__global__ void fail_kernel(float* p) { p[0] = 1e30f; }

// =====================================================================================
extern "C" void kernel_launch(void* const* d_in, const int* in_sizes, int n_in,
                              void* d_out, int out_size, void* d_ws, size_t ws_size,
                              hipStream_t stream)
{
    const float* x      = (const float*)d_in[0];
    const float* in_w   = (const float*)d_in[1];
    const float* in_b   = (const float*)d_in[2];
    const float* gq_w   = (const float*)d_in[3];
    const float* gq_b   = (const float*)d_in[4];
    const float* gk_w   = (const float*)d_in[5];
    const float* gk_b   = (const float*)d_in[6];
    const float* gv_w   = (const float*)d_in[7];
    const float* gv_b   = (const float*)d_in[8];
    const float* go_w   = (const float*)d_in[9];
    const float* go_b   = (const float*)d_in[10];
    const float* curv   = (const float*)d_in[11];
    const float* wav0   = (const float*)d_in[12];
    const float* wav1   = (const float*)d_in[13];
    const float* wav2   = (const float*)d_in[14];
    const float* wav3   = (const float*)d_in[15];
    const float* wrec_w = (const float*)d_in[16];
    const float* wrec_b = (const float*)d_in[17];
    const float* te1_w  = (const float*)d_in[18];
    const float* te1_b  = (const float*)d_in[19];
    const float* te2_w  = (const float*)d_in[20];
    const float* te2_b  = (const float*)d_in[21];
    const float* td1_w  = (const float*)d_in[22];
    const float* td1_b  = (const float*)d_in[23];
    const float* td2_w  = (const float*)d_in[24];
    const float* td2_b  = (const float*)d_in[25];
    const float* bd_w   = (const float*)d_in[26];
    const float* bd_b   = (const float*)d_in[27];
    const float* cc_w   = (const float*)d_in[28];
    const float* cc_b   = (const float*)d_in[29];
    const float* ln_g   = (const float*)d_in[30];
    const float* ln_b   = (const float*)d_in[31];
    const float* mm1_w  = (const float*)d_in[32];
    const float* mm1_b  = (const float*)d_in[33];
    const float* mm2_w  = (const float*)d_in[34];
    const float* mm2_b  = (const float*)d_in[35];
    const float* dn1_w  = (const float*)d_in[36];
    const float* dn1_b  = (const float*)d_in[37];
    const float* dn2_w  = (const float*)d_in[38];
    const float* dn2_b  = (const float*)d_in[39];
    const float* dn3_w  = (const float*)d_in[40];
    const float* dn3_b  = (const float*)d_in[41];
    const float* out_w  = (const float*)d_in[42];
    const float* out_b  = (const float*)d_in[43];
    const float* nsched = (const float*)d_in[44];
    const float* noise  = (const float*)d_in[45];
    float* out = (float*)d_out;
    float* ws  = (float*)d_ws;

    // ---- fp32 workspace layout (float offsets) ----
    const size_t o_h   = 0;          // 2097152
    const size_t o_dec = 2097152;    // 2097152 (pre1 for head: 81920)
    const size_t o_s   = 4194304;    // 2097152
    const size_t o_tf  = 6291456;    // 262144
    const size_t o_qn  = 6553600;    // 32768
    const size_t o_kn  = 6586368;    // 32768
    const size_t o_at  = 6619136;    // 8388608
    const size_t o_fl  = 15007744;   // 30720
    const size_t o_mix = 15038464;   // 8192
    const size_t o_cur = 15046656;   // 8192
    const size_t o_qkb = 15054848;   // 9216 (qkv bias [6][1536])
    const size_t FP32_TOTAL = 15095808;
    // ---- bf16 region (element offsets from bp) ----
    const size_t b_xb   = 0;          // 1572864
    const size_t b_hb   = 1572864;    // 2097152
    const size_t b_qkv  = 3670016;    // 6291456: packed qkv [4096][1536]
    const size_t b_vt   = 9961472;    // 2097152
    const size_t b_pb   = 12058624;   // 8388608 (head scratch aliases here after layers)
    const size_t b_gmb  = 20447232;   // 2097152
    const size_t b_tdb  = 22544384;   // 2097152
    const size_t b_t1b  = 24641536;   // 262144
    const size_t b_tfb  = 24903680;   // 262144
    const size_t b_zp   = 25165824;   // 512
    const size_t b_inwT = 25166336;   // 196608
    const size_t b_qkvT = 25362944;   // 4718592: [6][1536][512]
    const size_t b_goT  = 30081536;   // 1572864
    const size_t b_wrT  = 31654400;   // 6291456
    const size_t b_td1T = 37945856;   // 196608
    const size_t b_td2T = 38142464;   // 1572864
    const size_t b_te1T = 39715328;   // 196608
    const size_t b_te2T = 39911936;   // 24576
    const size_t b_ccT  = 39936512;   // 4718592: [6][512][1536]
    const size_t BF16_TOTAL = 44655104;
    const size_t TOTAL_BYTES = FP32_TOTAL * 4 + BF16_TOTAL * 2;
    if (ws_size < TOTAL_BYTES) { fail_kernel<<<1, 1, 0, stream>>>(out); return; }

    float* h_   = ws + o_h;
    float* dec_ = ws + o_dec;
    float* s_   = ws + o_s;
    float* tf_  = ws + o_tf;
    float* qn_  = ws + o_qn;
    float* kn_  = ws + o_kn;
    float* at_  = ws + o_at;
    float* fl_  = ws + o_fl;
    float* mixb = ws + o_mix;
    float* curf = ws + o_cur;
    float* qkvbias = ws + o_qkb;
    bh16* bp   = (bh16*)(ws + FP32_TOTAL);
    bh16* xb   = bp + b_xb;
    bh16* hb   = bp + b_hb;
    bh16* qkvb = bp + b_qkv;
    bh16* vt   = bp + b_vt;
    bh16* pb   = bp + b_pb;
    bh16* gmb  = bp + b_gmb;
    bh16* tdb  = bp + b_tdb;
    bh16* t1b  = bp + b_t1b;
    bh16* tfb  = bp + b_tfb;
    bh16* zp   = bp + b_zp;
    bh16* inwT = bp + b_inwT;
    bh16* qkvT = bp + b_qkvT;
    bh16* goT  = bp + b_goT;
    bh16* wrT  = bp + b_wrT;
    bh16* td1T = bp + b_td1T;
    bh16* td2T = bp + b_td2T;
    bh16* te1T = bp + b_te1T;
    bh16* te2T = bp + b_te2T;
    bh16* ccT  = bp + b_ccT;
    bh16* combb = (bh16*)at_;   // aliases at_ after softmax consumed it

    // head bf16 scratch: aliased into pb region (dead after layer loop)
    bh16* dn1T  = pb;             // 524288
    bh16* dn2T  = pb + 524288;    // 262144
    bh16* dn3T  = pb + 786432;    // 262144
    bh16* mm1T  = pb + 1048576;   // 524288
    bh16* mm2T  = pb + 1572864;   // 262144
    bh16* outT  = pb + 1835008;   // 196608
    bh16* E16   = pb + 2031616;   // 163840
    bh16* cat16 = pb + 2195456;   // 16384
    bh16* tmb16 = pb + 2211840;   // 8192
    bh16* cur16 = pb + 2220032;   // 8192
    bh16* d1b16 = pb + 2228224;   // 8192
    bh16* d2b16 = pb + 2236416;   // 8192
    float* pre1 = dec_;           // 81920 f32, aliases dec_ after layers

    auto mg = [&](const bh16* A, int lda, const bh16* Bt, int ldb,
                  const float* bias, float* Cf, bh16* Cb, int ldc,
                  int M, int N, int K, int shift, int accum, int act,
                  int nb, int zmask, int zshift,
                  long aS1, long aS0, long bS1, long bS0, long cS1, long cS0, int ccdil) {
        dim3 g(N / 64, M / 128, nb);
        mgemm_kernel<<<g, 256, 0, stream>>>(A, lda, Bt, ldb, bias, Cf, Cb, ldc, N, K,
                                            shift, accum, act, zmask, zshift,
                                            aS1, aS0, bS1, bS0, cS1, cS0, ccdil, zp);
    };
    auto mgp = [&](const bh16* A, int lda, const bh16* Bt, int ldb,
                   const float* bias, float* Cf, bh16* Cb, int ldc,
                   int M, int N, int K, int shift, int accum, int act) {
        mg(A, lda, Bt, ldb, bias, Cf, Cb, ldc, M, N, K, shift, accum, act, 1, 0, 0, 0, 0, 0, 0, 0, 0, 0);
    };
    auto hg = [&](const bh16* A, int lda, long aZ, const bh16* Bt, int ldb,
                  const float* bias, const float* pre, float* Of, bh16* Ob, long oZ,
                  int N, int K, int act, float* cf, bh16* cb, const float* sp, int nz) {
        hgemm16_kernel<<<dim3(N / 64, 1, nz), 256, 0, stream>>>(
            A, lda, aZ, Bt, ldb, bias, pre, Of, Ob, oZ, N, K, act, cf, cb, sp);
    };

    // ---- setup: zero page/loss, converts ----
    init_kernel<<<1, 128, 0, stream>>>(zp, out + BB * DIN);
    convx_kernel<<<BT * DIN / 256, 256, 0, stream>>>(x, xb);
    wtrans_kernel<<<dim3(DD/32, DIN/32, 1), 256, 0, stream>>>(in_w, inwT, DIN, DD, (long)DIN*DD);
    // packed qkvT: rows 0-511 q, 512-1023 k, 1024-1535 v; l-stride 786432
    wtrans_kernel<<<dim3(16, 16, 6), 256, 0, stream>>>(gq_w, qkvT,          DD, DD, 786432L);
    wtrans_kernel<<<dim3(16, 16, 6), 256, 0, stream>>>(gk_w, qkvT + 262144, DD, DD, 786432L);
    wtrans_kernel<<<dim3(16, 16, 6), 256, 0, stream>>>(gv_w, qkvT + 524288, DD, DD, 786432L);
    qkvbias_kernel<<<36, 256, 0, stream>>>(gq_b, gk_b, gv_b, qkvbias);
    wtrans_kernel<<<dim3(16, 16, 6), 256, 0, stream>>>(go_w, goT, DD, DD, (long)DD*DD);
    wtrans_kernel<<<dim3(16, 64, 6), 256, 0, stream>>>(wrec_w, wrT, 2048, DD, 2048L*DD);
    wtrans_kernel<<<dim3(16, 2, 6), 256, 0, stream>>>(td1_w, td1T, PP, DD, (long)PP*DD);
    wtrans_kernel<<<dim3(16, 16, 6), 256, 0, stream>>>(td2_w, td2T, DD, DD, (long)DD*DD);
    wtrans_kernel<<<dim3(2, 16, 6), 256, 0, stream>>>(te1_w, te1T, DD, PP, (long)DD*PP);
    wtrans_kernel<<<dim3(2, 2, 6), 256, 0, stream>>>(te2_w, te2T, PP, PP, (long)PP*PP);
    ccconv_kernel<<<18432, 256, 0, stream>>>(cc_w, ccT);

    // h = x @ in_w + in_b  (fp32 + bf16)
    mgp(xb, DIN, inwT, DIN, in_b, h_, hb, DD, BT, DD, DIN, 0, 0, ACT_NONE);

    for (int l = 0; l < LL; ++l) {
        // fused q|k|v projection: N=1536, packed output [BT][1536]
        mgp(hb, DD, qkvT + (size_t)l*786432, DD, qkvbias + (size_t)l*1536,
            nullptr, qkvb, 1536, BT, 1536, DD, 0, 0, ACT_NONE);
        // attention
        sqnorm2_kernel<<<dim3(8192, 2), 256, 0, stream>>>(qkvb, qn_, kn_);
        mg(qkvb, 1536, qkvb + 512, 1536, nullptr, at_, nullptr, TT, TT, TT, 64, 0, 0, ACT_NONE,
           128, 7, 3, 393216, 64, 393216, 64, 524288, 65536, 0);
        attn_softmax_kernel<<<8192, 256, 0, stream>>>(at_, pb, qn_, kn_, curv + (size_t)l*HH);
        vtrans_kernel<<<dim3(4, 128), 256, 0, stream>>>(qkvb + 1024, vt);
        mg(pb, TT, vt, TT, nullptr, nullptr, gmb, DD, TT, 64, TT, 0, 0, ACT_NONE,
           128, 7, 3, 524288, 65536, 131072, 16384, 131072, 64, 0);
        mgp(gmb, DD, goT + (size_t)l*262144, DD, go_b + (size_t)l*DD, s_, nullptr, DD, BT, DD, DD, 0, 0, ACT_NONE);
        // wavelet branch: merged-stream streaming kernel (comb aliases at_, softmax already consumed it)
        filt_softmax_kernel<<<8, 256, 0, stream>>>(wav0 + (size_t)l*DD*4, wav1 + (size_t)l*DD*8,
                                                   wav2 + (size_t)l*DD*16, wav3 + (size_t)l*DD*32, fl_);
        wave3_kernel<<<4096, 256, 0, stream>>>(hb, fl_, combb);
        mgp(combb, 2048, wrT + (size_t)l*1048576, 2048, wrec_b + (size_t)l*DD, s_, nullptr, DD, BT, DD, 2048, 0, 1, ACT_NONE);
        // topo branch
        mgp(hb, DD, te1T + (size_t)l*32768, DD, te1_b + (size_t)l*PP, nullptr, t1b, PP, BT, PP, DD, 0, 0, ACT_RELU);
        mgp(t1b, PP, te2T + (size_t)l*4096, PP, te2_b + (size_t)l*PP, tf_, tfb, PP, BT, PP, PP, 0, 0, ACT_NONE);
        bd_loss_kernel<<<32, 256, 0, stream>>>(tf_, bd_w + (size_t)l*PP*2, bd_b + (size_t)l*2, out + BB*DIN);
        mgp(tfb, PP, td1T + (size_t)l*32768, PP, td1_b + (size_t)l*DD, nullptr, tdb, DD, BT, DD, PP, 0, 0, ACT_RELU);
        mgp(tdb, DD, td2T + (size_t)l*262144, DD, td2_b + (size_t)l*DD, s_, nullptr, DD, BT, DD, DD, 0, 1, ACT_NONE);
        // fused causal dilated conv: single K=1536 GEMM, per-K-tile shift schedule
        int dil = 1 << l;
        mg(hb, DD, ccT + (size_t)l*786432, 1536, cc_b + (size_t)l*DD,
           s_, nullptr, DD, BT, DD, 1536, 0, 1, ACT_NONE, 1, 0, 0, 0, 0, 0, 0, 0, 0, dil);
        // h = LN(s + h)
        add_ln_kernel<<<BT/4, 256, 0, stream>>>(s_, h_, hb, ln_g, ln_b);
    }

    // ---- head: convert weights (into dead pb region), precompute E/pre1 ----
    wtrans_kernel<<<dim3(16, 32, 1), 256, 0, stream>>>(dn1_w, dn1T, 1024, 512, 0L);
    wtrans_kernel<<<dim3(16, 16, 1), 256, 0, stream>>>(dn2_w, dn2T, 512, 512, 0L);
    wtrans_kernel<<<dim3(16, 16, 1), 256, 0, stream>>>(dn3_w, dn3T, 512, 512, 0L);
    wtrans_kernel<<<dim3(16, 32, 1), 256, 0, stream>>>(mm1_w, mm1T, 1024, 512, 0L);
    wtrans_kernel<<<dim3(16, 16, 1), 256, 0, stream>>>(mm2_w, mm2T, 512, 512, 0L);
    wtrans_kernel<<<dim3(12, 16, 1), 256, 0, stream>>>(out_w, outT, 512, 384, 0L);
    build_E_kernel<<<640, 256, 0, stream>>>(noise, nsched, E16);
    // pre1[t] = E_t @ dn1_w + dn1_b   (z-batched over t)
    hg(E16, 1024, 16*1024, dn1T, 1024, dn1_b, nullptr, pre1, nullptr, 8192,
       512, 1024, ACT_NONE, nullptr, nullptr, nullptr, SS);
    // mix head
    build_cat16_kernel<<<64, 256, 0, stream>>>(h_, cat16);
    hg(cat16, 1024, 0, mm1T, 1024, mm1_b, nullptr, nullptr, tmb16, 0,
       512, 1024, ACT_TANH, nullptr, nullptr, nullptr, 1);
    hg(tmb16, 512, 0, mm2T, 512, mm2_b, nullptr, mixb, nullptr, 0,
       512, 512, ACT_NONE, nullptr, nullptr, nullptr, 1);
    cur_init2_kernel<<<32, 256, 0, stream>>>(h_, mixb, curf, cur16);
    // diffusion chain: 3 launches per step
    for (int t = 0; t < SS; ++t) {
        hg(cur16, 512, 0, dn1T, 1024, nullptr, pre1 + (size_t)t*8192, nullptr, d1b16, 0,
           512, 512, ACT_SILU, nullptr, nullptr, nullptr, 1);
        hg(d1b16, 512, 0, dn2T, 512, dn2_b, nullptr, nullptr, d2b16, 0,
           512, 512, ACT_SILU, nullptr, nullptr, nullptr, 1);
        hg(d2b16, 512, 0, dn3T, 512, dn3_b, nullptr, nullptr, nullptr, 0,
           512, 512, ACT_NONE, curf, cur16, nsched + t, 1);
    }
    // pred = cur @ out_w + out_b
    hg(cur16, 512, 0, outT, 512, out_b, nullptr, out, nullptr, 0,
       384, 512, ACT_NONE, nullptr, nullptr, nullptr, 1);
}

// Round 9
// 1889.052 us; speedup vs baseline: 1.1637x; 1.1331x over previous
//
#include <hip/hip_runtime.h>
#include <hip/hip_bf16.h>
#include <math.h>

#define BB 16
#define TT 256
#define DIN 384
#define DD 512
#define LL 6
#define HH 8
#define PP 64
#define SS 10
#define BT (BB*TT)   // 4096

enum { ACT_NONE=0, ACT_RELU=1, ACT_TANH=2, ACT_SILU=3 };

typedef __attribute__((ext_vector_type(8))) short bf16x8;
typedef __attribute__((ext_vector_type(4))) float f32x4;
typedef __hip_bfloat16 bh16;

typedef const __attribute__((address_space(1))) void gvoid_t;
typedef __attribute__((address_space(3))) void lvoid_t;
__device__ __forceinline__ void gload16(const void* g, void* l) {
    __builtin_amdgcn_global_load_lds((gvoid_t*)g, (lvoid_t*)l, 16, 0, 0);
}

__device__ __forceinline__ float b2f(unsigned short u) {
    return __uint_as_float(((unsigned int)u) << 16);
}

// =====================================================================================
// Generic bf16 MFMA GEMM: C = act(A @ Bt^T + bias)  (Bt stored [N][K])
// BM=128, BN=64, BK=64; 4 waves 2x2, wave tile 64x32 (4x2 frags of 16x16).
// Optional batch dim z; shift row-masking; ccdil fused 3-tap causal conv (see r5 notes).
__global__ __launch_bounds__(256) void mgemm_kernel(
    const bh16* __restrict__ A, int lda,
    const bh16* __restrict__ Bt, int ldb,
    const float* __restrict__ bias,
    float* __restrict__ Cf, bh16* __restrict__ Cb, int ldc,
    int N, int K, int shift, int accum, int act,
    int zmask, int zshift,
    long aS1, long aS0, long bS1, long bS0, long cS1, long cS0,
    int ccdil,
    const bh16* __restrict__ zp)
{
    __shared__ bf16x8 As[128*8];   // 16KB: [row][8 chunks], chunk XOR-swizzled by row&7
    __shared__ bf16x8 Bs[64*8];    // 8KB

    int z = blockIdx.z;
    long z1 = (long)(z >> zshift), z0 = (long)(z & zmask);
    A  += z1*aS1 + z0*aS0;
    Bt += z1*bS1 + z0*bS0;
    long coff = z1*cS1 + z0*cS0;

    const int tid  = threadIdx.x;
    const int lane = tid & 63, w = tid >> 6;
    const int wm = w >> 1, wn = w & 1;
    const int row0 = blockIdx.y * 128, col0 = blockIdx.x * 64;

    f32x4 acc[4][2];
    #pragma unroll
    for (int i = 0; i < 4; ++i)
        #pragma unroll
        for (int j = 0; j < 2; ++j) acc[i][j] = (f32x4){0.f,0.f,0.f,0.f};

    const int nkt = K >> 6;
    for (int kt = 0; kt < nkt; ++kt) {
        int k0 = kt << 6;
        int mask_sh, addr_sh;
        if (ccdil) {
            int tap = kt >> 3;
            mask_sh = (2 - tap) * ccdil;
            addr_sh = mask_sh + tap;      // compensates k0 row-aliasing (lda=512, k0 carries tap*512)
        } else {
            mask_sh = shift; addr_sh = shift;
        }
        // stage A: 1024 16B-chunks, 4 instr/wave
        #pragma unroll
        for (int j = 0; j < 4; ++j) {
            int c = ((w*4 + j) << 6) + lane;
            int row = c >> 3, chk = c & 7;
            int schk = chk ^ (row & 7);
            int grow = row0 + row;
            const bh16* src = ((grow & 255) >= mask_sh)
                ? (A + (size_t)(grow - addr_sh)*lda + k0 + schk*8) : zp;
            gload16(src, &As[(w*4 + j) * 64]);
        }
        // stage B: 512 chunks, 2 instr/wave
        #pragma unroll
        for (int j = 0; j < 2; ++j) {
            int c = ((w*2 + j) << 6) + lane;
            int row = c >> 3, chk = c & 7;
            int schk = chk ^ (row & 7);
            int gcol = col0 + row;
            const bh16* src = (gcol < N)
                ? (Bt + (size_t)gcol*ldb + k0 + schk*8) : zp;
            gload16(src, &Bs[(w*2 + j) * 64]);
        }
        asm volatile("s_waitcnt vmcnt(0)" ::: "memory");
        __syncthreads();

        bf16x8 a[4][2], b[2][2];
        #pragma unroll
        for (int fm = 0; fm < 4; ++fm) {
            int row = wm*64 + fm*16 + (lane & 15);
            #pragma unroll
            for (int ks = 0; ks < 2; ++ks)
                a[fm][ks] = As[row*8 + ((ks*4 + (lane>>4)) ^ (row & 7))];
        }
        #pragma unroll
        for (int fn = 0; fn < 2; ++fn) {
            int col = wn*32 + fn*16 + (lane & 15);
            #pragma unroll
            for (int ks = 0; ks < 2; ++ks)
                b[fn][ks] = Bs[col*8 + ((ks*4 + (lane>>4)) ^ (col & 7))];
        }
        #pragma unroll
        for (int ks = 0; ks < 2; ++ks)
            #pragma unroll
            for (int fm = 0; fm < 4; ++fm)
                #pragma unroll
                for (int fn = 0; fn < 2; ++fn)
                    acc[fm][fn] = __builtin_amdgcn_mfma_f32_16x16x32_bf16(
                        a[fm][ks], b[fn][ks], acc[fm][fn], 0, 0, 0);
        __syncthreads();
    }

    // epilogue: D[row][col], col=lane&15, row=(lane>>4)*4+r
    #pragma unroll
    for (int fm = 0; fm < 4; ++fm) {
        #pragma unroll
        for (int fn = 0; fn < 2; ++fn) {
            int gc = col0 + wn*32 + fn*16 + (lane & 15);
            float bs = bias ? bias[gc] : 0.f;
            #pragma unroll
            for (int r = 0; r < 4; ++r) {
                int gr = row0 + wm*64 + fm*16 + (lane>>4)*4 + r;
                float v = acc[fm][fn][r] + bs;
                if (act == ACT_RELU) v = fmaxf(v, 0.f);
                size_t o = (size_t)gr*ldc + gc + coff;
                if (Cf) { if (accum) Cf[o] += v; else Cf[o] = v; }
                if (Cb) Cb[o] = __float2bfloat16(v);
            }
        }
    }
}

// =====================================================================================
// Small-M (M=16) MFMA GEMM, one wave = 16x16xK tile, no LDS.
__global__ __launch_bounds__(256) void hgemm16_kernel(
    const bh16* __restrict__ A, int lda, long aZ,
    const bh16* __restrict__ Bt, int ldb,
    const float* __restrict__ bias,
    const float* __restrict__ pre,
    float* __restrict__ Of, bh16* __restrict__ Ob, long oZ,
    int N, int K, int act,
    float* __restrict__ curf, bh16* __restrict__ curb,
    const float* __restrict__ scaleptr)
{
    const int z = blockIdx.z;
    A += (long)z * aZ;
    const int lane = threadIdx.x & 63, w = threadIdx.x >> 6;
    const int col0 = blockIdx.x * 64 + w * 16;
    const int ar = lane & 15;
    const int koff = (lane >> 4) * 8;
    const bh16* arow = A + (size_t)ar * lda + koff;
    const bh16* brow = Bt + (size_t)(col0 + ar) * ldb + koff;
    f32x4 acc = {0.f, 0.f, 0.f, 0.f};
    const int nkt = K >> 5;
    for (int kt0 = 0; kt0 < nkt; kt0 += 8) {
        bf16x8 av[8], bv[8];
        #pragma unroll
        for (int j = 0; j < 8; ++j) {
            av[j] = *(const bf16x8*)(arow + (size_t)(kt0 + j) * 32);
            bv[j] = *(const bf16x8*)(brow + (size_t)(kt0 + j) * 32);
        }
        #pragma unroll
        for (int j = 0; j < 8; ++j)
            acc = __builtin_amdgcn_mfma_f32_16x16x32_bf16(av[j], bv[j], acc, 0, 0, 0);
    }
    const int col = col0 + ar;
    float bs = bias ? bias[col] : 0.f;
    float sc = scaleptr ? *scaleptr : 0.f;
    #pragma unroll
    for (int r = 0; r < 4; ++r) {
        int row = (lane >> 4) * 4 + r;
        float v = acc[r] + bs;
        if (pre) v += pre[(size_t)row * N + col];
        if (act == ACT_SILU)      v = v / (1.f + expf(-v));
        else if (act == ACT_TANH) v = tanhf(v);
        if (curf) {
            size_t o = (size_t)row * 512 + col;
            float nc = curf[o] - v * sc;
            curf[o] = nc;
            curb[o] = __float2bfloat16(nc);
        } else {
            size_t o = (size_t)z * oZ + (size_t)row * N + col;
            if (Of) Of[o] = v;
            if (Ob) Ob[o] = __float2bfloat16(v);
        }
    }
}

// ---------------- per-head squared norms from packed qkv (lda=1536) ----------------
__global__ __launch_bounds__(256) void sqnorm2_kernel(const bh16* __restrict__ qkv,
                                                      float* __restrict__ qn, float* __restrict__ kn)
{
    int lane = threadIdx.x & 63, wid = threadIdx.x >> 6;
    int row = blockIdx.x * 4 + wid;            // over B*H*T
    const bh16* src = qkv + (blockIdx.y ? 512 : 0);
    float* dst = blockIdx.y ? kn : qn;
    int t = row & 255; int bh = row >> 8; int b = bh >> 3, hh = bh & 7;
    float v = __bfloat162float(src[((size_t)b * TT + t) * 1536 + hh * 64 + lane]);
    float s = v * v;
    #pragma unroll
    for (int off = 32; off; off >>= 1) s += __shfl_xor(s, off);
    if (lane == 0) dst[row] = s;
}

// ---------------- hyperbolic distance + softmax: fp32 logits in, bf16 probs out ----------------
__global__ __launch_bounds__(256) void attn_softmax_kernel(const float* __restrict__ at, bh16* __restrict__ pb,
                                                           const float* __restrict__ qn,
                                                           const float* __restrict__ kn,
                                                           const float* __restrict__ curv)
{
    int lane = threadIdx.x & 63, wid = threadIdx.x >> 6;
    int row = blockIdx.x * 4 + wid;            // over B*H*T
    int i = row & 255; int bh = row >> 8; int hh = bh & 7;
    float c = fabsf(curv[hh]) + 1e-8f;
    float inv_sqrt_c = 1.f / sqrtf(c);
    float qni = qn[row];
    const float* srow = at + (size_t)bh * TT * TT + (size_t)i * TT;
    bh16* prow = pb + (size_t)bh * TT * TT + (size_t)i * TT;
    const float* knr = kn + (size_t)bh * TT;
    float logit[4];
    float mx = -1e30f;
    #pragma unroll
    for (int u = 0; u < 4; ++u) {
        int j = lane + u * 64;
        float s = srow[j];
        float knj = knr[j];
        float d2 = fmaxf(qni + knj - 2.f * s, 0.f);
        float denom = fmaxf((1.f - c * qni) * (1.f - c * knj), 1e-5f);
        float arg = fmaxf(1.f + (2.f * c * d2) / denom, 1.00001f);
        float dist = logf(arg + sqrtf((arg - 1.f) * (arg + 1.f))) * inv_sqrt_c;
        logit[u] = -dist;
        mx = fmaxf(mx, logit[u]);
    }
    #pragma unroll
    for (int off = 32; off; off >>= 1) mx = fmaxf(mx, __shfl_xor(mx, off));
    float e[4]; float sum = 0.f;
    #pragma unroll
    for (int u = 0; u < 4; ++u) { e[u] = expf(logit[u] - mx); sum += e[u]; }
    #pragma unroll
    for (int off = 32; off; off >>= 1) sum += __shfl_xor(sum, off);
    float inv = 1.f / sum;
    #pragma unroll
    for (int u = 0; u < 4; ++u) prow[lane + u * 64] = __float2bfloat16(e[u] * inv);
}

// ---------------- V transpose per (b,h): packed qkv (v at +1024, lda=1536) -> vt[bh][d][t] ----------------
__global__ __launch_bounds__(256) void vtrans_kernel(const bh16* __restrict__ vb, bh16* __restrict__ vt)
{
    int bh = blockIdx.y, b = bh >> 3, hh = bh & 7;
    int t0 = blockIdx.x * 64;
    __shared__ bh16 tile[64][65];
    for (int e = threadIdx.x; e < 4096; e += 256) {
        int r = e >> 6, c = e & 63;
        tile[r][c] = vb[((size_t)(b*256 + t0 + r))*1536 + hh*64 + c];
    }
    __syncthreads();
    for (int e = threadIdx.x; e < 4096; e += 256) {
        int d = e >> 6, t2 = e & 63;
        vt[((size_t)bh*64 + d)*256 + t0 + t2] = tile[t2][d];
    }
}

// ---------------- wavelet filter softmax -> TRANSPOSED layout fT[i][k][512] ----------------
__global__ __launch_bounds__(256) void filt_softmax_kernel(const float* __restrict__ w0, const float* __restrict__ w1,
                                                           const float* __restrict__ w2, const float* __restrict__ w3,
                                                           float* __restrict__ filt)
{
    int idx = blockIdx.x * 256 + threadIdx.x;
    if (idx >= 4 * DD) return;
    int d = idx & 511, i = idx >> 9;
    const float* w = (i == 0) ? w0 : (i == 1) ? w1 : (i == 2) ? w2 : w3;
    int K = 4 << i;
    int fb = (i == 0) ? 0 : (i == 1) ? 2048 : (i == 2) ? 6144 : 14336;
    const float* row = w + (size_t)d * K;
    float mx = -1e30f;
    for (int k = 0; k < K; ++k) mx = fmaxf(mx, row[k]);
    float s = 0.f;
    for (int k = 0; k < K; ++k) s += expf(row[k] - mx);
    float inv = 1.f / s;
    float* fo = filt + fb;
    for (int k = 0; k < K; ++k) fo[k * 512 + d] = expf(row[k] - mx) * inv;   // [k][d]
}

// ---------------- wavelet: dec (small LDS tile) + interp, per (dblk, i, thalf, b) ----------------
// grid (8, 8, 16): x = dblk (64 ch), y = i*2+thalf, z = b. 256 threads. LDS ~25KB.
__global__ __launch_bounds__(256) void wave4_kernel(const bh16* __restrict__ hb,
                                                    const float* __restrict__ filtT,
                                                    bh16* __restrict__ comb)
{
    __shared__ float dtile[66 * 64];   // dec sub-tile [jcount<=66][64]
    __shared__ float ftile[32 * 64];   // filter [K<=32][64]
    const int dblk = blockIdx.x;
    const int iy = blockIdx.y;
    const int b = blockIdx.z;
    const int i = iy >> 1, thalf = iy & 1;
    const int Karr[4] = {4, 8, 16, 32};
    const int fbarr[4] = {0, 2048, 6144, 14336};
    const int K = Karr[i], sv = 2 << i, Ti = 128 >> i;
    const int fb = fbarr[i];
    const int tid = threadIdx.x;
    const int dbase = dblk * 64;
    // filter -> LDS (transposed layout already: [k][512])
    for (int e = tid; e < K * 64; e += 256) {
        int k = e >> 6, d0 = e & 63;
        ftile[k * 64 + d0] = filtT[fb + k * 512 + dbase + d0];
    }
    // dec row range needed for t in [thalf*128, thalf*128+128)
    const float invsv = 1.f / (float)sv;
    const int t0 = thalf * 128;
    float p0 = ((float)t0 + 0.5f) * invsv - 0.5f;
    p0 = fminf(fmaxf(p0, 0.f), (float)(Ti - 1));
    const int jbase = (int)p0;
    float p1 = ((float)(t0 + 127) + 0.5f) * invsv - 0.5f;
    p1 = fminf(fmaxf(p1, 0.f), (float)(Ti - 1));
    const int him = min((int)p1 + 1, Ti - 1);
    const int jcount = him - jbase + 1;     // <= 66
    __syncthreads();
    // phase 1: dec rows [jbase, jbase+jcount) for channels [dbase, dbase+64)
    const bh16* hcol = hb + (size_t)b * (TT * DD) + dbase;
    for (int e = tid; e < jcount * 64; e += 256) {
        int jl = e >> 6, d0 = e & 63;
        int j = jbase + jl;
        int tb = j * sv - (K - 1);
        float acc = 0.f;
        #pragma unroll 4
        for (int k = 0; k < K; ++k) {
            int t = tb + k;
            if (t >= 0)
                acc += b2f(*(const unsigned short*)(hcol + (size_t)t * DD + d0)) * ftile[k * 64 + d0];
        }
        dtile[jl * 64 + d0] = acc;
    }
    __syncthreads();
    // phase 2: interp 128 t values from LDS, write comb bf16
    for (int e = tid; e < 128 * 64; e += 256) {
        int tl = e >> 6, d0 = e & 63;
        int t = t0 + tl;
        float pos = ((float)t + 0.5f) * invsv - 0.5f;
        pos = fminf(fmaxf(pos, 0.f), (float)(Ti - 1));
        int lo = (int)pos;
        int hi = min(lo + 1, Ti - 1);
        float w = pos - (float)lo;
        float v = dtile[(lo - jbase) * 64 + d0] * (1.f - w) + dtile[(hi - jbase) * 64 + d0] * w;
        comb[((size_t)b * TT + t) * 2048 + i * 512 + dbase + d0] = __float2bfloat16(v);
    }
}

// ---------------- boundary loss: 32 blocks, one atomic per block ----------------
__global__ __launch_bounds__(256) void bd_loss_kernel(const float* __restrict__ tfb, const float* __restrict__ bdw,
                                                      const float* __restrict__ bdb, float* __restrict__ loss)
{
    __shared__ float wsum[4];
    int lane = threadIdx.x & 63, wid = threadIdx.x >> 6;
    float w = bdw[lane * 2] - bdw[lane * 2 + 1];
    float bconst = (bdb[0] - bdb[1]) + 0.1f;
    float acc = 0.f;
    for (int row = blockIdx.x * 4 + wid; row < BT; row += 128) {
        float vv = tfb[(size_t)row * PP + lane] * w;
        #pragma unroll
        for (int off = 32; off; off >>= 1) vv += __shfl_xor(vv, off);
        if (lane == 0) acc += fmaxf(vv + bconst, 0.f);
    }
    if (lane == 0) wsum[wid] = acc;
    __syncthreads();
    if (threadIdx.x == 0) {
        atomicAdd(loss, (wsum[0] + wsum[1] + wsum[2] + wsum[3]) * (1.f / 4096.f));
    }
}

// ---------------- h = layernorm(s + h)*g + b, dual fp32+bf16 out ----------------
__global__ __launch_bounds__(256) void add_ln_kernel(const float* __restrict__ s, float* __restrict__ h,
                                                     bh16* __restrict__ hb,
                                                     const float* __restrict__ g, const float* __restrict__ be)
{
    int lane = threadIdx.x & 63, wid = threadIdx.x >> 6;
    size_t row = (size_t)blockIdx.x * 4 + wid;
    const float* sr = s + row * DD;
    float* hr = h + row * DD;
    bh16* hbr = hb + row * DD;
    float xv[8]; float sum = 0.f;
    #pragma unroll
    for (int u = 0; u < 8; ++u) { int c = lane + u * 64; xv[u] = sr[c] + hr[c]; sum += xv[u]; }
    #pragma unroll
    for (int off = 32; off; off >>= 1) sum += __shfl_xor(sum, off);
    float mu = sum * (1.f / 512.f);
    float sq = 0.f;
    #pragma unroll
    for (int u = 0; u < 8; ++u) { float d = xv[u] - mu; sq += d * d; }
    #pragma unroll
    for (int off = 32; off; off >>= 1) sq += __shfl_xor(sq, off);
    float rstd = 1.f / sqrtf(sq * (1.f / 512.f) + 1e-5f);
    #pragma unroll
    for (int u = 0; u < 8; ++u) {
        int c = lane + u * 64;
        float v = (xv[u] - mu) * rstd * g[c] + be[c];
        hr[c] = v;
        hbr[c] = __float2bfloat16(v);
    }
}

// ---------------- weight transpose-convert: [l-sel][K][N] f32 -> out + l*lstride, [N][K] bf16 ----------------
__global__ __launch_bounds__(256) void wtrans_kernel(const float* __restrict__ W, bh16* __restrict__ Wt,
                                                     int K, int N, long lstride)
{
    int l = blockIdx.z;
    const float* Wl = W + (size_t)l * K * N;
    bh16* Wo = Wt + (size_t)l * lstride;
    __shared__ float tile[32][33];
    int n0 = blockIdx.x * 32, k0 = blockIdx.y * 32;
    int lx = threadIdx.x & 31, ly = threadIdx.x >> 5;
    #pragma unroll
    for (int j = 0; j < 4; ++j) {
        int kk = ly + j * 8;
        tile[kk][lx] = Wl[(size_t)(k0 + kk) * N + n0 + lx];
    }
    __syncthreads();
    #pragma unroll
    for (int j = 0; j < 4; ++j) {
        int nr = ly + j * 8;
        Wo[(size_t)(n0 + nr) * K + k0 + lx] = __float2bfloat16(tile[lx][nr]);
    }
}

// ---------------- cc_w [L][O][I][3] f32 -> ccT [L][O][tap*512+I] bf16 (tap-major K for fused conv GEMM) ----------------
__global__ __launch_bounds__(256) void ccconv_kernel(const float* __restrict__ ccw, bh16* __restrict__ ccT)
{
    size_t idx = (size_t)blockIdx.x * 256 + threadIdx.x;   // 6*512*1536
    int i = idx & 511; size_t rem = idx >> 9;
    int tap = (int)(rem % 3); rem /= 3;
    int o = (int)(rem & 511); int l = (int)(rem >> 9);
    ccT[idx] = __float2bfloat16(ccw[(((size_t)l*512 + o)*512 + i)*3 + tap]);
}

// ---------------- qkv bias concat: [L][1536] ----------------
__global__ __launch_bounds__(256) void qkvbias_kernel(const float* __restrict__ qb_, const float* __restrict__ kb_,
                                                      const float* __restrict__ vb_, float* __restrict__ ob)
{
    int idx = blockIdx.x * 256 + threadIdx.x;   // 6*1536
    if (idx >= 6 * 1536) return;
    int l = idx / 1536, n = idx % 1536;
    float v = (n < 512) ? qb_[l*512 + n] : (n < 1024) ? kb_[l*512 + n - 512] : vb_[l*512 + n - 1024];
    ob[idx] = v;
}

// ---------------- x f32 -> bf16 ----------------
__global__ __launch_bounds__(256) void convx_kernel(const float* __restrict__ x, bh16* __restrict__ xb)
{
    size_t idx = (size_t)blockIdx.x * 256 + threadIdx.x;
    xb[idx] = __float2bfloat16(x[idx]);
}

// ---------------- E matrix: row (t,b) = [sched[t]*noise[t,b,:] | temb[t]] (bf16, 160x1024) ----------------
__global__ __launch_bounds__(256) void build_E_kernel(const float* __restrict__ noise, const float* __restrict__ sched,
                                                      bh16* __restrict__ E)
{
    int idx = blockIdx.x * 256 + threadIdx.x;   // 10*16*1024
    if (idx >= SS * BB * 1024) return;
    int k = idx & 1023; int rem = idx >> 10; int b = rem & 15; int t = rem >> 4;
    float v;
    if (k < 512) {
        v = sched[t] * noise[((size_t)t * BB + b) * 512 + k];
    } else {
        int j = k - 512;
        const float kfac = -9.210340371976184f / 255.f;   // -ln(10000)/255
        v = (j < 256) ? sinf((float)t * expf((float)j * kfac))
                      : cosf((float)t * expf((float)(j - 256) * kfac));
    }
    E[idx] = __float2bfloat16(v);
}

// ---------------- head helpers ----------------
__global__ void init_kernel(bh16* zp, float* loss)
{
    int t = threadIdx.x;
    if (t < 64) zp[t] = __float2bfloat16(0.f);
    if (t == 64) *loss = 0.f;
}

__global__ __launch_bounds__(256) void build_cat16_kernel(const float* __restrict__ h, bh16* __restrict__ catb)
{
    int idx = blockIdx.x * 256 + threadIdx.x;   // 16*1024
    if (idx >= BB * 1024) return;
    int k = idx & 1023, b = idx >> 10;
    float v = (k < 512) ? h[((size_t)b * TT + 255) * DD + k]
                        : h[((size_t)b * TT + 254) * DD + (k - 512)];
    catb[idx] = __float2bfloat16(v);
}

__global__ __launch_bounds__(256) void cur_init2_kernel(const float* __restrict__ h, const float* __restrict__ mix,
                                                        float* __restrict__ curf, bh16* __restrict__ curb)
{
    int idx = blockIdx.x * 256 + threadIdx.x;   // 16*512
    if (idx >= BB * DD) return;
    int c = idx & 511, b = idx >> 9;
    float v = h[((size_t)b * TT + 255) * DD + c] + mix[idx];
    curf[idx] = v;
    curb[idx] = __float2bfloat16(v);
}

__global__ void fail_kernel(float* p) { p[0] = 1e30f; }

// =====================================================================================
extern "C" void kernel_launch(void* const* d_in, const int* in_sizes, int n_in,
                              void* d_out, int out_size, void* d_ws, size_t ws_size,
                              hipStream_t stream)
{
    const float* x      = (const float*)d_in[0];
    const float* in_w   = (const float*)d_in[1];
    const float* in_b   = (const float*)d_in[2];
    const float* gq_w   = (const float*)d_in[3];
    const float* gq_b   = (const float*)d_in[4];
    const float* gk_w   = (const float*)d_in[5];
    const float* gk_b   = (const float*)d_in[6];
    const float* gv_w   = (const float*)d_in[7];
    const float* gv_b   = (const float*)d_in[8];
    const float* go_w   = (const float*)d_in[9];
    const float* go_b   = (const float*)d_in[10];
    const float* curv   = (const float*)d_in[11];
    const float* wav0   = (const float*)d_in[12];
    const float* wav1   = (const float*)d_in[13];
    const float* wav2   = (const float*)d_in[14];
    const float* wav3   = (const float*)d_in[15];
    const float* wrec_w = (const float*)d_in[16];
    const float* wrec_b = (const float*)d_in[17];
    const float* te1_w  = (const float*)d_in[18];
    const float* te1_b  = (const float*)d_in[19];
    const float* te2_w  = (const float*)d_in[20];
    const float* te2_b  = (const float*)d_in[21];
    const float* td1_w  = (const float*)d_in[22];
    const float* td1_b  = (const float*)d_in[23];
    const float* td2_w  = (const float*)d_in[24];
    const float* td2_b  = (const float*)d_in[25];
    const float* bd_w   = (const float*)d_in[26];
    const float* bd_b   = (const float*)d_in[27];
    const float* cc_w   = (const float*)d_in[28];
    const float* cc_b   = (const float*)d_in[29];
    const float* ln_g   = (const float*)d_in[30];
    const float* ln_b   = (const float*)d_in[31];
    const float* mm1_w  = (const float*)d_in[32];
    const float* mm1_b  = (const float*)d_in[33];
    const float* mm2_w  = (const float*)d_in[34];
    const float* mm2_b  = (const float*)d_in[35];
    const float* dn1_w  = (const float*)d_in[36];
    const float* dn1_b  = (const float*)d_in[37];
    const float* dn2_w  = (const float*)d_in[38];
    const float* dn2_b  = (const float*)d_in[39];
    const float* dn3_w  = (const float*)d_in[40];
    const float* dn3_b  = (const float*)d_in[41];
    const float* out_w  = (const float*)d_in[42];
    const float* out_b  = (const float*)d_in[43];
    const float* nsched = (const float*)d_in[44];
    const float* noise  = (const float*)d_in[45];
    float* out = (float*)d_out;
    float* ws  = (float*)d_ws;

    // ---- fp32 workspace layout (float offsets) ----
    const size_t o_h   = 0;          // 2097152
    const size_t o_dec = 2097152;    // 2097152 (pre1 for head: 81920)
    const size_t o_s   = 4194304;    // 2097152
    const size_t o_tf  = 6291456;    // 262144
    const size_t o_qn  = 6553600;    // 32768
    const size_t o_kn  = 6586368;    // 32768
    const size_t o_at  = 6619136;    // 8388608
    const size_t o_fl  = 15007744;   // 30720
    const size_t o_mix = 15038464;   // 8192
    const size_t o_cur = 15046656;   // 8192
    const size_t o_qkb = 15054848;   // 9216 (qkv bias [6][1536])
    const size_t FP32_TOTAL = 15095808;
    // ---- bf16 region (element offsets from bp) ----
    const size_t b_xb   = 0;          // 1572864
    const size_t b_hb   = 1572864;    // 2097152
    const size_t b_qkv  = 3670016;    // 6291456: packed qkv [4096][1536]
    const size_t b_vt   = 9961472;    // 2097152
    const size_t b_pb   = 12058624;   // 8388608 (head scratch aliases here after layers)
    const size_t b_gmb  = 20447232;   // 2097152
    const size_t b_tdb  = 22544384;   // 2097152
    const size_t b_t1b  = 24641536;   // 262144
    const size_t b_tfb  = 24903680;   // 262144
    const size_t b_zp   = 25165824;   // 512
    const size_t b_inwT = 25166336;   // 196608
    const size_t b_qkvT = 25362944;   // 4718592: [6][1536][512]
    const size_t b_goT  = 30081536;   // 1572864
    const size_t b_wrT  = 31654400;   // 6291456
    const size_t b_td1T = 37945856;   // 196608
    const size_t b_td2T = 38142464;   // 1572864
    const size_t b_te1T = 39715328;   // 196608
    const size_t b_te2T = 39911936;   // 24576
    const size_t b_ccT  = 39936512;   // 4718592: [6][512][1536]
    const size_t BF16_TOTAL = 44655104;
    const size_t TOTAL_BYTES = FP32_TOTAL * 4 + BF16_TOTAL * 2;
    if (ws_size < TOTAL_BYTES) { fail_kernel<<<1, 1, 0, stream>>>(out); return; }

    float* h_   = ws + o_h;
    float* dec_ = ws + o_dec;
    float* s_   = ws + o_s;
    float* tf_  = ws + o_tf;
    float* qn_  = ws + o_qn;
    float* kn_  = ws + o_kn;
    float* at_  = ws + o_at;
    float* fl_  = ws + o_fl;
    float* mixb = ws + o_mix;
    float* curf = ws + o_cur;
    float* qkvbias = ws + o_qkb;
    bh16* bp   = (bh16*)(ws + FP32_TOTAL);
    bh16* xb   = bp + b_xb;
    bh16* hb   = bp + b_hb;
    bh16* qkvb = bp + b_qkv;
    bh16* vt   = bp + b_vt;
    bh16* pb   = bp + b_pb;
    bh16* gmb  = bp + b_gmb;
    bh16* tdb  = bp + b_tdb;
    bh16* t1b  = bp + b_t1b;
    bh16* tfb  = bp + b_tfb;
    bh16* zp   = bp + b_zp;
    bh16* inwT = bp + b_inwT;
    bh16* qkvT = bp + b_qkvT;
    bh16* goT  = bp + b_goT;
    bh16* wrT  = bp + b_wrT;
    bh16* td1T = bp + b_td1T;
    bh16* td2T = bp + b_td2T;
    bh16* te1T = bp + b_te1T;
    bh16* te2T = bp + b_te2T;
    bh16* ccT  = bp + b_ccT;
    bh16* combb = (bh16*)at_;   // aliases at_ after softmax consumed it

    // head bf16 scratch: aliased into pb region (dead after layer loop)
    bh16* dn1T  = pb;             // 524288
    bh16* dn2T  = pb + 524288;    // 262144
    bh16* dn3T  = pb + 786432;    // 262144
    bh16* mm1T  = pb + 1048576;   // 524288
    bh16* mm2T  = pb + 1572864;   // 262144
    bh16* outT  = pb + 1835008;   // 196608
    bh16* E16   = pb + 2031616;   // 163840
    bh16* cat16 = pb + 2195456;   // 16384
    bh16* tmb16 = pb + 2211840;   // 8192
    bh16* cur16 = pb + 2220032;   // 8192
    bh16* d1b16 = pb + 2228224;   // 8192
    bh16* d2b16 = pb + 2236416;   // 8192
    float* pre1 = dec_;           // 81920 f32, aliases dec_ after layers

    auto mg = [&](const bh16* A, int lda, const bh16* Bt, int ldb,
                  const float* bias, float* Cf, bh16* Cb, int ldc,
                  int M, int N, int K, int shift, int accum, int act,
                  int nb, int zmask, int zshift,
                  long aS1, long aS0, long bS1, long bS0, long cS1, long cS0, int ccdil) {
        dim3 g(N / 64, M / 128, nb);
        mgemm_kernel<<<g, 256, 0, stream>>>(A, lda, Bt, ldb, bias, Cf, Cb, ldc, N, K,
                                            shift, accum, act, zmask, zshift,
                                            aS1, aS0, bS1, bS0, cS1, cS0, ccdil, zp);
    };
    auto mgp = [&](const bh16* A, int lda, const bh16* Bt, int ldb,
                   const float* bias, float* Cf, bh16* Cb, int ldc,
                   int M, int N, int K, int shift, int accum, int act) {
        mg(A, lda, Bt, ldb, bias, Cf, Cb, ldc, M, N, K, shift, accum, act, 1, 0, 0, 0, 0, 0, 0, 0, 0, 0);
    };
    auto hg = [&](const bh16* A, int lda, long aZ, const bh16* Bt, int ldb,
                  const float* bias, const float* pre, float* Of, bh16* Ob, long oZ,
                  int N, int K, int act, float* cf, bh16* cb, const float* sp, int nz) {
        hgemm16_kernel<<<dim3(N / 64, 1, nz), 256, 0, stream>>>(
            A, lda, aZ, Bt, ldb, bias, pre, Of, Ob, oZ, N, K, act, cf, cb, sp);
    };

    // ---- setup: zero page/loss, converts ----
    init_kernel<<<1, 128, 0, stream>>>(zp, out + BB * DIN);
    convx_kernel<<<BT * DIN / 256, 256, 0, stream>>>(x, xb);
    wtrans_kernel<<<dim3(DD/32, DIN/32, 1), 256, 0, stream>>>(in_w, inwT, DIN, DD, (long)DIN*DD);
    // packed qkvT: rows 0-511 q, 512-1023 k, 1024-1535 v; l-stride 786432
    wtrans_kernel<<<dim3(16, 16, 6), 256, 0, stream>>>(gq_w, qkvT,          DD, DD, 786432L);
    wtrans_kernel<<<dim3(16, 16, 6), 256, 0, stream>>>(gk_w, qkvT + 262144, DD, DD, 786432L);
    wtrans_kernel<<<dim3(16, 16, 6), 256, 0, stream>>>(gv_w, qkvT + 524288, DD, DD, 786432L);
    qkvbias_kernel<<<36, 256, 0, stream>>>(gq_b, gk_b, gv_b, qkvbias);
    wtrans_kernel<<<dim3(16, 16, 6), 256, 0, stream>>>(go_w, goT, DD, DD, (long)DD*DD);
    wtrans_kernel<<<dim3(16, 64, 6), 256, 0, stream>>>(wrec_w, wrT, 2048, DD, 2048L*DD);
    wtrans_kernel<<<dim3(16, 2, 6), 256, 0, stream>>>(td1_w, td1T, PP, DD, (long)PP*DD);
    wtrans_kernel<<<dim3(16, 16, 6), 256, 0, stream>>>(td2_w, td2T, DD, DD, (long)DD*DD);
    wtrans_kernel<<<dim3(2, 16, 6), 256, 0, stream>>>(te1_w, te1T, DD, PP, (long)DD*PP);
    wtrans_kernel<<<dim3(2, 2, 6), 256, 0, stream>>>(te2_w, te2T, PP, PP, (long)PP*PP);
    ccconv_kernel<<<18432, 256, 0, stream>>>(cc_w, ccT);

    // h = x @ in_w + in_b  (fp32 + bf16)
    mgp(xb, DIN, inwT, DIN, in_b, h_, hb, DD, BT, DD, DIN, 0, 0, ACT_NONE);

    for (int l = 0; l < LL; ++l) {
        // fused q|k|v projection: N=1536, packed output [BT][1536]
        mgp(hb, DD, qkvT + (size_t)l*786432, DD, qkvbias + (size_t)l*1536,
            nullptr, qkvb, 1536, BT, 1536, DD, 0, 0, ACT_NONE);
        // attention
        sqnorm2_kernel<<<dim3(8192, 2), 256, 0, stream>>>(qkvb, qn_, kn_);
        mg(qkvb, 1536, qkvb + 512, 1536, nullptr, at_, nullptr, TT, TT, TT, 64, 0, 0, ACT_NONE,
           128, 7, 3, 393216, 64, 393216, 64, 524288, 65536, 0);
        attn_softmax_kernel<<<8192, 256, 0, stream>>>(at_, pb, qn_, kn_, curv + (size_t)l*HH);
        vtrans_kernel<<<dim3(4, 128), 256, 0, stream>>>(qkvb + 1024, vt);
        mg(pb, TT, vt, TT, nullptr, nullptr, gmb, DD, TT, 64, TT, 0, 0, ACT_NONE,
           128, 7, 3, 524288, 65536, 131072, 16384, 131072, 64, 0);
        mgp(gmb, DD, goT + (size_t)l*262144, DD, go_b + (size_t)l*DD, s_, nullptr, DD, BT, DD, DD, 0, 0, ACT_NONE);
        // wavelet branch: dec+interp fused, small LDS tiles (comb aliases at_)
        filt_softmax_kernel<<<8, 256, 0, stream>>>(wav0 + (size_t)l*DD*4, wav1 + (size_t)l*DD*8,
                                                   wav2 + (size_t)l*DD*16, wav3 + (size_t)l*DD*32, fl_);
        wave4_kernel<<<dim3(8, 8, 16), 256, 0, stream>>>(hb, fl_, combb);
        mgp(combb, 2048, wrT + (size_t)l*1048576, 2048, wrec_b + (size_t)l*DD, s_, nullptr, DD, BT, DD, 2048, 0, 1, ACT_NONE);
        // topo branch
        mgp(hb, DD, te1T + (size_t)l*32768, DD, te1_b + (size_t)l*PP, nullptr, t1b, PP, BT, PP, DD, 0, 0, ACT_RELU);
        mgp(t1b, PP, te2T + (size_t)l*4096, PP, te2_b + (size_t)l*PP, tf_, tfb, PP, BT, PP, PP, 0, 0, ACT_NONE);
        bd_loss_kernel<<<32, 256, 0, stream>>>(tf_, bd_w + (size_t)l*PP*2, bd_b + (size_t)l*2, out + BB*DIN);
        mgp(tfb, PP, td1T + (size_t)l*32768, PP, td1_b + (size_t)l*DD, nullptr, tdb, DD, BT, DD, PP, 0, 0, ACT_RELU);
        mgp(tdb, DD, td2T + (size_t)l*262144, DD, td2_b + (size_t)l*DD, s_, nullptr, DD, BT, DD, DD, 0, 1, ACT_NONE);
        // fused causal dilated conv: single K=1536 GEMM, per-K-tile shift schedule
        int dil = 1 << l;
        mg(hb, DD, ccT + (size_t)l*786432, 1536, cc_b + (size_t)l*DD,
           s_, nullptr, DD, BT, DD, 1536, 0, 1, ACT_NONE, 1, 0, 0, 0, 0, 0, 0, 0, 0, dil);
        // h = LN(s + h)
        add_ln_kernel<<<BT/4, 256, 0, stream>>>(s_, h_, hb, ln_g, ln_b);
    }

    // ---- head: convert weights (into dead pb region), precompute E/pre1 ----
    wtrans_kernel<<<dim3(16, 32, 1), 256, 0, stream>>>(dn1_w, dn1T, 1024, 512, 0L);
    wtrans_kernel<<<dim3(16, 16, 1), 256, 0, stream>>>(dn2_w, dn2T, 512, 512, 0L);
    wtrans_kernel<<<dim3(16, 16, 1), 256, 0, stream>>>(dn3_w, dn3T, 512, 512, 0L);
    wtrans_kernel<<<dim3(16, 32, 1), 256, 0, stream>>>(mm1_w, mm1T, 1024, 512, 0L);
    wtrans_kernel<<<dim3(16, 16, 1), 256, 0, stream>>>(mm2_w, mm2T, 512, 512, 0L);
    wtrans_kernel<<<dim3(12, 16, 1), 256, 0, stream>>>(out_w, outT, 512, 384, 0L);
    build_E_kernel<<<640, 256, 0, stream>>>(noise, nsched, E16);
    // pre1[t] = E_t @ dn1_w + dn1_b   (z-batched over t)
    hg(E16, 1024, 16*1024, dn1T, 1024, dn1_b, nullptr, pre1, nullptr, 8192,
       512, 1024, ACT_NONE, nullptr, nullptr, nullptr, SS);
    // mix head
    build_cat16_kernel<<<64, 256, 0, stream>>>(h_, cat16);
    hg(cat16, 1024, 0, mm1T, 1024, mm1_b, nullptr, nullptr, tmb16, 0,
       512, 1024, ACT_TANH, nullptr, nullptr, nullptr, 1);
    hg(tmb16, 512, 0, mm2T, 512, mm2_b, nullptr, mixb, nullptr, 0,
       512, 512, ACT_NONE, nullptr, nullptr, nullptr, 1);
    cur_init2_kernel<<<32, 256, 0, stream>>>(h_, mixb, curf, cur16);
    // diffusion chain: 3 launches per step
    for (int t = 0; t < SS; ++t) {
        hg(cur16, 512, 0, dn1T, 1024, nullptr, pre1 + (size_t)t*8192, nullptr, d1b16, 0,
           512, 512, ACT_SILU, nullptr, nullptr, nullptr, 1);
        hg(d1b16, 512, 0, dn2T, 512, dn2_b, nullptr, nullptr, d2b16, 0,
           512, 512, ACT_SILU, nullptr, nullptr, nullptr, 1);
        hg(d2b16, 512, 0, dn3T, 512, dn3_b, nullptr, nullptr, nullptr, 0,
           512, 512, ACT_NONE, curf, cur16, nsched + t, 1);
    }
    // pred = cur @ out_w + out_b
    hg(cur16, 512, 0, outT, 512, out_b, nullptr, out, nullptr, 0,
       384, 512, ACT_NONE, nullptr, nullptr, nullptr, 1);
}

// Round 10
// 1653.979 us; speedup vs baseline: 1.3291x; 1.1421x over previous
//
#include <hip/hip_runtime.h>
#include <hip/hip_bf16.h>
#include <math.h>

#define BB 16
#define TT 256
#define DIN 384
#define DD 512
#define LL 6
#define HH 8
#define PP 64
#define SS 10
#define BT (BB*TT)   // 4096

enum { ACT_NONE=0, ACT_RELU=1, ACT_TANH=2, ACT_SILU=3 };

typedef __attribute__((ext_vector_type(8))) short bf16x8;
typedef __attribute__((ext_vector_type(4))) float f32x4;
typedef __hip_bfloat16 bh16;

typedef const __attribute__((address_space(1))) void gvoid_t;
typedef __attribute__((address_space(3))) void lvoid_t;
__device__ __forceinline__ void gload16(const void* g, void* l) {
    __builtin_amdgcn_global_load_lds((gvoid_t*)g, (lvoid_t*)l, 16, 0, 0);
}

__device__ __forceinline__ float b2f(unsigned short u) {
    return __uint_as_float(((unsigned int)u) << 16);
}

// bijective chunked XCD swizzle (m204): same-XCD blocks become contiguous in
// row-major grid order -> share A panels in per-XCD L2.
__device__ __forceinline__ void xcd_swizzle(int& bx, int& by) {
    if (gridDim.z == 1) {
        int gx = gridDim.x;
        int nwg = gx * gridDim.y;
        int lid = by * gx + bx;
        int q = nwg >> 3, r = nwg & 7;
        int xcd = lid & 7, idx = lid >> 3;
        int swz = (xcd < r) ? (xcd * (q + 1) + idx) : (r * (q + 1) + (xcd - r) * q + idx);
        bx = swz % gx;
        by = swz / gx;
    }
}

// =====================================================================================
// Generic bf16 MFMA GEMM: C = act(A @ Bt^T + bias)  (Bt stored [N][K])
// BM=128, BN=64, BK=64; 4 waves 2x2, wave tile 64x32 (4x2 frags of 16x16).
// Optional batch dim z; shift row-masking; ccdil fused 3-tap causal conv (see r5 notes).
__global__ __launch_bounds__(256) void mgemm_kernel(
    const bh16* __restrict__ A, int lda,
    const bh16* __restrict__ Bt, int ldb,
    const float* __restrict__ bias,
    float* __restrict__ Cf, bh16* __restrict__ Cb, int ldc,
    int N, int K, int shift, int accum, int act,
    int zmask, int zshift,
    long aS1, long aS0, long bS1, long bS0, long cS1, long cS0,
    int ccdil,
    const bh16* __restrict__ zp)
{
    __shared__ bf16x8 As[128*8];   // 16KB: [row][8 chunks], chunk XOR-swizzled by row&7
    __shared__ bf16x8 Bs[64*8];    // 8KB

    int z = blockIdx.z;
    long z1 = (long)(z >> zshift), z0 = (long)(z & zmask);
    A  += z1*aS1 + z0*aS0;
    Bt += z1*bS1 + z0*bS0;
    long coff = z1*cS1 + z0*cS0;

    int bx = blockIdx.x, by = blockIdx.y;
    xcd_swizzle(bx, by);

    const int tid  = threadIdx.x;
    const int lane = tid & 63, w = tid >> 6;
    const int wm = w >> 1, wn = w & 1;
    const int row0 = by * 128, col0 = bx * 64;

    f32x4 acc[4][2];
    #pragma unroll
    for (int i = 0; i < 4; ++i)
        #pragma unroll
        for (int j = 0; j < 2; ++j) acc[i][j] = (f32x4){0.f,0.f,0.f,0.f};

    const int nkt = K >> 6;
    for (int kt = 0; kt < nkt; ++kt) {
        int k0 = kt << 6;
        int mask_sh, addr_sh;
        if (ccdil) {
            int tap = kt >> 3;
            mask_sh = (2 - tap) * ccdil;
            addr_sh = mask_sh + tap;      // compensates k0 row-aliasing (lda=512, k0 carries tap*512)
        } else {
            mask_sh = shift; addr_sh = shift;
        }
        // stage A: 1024 16B-chunks, 4 instr/wave
        #pragma unroll
        for (int j = 0; j < 4; ++j) {
            int c = ((w*4 + j) << 6) + lane;
            int row = c >> 3, chk = c & 7;
            int schk = chk ^ (row & 7);
            int grow = row0 + row;
            const bh16* src = ((grow & 255) >= mask_sh)
                ? (A + (size_t)(grow - addr_sh)*lda + k0 + schk*8) : zp;
            gload16(src, &As[(w*4 + j) * 64]);
        }
        // stage B: 512 chunks, 2 instr/wave
        #pragma unroll
        for (int j = 0; j < 2; ++j) {
            int c = ((w*2 + j) << 6) + lane;
            int row = c >> 3, chk = c & 7;
            int schk = chk ^ (row & 7);
            int gcol = col0 + row;
            const bh16* src = (gcol < N)
                ? (Bt + (size_t)gcol*ldb + k0 + schk*8) : zp;
            gload16(src, &Bs[(w*2 + j) * 64]);
        }
        asm volatile("s_waitcnt vmcnt(0)" ::: "memory");
        __syncthreads();

        bf16x8 a[4][2], b[2][2];
        #pragma unroll
        for (int fm = 0; fm < 4; ++fm) {
            int row = wm*64 + fm*16 + (lane & 15);
            #pragma unroll
            for (int ks = 0; ks < 2; ++ks)
                a[fm][ks] = As[row*8 + ((ks*4 + (lane>>4)) ^ (row & 7))];
        }
        #pragma unroll
        for (int fn = 0; fn < 2; ++fn) {
            int col = wn*32 + fn*16 + (lane & 15);
            #pragma unroll
            for (int ks = 0; ks < 2; ++ks)
                b[fn][ks] = Bs[col*8 + ((ks*4 + (lane>>4)) ^ (col & 7))];
        }
        #pragma unroll
        for (int ks = 0; ks < 2; ++ks)
            #pragma unroll
            for (int fm = 0; fm < 4; ++fm)
                #pragma unroll
                for (int fn = 0; fn < 2; ++fn)
                    acc[fm][fn] = __builtin_amdgcn_mfma_f32_16x16x32_bf16(
                        a[fm][ks], b[fn][ks], acc[fm][fn], 0, 0, 0);
        __syncthreads();
    }

    // epilogue: D[row][col], col=lane&15, row=(lane>>4)*4+r
    #pragma unroll
    for (int fm = 0; fm < 4; ++fm) {
        #pragma unroll
        for (int fn = 0; fn < 2; ++fn) {
            int gc = col0 + wn*32 + fn*16 + (lane & 15);
            float bs = bias ? bias[gc] : 0.f;
            #pragma unroll
            for (int r = 0; r < 4; ++r) {
                int gr = row0 + wm*64 + fm*16 + (lane>>4)*4 + r;
                float v = acc[fm][fn][r] + bs;
                if (act == ACT_RELU) v = fmaxf(v, 0.f);
                size_t o = (size_t)gr*ldc + gc + coff;
                if (Cf) { if (accum) Cf[o] += v; else Cf[o] = v; }
                if (Cb) Cb[o] = __float2bfloat16(v);
            }
        }
    }
}

// =====================================================================================
// Fused 4-segment GEMM: s = gmb@goT + comb@wrT + tdb@td2T + cc(hb)@ccT + biassum
// K = 512 + 2048 + 512 + 1536 = 4608 (72 kt of 64). M=4096, N=512. Single fp32 write.
__global__ __launch_bounds__(256) void fgemm_kernel(
    const bh16* __restrict__ A0, const bh16* __restrict__ A1,
    const bh16* __restrict__ A2, const bh16* __restrict__ A3,
    const bh16* __restrict__ B0, const bh16* __restrict__ B1,
    const bh16* __restrict__ B2, const bh16* __restrict__ B3,
    const float* __restrict__ bias, float* __restrict__ Cf,
    int dil, const bh16* __restrict__ zp)
{
    __shared__ bf16x8 As[128*8];
    __shared__ bf16x8 Bs[64*8];

    int bx = blockIdx.x, by = blockIdx.y;
    xcd_swizzle(bx, by);

    const int tid  = threadIdx.x;
    const int lane = tid & 63, w = tid >> 6;
    const int wm = w >> 1, wn = w & 1;
    const int row0 = by * 128, col0 = bx * 64;

    f32x4 acc[4][2];
    #pragma unroll
    for (int i = 0; i < 4; ++i)
        #pragma unroll
        for (int j = 0; j < 2; ++j) acc[i][j] = (f32x4){0.f,0.f,0.f,0.f};

    for (int kt = 0; kt < 72; ++kt) {
        const bh16* Aseg; const bh16* Bseg;
        int ldas, ldbs, k0, mask_sh, addr_sh;
        if (kt < 8) {
            Aseg = A0; Bseg = B0; ldas = 512; ldbs = 512;
            k0 = kt << 6; mask_sh = 0; addr_sh = 0;
        } else if (kt < 40) {
            Aseg = A1; Bseg = B1; ldas = 2048; ldbs = 2048;
            k0 = (kt - 8) << 6; mask_sh = 0; addr_sh = 0;
        } else if (kt < 48) {
            Aseg = A2; Bseg = B2; ldas = 512; ldbs = 512;
            k0 = (kt - 40) << 6; mask_sh = 0; addr_sh = 0;
        } else {
            int kl = kt - 48, tap = kl >> 3;
            Aseg = A3; Bseg = B3; ldas = 512; ldbs = 1536;
            k0 = kl << 6;
            mask_sh = (2 - tap) * dil;
            addr_sh = mask_sh + tap;   // k0 carries tap*512 at lda=512 (see mgemm ccdil note)
        }
        #pragma unroll
        for (int j = 0; j < 4; ++j) {
            int c = ((w*4 + j) << 6) + lane;
            int row = c >> 3, chk = c & 7;
            int schk = chk ^ (row & 7);
            int grow = row0 + row;
            const bh16* src = ((grow & 255) >= mask_sh)
                ? (Aseg + (size_t)(grow - addr_sh)*ldas + k0 + schk*8) : zp;
            gload16(src, &As[(w*4 + j) * 64]);
        }
        #pragma unroll
        for (int j = 0; j < 2; ++j) {
            int c = ((w*2 + j) << 6) + lane;
            int row = c >> 3, chk = c & 7;
            int schk = chk ^ (row & 7);
            int gcol = col0 + row;
            gload16(Bseg + (size_t)gcol*ldbs + k0 + schk*8, &Bs[(w*2 + j) * 64]);
        }
        asm volatile("s_waitcnt vmcnt(0)" ::: "memory");
        __syncthreads();

        bf16x8 a[4][2], b[2][2];
        #pragma unroll
        for (int fm = 0; fm < 4; ++fm) {
            int row = wm*64 + fm*16 + (lane & 15);
            #pragma unroll
            for (int ks = 0; ks < 2; ++ks)
                a[fm][ks] = As[row*8 + ((ks*4 + (lane>>4)) ^ (row & 7))];
        }
        #pragma unroll
        for (int fn = 0; fn < 2; ++fn) {
            int col = wn*32 + fn*16 + (lane & 15);
            #pragma unroll
            for (int ks = 0; ks < 2; ++ks)
                b[fn][ks] = Bs[col*8 + ((ks*4 + (lane>>4)) ^ (col & 7))];
        }
        #pragma unroll
        for (int ks = 0; ks < 2; ++ks)
            #pragma unroll
            for (int fm = 0; fm < 4; ++fm)
                #pragma unroll
                for (int fn = 0; fn < 2; ++fn)
                    acc[fm][fn] = __builtin_amdgcn_mfma_f32_16x16x32_bf16(
                        a[fm][ks], b[fn][ks], acc[fm][fn], 0, 0, 0);
        __syncthreads();
    }

    #pragma unroll
    for (int fm = 0; fm < 4; ++fm) {
        #pragma unroll
        for (int fn = 0; fn < 2; ++fn) {
            int gc = col0 + wn*32 + fn*16 + (lane & 15);
            float bs = bias[gc];
            #pragma unroll
            for (int r = 0; r < 4; ++r) {
                int gr = row0 + wm*64 + fm*16 + (lane>>4)*4 + r;
                Cf[(size_t)gr*512 + gc] = acc[fm][fn][r] + bs;
            }
        }
    }
}

// =====================================================================================
// Small-M (M=16) MFMA GEMM, one wave = 16x16xK tile, no LDS.
__global__ __launch_bounds__(256) void hgemm16_kernel(
    const bh16* __restrict__ A, int lda, long aZ,
    const bh16* __restrict__ Bt, int ldb,
    const float* __restrict__ bias,
    const float* __restrict__ pre,
    float* __restrict__ Of, bh16* __restrict__ Ob, long oZ,
    int N, int K, int act,
    float* __restrict__ curf, bh16* __restrict__ curb,
    const float* __restrict__ scaleptr)
{
    const int z = blockIdx.z;
    A += (long)z * aZ;
    const int lane = threadIdx.x & 63, w = threadIdx.x >> 6;
    const int col0 = blockIdx.x * 64 + w * 16;
    const int ar = lane & 15;
    const int koff = (lane >> 4) * 8;
    const bh16* arow = A + (size_t)ar * lda + koff;
    const bh16* brow = Bt + (size_t)(col0 + ar) * ldb + koff;
    f32x4 acc = {0.f, 0.f, 0.f, 0.f};
    const int nkt = K >> 5;
    for (int kt0 = 0; kt0 < nkt; kt0 += 8) {
        bf16x8 av[8], bv[8];
        #pragma unroll
        for (int j = 0; j < 8; ++j) {
            av[j] = *(const bf16x8*)(arow + (size_t)(kt0 + j) * 32);
            bv[j] = *(const bf16x8*)(brow + (size_t)(kt0 + j) * 32);
        }
        #pragma unroll
        for (int j = 0; j < 8; ++j)
            acc = __builtin_amdgcn_mfma_f32_16x16x32_bf16(av[j], bv[j], acc, 0, 0, 0);
    }
    const int col = col0 + ar;
    float bs = bias ? bias[col] : 0.f;
    float sc = scaleptr ? *scaleptr : 0.f;
    #pragma unroll
    for (int r = 0; r < 4; ++r) {
        int row = (lane >> 4) * 4 + r;
        float v = acc[r] + bs;
        if (pre) v += pre[(size_t)row * N + col];
        if (act == ACT_SILU)      v = v / (1.f + expf(-v));
        else if (act == ACT_TANH) v = tanhf(v);
        if (curf) {
            size_t o = (size_t)row * 512 + col;
            float nc = curf[o] - v * sc;
            curf[o] = nc;
            curb[o] = __float2bfloat16(nc);
        } else {
            size_t o = (size_t)z * oZ + (size_t)row * N + col;
            if (Of) Of[o] = v;
            if (Ob) Ob[o] = __float2bfloat16(v);
        }
    }
}

// ---------------- per-head squared norms from packed qkv (lda=1536) ----------------
__global__ __launch_bounds__(256) void sqnorm2_kernel(const bh16* __restrict__ qkv,
                                                      float* __restrict__ qn, float* __restrict__ kn)
{
    int lane = threadIdx.x & 63, wid = threadIdx.x >> 6;
    int row = blockIdx.x * 4 + wid;            // over B*H*T
    const bh16* src = qkv + (blockIdx.y ? 512 : 0);
    float* dst = blockIdx.y ? kn : qn;
    int t = row & 255; int bh = row >> 8; int b = bh >> 3, hh = bh & 7;
    float v = __bfloat162float(src[((size_t)b * TT + t) * 1536 + hh * 64 + lane]);
    float s = v * v;
    #pragma unroll
    for (int off = 32; off; off >>= 1) s += __shfl_xor(s, off);
    if (lane == 0) dst[row] = s;
}

// ---------------- hyperbolic distance + softmax: fp32 logits in, bf16 probs out ----------------
__global__ __launch_bounds__(256) void attn_softmax_kernel(const float* __restrict__ at, bh16* __restrict__ pb,
                                                           const float* __restrict__ qn,
                                                           const float* __restrict__ kn,
                                                           const float* __restrict__ curv)
{
    int lane = threadIdx.x & 63, wid = threadIdx.x >> 6;
    int row = blockIdx.x * 4 + wid;            // over B*H*T
    int i = row & 255; int bh = row >> 8; int hh = bh & 7;
    float c = fabsf(curv[hh]) + 1e-8f;
    float inv_sqrt_c = 1.f / sqrtf(c);
    float qni = qn[row];
    const float* srow = at + (size_t)bh * TT * TT + (size_t)i * TT;
    bh16* prow = pb + (size_t)bh * TT * TT + (size_t)i * TT;
    const float* knr = kn + (size_t)bh * TT;
    float logit[4];
    float mx = -1e30f;
    #pragma unroll
    for (int u = 0; u < 4; ++u) {
        int j = lane + u * 64;
        float s = srow[j];
        float knj = knr[j];
        float d2 = fmaxf(qni + knj - 2.f * s, 0.f);
        float denom = fmaxf((1.f - c * qni) * (1.f - c * knj), 1e-5f);
        float arg = fmaxf(1.f + (2.f * c * d2) / denom, 1.00001f);
        float dist = logf(arg + sqrtf((arg - 1.f) * (arg + 1.f))) * inv_sqrt_c;
        logit[u] = -dist;
        mx = fmaxf(mx, logit[u]);
    }
    #pragma unroll
    for (int off = 32; off; off >>= 1) mx = fmaxf(mx, __shfl_xor(mx, off));
    float e[4]; float sum = 0.f;
    #pragma unroll
    for (int u = 0; u < 4; ++u) { e[u] = expf(logit[u] - mx); sum += e[u]; }
    #pragma unroll
    for (int off = 32; off; off >>= 1) sum += __shfl_xor(sum, off);
    float inv = 1.f / sum;
    #pragma unroll
    for (int u = 0; u < 4; ++u) prow[lane + u * 64] = __float2bfloat16(e[u] * inv);
}

// ---------------- V transpose per (b,h): packed qkv (v at +1024, lda=1536) -> vt[bh][d][t] ----------------
__global__ __launch_bounds__(256) void vtrans_kernel(const bh16* __restrict__ vb, bh16* __restrict__ vt)
{
    int bh = blockIdx.y, b = bh >> 3, hh = bh & 7;
    int t0 = blockIdx.x * 64;
    __shared__ bh16 tile[64][65];
    for (int e = threadIdx.x; e < 4096; e += 256) {
        int r = e >> 6, c = e & 63;
        tile[r][c] = vb[((size_t)(b*256 + t0 + r))*1536 + hh*64 + c];
    }
    __syncthreads();
    for (int e = threadIdx.x; e < 4096; e += 256) {
        int d = e >> 6, t2 = e & 63;
        vt[((size_t)bh*64 + d)*256 + t0 + t2] = tile[t2][d];
    }
}

// ---------------- wavelet filter softmax -> TRANSPOSED layout fT[i][k][512] ----------------
__global__ __launch_bounds__(256) void filt_softmax_kernel(const float* __restrict__ w0, const float* __restrict__ w1,
                                                           const float* __restrict__ w2, const float* __restrict__ w3,
                                                           float* __restrict__ filt)
{
    int idx = blockIdx.x * 256 + threadIdx.x;
    if (idx >= 4 * DD) return;
    int d = idx & 511, i = idx >> 9;
    const float* w = (i == 0) ? w0 : (i == 1) ? w1 : (i == 2) ? w2 : w3;
    int K = 4 << i;
    int fb = (i == 0) ? 0 : (i == 1) ? 2048 : (i == 2) ? 6144 : 14336;
    const float* row = w + (size_t)d * K;
    float mx = -1e30f;
    for (int k = 0; k < K; ++k) mx = fmaxf(mx, row[k]);
    float s = 0.f;
    for (int k = 0; k < K; ++k) s += expf(row[k] - mx);
    float inv = 1.f / s;
    float* fo = filt + fb;
    for (int k = 0; k < K; ++k) fo[k * 512 + d] = expf(row[k] - mx) * inv;   // [k][d]
}

// ---------------- wavelet: dec (small LDS tile) + interp, per (dblk, i, thalf, b) ----------------
// grid (8, 8, 16): x = dblk (64 ch), y = i*2+thalf, z = b. 256 threads. LDS ~25KB.
__global__ __launch_bounds__(256) void wave4_kernel(const bh16* __restrict__ hb,
                                                    const float* __restrict__ filtT,
                                                    bh16* __restrict__ comb)
{
    __shared__ float dtile[66 * 64];   // dec sub-tile [jcount<=66][64]
    __shared__ float ftile[32 * 64];   // filter [K<=32][64]
    const int dblk = blockIdx.x;
    const int iy = blockIdx.y;
    const int b = blockIdx.z;
    const int i = iy >> 1, thalf = iy & 1;
    const int Karr[4] = {4, 8, 16, 32};
    const int fbarr[4] = {0, 2048, 6144, 14336};
    const int K = Karr[i], sv = 2 << i, Ti = 128 >> i;
    const int fb = fbarr[i];
    const int tid = threadIdx.x;
    const int dbase = dblk * 64;
    // filter -> LDS (transposed layout already: [k][512])
    for (int e = tid; e < K * 64; e += 256) {
        int k = e >> 6, d0 = e & 63;
        ftile[k * 64 + d0] = filtT[fb + k * 512 + dbase + d0];
    }
    // dec row range needed for t in [thalf*128, thalf*128+128)
    const float invsv = 1.f / (float)sv;
    const int t0 = thalf * 128;
    float p0 = ((float)t0 + 0.5f) * invsv - 0.5f;
    p0 = fminf(fmaxf(p0, 0.f), (float)(Ti - 1));
    const int jbase = (int)p0;
    float p1 = ((float)(t0 + 127) + 0.5f) * invsv - 0.5f;
    p1 = fminf(fmaxf(p1, 0.f), (float)(Ti - 1));
    const int him = min((int)p1 + 1, Ti - 1);
    const int jcount = him - jbase + 1;     // <= 66
    __syncthreads();
    // phase 1: dec rows [jbase, jbase+jcount) for channels [dbase, dbase+64)
    const bh16* hcol = hb + (size_t)b * (TT * DD) + dbase;
    for (int e = tid; e < jcount * 64; e += 256) {
        int jl = e >> 6, d0 = e & 63;
        int j = jbase + jl;
        int tb = j * sv - (K - 1);
        float acc = 0.f;
        #pragma unroll 4
        for (int k = 0; k < K; ++k) {
            int t = tb + k;
            if (t >= 0)
                acc += b2f(*(const unsigned short*)(hcol + (size_t)t * DD + d0)) * ftile[k * 64 + d0];
        }
        dtile[jl * 64 + d0] = acc;
    }
    __syncthreads();
    // phase 2: interp 128 t values from LDS, write comb bf16
    for (int e = tid; e < 128 * 64; e += 256) {
        int tl = e >> 6, d0 = e & 63;
        int t = t0 + tl;
        float pos = ((float)t + 0.5f) * invsv - 0.5f;
        pos = fminf(fmaxf(pos, 0.f), (float)(Ti - 1));
        int lo = (int)pos;
        int hi = min(lo + 1, Ti - 1);
        float w = pos - (float)lo;
        float v = dtile[(lo - jbase) * 64 + d0] * (1.f - w) + dtile[(hi - jbase) * 64 + d0] * w;
        comb[((size_t)b * TT + t) * 2048 + i * 512 + dbase + d0] = __float2bfloat16(v);
    }
}

// ---------------- boundary loss: 32 blocks, one atomic per block ----------------
__global__ __launch_bounds__(256) void bd_loss_kernel(const float* __restrict__ tfb, const float* __restrict__ bdw,
                                                      const float* __restrict__ bdb, float* __restrict__ loss)
{
    __shared__ float wsum[4];
    int lane = threadIdx.x & 63, wid = threadIdx.x >> 6;
    float w = bdw[lane * 2] - bdw[lane * 2 + 1];
    float bconst = (bdb[0] - bdb[1]) + 0.1f;
    float acc = 0.f;
    for (int row = blockIdx.x * 4 + wid; row < BT; row += 128) {
        float vv = tfb[(size_t)row * PP + lane] * w;
        #pragma unroll
        for (int off = 32; off; off >>= 1) vv += __shfl_xor(vv, off);
        if (lane == 0) acc += fmaxf(vv + bconst, 0.f);
    }
    if (lane == 0) wsum[wid] = acc;
    __syncthreads();
    if (threadIdx.x == 0) {
        atomicAdd(loss, (wsum[0] + wsum[1] + wsum[2] + wsum[3]) * (1.f / 4096.f));
    }
}

// ---------------- h = layernorm(s + h)*g + b, dual fp32+bf16 out ----------------
__global__ __launch_bounds__(256) void add_ln_kernel(const float* __restrict__ s, float* __restrict__ h,
                                                     bh16* __restrict__ hb,
                                                     const float* __restrict__ g, const float* __restrict__ be)
{
    int lane = threadIdx.x & 63, wid = threadIdx.x >> 6;
    size_t row = (size_t)blockIdx.x * 4 + wid;
    const float* sr = s + row * DD;
    float* hr = h + row * DD;
    bh16* hbr = hb + row * DD;
    float xv[8]; float sum = 0.f;
    #pragma unroll
    for (int u = 0; u < 8; ++u) { int c = lane + u * 64; xv[u] = sr[c] + hr[c]; sum += xv[u]; }
    #pragma unroll
    for (int off = 32; off; off >>= 1) sum += __shfl_xor(sum, off);
    float mu = sum * (1.f / 512.f);
    float sq = 0.f;
    #pragma unroll
    for (int u = 0; u < 8; ++u) { float d = xv[u] - mu; sq += d * d; }
    #pragma unroll
    for (int off = 32; off; off >>= 1) sq += __shfl_xor(sq, off);
    float rstd = 1.f / sqrtf(sq * (1.f / 512.f) + 1e-5f);
    #pragma unroll
    for (int u = 0; u < 8; ++u) {
        int c = lane + u * 64;
        float v = (xv[u] - mu) * rstd * g[c] + be[c];
        hr[c] = v;
        hbr[c] = __float2bfloat16(v);
    }
}

// ---------------- weight transpose-convert: [l-sel][K][N] f32 -> out + l*lstride, [N][K] bf16 ----------------
__global__ __launch_bounds__(256) void wtrans_kernel(const float* __restrict__ W, bh16* __restrict__ Wt,
                                                     int K, int N, long lstride)
{
    int l = blockIdx.z;
    const float* Wl = W + (size_t)l * K * N;
    bh16* Wo = Wt + (size_t)l * lstride;
    __shared__ float tile[32][33];
    int n0 = blockIdx.x * 32, k0 = blockIdx.y * 32;
    int lx = threadIdx.x & 31, ly = threadIdx.x >> 5;
    #pragma unroll
    for (int j = 0; j < 4; ++j) {
        int kk = ly + j * 8;
        tile[kk][lx] = Wl[(size_t)(k0 + kk) * N + n0 + lx];
    }
    __syncthreads();
    #pragma unroll
    for (int j = 0; j < 4; ++j) {
        int nr = ly + j * 8;
        Wo[(size_t)(n0 + nr) * K + k0 + lx] = __float2bfloat16(tile[lx][nr]);
    }
}

// ---------------- cc_w [L][O][I][3] f32 -> ccT [L][O][tap*512+I] bf16 (tap-major K for fused conv GEMM) ----------------
__global__ __launch_bounds__(256) void ccconv_kernel(const float* __restrict__ ccw, bh16* __restrict__ ccT)
{
    size_t idx = (size_t)blockIdx.x * 256 + threadIdx.x;   // 6*512*1536
    int i = idx & 511; size_t rem = idx >> 9;
    int tap = (int)(rem % 3); rem /= 3;
    int o = (int)(rem & 511); int l = (int)(rem >> 9);
    ccT[idx] = __float2bfloat16(ccw[(((size_t)l*512 + o)*512 + i)*3 + tap]);
}

// ---------------- qkv bias concat [L][1536] + fused-epilogue bias sum [L][512] ----------------
__global__ __launch_bounds__(256) void qkvbias_kernel(const float* __restrict__ qb_, const float* __restrict__ kb_,
                                                      const float* __restrict__ vb_, float* __restrict__ ob,
                                                      const float* __restrict__ gob, const float* __restrict__ wrb,
                                                      const float* __restrict__ tdb, const float* __restrict__ ccb,
                                                      float* __restrict__ bsum)
{
    int idx = blockIdx.x * 256 + threadIdx.x;
    if (idx < 6 * 1536) {
        int l = idx / 1536, n = idx % 1536;
        float v = (n < 512) ? qb_[l*512 + n] : (n < 1024) ? kb_[l*512 + n - 512] : vb_[l*512 + n - 1024];
        ob[idx] = v;
    }
    if (idx < 6 * 512) {
        bsum[idx] = gob[idx] + wrb[idx] + tdb[idx] + ccb[idx];
    }
}

// ---------------- x f32 -> bf16 ----------------
__global__ __launch_bounds__(256) void convx_kernel(const float* __restrict__ x, bh16* __restrict__ xb)
{
    size_t idx = (size_t)blockIdx.x * 256 + threadIdx.x;
    xb[idx] = __float2bfloat16(x[idx]);
}

// ---------------- E matrix: row (t,b) = [sched[t]*noise[t,b,:] | temb[t]] (bf16, 160x1024) ----------------
__global__ __launch_bounds__(256) void build_E_kernel(const float* __restrict__ noise, const float* __restrict__ sched,
                                                      bh16* __restrict__ E)
{
    int idx = blockIdx.x * 256 + threadIdx.x;   // 10*16*1024
    if (idx >= SS * BB * 1024) return;
    int k = idx & 1023; int rem = idx >> 10; int b = rem & 15; int t = rem >> 4;
    float v;
    if (k < 512) {
        v = sched[t] * noise[((size_t)t * BB + b) * 512 + k];
    } else {
        int j = k - 512;
        const float kfac = -9.210340371976184f / 255.f;   // -ln(10000)/255
        v = (j < 256) ? sinf((float)t * expf((float)j * kfac))
                      : cosf((float)t * expf((float)(j - 256) * kfac));
    }
    E[idx] = __float2bfloat16(v);
}

// ---------------- head helpers ----------------
__global__ void init_kernel(bh16* zp, float* loss)
{
    int t = threadIdx.x;
    if (t < 64) zp[t] = __float2bfloat16(0.f);
    if (t == 64) *loss = 0.f;
}

__global__ __launch_bounds__(256) void build_cat16_kernel(const float* __restrict__ h, bh16* __restrict__ catb)
{
    int idx = blockIdx.x * 256 + threadIdx.x;   // 16*1024
    if (idx >= BB * 1024) return;
    int k = idx & 1023, b = idx >> 10;
    float v = (k < 512) ? h[((size_t)b * TT + 255) * DD + k]
                        : h[((size_t)b * TT + 254) * DD + (k - 512)];
    catb[idx] = __float2bfloat16(v);
}

__global__ __launch_bounds__(256) void cur_init2_kernel(const float* __restrict__ h, const float* __restrict__ mix,
                                                        float* __restrict__ curf, bh16* __restrict__ curb)
{
    int idx = blockIdx.x * 256 + threadIdx.x;   // 16*512
    if (idx >= BB * DD) return;
    int c = idx & 511, b = idx >> 9;
    float v = h[((size_t)b * TT + 255) * DD + c] + mix[idx];
    curf[idx] = v;
    curb[idx] = __float2bfloat16(v);
}

__global__ void fail_kernel(float* p) { p[0] = 1e30f; }

// =====================================================================================
extern "C" void kernel_launch(void* const* d_in, const int* in_sizes, int n_in,
                              void* d_out, int out_size, void* d_ws, size_t ws_size,
                              hipStream_t stream)
{
    const float* x      = (const float*)d_in[0];
    const float* in_w   = (const float*)d_in[1];
    const float* in_b   = (const float*)d_in[2];
    const float* gq_w   = (const float*)d_in[3];
    const float* gq_b   = (const float*)d_in[4];
    const float* gk_w   = (const float*)d_in[5];
    const float* gk_b   = (const float*)d_in[6];
    const float* gv_w   = (const float*)d_in[7];
    const float* gv_b   = (const float*)d_in[8];
    const float* go_w   = (const float*)d_in[9];
    const float* go_b   = (const float*)d_in[10];
    const float* curv   = (const float*)d_in[11];
    const float* wav0   = (const float*)d_in[12];
    const float* wav1   = (const float*)d_in[13];
    const float* wav2   = (const float*)d_in[14];
    const float* wav3   = (const float*)d_in[15];
    const float* wrec_w = (const float*)d_in[16];
    const float* wrec_b = (const float*)d_in[17];
    const float* te1_w  = (const float*)d_in[18];
    const float* te1_b  = (const float*)d_in[19];
    const float* te2_w  = (const float*)d_in[20];
    const float* te2_b  = (const float*)d_in[21];
    const float* td1_w  = (const float*)d_in[22];
    const float* td1_b  = (const float*)d_in[23];
    const float* td2_w  = (const float*)d_in[24];
    const float* td2_b  = (const float*)d_in[25];
    const float* bd_w   = (const float*)d_in[26];
    const float* bd_b   = (const float*)d_in[27];
    const float* cc_w   = (const float*)d_in[28];
    const float* cc_b   = (const float*)d_in[29];
    const float* ln_g   = (const float*)d_in[30];
    const float* ln_b   = (const float*)d_in[31];
    const float* mm1_w  = (const float*)d_in[32];
    const float* mm1_b  = (const float*)d_in[33];
    const float* mm2_w  = (const float*)d_in[34];
    const float* mm2_b  = (const float*)d_in[35];
    const float* dn1_w  = (const float*)d_in[36];
    const float* dn1_b  = (const float*)d_in[37];
    const float* dn2_w  = (const float*)d_in[38];
    const float* dn2_b  = (const float*)d_in[39];
    const float* dn3_w  = (const float*)d_in[40];
    const float* dn3_b  = (const float*)d_in[41];
    const float* out_w  = (const float*)d_in[42];
    const float* out_b  = (const float*)d_in[43];
    const float* nsched = (const float*)d_in[44];
    const float* noise  = (const float*)d_in[45];
    float* out = (float*)d_out;
    float* ws  = (float*)d_ws;

    // ---- fp32 workspace layout (float offsets) ----
    const size_t o_h   = 0;          // 2097152
    const size_t o_dec = 2097152;    // 2097152 (pre1 for head: 81920)
    const size_t o_s   = 4194304;    // 2097152
    const size_t o_tf  = 6291456;    // 262144
    const size_t o_qn  = 6553600;    // 32768
    const size_t o_kn  = 6586368;    // 32768
    const size_t o_at  = 6619136;    // 8388608
    const size_t o_fl  = 15007744;   // 30720
    const size_t o_mix = 15038464;   // 8192
    const size_t o_cur = 15046656;   // 8192
    const size_t o_qkb = 15054848;   // 9216 (qkv bias [6][1536])
    const size_t o_bs  = 15064064;   // 3072 (fused bias sum [6][512])
    const size_t FP32_TOTAL = 15095808;
    // ---- bf16 region (element offsets from bp) ----
    const size_t b_xb   = 0;          // 1572864
    const size_t b_hb   = 1572864;    // 2097152
    const size_t b_qkv  = 3670016;    // 6291456: packed qkv [4096][1536]
    const size_t b_vt   = 9961472;    // 2097152
    const size_t b_pb   = 12058624;   // 8388608 (head scratch aliases here after layers)
    const size_t b_gmb  = 20447232;   // 2097152
    const size_t b_tdb  = 22544384;   // 2097152
    const size_t b_t1b  = 24641536;   // 262144
    const size_t b_tfb  = 24903680;   // 262144
    const size_t b_zp   = 25165824;   // 512
    const size_t b_inwT = 25166336;   // 196608
    const size_t b_qkvT = 25362944;   // 4718592: [6][1536][512]
    const size_t b_goT  = 30081536;   // 1572864
    const size_t b_wrT  = 31654400;   // 6291456
    const size_t b_td1T = 37945856;   // 196608
    const size_t b_td2T = 38142464;   // 1572864
    const size_t b_te1T = 39715328;   // 196608
    const size_t b_te2T = 39911936;   // 24576
    const size_t b_ccT  = 39936512;   // 4718592: [6][512][1536]
    const size_t BF16_TOTAL = 44655104;
    const size_t TOTAL_BYTES = FP32_TOTAL * 4 + BF16_TOTAL * 2;
    if (ws_size < TOTAL_BYTES) { fail_kernel<<<1, 1, 0, stream>>>(out); return; }

    float* h_   = ws + o_h;
    float* dec_ = ws + o_dec;
    float* s_   = ws + o_s;
    float* tf_  = ws + o_tf;
    float* qn_  = ws + o_qn;
    float* kn_  = ws + o_kn;
    float* at_  = ws + o_at;
    float* fl_  = ws + o_fl;
    float* mixb = ws + o_mix;
    float* curf = ws + o_cur;
    float* qkvbias = ws + o_qkb;
    float* bsum = ws + o_bs;
    bh16* bp   = (bh16*)(ws + FP32_TOTAL);
    bh16* xb   = bp + b_xb;
    bh16* hb   = bp + b_hb;
    bh16* qkvb = bp + b_qkv;
    bh16* vt   = bp + b_vt;
    bh16* pb   = bp + b_pb;
    bh16* gmb  = bp + b_gmb;
    bh16* tdb  = bp + b_tdb;
    bh16* t1b  = bp + b_t1b;
    bh16* tfb  = bp + b_tfb;
    bh16* zp   = bp + b_zp;
    bh16* inwT = bp + b_inwT;
    bh16* qkvT = bp + b_qkvT;
    bh16* goT  = bp + b_goT;
    bh16* wrT  = bp + b_wrT;
    bh16* td1T = bp + b_td1T;
    bh16* td2T = bp + b_td2T;
    bh16* te1T = bp + b_te1T;
    bh16* te2T = bp + b_te2T;
    bh16* ccT  = bp + b_ccT;
    bh16* combb = (bh16*)at_;   // aliases at_ after softmax consumed it

    // head bf16 scratch: aliased into pb region (dead after layer loop)
    bh16* dn1T  = pb;             // 524288
    bh16* dn2T  = pb + 524288;    // 262144
    bh16* dn3T  = pb + 786432;    // 262144
    bh16* mm1T  = pb + 1048576;   // 524288
    bh16* mm2T  = pb + 1572864;   // 262144
    bh16* outT  = pb + 1835008;   // 196608
    bh16* E16   = pb + 2031616;   // 163840
    bh16* cat16 = pb + 2195456;   // 16384
    bh16* tmb16 = pb + 2211840;   // 8192
    bh16* cur16 = pb + 2220032;   // 8192
    bh16* d1b16 = pb + 2228224;   // 8192
    bh16* d2b16 = pb + 2236416;   // 8192
    float* pre1 = dec_;           // 81920 f32, aliases dec_ after layers

    auto mg = [&](const bh16* A, int lda, const bh16* Bt, int ldb,
                  const float* bias, float* Cf, bh16* Cb, int ldc,
                  int M, int N, int K, int shift, int accum, int act,
                  int nb, int zmask, int zshift,
                  long aS1, long aS0, long bS1, long bS0, long cS1, long cS0, int ccdil) {
        dim3 g(N / 64, M / 128, nb);
        mgemm_kernel<<<g, 256, 0, stream>>>(A, lda, Bt, ldb, bias, Cf, Cb, ldc, N, K,
                                            shift, accum, act, zmask, zshift,
                                            aS1, aS0, bS1, bS0, cS1, cS0, ccdil, zp);
    };
    auto mgp = [&](const bh16* A, int lda, const bh16* Bt, int ldb,
                   const float* bias, float* Cf, bh16* Cb, int ldc,
                   int M, int N, int K, int shift, int accum, int act) {
        mg(A, lda, Bt, ldb, bias, Cf, Cb, ldc, M, N, K, shift, accum, act, 1, 0, 0, 0, 0, 0, 0, 0, 0, 0);
    };
    auto hg = [&](const bh16* A, int lda, long aZ, const bh16* Bt, int ldb,
                  const float* bias, const float* pre, float* Of, bh16* Ob, long oZ,
                  int N, int K, int act, float* cf, bh16* cb, const float* sp, int nz) {
        hgemm16_kernel<<<dim3(N / 64, 1, nz), 256, 0, stream>>>(
            A, lda, aZ, Bt, ldb, bias, pre, Of, Ob, oZ, N, K, act, cf, cb, sp);
    };

    // ---- setup: zero page/loss, converts ----
    init_kernel<<<1, 128, 0, stream>>>(zp, out + BB * DIN);
    convx_kernel<<<BT * DIN / 256, 256, 0, stream>>>(x, xb);
    wtrans_kernel<<<dim3(DD/32, DIN/32, 1), 256, 0, stream>>>(in_w, inwT, DIN, DD, (long)DIN*DD);
    // packed qkvT: rows 0-511 q, 512-1023 k, 1024-1535 v; l-stride 786432
    wtrans_kernel<<<dim3(16, 16, 6), 256, 0, stream>>>(gq_w, qkvT,          DD, DD, 786432L);
    wtrans_kernel<<<dim3(16, 16, 6), 256, 0, stream>>>(gk_w, qkvT + 262144, DD, DD, 786432L);
    wtrans_kernel<<<dim3(16, 16, 6), 256, 0, stream>>>(gv_w, qkvT + 524288, DD, DD, 786432L);
    qkvbias_kernel<<<36, 256, 0, stream>>>(gq_b, gk_b, gv_b, qkvbias,
                                           go_b, wrec_b, td2_b, cc_b, bsum);
    wtrans_kernel<<<dim3(16, 16, 6), 256, 0, stream>>>(go_w, goT, DD, DD, (long)DD*DD);
    wtrans_kernel<<<dim3(16, 64, 6), 256, 0, stream>>>(wrec_w, wrT, 2048, DD, 2048L*DD);
    wtrans_kernel<<<dim3(16, 2, 6), 256, 0, stream>>>(td1_w, td1T, PP, DD, (long)PP*DD);
    wtrans_kernel<<<dim3(16, 16, 6), 256, 0, stream>>>(td2_w, td2T, DD, DD, (long)DD*DD);
    wtrans_kernel<<<dim3(2, 16, 6), 256, 0, stream>>>(te1_w, te1T, DD, PP, (long)DD*PP);
    wtrans_kernel<<<dim3(2, 2, 6), 256, 0, stream>>>(te2_w, te2T, PP, PP, (long)PP*PP);
    ccconv_kernel<<<18432, 256, 0, stream>>>(cc_w, ccT);

    // h = x @ in_w + in_b  (fp32 + bf16)
    mgp(xb, DIN, inwT, DIN, in_b, h_, hb, DD, BT, DD, DIN, 0, 0, ACT_NONE);

    for (int l = 0; l < LL; ++l) {
        // fused q|k|v projection: N=1536, packed output [BT][1536]
        mgp(hb, DD, qkvT + (size_t)l*786432, DD, qkvbias + (size_t)l*1536,
            nullptr, qkvb, 1536, BT, 1536, DD, 0, 0, ACT_NONE);
        // attention
        sqnorm2_kernel<<<dim3(8192, 2), 256, 0, stream>>>(qkvb, qn_, kn_);
        mg(qkvb, 1536, qkvb + 512, 1536, nullptr, at_, nullptr, TT, TT, TT, 64, 0, 0, ACT_NONE,
           128, 7, 3, 393216, 64, 393216, 64, 524288, 65536, 0);
        attn_softmax_kernel<<<8192, 256, 0, stream>>>(at_, pb, qn_, kn_, curv + (size_t)l*HH);
        vtrans_kernel<<<dim3(4, 128), 256, 0, stream>>>(qkvb + 1024, vt);
        mg(pb, TT, vt, TT, nullptr, nullptr, gmb, DD, TT, 64, TT, 0, 0, ACT_NONE,
           128, 7, 3, 524288, 65536, 131072, 16384, 131072, 64, 0);
        // wavelet branch: dec+interp fused (comb aliases at_, softmax already consumed it)
        filt_softmax_kernel<<<8, 256, 0, stream>>>(wav0 + (size_t)l*DD*4, wav1 + (size_t)l*DD*8,
                                                   wav2 + (size_t)l*DD*16, wav3 + (size_t)l*DD*32, fl_);
        wave4_kernel<<<dim3(8, 8, 16), 256, 0, stream>>>(hb, fl_, combb);
        // topo branch (up to td1)
        mgp(hb, DD, te1T + (size_t)l*32768, DD, te1_b + (size_t)l*PP, nullptr, t1b, PP, BT, PP, DD, 0, 0, ACT_RELU);
        mgp(t1b, PP, te2T + (size_t)l*4096, PP, te2_b + (size_t)l*PP, tf_, tfb, PP, BT, PP, PP, 0, 0, ACT_NONE);
        bd_loss_kernel<<<32, 256, 0, stream>>>(tf_, bd_w + (size_t)l*PP*2, bd_b + (size_t)l*2, out + BB*DIN);
        mgp(tfb, PP, td1T + (size_t)l*32768, PP, td1_b + (size_t)l*DD, nullptr, tdb, DD, BT, DD, PP, 0, 0, ACT_RELU);
        // fused s = gmb@go + comb@wrec + tdb@td2 + cc(hb) + biassum  (K=4608, one write)
        fgemm_kernel<<<dim3(8, 32), 256, 0, stream>>>(
            gmb, combb, tdb, hb,
            goT + (size_t)l*262144, wrT + (size_t)l*1048576,
            td2T + (size_t)l*262144, ccT + (size_t)l*786432,
            bsum + (size_t)l*512, s_, 1 << l, zp);
        // h = LN(s + h)
        add_ln_kernel<<<BT/4, 256, 0, stream>>>(s_, h_, hb, ln_g, ln_b);
    }

    // ---- head: convert weights (into dead pb region), precompute E/pre1 ----
    wtrans_kernel<<<dim3(16, 32, 1), 256, 0, stream>>>(dn1_w, dn1T, 1024, 512, 0L);
    wtrans_kernel<<<dim3(16, 16, 1), 256, 0, stream>>>(dn2_w, dn2T, 512, 512, 0L);
    wtrans_kernel<<<dim3(16, 16, 1), 256, 0, stream>>>(dn3_w, dn3T, 512, 512, 0L);
    wtrans_kernel<<<dim3(16, 32, 1), 256, 0, stream>>>(mm1_w, mm1T, 1024, 512, 0L);
    wtrans_kernel<<<dim3(16, 16, 1), 256, 0, stream>>>(mm2_w, mm2T, 512, 512, 0L);
    wtrans_kernel<<<dim3(12, 16, 1), 256, 0, stream>>>(out_w, outT, 512, 384, 0L);
    build_E_kernel<<<640, 256, 0, stream>>>(noise, nsched, E16);
    // pre1[t] = E_t @ dn1_w + dn1_b   (z-batched over t)
    hg(E16, 1024, 16*1024, dn1T, 1024, dn1_b, nullptr, pre1, nullptr, 8192,
       512, 1024, ACT_NONE, nullptr, nullptr, nullptr, SS);
    // mix head
    build_cat16_kernel<<<64, 256, 0, stream>>>(h_, cat16);
    hg(cat16, 1024, 0, mm1T, 1024, mm1_b, nullptr, nullptr, tmb16, 0,
       512, 1024, ACT_TANH, nullptr, nullptr, nullptr, 1);
    hg(tmb16, 512, 0, mm2T, 512, mm2_b, nullptr, mixb, nullptr, 0,
       512, 512, ACT_NONE, nullptr, nullptr, nullptr, 1);
    cur_init2_kernel<<<32, 256, 0, stream>>>(h_, mixb, curf, cur16);
    // diffusion chain: 3 launches per step
    for (int t = 0; t < SS; ++t) {
        hg(cur16, 512, 0, dn1T, 1024, nullptr, pre1 + (size_t)t*8192, nullptr, d1b16, 0,
           512, 512, ACT_SILU, nullptr, nullptr, nullptr, 1);
        hg(d1b16, 512, 0, dn2T, 512, dn2_b, nullptr, nullptr, d2b16, 0,
           512, 512, ACT_SILU, nullptr, nullptr, nullptr, 1);
        hg(d2b16, 512, 0, dn3T, 512, dn3_b, nullptr, nullptr, nullptr, 0,
           512, 512, ACT_NONE, curf, cur16, nsched + t, 1);
    }
    // pred = cur @ out_w + out_b
    hg(cur16, 512, 0, outT, 512, out_b, nullptr, out, nullptr, 0,
       384, 512, ACT_NONE, nullptr, nullptr, nullptr, 1);
}

// Round 11
// 1422.519 us; speedup vs baseline: 1.5454x; 1.1627x over previous
//
#include <hip/hip_runtime.h>
#include <hip/hip_bf16.h>
#include <math.h>

#define BB 16
#define TT 256
#define DIN 384
#define DD 512
#define LL 6
#define HH 8
#define PP 64
#define SS 10
#define BT (BB*TT)   // 4096

enum { ACT_NONE=0, ACT_RELU=1, ACT_TANH=2, ACT_SILU=3, ACT_RELU_TAIL=4 };

typedef __attribute__((ext_vector_type(8))) short bf16x8;
typedef __attribute__((ext_vector_type(4))) float f32x4;
typedef __hip_bfloat16 bh16;

typedef const __attribute__((address_space(1))) void gvoid_t;
typedef __attribute__((address_space(3))) void lvoid_t;
__device__ __forceinline__ void gload16(const void* g, void* l) {
    __builtin_amdgcn_global_load_lds((gvoid_t*)g, (lvoid_t*)l, 16, 0, 0);
}

__device__ __forceinline__ float b2f(unsigned short u) {
    return __uint_as_float(((unsigned int)u) << 16);
}

// bijective chunked XCD swizzle (m204) within one z-plane.
__device__ __forceinline__ void xcd_swizzle_always(int& bx, int& by) {
    int gx = gridDim.x;
    int nwg = gx * gridDim.y;
    int lid = by * gx + bx;
    int q = nwg >> 3, r = nwg & 7;
    int xcd = lid & 7, idx = lid >> 3;
    int swz = (xcd < r) ? (xcd * (q + 1) + idx) : (r * (q + 1) + (xcd - r) * q + idx);
    bx = swz % gx;
    by = swz / gx;
}
__device__ __forceinline__ void xcd_swizzle(int& bx, int& by) {
    if (gridDim.z == 1) xcd_swizzle_always(bx, by);
}

// =====================================================================================
// Generic bf16 MFMA GEMM: C = act(A @ Bt^T + bias)  (Bt stored [N][K])
// BM=128, BN=64, BK=64; 4 waves 2x2, wave tile 64x32 (4x2 frags of 16x16).
// Optional batch dim z; shift row-masking; ccdil fused 3-tap causal conv (see r5 notes).
__global__ __launch_bounds__(256) void mgemm_kernel(
    const bh16* __restrict__ A, int lda,
    const bh16* __restrict__ Bt, int ldb,
    const float* __restrict__ bias,
    float* __restrict__ Cf, bh16* __restrict__ Cb, int ldc,
    int N, int K, int shift, int accum, int act,
    int zmask, int zshift,
    long aS1, long aS0, long bS1, long bS0, long cS1, long cS0,
    int ccdil,
    const bh16* __restrict__ zp)
{
    __shared__ bf16x8 As[128*8];   // 16KB: [row][8 chunks], chunk XOR-swizzled by row&7
    __shared__ bf16x8 Bs[64*8];    // 8KB

    int z = blockIdx.z;
    long z1 = (long)(z >> zshift), z0 = (long)(z & zmask);
    A  += z1*aS1 + z0*aS0;
    Bt += z1*bS1 + z0*bS0;
    long coff = z1*cS1 + z0*cS0;

    int bx = blockIdx.x, by = blockIdx.y;
    xcd_swizzle(bx, by);

    const int tid  = threadIdx.x;
    const int lane = tid & 63, w = tid >> 6;
    const int wm = w >> 1, wn = w & 1;
    const int row0 = by * 128, col0 = bx * 64;

    f32x4 acc[4][2];
    #pragma unroll
    for (int i = 0; i < 4; ++i)
        #pragma unroll
        for (int j = 0; j < 2; ++j) acc[i][j] = (f32x4){0.f,0.f,0.f,0.f};

    const int nkt = K >> 6;
    for (int kt = 0; kt < nkt; ++kt) {
        int k0 = kt << 6;
        int mask_sh, addr_sh;
        if (ccdil) {
            int tap = kt >> 3;
            mask_sh = (2 - tap) * ccdil;
            addr_sh = mask_sh + tap;
        } else {
            mask_sh = shift; addr_sh = shift;
        }
        #pragma unroll
        for (int j = 0; j < 4; ++j) {
            int c = ((w*4 + j) << 6) + lane;
            int row = c >> 3, chk = c & 7;
            int schk = chk ^ (row & 7);
            int grow = row0 + row;
            const bh16* src = ((grow & 255) >= mask_sh)
                ? (A + (size_t)(grow - addr_sh)*lda + k0 + schk*8) : zp;
            gload16(src, &As[(w*4 + j) * 64]);
        }
        #pragma unroll
        for (int j = 0; j < 2; ++j) {
            int c = ((w*2 + j) << 6) + lane;
            int row = c >> 3, chk = c & 7;
            int schk = chk ^ (row & 7);
            int gcol = col0 + row;
            const bh16* src = (gcol < N)
                ? (Bt + (size_t)gcol*ldb + k0 + schk*8) : zp;
            gload16(src, &Bs[(w*2 + j) * 64]);
        }
        asm volatile("s_waitcnt vmcnt(0)" ::: "memory");
        __syncthreads();

        bf16x8 a[4][2], b[2][2];
        #pragma unroll
        for (int fm = 0; fm < 4; ++fm) {
            int row = wm*64 + fm*16 + (lane & 15);
            #pragma unroll
            for (int ks = 0; ks < 2; ++ks)
                a[fm][ks] = As[row*8 + ((ks*4 + (lane>>4)) ^ (row & 7))];
        }
        #pragma unroll
        for (int fn = 0; fn < 2; ++fn) {
            int col = wn*32 + fn*16 + (lane & 15);
            #pragma unroll
            for (int ks = 0; ks < 2; ++ks)
                b[fn][ks] = Bs[col*8 + ((ks*4 + (lane>>4)) ^ (col & 7))];
        }
        #pragma unroll
        for (int ks = 0; ks < 2; ++ks)
            #pragma unroll
            for (int fm = 0; fm < 4; ++fm)
                #pragma unroll
                for (int fn = 0; fn < 2; ++fn)
                    acc[fm][fn] = __builtin_amdgcn_mfma_f32_16x16x32_bf16(
                        a[fm][ks], b[fn][ks], acc[fm][fn], 0, 0, 0);
        __syncthreads();
    }

    #pragma unroll
    for (int fm = 0; fm < 4; ++fm) {
        #pragma unroll
        for (int fn = 0; fn < 2; ++fn) {
            int gc = col0 + wn*32 + fn*16 + (lane & 15);
            float bs = bias ? bias[gc] : 0.f;
            #pragma unroll
            for (int r = 0; r < 4; ++r) {
                int gr = row0 + wm*64 + fm*16 + (lane>>4)*4 + r;
                float v = acc[fm][fn][r] + bs;
                if (act == ACT_RELU) v = fmaxf(v, 0.f);
                else if (act == ACT_RELU_TAIL && gc >= 1536) v = fmaxf(v, 0.f);
                size_t o = (size_t)gr*ldc + gc + coff;
                if (Cf) { if (accum) Cf[o] += v; else Cf[o] = v; }
                if (Cb) Cb[o] = __float2bfloat16(v);
            }
        }
    }
}

// =====================================================================================
// Fused 4-segment GEMM, split-K over blockIdx.z (0: kt 0..35 -> Cf0+bias, 1: kt 36..71 -> Cf1)
// s = gmb@goT + comb@wrT + tdb@td2T + cc(hb)@ccT + biassum, K = 512+2048+512+1536 = 4608.
__global__ __launch_bounds__(256) void fgemm_kernel(
    const bh16* __restrict__ A0, const bh16* __restrict__ A1,
    const bh16* __restrict__ A2, const bh16* __restrict__ A3,
    const bh16* __restrict__ B0, const bh16* __restrict__ B1,
    const bh16* __restrict__ B2, const bh16* __restrict__ B3,
    const float* __restrict__ bias, float* __restrict__ Cf0, float* __restrict__ Cf1,
    int dil, const bh16* __restrict__ zp)
{
    __shared__ bf16x8 As[128*8];
    __shared__ bf16x8 Bs[64*8];

    int bx = blockIdx.x, by = blockIdx.y;
    xcd_swizzle_always(bx, by);
    const int zz = blockIdx.z;
    const int ktlo = zz ? 36 : 0;
    const int kthi = zz ? 72 : 36;

    const int tid  = threadIdx.x;
    const int lane = tid & 63, w = tid >> 6;
    const int wm = w >> 1, wn = w & 1;
    const int row0 = by * 128, col0 = bx * 64;

    f32x4 acc[4][2];
    #pragma unroll
    for (int i = 0; i < 4; ++i)
        #pragma unroll
        for (int j = 0; j < 2; ++j) acc[i][j] = (f32x4){0.f,0.f,0.f,0.f};

    for (int kt = ktlo; kt < kthi; ++kt) {
        const bh16* Aseg; const bh16* Bseg;
        int ldas, ldbs, k0, mask_sh, addr_sh;
        if (kt < 8) {
            Aseg = A0; Bseg = B0; ldas = 512; ldbs = 512;
            k0 = kt << 6; mask_sh = 0; addr_sh = 0;
        } else if (kt < 40) {
            Aseg = A1; Bseg = B1; ldas = 2048; ldbs = 2048;
            k0 = (kt - 8) << 6; mask_sh = 0; addr_sh = 0;
        } else if (kt < 48) {
            Aseg = A2; Bseg = B2; ldas = 512; ldbs = 512;
            k0 = (kt - 40) << 6; mask_sh = 0; addr_sh = 0;
        } else {
            int kl = kt - 48, tap = kl >> 3;
            Aseg = A3; Bseg = B3; ldas = 512; ldbs = 1536;
            k0 = kl << 6;
            mask_sh = (2 - tap) * dil;
            addr_sh = mask_sh + tap;
        }
        #pragma unroll
        for (int j = 0; j < 4; ++j) {
            int c = ((w*4 + j) << 6) + lane;
            int row = c >> 3, chk = c & 7;
            int schk = chk ^ (row & 7);
            int grow = row0 + row;
            const bh16* src = ((grow & 255) >= mask_sh)
                ? (Aseg + (size_t)(grow - addr_sh)*ldas + k0 + schk*8) : zp;
            gload16(src, &As[(w*4 + j) * 64]);
        }
        #pragma unroll
        for (int j = 0; j < 2; ++j) {
            int c = ((w*2 + j) << 6) + lane;
            int row = c >> 3, chk = c & 7;
            int schk = chk ^ (row & 7);
            int gcol = col0 + row;
            gload16(Bseg + (size_t)gcol*ldbs + k0 + schk*8, &Bs[(w*2 + j) * 64]);
        }
        asm volatile("s_waitcnt vmcnt(0)" ::: "memory");
        __syncthreads();

        bf16x8 a[4][2], b[2][2];
        #pragma unroll
        for (int fm = 0; fm < 4; ++fm) {
            int row = wm*64 + fm*16 + (lane & 15);
            #pragma unroll
            for (int ks = 0; ks < 2; ++ks)
                a[fm][ks] = As[row*8 + ((ks*4 + (lane>>4)) ^ (row & 7))];
        }
        #pragma unroll
        for (int fn = 0; fn < 2; ++fn) {
            int col = wn*32 + fn*16 + (lane & 15);
            #pragma unroll
            for (int ks = 0; ks < 2; ++ks)
                b[fn][ks] = Bs[col*8 + ((ks*4 + (lane>>4)) ^ (col & 7))];
        }
        #pragma unroll
        for (int ks = 0; ks < 2; ++ks)
            #pragma unroll
            for (int fm = 0; fm < 4; ++fm)
                #pragma unroll
                for (int fn = 0; fn < 2; ++fn)
                    acc[fm][fn] = __builtin_amdgcn_mfma_f32_16x16x32_bf16(
                        a[fm][ks], b[fn][ks], acc[fm][fn], 0, 0, 0);
        __syncthreads();
    }

    float* Cf = zz ? Cf1 : Cf0;
    #pragma unroll
    for (int fm = 0; fm < 4; ++fm) {
        #pragma unroll
        for (int fn = 0; fn < 2; ++fn) {
            int gc = col0 + wn*32 + fn*16 + (lane & 15);
            float bs = zz ? 0.f : bias[gc];
            #pragma unroll
            for (int r = 0; r < 4; ++r) {
                int gr = row0 + wm*64 + fm*16 + (lane>>4)*4 + r;
                Cf[(size_t)gr*512 + gc] = acc[fm][fn][r] + bs;
            }
        }
    }
}

// =====================================================================================
// Small-M (M=16) MFMA GEMM, one wave = 16x16xK tile, no LDS.
__global__ __launch_bounds__(256) void hgemm16_kernel(
    const bh16* __restrict__ A, int lda, long aZ,
    const bh16* __restrict__ Bt, int ldb,
    const float* __restrict__ bias,
    const float* __restrict__ pre,
    float* __restrict__ Of, bh16* __restrict__ Ob, long oZ,
    int N, int K, int act,
    float* __restrict__ curf, bh16* __restrict__ curb,
    const float* __restrict__ scaleptr)
{
    const int z = blockIdx.z;
    A += (long)z * aZ;
    const int lane = threadIdx.x & 63, w = threadIdx.x >> 6;
    const int col0 = blockIdx.x * 64 + w * 16;
    const int ar = lane & 15;
    const int koff = (lane >> 4) * 8;
    const bh16* arow = A + (size_t)ar * lda + koff;
    const bh16* brow = Bt + (size_t)(col0 + ar) * ldb + koff;
    f32x4 acc = {0.f, 0.f, 0.f, 0.f};
    const int nkt = K >> 5;
    for (int kt0 = 0; kt0 < nkt; kt0 += 8) {
        bf16x8 av[8], bv[8];
        #pragma unroll
        for (int j = 0; j < 8; ++j) {
            av[j] = *(const bf16x8*)(arow + (size_t)(kt0 + j) * 32);
            bv[j] = *(const bf16x8*)(brow + (size_t)(kt0 + j) * 32);
        }
        #pragma unroll
        for (int j = 0; j < 8; ++j)
            acc = __builtin_amdgcn_mfma_f32_16x16x32_bf16(av[j], bv[j], acc, 0, 0, 0);
    }
    const int col = col0 + ar;
    float bs = bias ? bias[col] : 0.f;
    float sc = scaleptr ? *scaleptr : 0.f;
    #pragma unroll
    for (int r = 0; r < 4; ++r) {
        int row = (lane >> 4) * 4 + r;
        float v = acc[r] + bs;
        if (pre) v += pre[(size_t)row * N + col];
        if (act == ACT_SILU)      v = v / (1.f + expf(-v));
        else if (act == ACT_TANH) v = tanhf(v);
        if (curf) {
            size_t o = (size_t)row * 512 + col;
            float nc = curf[o] - v * sc;
            curf[o] = nc;
            curb[o] = __float2bfloat16(nc);
        } else {
            size_t o = (size_t)z * oZ + (size_t)row * N + col;
            if (Of) Of[o] = v;
            if (Ob) Ob[o] = __float2bfloat16(v);
        }
    }
}

// ---------------- per-head squared norms from packed qkv (lda=1600) ----------------
__global__ __launch_bounds__(256) void sqnorm2_kernel(const bh16* __restrict__ qkv,
                                                      float* __restrict__ qn, float* __restrict__ kn)
{
    int lane = threadIdx.x & 63, wid = threadIdx.x >> 6;
    int row = blockIdx.x * 4 + wid;            // over B*H*T
    const bh16* src = qkv + (blockIdx.y ? 512 : 0);
    float* dst = blockIdx.y ? kn : qn;
    int t = row & 255; int bh = row >> 8; int b = bh >> 3, hh = bh & 7;
    float v = __bfloat162float(src[((size_t)b * TT + t) * 1600 + hh * 64 + lane]);
    float s = v * v;
    #pragma unroll
    for (int off = 32; off; off >>= 1) s += __shfl_xor(s, off);
    if (lane == 0) dst[row] = s;
}

// ---------------- hyperbolic distance + softmax: fp32 logits in, bf16 probs out ----------------
__global__ __launch_bounds__(256) void attn_softmax_kernel(const float* __restrict__ at, bh16* __restrict__ pb,
                                                           const float* __restrict__ qn,
                                                           const float* __restrict__ kn,
                                                           const float* __restrict__ curv)
{
    int lane = threadIdx.x & 63, wid = threadIdx.x >> 6;
    int row = blockIdx.x * 4 + wid;            // over B*H*T
    int i = row & 255; int bh = row >> 8; int hh = bh & 7;
    float c = fabsf(curv[hh]) + 1e-8f;
    float inv_sqrt_c = 1.f / sqrtf(c);
    float qni = qn[row];
    const float* srow = at + (size_t)bh * TT * TT + (size_t)i * TT;
    bh16* prow = pb + (size_t)bh * TT * TT + (size_t)i * TT;
    const float* knr = kn + (size_t)bh * TT;
    float logit[4];
    float mx = -1e30f;
    #pragma unroll
    for (int u = 0; u < 4; ++u) {
        int j = lane + u * 64;
        float s = srow[j];
        float knj = knr[j];
        float d2 = fmaxf(qni + knj - 2.f * s, 0.f);
        float denom = fmaxf((1.f - c * qni) * (1.f - c * knj), 1e-5f);
        float arg = fmaxf(1.f + (2.f * c * d2) / denom, 1.00001f);
        float dist = logf(arg + sqrtf((arg - 1.f) * (arg + 1.f))) * inv_sqrt_c;
        logit[u] = -dist;
        mx = fmaxf(mx, logit[u]);
    }
    #pragma unroll
    for (int off = 32; off; off >>= 1) mx = fmaxf(mx, __shfl_xor(mx, off));
    float e[4]; float sum = 0.f;
    #pragma unroll
    for (int u = 0; u < 4; ++u) { e[u] = expf(logit[u] - mx); sum += e[u]; }
    #pragma unroll
    for (int off = 32; off; off >>= 1) sum += __shfl_xor(sum, off);
    float inv = 1.f / sum;
    #pragma unroll
    for (int u = 0; u < 4; ++u) prow[lane + u * 64] = __float2bfloat16(e[u] * inv);
}

// ---------------- V transpose per (b,h): packed qkv (v at +1024, lda=1600) -> vt[bh][d][t] ----------------
__global__ __launch_bounds__(256) void vtrans_kernel(const bh16* __restrict__ vb, bh16* __restrict__ vt)
{
    int bh = blockIdx.y, b = bh >> 3, hh = bh & 7;
    int t0 = blockIdx.x * 64;
    __shared__ bh16 tile[64][65];
    for (int e = threadIdx.x; e < 4096; e += 256) {
        int r = e >> 6, c = e & 63;
        tile[r][c] = vb[((size_t)(b*256 + t0 + r))*1600 + hh*64 + c];
    }
    __syncthreads();
    for (int e = threadIdx.x; e < 4096; e += 256) {
        int d = e >> 6, t2 = e & 63;
        vt[((size_t)bh*64 + d)*256 + t0 + t2] = tile[t2][d];
    }
}

// ---------------- wavelet filter softmax -> TRANSPOSED layout fT[i][k][512] ----------------
__global__ __launch_bounds__(256) void filt_softmax_kernel(const float* __restrict__ w0, const float* __restrict__ w1,
                                                           const float* __restrict__ w2, const float* __restrict__ w3,
                                                           float* __restrict__ filt)
{
    int idx = blockIdx.x * 256 + threadIdx.x;
    if (idx >= 4 * DD) return;
    int d = idx & 511, i = idx >> 9;
    const float* w = (i == 0) ? w0 : (i == 1) ? w1 : (i == 2) ? w2 : w3;
    int K = 4 << i;
    int fb = (i == 0) ? 0 : (i == 1) ? 2048 : (i == 2) ? 6144 : 14336;
    const float* row = w + (size_t)d * K;
    float mx = -1e30f;
    for (int k = 0; k < K; ++k) mx = fmaxf(mx, row[k]);
    float s = 0.f;
    for (int k = 0; k < K; ++k) s += expf(row[k] - mx);
    float inv = 1.f / s;
    float* fo = filt + fb;
    for (int k = 0; k < K; ++k) fo[k * 512 + d] = expf(row[k] - mx) * inv;   // [k][d]
}

// ---------------- wavelet: dec (small LDS tile) + interp, per (dblk, i, thalf, b) ----------------
__global__ __launch_bounds__(256) void wave4_kernel(const bh16* __restrict__ hb,
                                                    const float* __restrict__ filtT,
                                                    bh16* __restrict__ comb)
{
    __shared__ float dtile[66 * 64];   // dec sub-tile [jcount<=66][64]
    __shared__ float ftile[32 * 64];   // filter [K<=32][64]
    const int dblk = blockIdx.x;
    const int iy = blockIdx.y;
    const int b = blockIdx.z;
    const int i = iy >> 1, thalf = iy & 1;
    const int Karr[4] = {4, 8, 16, 32};
    const int fbarr[4] = {0, 2048, 6144, 14336};
    const int K = Karr[i], sv = 2 << i, Ti = 128 >> i;
    const int fb = fbarr[i];
    const int tid = threadIdx.x;
    const int dbase = dblk * 64;
    for (int e = tid; e < K * 64; e += 256) {
        int k = e >> 6, d0 = e & 63;
        ftile[k * 64 + d0] = filtT[fb + k * 512 + dbase + d0];
    }
    const float invsv = 1.f / (float)sv;
    const int t0 = thalf * 128;
    float p0 = ((float)t0 + 0.5f) * invsv - 0.5f;
    p0 = fminf(fmaxf(p0, 0.f), (float)(Ti - 1));
    const int jbase = (int)p0;
    float p1 = ((float)(t0 + 127) + 0.5f) * invsv - 0.5f;
    p1 = fminf(fmaxf(p1, 0.f), (float)(Ti - 1));
    const int him = min((int)p1 + 1, Ti - 1);
    const int jcount = him - jbase + 1;     // <= 66
    __syncthreads();
    const bh16* hcol = hb + (size_t)b * (TT * DD) + dbase;
    for (int e = tid; e < jcount * 64; e += 256) {
        int jl = e >> 6, d0 = e & 63;
        int j = jbase + jl;
        int tb = j * sv - (K - 1);
        float acc = 0.f;
        #pragma unroll 4
        for (int k = 0; k < K; ++k) {
            int t = tb + k;
            if (t >= 0)
                acc += b2f(*(const unsigned short*)(hcol + (size_t)t * DD + d0)) * ftile[k * 64 + d0];
        }
        dtile[jl * 64 + d0] = acc;
    }
    __syncthreads();
    for (int e = tid; e < 128 * 64; e += 256) {
        int tl = e >> 6, d0 = e & 63;
        int t = t0 + tl;
        float pos = ((float)t + 0.5f) * invsv - 0.5f;
        pos = fminf(fmaxf(pos, 0.f), (float)(Ti - 1));
        int lo = (int)pos;
        int hi = min(lo + 1, Ti - 1);
        float w = pos - (float)lo;
        float v = dtile[(lo - jbase) * 64 + d0] * (1.f - w) + dtile[(hi - jbase) * 64 + d0] * w;
        comb[((size_t)b * TT + t) * 2048 + i * 512 + dbase + d0] = __float2bfloat16(v);
    }
}

// ---------------- boundary loss: 32 blocks, one atomic per block ----------------
__global__ __launch_bounds__(256) void bd_loss_kernel(const float* __restrict__ tfb, const float* __restrict__ bdw,
                                                      const float* __restrict__ bdb, float* __restrict__ loss)
{
    __shared__ float wsum[4];
    int lane = threadIdx.x & 63, wid = threadIdx.x >> 6;
    float w = bdw[lane * 2] - bdw[lane * 2 + 1];
    float bconst = (bdb[0] - bdb[1]) + 0.1f;
    float acc = 0.f;
    for (int row = blockIdx.x * 4 + wid; row < BT; row += 128) {
        float vv = tfb[(size_t)row * PP + lane] * w;
        #pragma unroll
        for (int off = 32; off; off >>= 1) vv += __shfl_xor(vv, off);
        if (lane == 0) acc += fmaxf(vv + bconst, 0.f);
    }
    if (lane == 0) wsum[wid] = acc;
    __syncthreads();
    if (threadIdx.x == 0) {
        atomicAdd(loss, (wsum[0] + wsum[1] + wsum[2] + wsum[3]) * (1.f / 4096.f));
    }
}

// ---------------- h = layernorm(s0 + s1 + h)*g + b, dual fp32+bf16 out ----------------
__global__ __launch_bounds__(256) void add_ln_kernel(const float* __restrict__ s0, const float* __restrict__ s1,
                                                     float* __restrict__ h, bh16* __restrict__ hb,
                                                     const float* __restrict__ g, const float* __restrict__ be)
{
    int lane = threadIdx.x & 63, wid = threadIdx.x >> 6;
    size_t row = (size_t)blockIdx.x * 4 + wid;
    const float* sr0 = s0 + row * DD;
    const float* sr1 = s1 + row * DD;
    float* hr = h + row * DD;
    bh16* hbr = hb + row * DD;
    float xv[8]; float sum = 0.f;
    #pragma unroll
    for (int u = 0; u < 8; ++u) { int c = lane + u * 64; xv[u] = sr0[c] + sr1[c] + hr[c]; sum += xv[u]; }
    #pragma unroll
    for (int off = 32; off; off >>= 1) sum += __shfl_xor(sum, off);
    float mu = sum * (1.f / 512.f);
    float sq = 0.f;
    #pragma unroll
    for (int u = 0; u < 8; ++u) { float d = xv[u] - mu; sq += d * d; }
    #pragma unroll
    for (int off = 32; off; off >>= 1) sq += __shfl_xor(sq, off);
    float rstd = 1.f / sqrtf(sq * (1.f / 512.f) + 1e-5f);
    #pragma unroll
    for (int u = 0; u < 8; ++u) {
        int c = lane + u * 64;
        float v = (xv[u] - mu) * rstd * g[c] + be[c];
        hr[c] = v;
        hbr[c] = __float2bfloat16(v);
    }
}

// ---------------- weight transpose-convert: [l-sel][K][N] f32 -> out + l*lstride, [N][K] bf16 ----------------
__global__ __launch_bounds__(256) void wtrans_kernel(const float* __restrict__ W, bh16* __restrict__ Wt,
                                                     int K, int N, long lstride)
{
    int l = blockIdx.z;
    const float* Wl = W + (size_t)l * K * N;
    bh16* Wo = Wt + (size_t)l * lstride;
    __shared__ float tile[32][33];
    int n0 = blockIdx.x * 32, k0 = blockIdx.y * 32;
    int lx = threadIdx.x & 31, ly = threadIdx.x >> 5;
    #pragma unroll
    for (int j = 0; j < 4; ++j) {
        int kk = ly + j * 8;
        tile[kk][lx] = Wl[(size_t)(k0 + kk) * N + n0 + lx];
    }
    __syncthreads();
    #pragma unroll
    for (int j = 0; j < 4; ++j) {
        int nr = ly + j * 8;
        Wo[(size_t)(n0 + nr) * K + k0 + lx] = __float2bfloat16(tile[lx][nr]);
    }
}

// ---------------- cc_w [L][O][I][3] f32 -> ccT [L][O][tap*512+I] bf16 ----------------
__global__ __launch_bounds__(256) void ccconv_kernel(const float* __restrict__ ccw, bh16* __restrict__ ccT)
{
    size_t idx = (size_t)blockIdx.x * 256 + threadIdx.x;   // 6*512*1536
    int i = idx & 511; size_t rem = idx >> 9;
    int tap = (int)(rem % 3); rem /= 3;
    int o = (int)(rem & 511); int l = (int)(rem >> 9);
    ccT[idx] = __float2bfloat16(ccw[(((size_t)l*512 + o)*512 + i)*3 + tap]);
}

// ---------------- qkv|te1 bias concat [L][1600] + fused-epilogue bias sum [L][512] ----------------
__global__ __launch_bounds__(256) void qkvbias_kernel(const float* __restrict__ qb_, const float* __restrict__ kb_,
                                                      const float* __restrict__ vb_, const float* __restrict__ t1b_,
                                                      float* __restrict__ ob,
                                                      const float* __restrict__ gob, const float* __restrict__ wrb,
                                                      const float* __restrict__ tdb, const float* __restrict__ ccb,
                                                      float* __restrict__ bsum)
{
    int idx = blockIdx.x * 256 + threadIdx.x;
    if (idx < 6 * 1600) {
        int l = idx / 1600, n = idx % 1600;
        float v = (n < 512) ? qb_[l*512 + n]
                : (n < 1024) ? kb_[l*512 + n - 512]
                : (n < 1536) ? vb_[l*512 + n - 1024]
                : t1b_[l*64 + n - 1536];
        ob[idx] = v;
    }
    if (idx < 6 * 512) {
        bsum[idx] = gob[idx] + wrb[idx] + tdb[idx] + ccb[idx];
    }
}

// ---------------- x f32 -> bf16 ----------------
__global__ __launch_bounds__(256) void convx_kernel(const float* __restrict__ x, bh16* __restrict__ xb)
{
    size_t idx = (size_t)blockIdx.x * 256 + threadIdx.x;
    xb[idx] = __float2bfloat16(x[idx]);
}

// ---------------- E matrix: row (t,b) = [sched[t]*noise[t,b,:] | temb[t]] (bf16, 160x1024) ----------------
__global__ __launch_bounds__(256) void build_E_kernel(const float* __restrict__ noise, const float* __restrict__ sched,
                                                      bh16* __restrict__ E)
{
    int idx = blockIdx.x * 256 + threadIdx.x;   // 10*16*1024
    if (idx >= SS * BB * 1024) return;
    int k = idx & 1023; int rem = idx >> 10; int b = rem & 15; int t = rem >> 4;
    float v;
    if (k < 512) {
        v = sched[t] * noise[((size_t)t * BB + b) * 512 + k];
    } else {
        int j = k - 512;
        const float kfac = -9.210340371976184f / 255.f;   // -ln(10000)/255
        v = (j < 256) ? sinf((float)t * expf((float)j * kfac))
                      : cosf((float)t * expf((float)(j - 256) * kfac));
    }
    E[idx] = __float2bfloat16(v);
}

// ---------------- head helpers ----------------
__global__ void init_kernel(bh16* zp, float* loss)
{
    int t = threadIdx.x;
    if (t < 64) zp[t] = __float2bfloat16(0.f);
    if (t == 64) *loss = 0.f;
}

__global__ __launch_bounds__(256) void build_cat16_kernel(const float* __restrict__ h, bh16* __restrict__ catb)
{
    int idx = blockIdx.x * 256 + threadIdx.x;   // 16*1024
    if (idx >= BB * 1024) return;
    int k = idx & 1023, b = idx >> 10;
    float v = (k < 512) ? h[((size_t)b * TT + 255) * DD + k]
                        : h[((size_t)b * TT + 254) * DD + (k - 512)];
    catb[idx] = __float2bfloat16(v);
}

__global__ __launch_bounds__(256) void cur_init2_kernel(const float* __restrict__ h, const float* __restrict__ mix,
                                                        float* __restrict__ curf, bh16* __restrict__ curb)
{
    int idx = blockIdx.x * 256 + threadIdx.x;   // 16*512
    if (idx >= BB * DD) return;
    int c = idx & 511, b = idx >> 9;
    float v = h[((size_t)b * TT + 255) * DD + c] + mix[idx];
    curf[idx] = v;
    curb[idx] = __float2bfloat16(v);
}

__global__ void fail_kernel(float* p) { p[0] = 1e30f; }

// =====================================================================================
extern "C" void kernel_launch(void* const* d_in, const int* in_sizes, int n_in,
                              void* d_out, int out_size, void* d_ws, size_t ws_size,
                              hipStream_t stream)
{
    const float* x      = (const float*)d_in[0];
    const float* in_w   = (const float*)d_in[1];
    const float* in_b   = (const float*)d_in[2];
    const float* gq_w   = (const float*)d_in[3];
    const float* gq_b   = (const float*)d_in[4];
    const float* gk_w   = (const float*)d_in[5];
    const float* gk_b   = (const float*)d_in[6];
    const float* gv_w   = (const float*)d_in[7];
    const float* gv_b   = (const float*)d_in[8];
    const float* go_w   = (const float*)d_in[9];
    const float* go_b   = (const float*)d_in[10];
    const float* curv   = (const float*)d_in[11];
    const float* wav0   = (const float*)d_in[12];
    const float* wav1   = (const float*)d_in[13];
    const float* wav2   = (const float*)d_in[14];
    const float* wav3   = (const float*)d_in[15];
    const float* wrec_w = (const float*)d_in[16];
    const float* wrec_b = (const float*)d_in[17];
    const float* te1_w  = (const float*)d_in[18];
    const float* te1_b  = (const float*)d_in[19];
    const float* te2_w  = (const float*)d_in[20];
    const float* te2_b  = (const float*)d_in[21];
    const float* td1_w  = (const float*)d_in[22];
    const float* td1_b  = (const float*)d_in[23];
    const float* td2_w  = (const float*)d_in[24];
    const float* td2_b  = (const float*)d_in[25];
    const float* bd_w   = (const float*)d_in[26];
    const float* bd_b   = (const float*)d_in[27];
    const float* cc_w   = (const float*)d_in[28];
    const float* cc_b   = (const float*)d_in[29];
    const float* ln_g   = (const float*)d_in[30];
    const float* ln_b   = (const float*)d_in[31];
    const float* mm1_w  = (const float*)d_in[32];
    const float* mm1_b  = (const float*)d_in[33];
    const float* mm2_w  = (const float*)d_in[34];
    const float* mm2_b  = (const float*)d_in[35];
    const float* dn1_w  = (const float*)d_in[36];
    const float* dn1_b  = (const float*)d_in[37];
    const float* dn2_w  = (const float*)d_in[38];
    const float* dn2_b  = (const float*)d_in[39];
    const float* dn3_w  = (const float*)d_in[40];
    const float* dn3_b  = (const float*)d_in[41];
    const float* out_w  = (const float*)d_in[42];
    const float* out_b  = (const float*)d_in[43];
    const float* nsched = (const float*)d_in[44];
    const float* noise  = (const float*)d_in[45];
    float* out = (float*)d_out;
    float* ws  = (float*)d_ws;

    // ---- fp32 workspace layout (float offsets) ----
    const size_t o_h   = 0;          // 2097152
    const size_t o_dec = 2097152;    // 2097152 (s2 partial; pre1 for head)
    const size_t o_s   = 4194304;    // 2097152
    const size_t o_tf  = 6291456;    // 262144
    const size_t o_qn  = 6553600;    // 32768
    const size_t o_kn  = 6586368;    // 32768
    const size_t o_at  = 6619136;    // 8388608
    const size_t o_fl  = 15007744;   // 30720
    const size_t o_mix = 15038464;   // 8192
    const size_t o_cur = 15046656;   // 8192
    const size_t o_qkb = 15054848;   // 9600 (qkv|te1 bias [6][1600])
    const size_t o_bs  = 15064448;   // 3072 (fused bias sum [6][512])
    const size_t FP32_TOTAL = 15095808;
    // ---- bf16 region (element offsets from bp) ----
    const size_t b_xb   = 0;          // 1572864
    const size_t b_hb   = 1572864;    // 2097152
    const size_t b_qkv  = 3670016;    // 6553600: packed qkv|t1 [4096][1600]
    const size_t b_vt   = 10223616;   // 2097152
    const size_t b_pb   = 12320768;   // 8388608 (head scratch aliases here after layers)
    const size_t b_gmb  = 20709376;   // 2097152
    const size_t b_tdb  = 22806528;   // 2097152
    const size_t b_tfb  = 24903680;   // 262144
    const size_t b_zp   = 25165824;   // 512
    const size_t b_inwT = 25166336;   // 196608
    const size_t b_qkvT = 25362944;   // 4915200: [6][1600][512] (q|k|v|te1)
    const size_t b_goT  = 30278144;   // 1572864
    const size_t b_wrT  = 31851008;   // 6291456
    const size_t b_td1T = 38142464;   // 196608
    const size_t b_td2T = 38339072;   // 1572864
    const size_t b_te2T = 39911936;   // 24576
    const size_t b_ccT  = 39936512;   // 4718592: [6][512][1536]
    const size_t BF16_TOTAL = 44655104;
    const size_t TOTAL_BYTES = FP32_TOTAL * 4 + BF16_TOTAL * 2;
    if (ws_size < TOTAL_BYTES) { fail_kernel<<<1, 1, 0, stream>>>(out); return; }

    float* h_   = ws + o_h;
    float* s2_  = ws + o_dec;
    float* s_   = ws + o_s;
    float* tf_  = ws + o_tf;
    float* qn_  = ws + o_qn;
    float* kn_  = ws + o_kn;
    float* at_  = ws + o_at;
    float* fl_  = ws + o_fl;
    float* mixb = ws + o_mix;
    float* curf = ws + o_cur;
    float* qkvbias = ws + o_qkb;
    float* bsum = ws + o_bs;
    bh16* bp   = (bh16*)(ws + FP32_TOTAL);
    bh16* xb   = bp + b_xb;
    bh16* hb   = bp + b_hb;
    bh16* qkvb = bp + b_qkv;
    bh16* vt   = bp + b_vt;
    bh16* pb   = bp + b_pb;
    bh16* gmb  = bp + b_gmb;
    bh16* tdb  = bp + b_tdb;
    bh16* tfb  = bp + b_tfb;
    bh16* zp   = bp + b_zp;
    bh16* inwT = bp + b_inwT;
    bh16* qkvT = bp + b_qkvT;
    bh16* goT  = bp + b_goT;
    bh16* wrT  = bp + b_wrT;
    bh16* td1T = bp + b_td1T;
    bh16* td2T = bp + b_td2T;
    bh16* te2T = bp + b_te2T;
    bh16* ccT  = bp + b_ccT;
    bh16* combb = (bh16*)at_;   // aliases at_ after softmax consumed it

    // head bf16 scratch: aliased into pb region (dead after layer loop)
    bh16* dn1T  = pb;             // 524288
    bh16* dn2T  = pb + 524288;    // 262144
    bh16* dn3T  = pb + 786432;    // 262144
    bh16* mm1T  = pb + 1048576;   // 524288
    bh16* mm2T  = pb + 1572864;   // 262144
    bh16* outT  = pb + 1835008;   // 196608
    bh16* E16   = pb + 2031616;   // 163840
    bh16* cat16 = pb + 2195456;   // 16384
    bh16* tmb16 = pb + 2211840;   // 8192
    bh16* cur16 = pb + 2220032;   // 8192
    bh16* d1b16 = pb + 2228224;   // 8192
    bh16* d2b16 = pb + 2236416;   // 8192
    float* pre1 = s2_;            // 81920 f32, aliases s2 after layers

    auto mg = [&](const bh16* A, int lda, const bh16* Bt, int ldb,
                  const float* bias, float* Cf, bh16* Cb, int ldc,
                  int M, int N, int K, int shift, int accum, int act,
                  int nb, int zmask, int zshift,
                  long aS1, long aS0, long bS1, long bS0, long cS1, long cS0, int ccdil) {
        dim3 g((N + 63) / 64, M / 128, nb);
        mgemm_kernel<<<g, 256, 0, stream>>>(A, lda, Bt, ldb, bias, Cf, Cb, ldc, N, K,
                                            shift, accum, act, zmask, zshift,
                                            aS1, aS0, bS1, bS0, cS1, cS0, ccdil, zp);
    };
    auto mgp = [&](const bh16* A, int lda, const bh16* Bt, int ldb,
                   const float* bias, float* Cf, bh16* Cb, int ldc,
                   int M, int N, int K, int shift, int accum, int act) {
        mg(A, lda, Bt, ldb, bias, Cf, Cb, ldc, M, N, K, shift, accum, act, 1, 0, 0, 0, 0, 0, 0, 0, 0, 0);
    };
    auto hg = [&](const bh16* A, int lda, long aZ, const bh16* Bt, int ldb,
                  const float* bias, const float* pre, float* Of, bh16* Ob, long oZ,
                  int N, int K, int act, float* cf, bh16* cb, const float* sp, int nz) {
        hgemm16_kernel<<<dim3(N / 64, 1, nz), 256, 0, stream>>>(
            A, lda, aZ, Bt, ldb, bias, pre, Of, Ob, oZ, N, K, act, cf, cb, sp);
    };

    // ---- setup: zero page/loss, converts ----
    init_kernel<<<1, 128, 0, stream>>>(zp, out + BB * DIN);
    convx_kernel<<<BT * DIN / 256, 256, 0, stream>>>(x, xb);
    wtrans_kernel<<<dim3(DD/32, DIN/32, 1), 256, 0, stream>>>(in_w, inwT, DIN, DD, (long)DIN*DD);
    // packed qkvT: rows 0-511 q, 512-1023 k, 1024-1535 v, 1536-1599 te1; l-stride 819200
    wtrans_kernel<<<dim3(16, 16, 6), 256, 0, stream>>>(gq_w, qkvT,          DD, DD, 819200L);
    wtrans_kernel<<<dim3(16, 16, 6), 256, 0, stream>>>(gk_w, qkvT + 262144, DD, DD, 819200L);
    wtrans_kernel<<<dim3(16, 16, 6), 256, 0, stream>>>(gv_w, qkvT + 524288, DD, DD, 819200L);
    wtrans_kernel<<<dim3(2, 16, 6), 256, 0, stream>>>(te1_w, qkvT + 786432, DD, PP, 819200L);
    qkvbias_kernel<<<38, 256, 0, stream>>>(gq_b, gk_b, gv_b, te1_b, qkvbias,
                                           go_b, wrec_b, td2_b, cc_b, bsum);
    wtrans_kernel<<<dim3(16, 16, 6), 256, 0, stream>>>(go_w, goT, DD, DD, (long)DD*DD);
    wtrans_kernel<<<dim3(16, 64, 6), 256, 0, stream>>>(wrec_w, wrT, 2048, DD, 2048L*DD);
    wtrans_kernel<<<dim3(16, 2, 6), 256, 0, stream>>>(td1_w, td1T, PP, DD, (long)PP*DD);
    wtrans_kernel<<<dim3(16, 16, 6), 256, 0, stream>>>(td2_w, td2T, DD, DD, (long)DD*DD);
    wtrans_kernel<<<dim3(2, 2, 6), 256, 0, stream>>>(te2_w, te2T, PP, PP, (long)PP*PP);
    ccconv_kernel<<<18432, 256, 0, stream>>>(cc_w, ccT);

    // h = x @ in_w + in_b  (fp32 + bf16)
    mgp(xb, DIN, inwT, DIN, in_b, h_, hb, DD, BT, DD, DIN, 0, 0, ACT_NONE);

    for (int l = 0; l < LL; ++l) {
        // fused q|k|v|te1 projection: N=1600, packed output [BT][1600], tail relu on te1
        mgp(hb, DD, qkvT + (size_t)l*819200, DD, qkvbias + (size_t)l*1600,
            nullptr, qkvb, 1600, BT, 1600, DD, 0, 0, ACT_RELU_TAIL);
        // attention
        sqnorm2_kernel<<<dim3(8192, 2), 256, 0, stream>>>(qkvb, qn_, kn_);
        mg(qkvb, 1600, qkvb + 512, 1600, nullptr, at_, nullptr, TT, TT, TT, 64, 0, 0, ACT_NONE,
           128, 7, 3, 409600, 64, 409600, 64, 524288, 65536, 0);
        attn_softmax_kernel<<<8192, 256, 0, stream>>>(at_, pb, qn_, kn_, curv + (size_t)l*HH);
        vtrans_kernel<<<dim3(4, 128), 256, 0, stream>>>(qkvb + 1024, vt);
        mg(pb, TT, vt, TT, nullptr, nullptr, gmb, DD, TT, 64, TT, 0, 0, ACT_NONE,
           128, 7, 3, 524288, 65536, 131072, 16384, 131072, 64, 0);
        // wavelet branch: dec+interp fused (comb aliases at_, softmax already consumed it)
        filt_softmax_kernel<<<8, 256, 0, stream>>>(wav0 + (size_t)l*DD*4, wav1 + (size_t)l*DD*8,
                                                   wav2 + (size_t)l*DD*16, wav3 + (size_t)l*DD*32, fl_);
        wave4_kernel<<<dim3(8, 8, 16), 256, 0, stream>>>(hb, fl_, combb);
        // topo branch: te2 from t1 (packed at qkvb+1536), bd loss, td1
        mgp(qkvb + 1536, 1600, te2T + (size_t)l*4096, PP, te2_b + (size_t)l*PP, tf_, tfb, PP, BT, PP, PP, 0, 0, ACT_NONE);
        bd_loss_kernel<<<32, 256, 0, stream>>>(tf_, bd_w + (size_t)l*PP*2, bd_b + (size_t)l*2, out + BB*DIN);
        mgp(tfb, PP, td1T + (size_t)l*32768, PP, td1_b + (size_t)l*DD, nullptr, tdb, DD, BT, DD, PP, 0, 0, ACT_RELU);
        // fused split-K s = gmb@go + comb@wrec + tdb@td2 + cc(hb) + biassum
        fgemm_kernel<<<dim3(8, 32, 2), 256, 0, stream>>>(
            gmb, combb, tdb, hb,
            goT + (size_t)l*262144, wrT + (size_t)l*1048576,
            td2T + (size_t)l*262144, ccT + (size_t)l*786432,
            bsum + (size_t)l*512, s_, s2_, 1 << l, zp);
        // h = LN(s + s2 + h)
        add_ln_kernel<<<BT/4, 256, 0, stream>>>(s_, s2_, h_, hb, ln_g, ln_b);
    }

    // ---- head: convert weights (into dead pb region), precompute E/pre1 ----
    wtrans_kernel<<<dim3(16, 32, 1), 256, 0, stream>>>(dn1_w, dn1T, 1024, 512, 0L);
    wtrans_kernel<<<dim3(16, 16, 1), 256, 0, stream>>>(dn2_w, dn2T, 512, 512, 0L);
    wtrans_kernel<<<dim3(16, 16, 1), 256, 0, stream>>>(dn3_w, dn3T, 512, 512, 0L);
    wtrans_kernel<<<dim3(16, 32, 1), 256, 0, stream>>>(mm1_w, mm1T, 1024, 512, 0L);
    wtrans_kernel<<<dim3(16, 16, 1), 256, 0, stream>>>(mm2_w, mm2T, 512, 512, 0L);
    wtrans_kernel<<<dim3(12, 16, 1), 256, 0, stream>>>(out_w, outT, 512, 384, 0L);
    build_E_kernel<<<640, 256, 0, stream>>>(noise, nsched, E16);
    // pre1[t] = E_t @ dn1_w + dn1_b   (z-batched over t)
    hg(E16, 1024, 16*1024, dn1T, 1024, dn1_b, nullptr, pre1, nullptr, 8192,
       512, 1024, ACT_NONE, nullptr, nullptr, nullptr, SS);
    // mix head
    build_cat16_kernel<<<64, 256, 0, stream>>>(h_, cat16);
    hg(cat16, 1024, 0, mm1T, 1024, mm1_b, nullptr, nullptr, tmb16, 0,
       512, 1024, ACT_TANH, nullptr, nullptr, nullptr, 1);
    hg(tmb16, 512, 0, mm2T, 512, mm2_b, nullptr, mixb, nullptr, 0,
       512, 512, ACT_NONE, nullptr, nullptr, nullptr, 1);
    cur_init2_kernel<<<32, 256, 0, stream>>>(h_, mixb, curf, cur16);
    // diffusion chain: 3 launches per step
    for (int t = 0; t < SS; ++t) {
        hg(cur16, 512, 0, dn1T, 1024, nullptr, pre1 + (size_t)t*8192, nullptr, d1b16, 0,
           512, 512, ACT_SILU, nullptr, nullptr, nullptr, 1);
        hg(d1b16, 512, 0, dn2T, 512, dn2_b, nullptr, nullptr, d2b16, 0,
           512, 512, ACT_SILU, nullptr, nullptr, nullptr, 1);
        hg(d2b16, 512, 0, dn3T, 512, dn3_b, nullptr, nullptr, nullptr, 0,
           512, 512, ACT_NONE, curf, cur16, nsched + t, 1);
    }
    // pred = cur @ out_w + out_b
    hg(cur16, 512, 0, outT, 512, out_b, nullptr, out, nullptr, 0,
       384, 512, ACT_NONE, nullptr, nullptr, nullptr, 1);
}

// Round 12
// 1328.713 us; speedup vs baseline: 1.6545x; 1.0706x over previous
//
#include <hip/hip_runtime.h>
#include <hip/hip_bf16.h>
#include <math.h>

#define BB 16
#define TT 256
#define DIN 384
#define DD 512
#define LL 6
#define HH 8
#define PP 64
#define SS 10
#define BT (BB*TT)   // 4096

enum { ACT_NONE=0, ACT_RELU=1, ACT_TANH=2, ACT_SILU=3, ACT_RELU_TAIL=4 };

typedef __attribute__((ext_vector_type(8))) short bf16x8;
typedef __attribute__((ext_vector_type(4))) float f32x4;
typedef __hip_bfloat16 bh16;

typedef const __attribute__((address_space(1))) void gvoid_t;
typedef __attribute__((address_space(3))) void lvoid_t;
__device__ __forceinline__ void gload16(const void* g, void* l) {
    __builtin_amdgcn_global_load_lds((gvoid_t*)g, (lvoid_t*)l, 16, 0, 0);
}

__device__ __forceinline__ float b2f(unsigned short u) {
    return __uint_as_float(((unsigned int)u) << 16);
}

// bijective chunked XCD swizzle (m204) within one z-plane.
__device__ __forceinline__ void xcd_swizzle_always(int& bx, int& by) {
    int gx = gridDim.x;
    int nwg = gx * gridDim.y;
    int lid = by * gx + bx;
    int q = nwg >> 3, r = nwg & 7;
    int xcd = lid & 7, idx = lid >> 3;
    int swz = (xcd < r) ? (xcd * (q + 1) + idx) : (r * (q + 1) + (xcd - r) * q + idx);
    bx = swz % gx;
    by = swz / gx;
}
__device__ __forceinline__ void xcd_swizzle(int& bx, int& by) {
    if (gridDim.z == 1) xcd_swizzle_always(bx, by);
}

// =====================================================================================
// Generic bf16 MFMA GEMM: C = act(A @ Bt^T + bias)  (Bt stored [N][K])
__global__ __launch_bounds__(256) void mgemm_kernel(
    const bh16* __restrict__ A, int lda,
    const bh16* __restrict__ Bt, int ldb,
    const float* __restrict__ bias,
    float* __restrict__ Cf, bh16* __restrict__ Cb, int ldc,
    int N, int K, int shift, int accum, int act,
    int zmask, int zshift,
    long aS1, long aS0, long bS1, long bS0, long cS1, long cS0,
    int ccdil,
    const bh16* __restrict__ zp)
{
    __shared__ bf16x8 As[128*8];
    __shared__ bf16x8 Bs[64*8];

    int z = blockIdx.z;
    long z1 = (long)(z >> zshift), z0 = (long)(z & zmask);
    A  += z1*aS1 + z0*aS0;
    Bt += z1*bS1 + z0*bS0;
    long coff = z1*cS1 + z0*cS0;

    int bx = blockIdx.x, by = blockIdx.y;
    xcd_swizzle(bx, by);

    const int tid  = threadIdx.x;
    const int lane = tid & 63, w = tid >> 6;
    const int wm = w >> 1, wn = w & 1;
    const int row0 = by * 128, col0 = bx * 64;

    f32x4 acc[4][2];
    #pragma unroll
    for (int i = 0; i < 4; ++i)
        #pragma unroll
        for (int j = 0; j < 2; ++j) acc[i][j] = (f32x4){0.f,0.f,0.f,0.f};

    const int nkt = K >> 6;
    for (int kt = 0; kt < nkt; ++kt) {
        int k0 = kt << 6;
        int mask_sh, addr_sh;
        if (ccdil) {
            int tap = kt >> 3;
            mask_sh = (2 - tap) * ccdil;
            addr_sh = mask_sh + tap;
        } else {
            mask_sh = shift; addr_sh = shift;
        }
        #pragma unroll
        for (int j = 0; j < 4; ++j) {
            int c = ((w*4 + j) << 6) + lane;
            int row = c >> 3, chk = c & 7;
            int schk = chk ^ (row & 7);
            int grow = row0 + row;
            const bh16* src = ((grow & 255) >= mask_sh)
                ? (A + (size_t)(grow - addr_sh)*lda + k0 + schk*8) : zp;
            gload16(src, &As[(w*4 + j) * 64]);
        }
        #pragma unroll
        for (int j = 0; j < 2; ++j) {
            int c = ((w*2 + j) << 6) + lane;
            int row = c >> 3, chk = c & 7;
            int schk = chk ^ (row & 7);
            int gcol = col0 + row;
            const bh16* src = (gcol < N)
                ? (Bt + (size_t)gcol*ldb + k0 + schk*8) : zp;
            gload16(src, &Bs[(w*2 + j) * 64]);
        }
        asm volatile("s_waitcnt vmcnt(0)" ::: "memory");
        __syncthreads();

        bf16x8 a[4][2], b[2][2];
        #pragma unroll
        for (int fm = 0; fm < 4; ++fm) {
            int row = wm*64 + fm*16 + (lane & 15);
            #pragma unroll
            for (int ks = 0; ks < 2; ++ks)
                a[fm][ks] = As[row*8 + ((ks*4 + (lane>>4)) ^ (row & 7))];
        }
        #pragma unroll
        for (int fn = 0; fn < 2; ++fn) {
            int col = wn*32 + fn*16 + (lane & 15);
            #pragma unroll
            for (int ks = 0; ks < 2; ++ks)
                b[fn][ks] = Bs[col*8 + ((ks*4 + (lane>>4)) ^ (col & 7))];
        }
        #pragma unroll
        for (int ks = 0; ks < 2; ++ks)
            #pragma unroll
            for (int fm = 0; fm < 4; ++fm)
                #pragma unroll
                for (int fn = 0; fn < 2; ++fn)
                    acc[fm][fn] = __builtin_amdgcn_mfma_f32_16x16x32_bf16(
                        a[fm][ks], b[fn][ks], acc[fm][fn], 0, 0, 0);
        __syncthreads();
    }

    #pragma unroll
    for (int fm = 0; fm < 4; ++fm) {
        #pragma unroll
        for (int fn = 0; fn < 2; ++fn) {
            int gc = col0 + wn*32 + fn*16 + (lane & 15);
            float bs = bias ? bias[gc] : 0.f;
            #pragma unroll
            for (int r = 0; r < 4; ++r) {
                int gr = row0 + wm*64 + fm*16 + (lane>>4)*4 + r;
                float v = acc[fm][fn][r] + bs;
                if (act == ACT_RELU) v = fmaxf(v, 0.f);
                else if (act == ACT_RELU_TAIL && gc >= 1536) v = fmaxf(v, 0.f);
                size_t o = (size_t)gr*ldc + gc + coff;
                if (Cf) { if (accum) Cf[o] += v; else Cf[o] = v; }
                if (Cb) Cb[o] = __float2bfloat16(v);
            }
        }
    }
}

// =====================================================================================
// Fused attention: per block = 64 Q-rows of one (b,h). S=QK^T (regs) -> hyperbolic
// softmax (in-reg + LDS cross-wave) -> P restage (LDS, swizzled) -> PV via vt.
__global__ __launch_bounds__(256) void fattn_kernel(
    const bh16* __restrict__ qkv,      // [4096][1600]: q@0, k@+512
    const bh16* __restrict__ vt,       // [(bh*64+d)][256]
    const float* __restrict__ qn, const float* __restrict__ kn,   // [bh*256+t]
    const float* __restrict__ curv,    // per-layer, 8 heads
    bh16* __restrict__ gmb)            // [4096][512]
{
    __shared__ bf16x8 Qs[64*8];                    // 8KB
    __shared__ bf16x8 Ks[256*8];                   // 32KB
    __shared__ __align__(16) bh16 Ps[64*64];       // 8KB
    __shared__ bf16x8 Bv[64*8];                    // 8KB
    __shared__ float redA[2][64];
    __shared__ float redB[2][64];

    const int rh = blockIdx.x;         // 0..3 (64-row slab)
    const int bh = blockIdx.y;         // 0..127
    const int b = bh >> 3, hh = bh & 7;
    const int lane = threadIdx.x & 63, w = threadIdx.x >> 6;
    const int wm = w >> 1, wn = w & 1;

    const bh16* qbase = qkv + hh * 64;
    const bh16* kbase = qkv + 512 + hh * 64;
    // stage Q (64x64) and K (256x64), XOR-swizzled like mgemm
    #pragma unroll
    for (int j = 0; j < 2; ++j) {
        int c = ((w*2 + j) << 6) + lane;
        int row = c >> 3, chk = c & 7, schk = chk ^ (row & 7);
        gload16(qbase + (size_t)(b*256 + rh*64 + row)*1600 + schk*8, &Qs[(w*2+j)*64]);
    }
    #pragma unroll
    for (int j = 0; j < 8; ++j) {
        int c = ((w*8 + j) << 6) + lane;
        int row = c >> 3, chk = c & 7, schk = chk ^ (row & 7);
        gload16(kbase + (size_t)(b*256 + row)*1600 + schk*8, &Ks[(w*8+j)*64]);
    }
    asm volatile("s_waitcnt vmcnt(0)" ::: "memory");
    __syncthreads();

    // S = Q K^T : wave tile 32 rows x 128 cols; acc[fm 0..1][fn 0..7]
    f32x4 acc[2][8];
    #pragma unroll
    for (int i = 0; i < 2; ++i)
        #pragma unroll
        for (int j = 0; j < 8; ++j) acc[i][j] = (f32x4){0.f,0.f,0.f,0.f};

    bf16x8 af[2][2];
    #pragma unroll
    for (int fm = 0; fm < 2; ++fm) {
        int row = wm*32 + fm*16 + (lane & 15);
        #pragma unroll
        for (int ks = 0; ks < 2; ++ks)
            af[fm][ks] = Qs[row*8 + ((ks*4 + (lane>>4)) ^ (row & 7))];
    }
    #pragma unroll
    for (int fn = 0; fn < 8; ++fn) {
        int col = wn*128 + fn*16 + (lane & 15);
        #pragma unroll
        for (int ks = 0; ks < 2; ++ks) {
            bf16x8 bf = Ks[col*8 + ((ks*4 + (lane>>4)) ^ (col & 7))];
            #pragma unroll
            for (int fm = 0; fm < 2; ++fm)
                acc[fm][fn] = __builtin_amdgcn_mfma_f32_16x16x32_bf16(
                    af[fm][ks], bf, acc[fm][fn], 0, 0, 0);
        }
    }

    // hyperbolic distance -> logits (in place), track row max
    const float c_ = fabsf(curv[hh]) + 1e-8f;
    const float isc = 1.f / sqrtf(c_);
    float qnv[2][4], knv[8];
    #pragma unroll
    for (int fm = 0; fm < 2; ++fm)
        #pragma unroll
        for (int r = 0; r < 4; ++r)
            qnv[fm][r] = qn[bh*256 + rh*64 + wm*32 + fm*16 + (lane>>4)*4 + r];
    #pragma unroll
    for (int fn = 0; fn < 8; ++fn)
        knv[fn] = kn[bh*256 + wn*128 + fn*16 + (lane & 15)];

    float rmax[2][4];
    #pragma unroll
    for (int fm = 0; fm < 2; ++fm)
        #pragma unroll
        for (int r = 0; r < 4; ++r) rmax[fm][r] = -1e30f;
    #pragma unroll
    for (int fm = 0; fm < 2; ++fm)
        #pragma unroll
        for (int fn = 0; fn < 8; ++fn)
            #pragma unroll
            for (int r = 0; r < 4; ++r) {
                float s = acc[fm][fn][r];
                float d2 = fmaxf(qnv[fm][r] + knv[fn] - 2.f * s, 0.f);
                float denom = fmaxf((1.f - c_ * qnv[fm][r]) * (1.f - c_ * knv[fn]), 1e-5f);
                float arg = fmaxf(1.f + (2.f * c_ * d2) / denom, 1.00001f);
                float dist = logf(arg + sqrtf((arg - 1.f) * (arg + 1.f))) * isc;
                float lg = -dist;
                acc[fm][fn][r] = lg;
                rmax[fm][r] = fmaxf(rmax[fm][r], lg);
            }
    // reduce max across 16 col-lanes, then across wn pair via LDS
    #pragma unroll
    for (int off = 1; off < 16; off <<= 1)
        #pragma unroll
        for (int fm = 0; fm < 2; ++fm)
            #pragma unroll
            for (int r = 0; r < 4; ++r)
                rmax[fm][r] = fmaxf(rmax[fm][r], __shfl_xor(rmax[fm][r], off));
    if ((lane & 15) == 0)
        #pragma unroll
        for (int fm = 0; fm < 2; ++fm)
            #pragma unroll
            for (int r = 0; r < 4; ++r)
                redA[wn][wm*32 + fm*16 + (lane>>4)*4 + r] = rmax[fm][r];
    __syncthreads();
    #pragma unroll
    for (int fm = 0; fm < 2; ++fm)
        #pragma unroll
        for (int r = 0; r < 4; ++r)
            rmax[fm][r] = fmaxf(rmax[fm][r], redA[wn ^ 1][wm*32 + fm*16 + (lane>>4)*4 + r]);
    // exp + row sum
    float rsum[2][4];
    #pragma unroll
    for (int fm = 0; fm < 2; ++fm)
        #pragma unroll
        for (int r = 0; r < 4; ++r) rsum[fm][r] = 0.f;
    #pragma unroll
    for (int fm = 0; fm < 2; ++fm)
        #pragma unroll
        for (int fn = 0; fn < 8; ++fn)
            #pragma unroll
            for (int r = 0; r < 4; ++r) {
                float e = expf(acc[fm][fn][r] - rmax[fm][r]);
                acc[fm][fn][r] = e;
                rsum[fm][r] += e;
            }
    #pragma unroll
    for (int off = 1; off < 16; off <<= 1)
        #pragma unroll
        for (int fm = 0; fm < 2; ++fm)
            #pragma unroll
            for (int r = 0; r < 4; ++r)
                rsum[fm][r] += __shfl_xor(rsum[fm][r], off);
    if ((lane & 15) == 0)
        #pragma unroll
        for (int fm = 0; fm < 2; ++fm)
            #pragma unroll
            for (int r = 0; r < 4; ++r)
                redB[wn][wm*32 + fm*16 + (lane>>4)*4 + r] = rsum[fm][r];
    __syncthreads();
    float pinv[2][4];
    #pragma unroll
    for (int fm = 0; fm < 2; ++fm)
        #pragma unroll
        for (int r = 0; r < 4; ++r)
            pinv[fm][r] = 1.f / (rsum[fm][r] + redB[wn ^ 1][wm*32 + fm*16 + (lane>>4)*4 + r]);

    // PV: loop over 4 k-tiles of 64; restage P into swizzled LDS A-tile
    f32x4 acc2[2][2];
    #pragma unroll
    for (int i = 0; i < 2; ++i)
        #pragma unroll
        for (int j = 0; j < 2; ++j) acc2[i][j] = (f32x4){0.f,0.f,0.f,0.f};

    for (int kt = 0; kt < 4; ++kt) {
        __syncthreads();   // previous-iteration reads done
        if (wn == (kt >> 1)) {
            int fnb = (kt & 1) * 4;
            #pragma unroll
            for (int fm = 0; fm < 2; ++fm)
                #pragma unroll
                for (int fnl = 0; fnl < 4; ++fnl)
                    #pragma unroll
                    for (int r = 0; r < 4; ++r) {
                        int rowl = wm*32 + fm*16 + (lane>>4)*4 + r;
                        int kl = fnl*16 + (lane & 15);
                        float p = acc[fm][fnb + fnl][r] * pinv[fm][r];
                        Ps[(rowl*8 + ((kl >> 3) ^ (rowl & 7)))*8 + (kl & 7)] = __float2bfloat16(p);
                    }
        }
        #pragma unroll
        for (int j = 0; j < 2; ++j) {
            int c = ((w*2 + j) << 6) + lane;
            int col = c >> 3, chk = c & 7, schk = chk ^ (col & 7);
            gload16(vt + (size_t)(bh*64 + col)*256 + kt*64 + schk*8, &Bv[(w*2+j)*64]);
        }
        asm volatile("s_waitcnt vmcnt(0)" ::: "memory");
        __syncthreads();

        bf16x8 pa[2][2], vb[2][2];
        #pragma unroll
        for (int fm = 0; fm < 2; ++fm) {
            int row = wm*32 + fm*16 + (lane & 15);
            #pragma unroll
            for (int ks = 0; ks < 2; ++ks)
                pa[fm][ks] = ((bf16x8*)Ps)[row*8 + ((ks*4 + (lane>>4)) ^ (row & 7))];
        }
        #pragma unroll
        for (int fn = 0; fn < 2; ++fn) {
            int col = wn*32 + fn*16 + (lane & 15);
            #pragma unroll
            for (int ks = 0; ks < 2; ++ks)
                vb[fn][ks] = Bv[col*8 + ((ks*4 + (lane>>4)) ^ (col & 7))];
        }
        #pragma unroll
        for (int ks = 0; ks < 2; ++ks)
            #pragma unroll
            for (int fm = 0; fm < 2; ++fm)
                #pragma unroll
                for (int fn = 0; fn < 2; ++fn)
                    acc2[fm][fn] = __builtin_amdgcn_mfma_f32_16x16x32_bf16(
                        pa[fm][ks], vb[fn][ks], acc2[fm][fn], 0, 0, 0);
    }

    #pragma unroll
    for (int fm = 0; fm < 2; ++fm)
        #pragma unroll
        for (int fn = 0; fn < 2; ++fn)
            #pragma unroll
            for (int r = 0; r < 4; ++r) {
                int rowl = wm*32 + fm*16 + (lane>>4)*4 + r;
                int col = wn*32 + fn*16 + (lane & 15);
                gmb[((size_t)(b*256 + rh*64 + rowl))*512 + hh*64 + col] =
                    __float2bfloat16(acc2[fm][fn][r]);
            }
}

// =====================================================================================
// Fused 4-segment GEMM, split-K over blockIdx.z
__global__ __launch_bounds__(256) void fgemm_kernel(
    const bh16* __restrict__ A0, const bh16* __restrict__ A1,
    const bh16* __restrict__ A2, const bh16* __restrict__ A3,
    const bh16* __restrict__ B0, const bh16* __restrict__ B1,
    const bh16* __restrict__ B2, const bh16* __restrict__ B3,
    const float* __restrict__ bias, float* __restrict__ Cf0, float* __restrict__ Cf1,
    int dil, const bh16* __restrict__ zp)
{
    __shared__ bf16x8 As[128*8];
    __shared__ bf16x8 Bs[64*8];

    int bx = blockIdx.x, by = blockIdx.y;
    xcd_swizzle_always(bx, by);
    const int zz = blockIdx.z;
    const int ktlo = zz ? 36 : 0;
    const int kthi = zz ? 72 : 36;

    const int tid  = threadIdx.x;
    const int lane = tid & 63, w = tid >> 6;
    const int wm = w >> 1, wn = w & 1;
    const int row0 = by * 128, col0 = bx * 64;

    f32x4 acc[4][2];
    #pragma unroll
    for (int i = 0; i < 4; ++i)
        #pragma unroll
        for (int j = 0; j < 2; ++j) acc[i][j] = (f32x4){0.f,0.f,0.f,0.f};

    for (int kt = ktlo; kt < kthi; ++kt) {
        const bh16* Aseg; const bh16* Bseg;
        int ldas, ldbs, k0, mask_sh, addr_sh;
        if (kt < 8) {
            Aseg = A0; Bseg = B0; ldas = 512; ldbs = 512;
            k0 = kt << 6; mask_sh = 0; addr_sh = 0;
        } else if (kt < 40) {
            Aseg = A1; Bseg = B1; ldas = 2048; ldbs = 2048;
            k0 = (kt - 8) << 6; mask_sh = 0; addr_sh = 0;
        } else if (kt < 48) {
            Aseg = A2; Bseg = B2; ldas = 512; ldbs = 512;
            k0 = (kt - 40) << 6; mask_sh = 0; addr_sh = 0;
        } else {
            int kl = kt - 48, tap = kl >> 3;
            Aseg = A3; Bseg = B3; ldas = 512; ldbs = 1536;
            k0 = kl << 6;
            mask_sh = (2 - tap) * dil;
            addr_sh = mask_sh + tap;
        }
        #pragma unroll
        for (int j = 0; j < 4; ++j) {
            int c = ((w*4 + j) << 6) + lane;
            int row = c >> 3, chk = c & 7;
            int schk = chk ^ (row & 7);
            int grow = row0 + row;
            const bh16* src = ((grow & 255) >= mask_sh)
                ? (Aseg + (size_t)(grow - addr_sh)*ldas + k0 + schk*8) : zp;
            gload16(src, &As[(w*4 + j) * 64]);
        }
        #pragma unroll
        for (int j = 0; j < 2; ++j) {
            int c = ((w*2 + j) << 6) + lane;
            int row = c >> 3, chk = c & 7;
            int schk = chk ^ (row & 7);
            int gcol = col0 + row;
            gload16(Bseg + (size_t)gcol*ldbs + k0 + schk*8, &Bs[(w*2 + j) * 64]);
        }
        asm volatile("s_waitcnt vmcnt(0)" ::: "memory");
        __syncthreads();

        bf16x8 a[4][2], b[2][2];
        #pragma unroll
        for (int fm = 0; fm < 4; ++fm) {
            int row = wm*64 + fm*16 + (lane & 15);
            #pragma unroll
            for (int ks = 0; ks < 2; ++ks)
                a[fm][ks] = As[row*8 + ((ks*4 + (lane>>4)) ^ (row & 7))];
        }
        #pragma unroll
        for (int fn = 0; fn < 2; ++fn) {
            int col = wn*32 + fn*16 + (lane & 15);
            #pragma unroll
            for (int ks = 0; ks < 2; ++ks)
                b[fn][ks] = Bs[col*8 + ((ks*4 + (lane>>4)) ^ (col & 7))];
        }
        #pragma unroll
        for (int ks = 0; ks < 2; ++ks)
            #pragma unroll
            for (int fm = 0; fm < 4; ++fm)
                #pragma unroll
                for (int fn = 0; fn < 2; ++fn)
                    acc[fm][fn] = __builtin_amdgcn_mfma_f32_16x16x32_bf16(
                        a[fm][ks], b[fn][ks], acc[fm][fn], 0, 0, 0);
        __syncthreads();
    }

    float* Cf = zz ? Cf1 : Cf0;
    #pragma unroll
    for (int fm = 0; fm < 4; ++fm) {
        #pragma unroll
        for (int fn = 0; fn < 2; ++fn) {
            int gc = col0 + wn*32 + fn*16 + (lane & 15);
            float bs = zz ? 0.f : bias[gc];
            #pragma unroll
            for (int r = 0; r < 4; ++r) {
                int gr = row0 + wm*64 + fm*16 + (lane>>4)*4 + r;
                Cf[(size_t)gr*512 + gc] = acc[fm][fn][r] + bs;
            }
        }
    }
}

// =====================================================================================
// Small-M (M=16) MFMA GEMM, one wave = 16x16xK tile, no LDS.
__global__ __launch_bounds__(256) void hgemm16_kernel(
    const bh16* __restrict__ A, int lda, long aZ,
    const bh16* __restrict__ Bt, int ldb,
    const float* __restrict__ bias,
    const float* __restrict__ pre,
    float* __restrict__ Of, bh16* __restrict__ Ob, long oZ,
    int N, int K, int act,
    float* __restrict__ curf, bh16* __restrict__ curb,
    const float* __restrict__ scaleptr)
{
    const int z = blockIdx.z;
    A += (long)z * aZ;
    const int lane = threadIdx.x & 63, w = threadIdx.x >> 6;
    const int col0 = blockIdx.x * 64 + w * 16;
    const int ar = lane & 15;
    const int koff = (lane >> 4) * 8;
    const bh16* arow = A + (size_t)ar * lda + koff;
    const bh16* brow = Bt + (size_t)(col0 + ar) * ldb + koff;
    f32x4 acc = {0.f, 0.f, 0.f, 0.f};
    const int nkt = K >> 5;
    for (int kt0 = 0; kt0 < nkt; kt0 += 8) {
        bf16x8 av[8], bv[8];
        #pragma unroll
        for (int j = 0; j < 8; ++j) {
            av[j] = *(const bf16x8*)(arow + (size_t)(kt0 + j) * 32);
            bv[j] = *(const bf16x8*)(brow + (size_t)(kt0 + j) * 32);
        }
        #pragma unroll
        for (int j = 0; j < 8; ++j)
            acc = __builtin_amdgcn_mfma_f32_16x16x32_bf16(av[j], bv[j], acc, 0, 0, 0);
    }
    const int col = col0 + ar;
    float bs = bias ? bias[col] : 0.f;
    float sc = scaleptr ? *scaleptr : 0.f;
    #pragma unroll
    for (int r = 0; r < 4; ++r) {
        int row = (lane >> 4) * 4 + r;
        float v = acc[r] + bs;
        if (pre) v += pre[(size_t)row * N + col];
        if (act == ACT_SILU)      v = v / (1.f + expf(-v));
        else if (act == ACT_TANH) v = tanhf(v);
        if (curf) {
            size_t o = (size_t)row * 512 + col;
            float nc = curf[o] - v * sc;
            curf[o] = nc;
            curb[o] = __float2bfloat16(nc);
        } else {
            size_t o = (size_t)z * oZ + (size_t)row * N + col;
            if (Of) Of[o] = v;
            if (Ob) Ob[o] = __float2bfloat16(v);
        }
    }
}

// ---------------- per-head squared norms from packed qkv (lda=1600) ----------------
__global__ __launch_bounds__(256) void sqnorm2_kernel(const bh16* __restrict__ qkv,
                                                      float* __restrict__ qn, float* __restrict__ kn)
{
    int lane = threadIdx.x & 63, wid = threadIdx.x >> 6;
    int row = blockIdx.x * 4 + wid;            // over B*H*T
    const bh16* src = qkv + (blockIdx.y ? 512 : 0);
    float* dst = blockIdx.y ? kn : qn;
    int t = row & 255; int bh = row >> 8; int b = bh >> 3, hh = bh & 7;
    float v = __bfloat162float(src[((size_t)b * TT + t) * 1600 + hh * 64 + lane]);
    float s = v * v;
    #pragma unroll
    for (int off = 32; off; off >>= 1) s += __shfl_xor(s, off);
    if (lane == 0) dst[row] = s;
}

// ---------------- V transpose per (b,h): packed qkv (v at +1024, lda=1600) -> vt[bh][d][t] ----------------
__global__ __launch_bounds__(256) void vtrans_kernel(const bh16* __restrict__ vb, bh16* __restrict__ vt)
{
    int bh = blockIdx.y, b = bh >> 3, hh = bh & 7;
    int t0 = blockIdx.x * 64;
    __shared__ bh16 tile[64][65];
    for (int e = threadIdx.x; e < 4096; e += 256) {
        int r = e >> 6, c = e & 63;
        tile[r][c] = vb[((size_t)(b*256 + t0 + r))*1600 + hh*64 + c];
    }
    __syncthreads();
    for (int e = threadIdx.x; e < 4096; e += 256) {
        int d = e >> 6, t2 = e & 63;
        vt[((size_t)bh*64 + d)*256 + t0 + t2] = tile[t2][d];
    }
}

// ---------------- wavelet filter softmax -> TRANSPOSED layout fT[i][k][512] ----------------
__global__ __launch_bounds__(256) void filt_softmax_kernel(const float* __restrict__ w0, const float* __restrict__ w1,
                                                           const float* __restrict__ w2, const float* __restrict__ w3,
                                                           float* __restrict__ filt)
{
    int idx = blockIdx.x * 256 + threadIdx.x;
    if (idx >= 4 * DD) return;
    int d = idx & 511, i = idx >> 9;
    const float* w = (i == 0) ? w0 : (i == 1) ? w1 : (i == 2) ? w2 : w3;
    int K = 4 << i;
    int fb = (i == 0) ? 0 : (i == 1) ? 2048 : (i == 2) ? 6144 : 14336;
    const float* row = w + (size_t)d * K;
    float mx = -1e30f;
    for (int k = 0; k < K; ++k) mx = fmaxf(mx, row[k]);
    float s = 0.f;
    for (int k = 0; k < K; ++k) s += expf(row[k] - mx);
    float inv = 1.f / s;
    float* fo = filt + fb;
    for (int k = 0; k < K; ++k) fo[k * 512 + d] = expf(row[k] - mx) * inv;   // [k][d]
}

// ---------------- wavelet: dec (small LDS tile) + interp, per (dblk, i, thalf, b) ----------------
__global__ __launch_bounds__(256) void wave4_kernel(const bh16* __restrict__ hb,
                                                    const float* __restrict__ filtT,
                                                    bh16* __restrict__ comb)
{
    __shared__ float dtile[66 * 64];
    __shared__ float ftile[32 * 64];
    const int dblk = blockIdx.x;
    const int iy = blockIdx.y;
    const int b = blockIdx.z;
    const int i = iy >> 1, thalf = iy & 1;
    const int Karr[4] = {4, 8, 16, 32};
    const int fbarr[4] = {0, 2048, 6144, 14336};
    const int K = Karr[i], sv = 2 << i, Ti = 128 >> i;
    const int fb = fbarr[i];
    const int tid = threadIdx.x;
    const int dbase = dblk * 64;
    for (int e = tid; e < K * 64; e += 256) {
        int k = e >> 6, d0 = e & 63;
        ftile[k * 64 + d0] = filtT[fb + k * 512 + dbase + d0];
    }
    const float invsv = 1.f / (float)sv;
    const int t0 = thalf * 128;
    float p0 = ((float)t0 + 0.5f) * invsv - 0.5f;
    p0 = fminf(fmaxf(p0, 0.f), (float)(Ti - 1));
    const int jbase = (int)p0;
    float p1 = ((float)(t0 + 127) + 0.5f) * invsv - 0.5f;
    p1 = fminf(fmaxf(p1, 0.f), (float)(Ti - 1));
    const int him = min((int)p1 + 1, Ti - 1);
    const int jcount = him - jbase + 1;     // <= 66
    __syncthreads();
    const bh16* hcol = hb + (size_t)b * (TT * DD) + dbase;
    for (int e = tid; e < jcount * 64; e += 256) {
        int jl = e >> 6, d0 = e & 63;
        int j = jbase + jl;
        int tb = j * sv - (K - 1);
        float acc = 0.f;
        #pragma unroll 4
        for (int k = 0; k < K; ++k) {
            int t = tb + k;
            if (t >= 0)
                acc += b2f(*(const unsigned short*)(hcol + (size_t)t * DD + d0)) * ftile[k * 64 + d0];
        }
        dtile[jl * 64 + d0] = acc;
    }
    __syncthreads();
    for (int e = tid; e < 128 * 64; e += 256) {
        int tl = e >> 6, d0 = e & 63;
        int t = t0 + tl;
        float pos = ((float)t + 0.5f) * invsv - 0.5f;
        pos = fminf(fmaxf(pos, 0.f), (float)(Ti - 1));
        int lo = (int)pos;
        int hi = min(lo + 1, Ti - 1);
        float w = pos - (float)lo;
        float v = dtile[(lo - jbase) * 64 + d0] * (1.f - w) + dtile[(hi - jbase) * 64 + d0] * w;
        comb[((size_t)b * TT + t) * 2048 + i * 512 + dbase + d0] = __float2bfloat16(v);
    }
}

// ---------------- boundary loss: 32 blocks, one atomic per block ----------------
__global__ __launch_bounds__(256) void bd_loss_kernel(const float* __restrict__ tfb, const float* __restrict__ bdw,
                                                      const float* __restrict__ bdb, float* __restrict__ loss)
{
    __shared__ float wsum[4];
    int lane = threadIdx.x & 63, wid = threadIdx.x >> 6;
    float w = bdw[lane * 2] - bdw[lane * 2 + 1];
    float bconst = (bdb[0] - bdb[1]) + 0.1f;
    float acc = 0.f;
    for (int row = blockIdx.x * 4 + wid; row < BT; row += 128) {
        float vv = tfb[(size_t)row * PP + lane] * w;
        #pragma unroll
        for (int off = 32; off; off >>= 1) vv += __shfl_xor(vv, off);
        if (lane == 0) acc += fmaxf(vv + bconst, 0.f);
    }
    if (lane == 0) wsum[wid] = acc;
    __syncthreads();
    if (threadIdx.x == 0) {
        atomicAdd(loss, (wsum[0] + wsum[1] + wsum[2] + wsum[3]) * (1.f / 4096.f));
    }
}

// ---------------- h = layernorm(s0 + s1 + h)*g + b, dual fp32+bf16 out ----------------
__global__ __launch_bounds__(256) void add_ln_kernel(const float* __restrict__ s0, const float* __restrict__ s1,
                                                     float* __restrict__ h, bh16* __restrict__ hb,
                                                     const float* __restrict__ g, const float* __restrict__ be)
{
    int lane = threadIdx.x & 63, wid = threadIdx.x >> 6;
    size_t row = (size_t)blockIdx.x * 4 + wid;
    const float* sr0 = s0 + row * DD;
    const float* sr1 = s1 + row * DD;
    float* hr = h + row * DD;
    bh16* hbr = hb + row * DD;
    float xv[8]; float sum = 0.f;
    #pragma unroll
    for (int u = 0; u < 8; ++u) { int c = lane + u * 64; xv[u] = sr0[c] + sr1[c] + hr[c]; sum += xv[u]; }
    #pragma unroll
    for (int off = 32; off; off >>= 1) sum += __shfl_xor(sum, off);
    float mu = sum * (1.f / 512.f);
    float sq = 0.f;
    #pragma unroll
    for (int u = 0; u < 8; ++u) { float d = xv[u] - mu; sq += d * d; }
    #pragma unroll
    for (int off = 32; off; off >>= 1) sq += __shfl_xor(sq, off);
    float rstd = 1.f / sqrtf(sq * (1.f / 512.f) + 1e-5f);
    #pragma unroll
    for (int u = 0; u < 8; ++u) {
        int c = lane + u * 64;
        float v = (xv[u] - mu) * rstd * g[c] + be[c];
        hr[c] = v;
        hbr[c] = __float2bfloat16(v);
    }
}

// ---------------- weight transpose-convert ----------------
__global__ __launch_bounds__(256) void wtrans_kernel(const float* __restrict__ W, bh16* __restrict__ Wt,
                                                     int K, int N, long lstride)
{
    int l = blockIdx.z;
    const float* Wl = W + (size_t)l * K * N;
    bh16* Wo = Wt + (size_t)l * lstride;
    __shared__ float tile[32][33];
    int n0 = blockIdx.x * 32, k0 = blockIdx.y * 32;
    int lx = threadIdx.x & 31, ly = threadIdx.x >> 5;
    #pragma unroll
    for (int j = 0; j < 4; ++j) {
        int kk = ly + j * 8;
        tile[kk][lx] = Wl[(size_t)(k0 + kk) * N + n0 + lx];
    }
    __syncthreads();
    #pragma unroll
    for (int j = 0; j < 4; ++j) {
        int nr = ly + j * 8;
        Wo[(size_t)(n0 + nr) * K + k0 + lx] = __float2bfloat16(tile[lx][nr]);
    }
}

// ---------------- cc_w [L][O][I][3] f32 -> ccT [L][O][tap*512+I] bf16 ----------------
__global__ __launch_bounds__(256) void ccconv_kernel(const float* __restrict__ ccw, bh16* __restrict__ ccT)
{
    size_t idx = (size_t)blockIdx.x * 256 + threadIdx.x;   // 6*512*1536
    int i = idx & 511; size_t rem = idx >> 9;
    int tap = (int)(rem % 3); rem /= 3;
    int o = (int)(rem & 511); int l = (int)(rem >> 9);
    ccT[idx] = __float2bfloat16(ccw[(((size_t)l*512 + o)*512 + i)*3 + tap]);
}

// ---------------- qkv|te1 bias concat [L][1600] + fused-epilogue bias sum [L][512] ----------------
__global__ __launch_bounds__(256) void qkvbias_kernel(const float* __restrict__ qb_, const float* __restrict__ kb_,
                                                      const float* __restrict__ vb_, const float* __restrict__ t1b_,
                                                      float* __restrict__ ob,
                                                      const float* __restrict__ gob, const float* __restrict__ wrb,
                                                      const float* __restrict__ tdb, const float* __restrict__ ccb,
                                                      float* __restrict__ bsum)
{
    int idx = blockIdx.x * 256 + threadIdx.x;
    if (idx < 6 * 1600) {
        int l = idx / 1600, n = idx % 1600;
        float v = (n < 512) ? qb_[l*512 + n]
                : (n < 1024) ? kb_[l*512 + n - 512]
                : (n < 1536) ? vb_[l*512 + n - 1024]
                : t1b_[l*64 + n - 1536];
        ob[idx] = v;
    }
    if (idx < 6 * 512) {
        bsum[idx] = gob[idx] + wrb[idx] + tdb[idx] + ccb[idx];
    }
}

// ---------------- x f32 -> bf16 ----------------
__global__ __launch_bounds__(256) void convx_kernel(const float* __restrict__ x, bh16* __restrict__ xb)
{
    size_t idx = (size_t)blockIdx.x * 256 + threadIdx.x;
    xb[idx] = __float2bfloat16(x[idx]);
}

// ---------------- E matrix: row (t,b) = [sched[t]*noise[t,b,:] | temb[t]] ----------------
__global__ __launch_bounds__(256) void build_E_kernel(const float* __restrict__ noise, const float* __restrict__ sched,
                                                      bh16* __restrict__ E)
{
    int idx = blockIdx.x * 256 + threadIdx.x;   // 10*16*1024
    if (idx >= SS * BB * 1024) return;
    int k = idx & 1023; int rem = idx >> 10; int b = rem & 15; int t = rem >> 4;
    float v;
    if (k < 512) {
        v = sched[t] * noise[((size_t)t * BB + b) * 512 + k];
    } else {
        int j = k - 512;
        const float kfac = -9.210340371976184f / 255.f;
        v = (j < 256) ? sinf((float)t * expf((float)j * kfac))
                      : cosf((float)t * expf((float)(j - 256) * kfac));
    }
    E[idx] = __float2bfloat16(v);
}

// ---------------- head helpers ----------------
__global__ void init_kernel(bh16* zp, float* loss)
{
    int t = threadIdx.x;
    if (t < 64) zp[t] = __float2bfloat16(0.f);
    if (t == 64) *loss = 0.f;
}

__global__ __launch_bounds__(256) void build_cat16_kernel(const float* __restrict__ h, bh16* __restrict__ catb)
{
    int idx = blockIdx.x * 256 + threadIdx.x;   // 16*1024
    if (idx >= BB * 1024) return;
    int k = idx & 1023, b = idx >> 10;
    float v = (k < 512) ? h[((size_t)b * TT + 255) * DD + k]
                        : h[((size_t)b * TT + 254) * DD + (k - 512)];
    catb[idx] = __float2bfloat16(v);
}

__global__ __launch_bounds__(256) void cur_init2_kernel(const float* __restrict__ h, const float* __restrict__ mix,
                                                        float* __restrict__ curf, bh16* __restrict__ curb)
{
    int idx = blockIdx.x * 256 + threadIdx.x;   // 16*512
    if (idx >= BB * DD) return;
    int c = idx & 511, b = idx >> 9;
    float v = h[((size_t)b * TT + 255) * DD + c] + mix[idx];
    curf[idx] = v;
    curb[idx] = __float2bfloat16(v);
}

__global__ void fail_kernel(float* p) { p[0] = 1e30f; }

// =====================================================================================
extern "C" void kernel_launch(void* const* d_in, const int* in_sizes, int n_in,
                              void* d_out, int out_size, void* d_ws, size_t ws_size,
                              hipStream_t stream)
{
    const float* x      = (const float*)d_in[0];
    const float* in_w   = (const float*)d_in[1];
    const float* in_b   = (const float*)d_in[2];
    const float* gq_w   = (const float*)d_in[3];
    const float* gq_b   = (const float*)d_in[4];
    const float* gk_w   = (const float*)d_in[5];
    const float* gk_b   = (const float*)d_in[6];
    const float* gv_w   = (const float*)d_in[7];
    const float* gv_b   = (const float*)d_in[8];
    const float* go_w   = (const float*)d_in[9];
    const float* go_b   = (const float*)d_in[10];
    const float* curv   = (const float*)d_in[11];
    const float* wav0   = (const float*)d_in[12];
    const float* wav1   = (const float*)d_in[13];
    const float* wav2   = (const float*)d_in[14];
    const float* wav3   = (const float*)d_in[15];
    const float* wrec_w = (const float*)d_in[16];
    const float* wrec_b = (const float*)d_in[17];
    const float* te1_w  = (const float*)d_in[18];
    const float* te1_b  = (const float*)d_in[19];
    const float* te2_w  = (const float*)d_in[20];
    const float* te2_b  = (const float*)d_in[21];
    const float* td1_w  = (const float*)d_in[22];
    const float* td1_b  = (const float*)d_in[23];
    const float* td2_w  = (const float*)d_in[24];
    const float* td2_b  = (const float*)d_in[25];
    const float* bd_w   = (const float*)d_in[26];
    const float* bd_b   = (const float*)d_in[27];
    const float* cc_w   = (const float*)d_in[28];
    const float* cc_b   = (const float*)d_in[29];
    const float* ln_g   = (const float*)d_in[30];
    const float* ln_b   = (const float*)d_in[31];
    const float* mm1_w  = (const float*)d_in[32];
    const float* mm1_b  = (const float*)d_in[33];
    const float* mm2_w  = (const float*)d_in[34];
    const float* mm2_b  = (const float*)d_in[35];
    const float* dn1_w  = (const float*)d_in[36];
    const float* dn1_b  = (const float*)d_in[37];
    const float* dn2_w  = (const float*)d_in[38];
    const float* dn2_b  = (const float*)d_in[39];
    const float* dn3_w  = (const float*)d_in[40];
    const float* dn3_b  = (const float*)d_in[41];
    const float* out_w  = (const float*)d_in[42];
    const float* out_b  = (const float*)d_in[43];
    const float* nsched = (const float*)d_in[44];
    const float* noise  = (const float*)d_in[45];
    float* out = (float*)d_out;
    float* ws  = (float*)d_ws;

    // ---- fp32 workspace layout (float offsets) ----
    const size_t o_h   = 0;          // 2097152
    const size_t o_dec = 2097152;    // 2097152 (s2 partial; pre1 for head)
    const size_t o_s   = 4194304;    // 2097152
    const size_t o_tf  = 6291456;    // 262144
    const size_t o_qn  = 6553600;    // 32768
    const size_t o_kn  = 6586368;    // 32768
    const size_t o_at  = 6619136;    // 8388608 (comb aliases)
    const size_t o_fl  = 15007744;   // 30720
    const size_t o_mix = 15038464;   // 8192
    const size_t o_cur = 15046656;   // 8192
    const size_t o_qkb = 15054848;   // 9600
    const size_t o_bs  = 15064448;   // 3072
    const size_t FP32_TOTAL = 15095808;
    // ---- bf16 region (element offsets from bp) ----
    const size_t b_xb   = 0;          // 1572864
    const size_t b_hb   = 1572864;    // 2097152
    const size_t b_qkv  = 3670016;    // 6553600: packed qkv|t1 [4096][1600]
    const size_t b_vt   = 10223616;   // 2097152
    const size_t b_pb   = 12320768;   // 8388608 (head scratch region)
    const size_t b_gmb  = 20709376;   // 2097152
    const size_t b_tdb  = 22806528;   // 2097152
    const size_t b_tfb  = 24903680;   // 262144
    const size_t b_zp   = 25165824;   // 512
    const size_t b_inwT = 25166336;   // 196608
    const size_t b_qkvT = 25362944;   // 4915200
    const size_t b_goT  = 30278144;   // 1572864
    const size_t b_wrT  = 31851008;   // 6291456
    const size_t b_td1T = 38142464;   // 196608
    const size_t b_td2T = 38339072;   // 1572864
    const size_t b_te2T = 39911936;   // 24576
    const size_t b_ccT  = 39936512;   // 4718592
    const size_t BF16_TOTAL = 44655104;
    const size_t TOTAL_BYTES = FP32_TOTAL * 4 + BF16_TOTAL * 2;
    if (ws_size < TOTAL_BYTES) { fail_kernel<<<1, 1, 0, stream>>>(out); return; }

    float* h_   = ws + o_h;
    float* s2_  = ws + o_dec;
    float* s_   = ws + o_s;
    float* tf_  = ws + o_tf;
    float* qn_  = ws + o_qn;
    float* kn_  = ws + o_kn;
    float* at_  = ws + o_at;
    float* fl_  = ws + o_fl;
    float* mixb = ws + o_mix;
    float* curf = ws + o_cur;
    float* qkvbias = ws + o_qkb;
    float* bsum = ws + o_bs;
    bh16* bp   = (bh16*)(ws + FP32_TOTAL);
    bh16* xb   = bp + b_xb;
    bh16* hb   = bp + b_hb;
    bh16* qkvb = bp + b_qkv;
    bh16* vt   = bp + b_vt;
    bh16* pb   = bp + b_pb;
    bh16* gmb  = bp + b_gmb;
    bh16* tdb  = bp + b_tdb;
    bh16* tfb  = bp + b_tfb;
    bh16* zp   = bp + b_zp;
    bh16* inwT = bp + b_inwT;
    bh16* qkvT = bp + b_qkvT;
    bh16* goT  = bp + b_goT;
    bh16* wrT  = bp + b_wrT;
    bh16* td1T = bp + b_td1T;
    bh16* td2T = bp + b_td2T;
    bh16* te2T = bp + b_te2T;
    bh16* ccT  = bp + b_ccT;
    bh16* combb = (bh16*)at_;   // comb aliases at_

    // head bf16 scratch: aliased into pb region (dead during layers)
    bh16* dn1T  = pb;             // 524288
    bh16* dn2T  = pb + 524288;    // 262144
    bh16* dn3T  = pb + 786432;    // 262144
    bh16* mm1T  = pb + 1048576;   // 524288
    bh16* mm2T  = pb + 1572864;   // 262144
    bh16* outT  = pb + 1835008;   // 196608
    bh16* E16   = pb + 2031616;   // 163840
    bh16* cat16 = pb + 2195456;   // 16384
    bh16* tmb16 = pb + 2211840;   // 8192
    bh16* cur16 = pb + 2220032;   // 8192
    bh16* d1b16 = pb + 2228224;   // 8192
    bh16* d2b16 = pb + 2236416;   // 8192
    float* pre1 = s2_;            // 81920 f32, aliases s2 after layers

    auto mgp = [&](const bh16* A, int lda, const bh16* Bt, int ldb,
                   const float* bias, float* Cf, bh16* Cb, int ldc,
                   int M, int N, int K, int shift, int accum, int act) {
        dim3 g((N + 63) / 64, M / 128, 1);
        mgemm_kernel<<<g, 256, 0, stream>>>(A, lda, Bt, ldb, bias, Cf, Cb, ldc, N, K,
                                            shift, accum, act, 0, 0,
                                            0, 0, 0, 0, 0, 0, 0, zp);
    };
    auto hg = [&](const bh16* A, int lda, long aZ, const bh16* Bt, int ldb,
                  const float* bias, const float* pre, float* Of, bh16* Ob, long oZ,
                  int N, int K, int act, float* cf, bh16* cb, const float* sp, int nz) {
        hgemm16_kernel<<<dim3(N / 64, 1, nz), 256, 0, stream>>>(
            A, lda, aZ, Bt, ldb, bias, pre, Of, Ob, oZ, N, K, act, cf, cb, sp);
    };

    // ---- setup: zero page/loss, converts ----
    init_kernel<<<1, 128, 0, stream>>>(zp, out + BB * DIN);
    convx_kernel<<<BT * DIN / 256, 256, 0, stream>>>(x, xb);
    wtrans_kernel<<<dim3(DD/32, DIN/32, 1), 256, 0, stream>>>(in_w, inwT, DIN, DD, (long)DIN*DD);
    wtrans_kernel<<<dim3(16, 16, 6), 256, 0, stream>>>(gq_w, qkvT,          DD, DD, 819200L);
    wtrans_kernel<<<dim3(16, 16, 6), 256, 0, stream>>>(gk_w, qkvT + 262144, DD, DD, 819200L);
    wtrans_kernel<<<dim3(16, 16, 6), 256, 0, stream>>>(gv_w, qkvT + 524288, DD, DD, 819200L);
    wtrans_kernel<<<dim3(2, 16, 6), 256, 0, stream>>>(te1_w, qkvT + 786432, DD, PP, 819200L);
    qkvbias_kernel<<<38, 256, 0, stream>>>(gq_b, gk_b, gv_b, te1_b, qkvbias,
                                           go_b, wrec_b, td2_b, cc_b, bsum);
    wtrans_kernel<<<dim3(16, 16, 6), 256, 0, stream>>>(go_w, goT, DD, DD, (long)DD*DD);
    wtrans_kernel<<<dim3(16, 64, 6), 256, 0, stream>>>(wrec_w, wrT, 2048, DD, 2048L*DD);
    wtrans_kernel<<<dim3(16, 2, 6), 256, 0, stream>>>(td1_w, td1T, PP, DD, (long)PP*DD);
    wtrans_kernel<<<dim3(16, 16, 6), 256, 0, stream>>>(td2_w, td2T, DD, DD, (long)DD*DD);
    wtrans_kernel<<<dim3(2, 2, 6), 256, 0, stream>>>(te2_w, te2T, PP, PP, (long)PP*PP);
    ccconv_kernel<<<18432, 256, 0, stream>>>(cc_w, ccT);

    // h = x @ in_w + in_b  (fp32 + bf16)
    mgp(xb, DIN, inwT, DIN, in_b, h_, hb, DD, BT, DD, DIN, 0, 0, ACT_NONE);

    for (int l = 0; l < LL; ++l) {
        // fused q|k|v|te1 projection: N=1600, tail relu on te1
        mgp(hb, DD, qkvT + (size_t)l*819200, DD, qkvbias + (size_t)l*1600,
            nullptr, qkvb, 1600, BT, 1600, DD, 0, 0, ACT_RELU_TAIL);
        // attention: norms, V-transpose, then fully fused QK^T+softmax+PV
        sqnorm2_kernel<<<dim3(8192, 2), 256, 0, stream>>>(qkvb, qn_, kn_);
        vtrans_kernel<<<dim3(4, 128), 256, 0, stream>>>(qkvb + 1024, vt);
        fattn_kernel<<<dim3(4, 128), 256, 0, stream>>>(qkvb, vt, qn_, kn_, curv + (size_t)l*HH, gmb);
        // wavelet branch: dec+interp fused (comb aliases at_)
        filt_softmax_kernel<<<8, 256, 0, stream>>>(wav0 + (size_t)l*DD*4, wav1 + (size_t)l*DD*8,
                                                   wav2 + (size_t)l*DD*16, wav3 + (size_t)l*DD*32, fl_);
        wave4_kernel<<<dim3(8, 8, 16), 256, 0, stream>>>(hb, fl_, combb);
        // topo branch: te2 from t1 (packed at qkvb+1536), bd loss, td1
        mgp(qkvb + 1536, 1600, te2T + (size_t)l*4096, PP, te2_b + (size_t)l*PP, tf_, tfb, PP, BT, PP, PP, 0, 0, ACT_NONE);
        bd_loss_kernel<<<32, 256, 0, stream>>>(tf_, bd_w + (size_t)l*PP*2, bd_b + (size_t)l*2, out + BB*DIN);
        mgp(tfb, PP, td1T + (size_t)l*32768, PP, td1_b + (size_t)l*DD, nullptr, tdb, DD, BT, DD, PP, 0, 0, ACT_RELU);
        // fused split-K s = gmb@go + comb@wrec + tdb@td2 + cc(hb) + biassum
        fgemm_kernel<<<dim3(8, 32, 2), 256, 0, stream>>>(
            gmb, combb, tdb, hb,
            goT + (size_t)l*262144, wrT + (size_t)l*1048576,
            td2T + (size_t)l*262144, ccT + (size_t)l*786432,
            bsum + (size_t)l*512, s_, s2_, 1 << l, zp);
        // h = LN(s + s2 + h)
        add_ln_kernel<<<BT/4, 256, 0, stream>>>(s_, s2_, h_, hb, ln_g, ln_b);
    }

    // ---- head ----
    wtrans_kernel<<<dim3(16, 32, 1), 256, 0, stream>>>(dn1_w, dn1T, 1024, 512, 0L);
    wtrans_kernel<<<dim3(16, 16, 1), 256, 0, stream>>>(dn2_w, dn2T, 512, 512, 0L);
    wtrans_kernel<<<dim3(16, 16, 1), 256, 0, stream>>>(dn3_w, dn3T, 512, 512, 0L);
    wtrans_kernel<<<dim3(16, 32, 1), 256, 0, stream>>>(mm1_w, mm1T, 1024, 512, 0L);
    wtrans_kernel<<<dim3(16, 16, 1), 256, 0, stream>>>(mm2_w, mm2T, 512, 512, 0L);
    wtrans_kernel<<<dim3(12, 16, 1), 256, 0, stream>>>(out_w, outT, 512, 384, 0L);
    build_E_kernel<<<640, 256, 0, stream>>>(noise, nsched, E16);
    hg(E16, 1024, 16*1024, dn1T, 1024, dn1_b, nullptr, pre1, nullptr, 8192,
       512, 1024, ACT_NONE, nullptr, nullptr, nullptr, SS);
    build_cat16_kernel<<<64, 256, 0, stream>>>(h_, cat16);
    hg(cat16, 1024, 0, mm1T, 1024, mm1_b, nullptr, nullptr, tmb16, 0,
       512, 1024, ACT_TANH, nullptr, nullptr, nullptr, 1);
    hg(tmb16, 512, 0, mm2T, 512, mm2_b, nullptr, mixb, nullptr, 0,
       512, 512, ACT_NONE, nullptr, nullptr, nullptr, 1);
    cur_init2_kernel<<<32, 256, 0, stream>>>(h_, mixb, curf, cur16);
    for (int t = 0; t < SS; ++t) {
        hg(cur16, 512, 0, dn1T, 1024, nullptr, pre1 + (size_t)t*8192, nullptr, d1b16, 0,
           512, 512, ACT_SILU, nullptr, nullptr, nullptr, 1);
        hg(d1b16, 512, 0, dn2T, 512, dn2_b, nullptr, nullptr, d2b16, 0,
           512, 512, ACT_SILU, nullptr, nullptr, nullptr, 1);
        hg(d2b16, 512, 0, dn3T, 512, dn3_b, nullptr, nullptr, nullptr, 0,
           512, 512, ACT_NONE, curf, cur16, nsched + t, 1);
    }
    hg(cur16, 512, 0, outT, 512, out_b, nullptr, out, nullptr, 0,
       384, 512, ACT_NONE, nullptr, nullptr, nullptr, 1);
}

// Round 13
// 1207.788 us; speedup vs baseline: 1.8201x; 1.1001x over previous
//
#include <hip/hip_runtime.h>
#include <hip/hip_bf16.h>
#include <math.h>

#define BB 16
#define TT 256
#define DIN 384
#define DD 512
#define LL 6
#define HH 8
#define PP 64
#define SS 10
#define BT (BB*TT)   // 4096

enum { ACT_NONE=0, ACT_RELU=1, ACT_TANH=2, ACT_SILU=3, ACT_RELU_TAIL=4 };

typedef __attribute__((ext_vector_type(8))) short bf16x8;
typedef __attribute__((ext_vector_type(4))) float f32x4;
typedef __hip_bfloat16 bh16;

typedef const __attribute__((address_space(1))) void gvoid_t;
typedef __attribute__((address_space(3))) void lvoid_t;
__device__ __forceinline__ void gload16(const void* g, void* l) {
    __builtin_amdgcn_global_load_lds((gvoid_t*)g, (lvoid_t*)l, 16, 0, 0);
}

__device__ __forceinline__ float b2f(unsigned short u) {
    return __uint_as_float(((unsigned int)u) << 16);
}

// bijective chunked XCD swizzle (m204) within one z-plane.
__device__ __forceinline__ void xcd_swizzle_always(int& bx, int& by) {
    int gx = gridDim.x;
    int nwg = gx * gridDim.y;
    int lid = by * gx + bx;
    int q = nwg >> 3, r = nwg & 7;
    int xcd = lid & 7, idx = lid >> 3;
    int swz = (xcd < r) ? (xcd * (q + 1) + idx) : (r * (q + 1) + (xcd - r) * q + idx);
    bx = swz % gx;
    by = swz / gx;
}
__device__ __forceinline__ void xcd_swizzle(int& bx, int& by) {
    if (gridDim.z == 1) xcd_swizzle_always(bx, by);
}

// =====================================================================================
// Generic bf16 MFMA GEMM: C = act(A @ Bt^T + bias)  (Bt stored [N][K])
__global__ __launch_bounds__(256) void mgemm_kernel(
    const bh16* __restrict__ A, int lda,
    const bh16* __restrict__ Bt, int ldb,
    const float* __restrict__ bias,
    float* __restrict__ Cf, bh16* __restrict__ Cb, int ldc,
    int N, int K, int shift, int accum, int act,
    int zmask, int zshift,
    long aS1, long aS0, long bS1, long bS0, long cS1, long cS0,
    int ccdil,
    const bh16* __restrict__ zp)
{
    __shared__ bf16x8 As[128*8];
    __shared__ bf16x8 Bs[64*8];

    int z = blockIdx.z;
    long z1 = (long)(z >> zshift), z0 = (long)(z & zmask);
    A  += z1*aS1 + z0*aS0;
    Bt += z1*bS1 + z0*bS0;
    long coff = z1*cS1 + z0*cS0;

    int bx = blockIdx.x, by = blockIdx.y;
    xcd_swizzle(bx, by);

    const int tid  = threadIdx.x;
    const int lane = tid & 63, w = tid >> 6;
    const int wm = w >> 1, wn = w & 1;
    const int row0 = by * 128, col0 = bx * 64;

    f32x4 acc[4][2];
    #pragma unroll
    for (int i = 0; i < 4; ++i)
        #pragma unroll
        for (int j = 0; j < 2; ++j) acc[i][j] = (f32x4){0.f,0.f,0.f,0.f};

    const int nkt = K >> 6;
    for (int kt = 0; kt < nkt; ++kt) {
        int k0 = kt << 6;
        int mask_sh, addr_sh;
        if (ccdil) {
            int tap = kt >> 3;
            mask_sh = (2 - tap) * ccdil;
            addr_sh = mask_sh + tap;
        } else {
            mask_sh = shift; addr_sh = shift;
        }
        #pragma unroll
        for (int j = 0; j < 4; ++j) {
            int c = ((w*4 + j) << 6) + lane;
            int row = c >> 3, chk = c & 7;
            int schk = chk ^ (row & 7);
            int grow = row0 + row;
            const bh16* src = ((grow & 255) >= mask_sh)
                ? (A + (size_t)(grow - addr_sh)*lda + k0 + schk*8) : zp;
            gload16(src, &As[(w*4 + j) * 64]);
        }
        #pragma unroll
        for (int j = 0; j < 2; ++j) {
            int c = ((w*2 + j) << 6) + lane;
            int row = c >> 3, chk = c & 7;
            int schk = chk ^ (row & 7);
            int gcol = col0 + row;
            const bh16* src = (gcol < N)
                ? (Bt + (size_t)gcol*ldb + k0 + schk*8) : zp;
            gload16(src, &Bs[(w*2 + j) * 64]);
        }
        asm volatile("s_waitcnt vmcnt(0)" ::: "memory");
        __syncthreads();

        bf16x8 a[4][2], b[2][2];
        #pragma unroll
        for (int fm = 0; fm < 4; ++fm) {
            int row = wm*64 + fm*16 + (lane & 15);
            #pragma unroll
            for (int ks = 0; ks < 2; ++ks)
                a[fm][ks] = As[row*8 + ((ks*4 + (lane>>4)) ^ (row & 7))];
        }
        #pragma unroll
        for (int fn = 0; fn < 2; ++fn) {
            int col = wn*32 + fn*16 + (lane & 15);
            #pragma unroll
            for (int ks = 0; ks < 2; ++ks)
                b[fn][ks] = Bs[col*8 + ((ks*4 + (lane>>4)) ^ (col & 7))];
        }
        #pragma unroll
        for (int ks = 0; ks < 2; ++ks)
            #pragma unroll
            for (int fm = 0; fm < 4; ++fm)
                #pragma unroll
                for (int fn = 0; fn < 2; ++fn)
                    acc[fm][fn] = __builtin_amdgcn_mfma_f32_16x16x32_bf16(
                        a[fm][ks], b[fn][ks], acc[fm][fn], 0, 0, 0);
        __syncthreads();
    }

    #pragma unroll
    for (int fm = 0; fm < 4; ++fm) {
        #pragma unroll
        for (int fn = 0; fn < 2; ++fn) {
            int gc = col0 + wn*32 + fn*16 + (lane & 15);
            float bs = bias ? bias[gc] : 0.f;
            #pragma unroll
            for (int r = 0; r < 4; ++r) {
                int gr = row0 + wm*64 + fm*16 + (lane>>4)*4 + r;
                float v = acc[fm][fn][r] + bs;
                if (act == ACT_RELU) v = fmaxf(v, 0.f);
                else if (act == ACT_RELU_TAIL && gc >= 1536) v = fmaxf(v, 0.f);
                size_t o = (size_t)gr*ldc + gc + coff;
                if (Cf) { if (accum) Cf[o] += v; else Cf[o] = v; }
                if (Cb) Cb[o] = __float2bfloat16(v);
            }
        }
    }
}

// =====================================================================================
// Fused attention v2: norms + QK^T + hyperbolic softmax + V-transpose + PV, one kernel.
__global__ __launch_bounds__(256) void fattn_kernel(
    const bh16* __restrict__ qkv,      // [4096][1600]: q@0, k@+512, v@+1024
    const float* __restrict__ curv,    // per-layer, 8 heads
    bh16* __restrict__ gmb)            // [4096][512]
{
    __shared__ bf16x8 Qs[64*8];                    // 8KB
    __shared__ bf16x8 Ks[256*8];                   // 32KB
    __shared__ __align__(16) bh16 Ps[64*64];       // 8KB
    __shared__ bf16x8 Bv[64*8];                    // 8KB
    __shared__ unsigned short Vst[64*72];          // 9KB (padded, 16B-aligned rows)
    __shared__ float redA[2][64];
    __shared__ float redB[2][64];
    __shared__ float qnS[64];
    __shared__ float knS[256];

    const int rh = blockIdx.x;         // 0..3 (64-row slab)
    const int bh = blockIdx.y;         // 0..127
    const int b = bh >> 3, hh = bh & 7;
    const int lane = threadIdx.x & 63, w = threadIdx.x >> 6;
    const int wm = w >> 1, wn = w & 1;

    const bh16* qbase = qkv + hh * 64;
    const bh16* kbase = qkv + 512 + hh * 64;
    // stage Q (64x64) and K (256x64), XOR-swizzled like mgemm
    #pragma unroll
    for (int j = 0; j < 2; ++j) {
        int c = ((w*2 + j) << 6) + lane;
        int row = c >> 3, chk = c & 7, schk = chk ^ (row & 7);
        gload16(qbase + (size_t)(b*256 + rh*64 + row)*1600 + schk*8, &Qs[(w*2+j)*64]);
    }
    #pragma unroll
    for (int j = 0; j < 8; ++j) {
        int c = ((w*8 + j) << 6) + lane;
        int row = c >> 3, chk = c & 7, schk = chk ^ (row & 7);
        gload16(kbase + (size_t)(b*256 + row)*1600 + schk*8, &Ks[(w*8+j)*64]);
    }
    asm volatile("s_waitcnt vmcnt(0)" ::: "memory");
    __syncthreads();

    // norms from staged tiles (swizzle is a per-row chunk bijection -> plain sums)
    {
        int t = threadIdx.x;
        float s = 0.f;
        #pragma unroll
        for (int jj = 0; jj < 8; ++jj) {
            bf16x8 v = Ks[t*8 + ((t + jj) & 7)];
            #pragma unroll
            for (int e = 0; e < 8; ++e) { float f = b2f((unsigned short)v[e]); s += f * f; }
        }
        knS[t] = s;
        if (t < 64) {
            float sq = 0.f;
            #pragma unroll
            for (int jj = 0; jj < 8; ++jj) {
                bf16x8 v = Qs[t*8 + ((t + jj) & 7)];
                #pragma unroll
                for (int e = 0; e < 8; ++e) { float f = b2f((unsigned short)v[e]); sq += f * f; }
            }
            qnS[t] = sq;
        }
    }
    __syncthreads();

    // S = Q K^T : wave tile 32 rows x 128 cols; acc[fm 0..1][fn 0..7]
    f32x4 acc[2][8];
    #pragma unroll
    for (int i = 0; i < 2; ++i)
        #pragma unroll
        for (int j = 0; j < 8; ++j) acc[i][j] = (f32x4){0.f,0.f,0.f,0.f};

    bf16x8 af[2][2];
    #pragma unroll
    for (int fm = 0; fm < 2; ++fm) {
        int row = wm*32 + fm*16 + (lane & 15);
        #pragma unroll
        for (int ks = 0; ks < 2; ++ks)
            af[fm][ks] = Qs[row*8 + ((ks*4 + (lane>>4)) ^ (row & 7))];
    }
    #pragma unroll
    for (int fn = 0; fn < 8; ++fn) {
        int col = wn*128 + fn*16 + (lane & 15);
        #pragma unroll
        for (int ks = 0; ks < 2; ++ks) {
            bf16x8 bf = Ks[col*8 + ((ks*4 + (lane>>4)) ^ (col & 7))];
            #pragma unroll
            for (int fm = 0; fm < 2; ++fm)
                acc[fm][fn] = __builtin_amdgcn_mfma_f32_16x16x32_bf16(
                    af[fm][ks], bf, acc[fm][fn], 0, 0, 0);
        }
    }

    // hyperbolic distance -> logits (in place), track row max
    const float c_ = fabsf(curv[hh]) + 1e-8f;
    const float isc = 1.f / sqrtf(c_);
    float qnv[2][4], knv[8];
    #pragma unroll
    for (int fm = 0; fm < 2; ++fm)
        #pragma unroll
        for (int r = 0; r < 4; ++r)
            qnv[fm][r] = qnS[wm*32 + fm*16 + (lane>>4)*4 + r];
    #pragma unroll
    for (int fn = 0; fn < 8; ++fn)
        knv[fn] = knS[wn*128 + fn*16 + (lane & 15)];

    float rmax[2][4];
    #pragma unroll
    for (int fm = 0; fm < 2; ++fm)
        #pragma unroll
        for (int r = 0; r < 4; ++r) rmax[fm][r] = -1e30f;
    #pragma unroll
    for (int fm = 0; fm < 2; ++fm)
        #pragma unroll
        for (int fn = 0; fn < 8; ++fn)
            #pragma unroll
            for (int r = 0; r < 4; ++r) {
                float s = acc[fm][fn][r];
                float d2 = fmaxf(qnv[fm][r] + knv[fn] - 2.f * s, 0.f);
                float denom = fmaxf((1.f - c_ * qnv[fm][r]) * (1.f - c_ * knv[fn]), 1e-5f);
                float arg = fmaxf(1.f + (2.f * c_ * d2) / denom, 1.00001f);
                float dist = logf(arg + sqrtf((arg - 1.f) * (arg + 1.f))) * isc;
                float lg = -dist;
                acc[fm][fn][r] = lg;
                rmax[fm][r] = fmaxf(rmax[fm][r], lg);
            }
    #pragma unroll
    for (int off = 1; off < 16; off <<= 1)
        #pragma unroll
        for (int fm = 0; fm < 2; ++fm)
            #pragma unroll
            for (int r = 0; r < 4; ++r)
                rmax[fm][r] = fmaxf(rmax[fm][r], __shfl_xor(rmax[fm][r], off));
    if ((lane & 15) == 0)
        #pragma unroll
        for (int fm = 0; fm < 2; ++fm)
            #pragma unroll
            for (int r = 0; r < 4; ++r)
                redA[wn][wm*32 + fm*16 + (lane>>4)*4 + r] = rmax[fm][r];
    __syncthreads();
    #pragma unroll
    for (int fm = 0; fm < 2; ++fm)
        #pragma unroll
        for (int r = 0; r < 4; ++r)
            rmax[fm][r] = fmaxf(rmax[fm][r], redA[wn ^ 1][wm*32 + fm*16 + (lane>>4)*4 + r]);
    float rsum[2][4];
    #pragma unroll
    for (int fm = 0; fm < 2; ++fm)
        #pragma unroll
        for (int r = 0; r < 4; ++r) rsum[fm][r] = 0.f;
    #pragma unroll
    for (int fm = 0; fm < 2; ++fm)
        #pragma unroll
        for (int fn = 0; fn < 8; ++fn)
            #pragma unroll
            for (int r = 0; r < 4; ++r) {
                float e = expf(acc[fm][fn][r] - rmax[fm][r]);
                acc[fm][fn][r] = e;
                rsum[fm][r] += e;
            }
    #pragma unroll
    for (int off = 1; off < 16; off <<= 1)
        #pragma unroll
        for (int fm = 0; fm < 2; ++fm)
            #pragma unroll
            for (int r = 0; r < 4; ++r)
                rsum[fm][r] += __shfl_xor(rsum[fm][r], off);
    if ((lane & 15) == 0)
        #pragma unroll
        for (int fm = 0; fm < 2; ++fm)
            #pragma unroll
            for (int r = 0; r < 4; ++r)
                redB[wn][wm*32 + fm*16 + (lane>>4)*4 + r] = rsum[fm][r];
    __syncthreads();
    float pinv[2][4];
    #pragma unroll
    for (int fm = 0; fm < 2; ++fm)
        #pragma unroll
        for (int r = 0; r < 4; ++r)
            pinv[fm][r] = 1.f / (rsum[fm][r] + redB[wn ^ 1][wm*32 + fm*16 + (lane>>4)*4 + r]);

    // PV: loop over 4 k-tiles of 64; restage P + transpose V inside LDS
    f32x4 acc2[2][2];
    #pragma unroll
    for (int i = 0; i < 2; ++i)
        #pragma unroll
        for (int j = 0; j < 2; ++j) acc2[i][j] = (f32x4){0.f,0.f,0.f,0.f};

    const bh16* vbase = qkv + 1024 + hh * 64;
    for (int kt = 0; kt < 4; ++kt) {
        __syncthreads();   // previous-iteration reads done
        if (wn == (kt >> 1)) {
            int fnb = (kt & 1) * 4;
            #pragma unroll
            for (int fm = 0; fm < 2; ++fm)
                #pragma unroll
                for (int fnl = 0; fnl < 4; ++fnl)
                    #pragma unroll
                    for (int r = 0; r < 4; ++r) {
                        int rowl = wm*32 + fm*16 + (lane>>4)*4 + r;
                        int kl = fnl*16 + (lane & 15);
                        float p = acc[fm][fnb + fnl][r] * pinv[fm][r];
                        Ps[(rowl*8 + ((kl >> 3) ^ (rowl & 7)))*8 + (kl & 7)] = __float2bfloat16(p);
                    }
        }
        // stage V tile rows kt*64.. into padded Vst[64][72]
        #pragma unroll
        for (int j = 0; j < 2; ++j) {
            int c = threadIdx.x + j*256;     // 0..511
            int tr = c >> 3, chk = c & 7;
            bf16x8 v = *(const bf16x8*)(vbase + (size_t)(b*256 + kt*64 + tr)*1600 + chk*8);
            *(bf16x8*)(&Vst[tr*72 + chk*8]) = v;
        }
        __syncthreads();
        // transpose Vst -> Bv (swizzled B-tile: [col=d][chunk of 8 t])
        #pragma unroll
        for (int j = 0; j < 2; ++j) {
            int c = threadIdx.x + j*256;
            int col = c & 63, chk = c >> 6;  // chk 0..7
            bf16x8 v;
            #pragma unroll
            for (int e = 0; e < 8; ++e)
                v[e] = (short)Vst[(chk*8 + e)*72 + col];
            Bv[col*8 + (chk ^ (col & 7))] = v;
        }
        __syncthreads();

        bf16x8 pa[2][2], vb[2][2];
        #pragma unroll
        for (int fm = 0; fm < 2; ++fm) {
            int row = wm*32 + fm*16 + (lane & 15);
            #pragma unroll
            for (int ks = 0; ks < 2; ++ks)
                pa[fm][ks] = ((bf16x8*)Ps)[row*8 + ((ks*4 + (lane>>4)) ^ (row & 7))];
        }
        #pragma unroll
        for (int fn = 0; fn < 2; ++fn) {
            int col = wn*32 + fn*16 + (lane & 15);
            #pragma unroll
            for (int ks = 0; ks < 2; ++ks)
                vb[fn][ks] = Bv[col*8 + ((ks*4 + (lane>>4)) ^ (col & 7))];
        }
        #pragma unroll
        for (int ks = 0; ks < 2; ++ks)
            #pragma unroll
            for (int fm = 0; fm < 2; ++fm)
                #pragma unroll
                for (int fn = 0; fn < 2; ++fn)
                    acc2[fm][fn] = __builtin_amdgcn_mfma_f32_16x16x32_bf16(
                        pa[fm][ks], vb[fn][ks], acc2[fm][fn], 0, 0, 0);
    }

    #pragma unroll
    for (int fm = 0; fm < 2; ++fm)
        #pragma unroll
        for (int fn = 0; fn < 2; ++fn)
            #pragma unroll
            for (int r = 0; r < 4; ++r) {
                int rowl = wm*32 + fm*16 + (lane>>4)*4 + r;
                int col = wn*32 + fn*16 + (lane & 15);
                gmb[((size_t)(b*256 + rh*64 + rowl))*512 + hh*64 + col] =
                    __float2bfloat16(acc2[fm][fn][r]);
            }
}

// =====================================================================================
// Fused 4-segment GEMM, split-K=4 over blockIdx.z (18 kt each)
__global__ __launch_bounds__(256) void fgemm_kernel(
    const bh16* __restrict__ A0, const bh16* __restrict__ A1,
    const bh16* __restrict__ A2, const bh16* __restrict__ A3,
    const bh16* __restrict__ B0, const bh16* __restrict__ B1,
    const bh16* __restrict__ B2, const bh16* __restrict__ B3,
    const float* __restrict__ bias,
    float* __restrict__ Cf0, float* __restrict__ Cf1,
    float* __restrict__ Cf2, float* __restrict__ Cf3,
    int dil, const bh16* __restrict__ zp)
{
    __shared__ bf16x8 As[128*8];
    __shared__ bf16x8 Bs[64*8];

    int bx = blockIdx.x, by = blockIdx.y;
    xcd_swizzle_always(bx, by);
    const int zz = blockIdx.z;
    const int ktlo = zz * 18;
    const int kthi = ktlo + 18;

    const int tid  = threadIdx.x;
    const int lane = tid & 63, w = tid >> 6;
    const int wm = w >> 1, wn = w & 1;
    const int row0 = by * 128, col0 = bx * 64;

    f32x4 acc[4][2];
    #pragma unroll
    for (int i = 0; i < 4; ++i)
        #pragma unroll
        for (int j = 0; j < 2; ++j) acc[i][j] = (f32x4){0.f,0.f,0.f,0.f};

    for (int kt = ktlo; kt < kthi; ++kt) {
        const bh16* Aseg; const bh16* Bseg;
        int ldas, ldbs, k0, mask_sh, addr_sh;
        if (kt < 8) {
            Aseg = A0; Bseg = B0; ldas = 512; ldbs = 512;
            k0 = kt << 6; mask_sh = 0; addr_sh = 0;
        } else if (kt < 40) {
            Aseg = A1; Bseg = B1; ldas = 2048; ldbs = 2048;
            k0 = (kt - 8) << 6; mask_sh = 0; addr_sh = 0;
        } else if (kt < 48) {
            Aseg = A2; Bseg = B2; ldas = 512; ldbs = 512;
            k0 = (kt - 40) << 6; mask_sh = 0; addr_sh = 0;
        } else {
            int kl = kt - 48, tap = kl >> 3;
            Aseg = A3; Bseg = B3; ldas = 512; ldbs = 1536;
            k0 = kl << 6;
            mask_sh = (2 - tap) * dil;
            addr_sh = mask_sh + tap;
        }
        #pragma unroll
        for (int j = 0; j < 4; ++j) {
            int c = ((w*4 + j) << 6) + lane;
            int row = c >> 3, chk = c & 7;
            int schk = chk ^ (row & 7);
            int grow = row0 + row;
            const bh16* src = ((grow & 255) >= mask_sh)
                ? (Aseg + (size_t)(grow - addr_sh)*ldas + k0 + schk*8) : zp;
            gload16(src, &As[(w*4 + j) * 64]);
        }
        #pragma unroll
        for (int j = 0; j < 2; ++j) {
            int c = ((w*2 + j) << 6) + lane;
            int row = c >> 3, chk = c & 7;
            int schk = chk ^ (row & 7);
            int gcol = col0 + row;
            gload16(Bseg + (size_t)gcol*ldbs + k0 + schk*8, &Bs[(w*2 + j) * 64]);
        }
        asm volatile("s_waitcnt vmcnt(0)" ::: "memory");
        __syncthreads();

        bf16x8 a[4][2], b[2][2];
        #pragma unroll
        for (int fm = 0; fm < 4; ++fm) {
            int row = wm*64 + fm*16 + (lane & 15);
            #pragma unroll
            for (int ks = 0; ks < 2; ++ks)
                a[fm][ks] = As[row*8 + ((ks*4 + (lane>>4)) ^ (row & 7))];
        }
        #pragma unroll
        for (int fn = 0; fn < 2; ++fn) {
            int col = wn*32 + fn*16 + (lane & 15);
            #pragma unroll
            for (int ks = 0; ks < 2; ++ks)
                b[fn][ks] = Bs[col*8 + ((ks*4 + (lane>>4)) ^ (col & 7))];
        }
        #pragma unroll
        for (int ks = 0; ks < 2; ++ks)
            #pragma unroll
            for (int fm = 0; fm < 4; ++fm)
                #pragma unroll
                for (int fn = 0; fn < 2; ++fn)
                    acc[fm][fn] = __builtin_amdgcn_mfma_f32_16x16x32_bf16(
                        a[fm][ks], b[fn][ks], acc[fm][fn], 0, 0, 0);
        __syncthreads();
    }

    float* Cf = (zz == 0) ? Cf0 : (zz == 1) ? Cf1 : (zz == 2) ? Cf2 : Cf3;
    #pragma unroll
    for (int fm = 0; fm < 4; ++fm) {
        #pragma unroll
        for (int fn = 0; fn < 2; ++fn) {
            int gc = col0 + wn*32 + fn*16 + (lane & 15);
            float bs = (zz == 0) ? bias[gc] : 0.f;
            #pragma unroll
            for (int r = 0; r < 4; ++r) {
                int gr = row0 + wm*64 + fm*16 + (lane>>4)*4 + r;
                Cf[(size_t)gr*512 + gc] = acc[fm][fn][r] + bs;
            }
        }
    }
}

// =====================================================================================
// Small-M (M=16) MFMA GEMM, one wave = 16x16xK tile, no LDS.
__global__ __launch_bounds__(256) void hgemm16_kernel(
    const bh16* __restrict__ A, int lda, long aZ,
    const bh16* __restrict__ Bt, int ldb,
    const float* __restrict__ bias,
    const float* __restrict__ pre,
    float* __restrict__ Of, bh16* __restrict__ Ob, long oZ,
    int N, int K, int act,
    float* __restrict__ curf, bh16* __restrict__ curb,
    const float* __restrict__ scaleptr)
{
    const int z = blockIdx.z;
    A += (long)z * aZ;
    const int lane = threadIdx.x & 63, w = threadIdx.x >> 6;
    const int col0 = blockIdx.x * 64 + w * 16;
    const int ar = lane & 15;
    const int koff = (lane >> 4) * 8;
    const bh16* arow = A + (size_t)ar * lda + koff;
    const bh16* brow = Bt + (size_t)(col0 + ar) * ldb + koff;
    f32x4 acc = {0.f, 0.f, 0.f, 0.f};
    const int nkt = K >> 5;
    for (int kt0 = 0; kt0 < nkt; kt0 += 8) {
        bf16x8 av[8], bv[8];
        #pragma unroll
        for (int j = 0; j < 8; ++j) {
            av[j] = *(const bf16x8*)(arow + (size_t)(kt0 + j) * 32);
            bv[j] = *(const bf16x8*)(brow + (size_t)(kt0 + j) * 32);
        }
        #pragma unroll
        for (int j = 0; j < 8; ++j)
            acc = __builtin_amdgcn_mfma_f32_16x16x32_bf16(av[j], bv[j], acc, 0, 0, 0);
    }
    const int col = col0 + ar;
    float bs = bias ? bias[col] : 0.f;
    float sc = scaleptr ? *scaleptr : 0.f;
    #pragma unroll
    for (int r = 0; r < 4; ++r) {
        int row = (lane >> 4) * 4 + r;
        float v = acc[r] + bs;
        if (pre) v += pre[(size_t)row * N + col];
        if (act == ACT_SILU)      v = v / (1.f + expf(-v));
        else if (act == ACT_TANH) v = tanhf(v);
        if (curf) {
            size_t o = (size_t)row * 512 + col;
            float nc = curf[o] - v * sc;
            curf[o] = nc;
            curb[o] = __float2bfloat16(nc);
        } else {
            size_t o = (size_t)z * oZ + (size_t)row * N + col;
            if (Of) Of[o] = v;
            if (Ob) Ob[o] = __float2bfloat16(v);
        }
    }
}

// ---------------- wavelet filter softmax -> TRANSPOSED layout fT[i][k][512] ----------------
__global__ __launch_bounds__(256) void filt_softmax_kernel(const float* __restrict__ w0, const float* __restrict__ w1,
                                                           const float* __restrict__ w2, const float* __restrict__ w3,
                                                           float* __restrict__ filt)
{
    int idx = blockIdx.x * 256 + threadIdx.x;
    if (idx >= 4 * DD) return;
    int d = idx & 511, i = idx >> 9;
    const float* w = (i == 0) ? w0 : (i == 1) ? w1 : (i == 2) ? w2 : w3;
    int K = 4 << i;
    int fb = (i == 0) ? 0 : (i == 1) ? 2048 : (i == 2) ? 6144 : 14336;
    const float* row = w + (size_t)d * K;
    float mx = -1e30f;
    for (int k = 0; k < K; ++k) mx = fmaxf(mx, row[k]);
    float s = 0.f;
    for (int k = 0; k < K; ++k) s += expf(row[k] - mx);
    float inv = 1.f / s;
    float* fo = filt + fb;
    for (int k = 0; k < K; ++k) fo[k * 512 + d] = expf(row[k] - mx) * inv;   // [k][d]
}

// ---------------- wavelet: dec (small LDS tile) + interp, per (dblk, i, thalf, b) ----------------
__global__ __launch_bounds__(256) void wave4_kernel(const bh16* __restrict__ hb,
                                                    const float* __restrict__ filtT,
                                                    bh16* __restrict__ comb)
{
    __shared__ float dtile[66 * 64];
    __shared__ float ftile[32 * 64];
    const int dblk = blockIdx.x;
    const int iy = blockIdx.y;
    const int b = blockIdx.z;
    const int i = iy >> 1, thalf = iy & 1;
    const int Karr[4] = {4, 8, 16, 32};
    const int fbarr[4] = {0, 2048, 6144, 14336};
    const int K = Karr[i], sv = 2 << i, Ti = 128 >> i;
    const int fb = fbarr[i];
    const int tid = threadIdx.x;
    const int dbase = dblk * 64;
    for (int e = tid; e < K * 64; e += 256) {
        int k = e >> 6, d0 = e & 63;
        ftile[k * 64 + d0] = filtT[fb + k * 512 + dbase + d0];
    }
    const float invsv = 1.f / (float)sv;
    const int t0 = thalf * 128;
    float p0 = ((float)t0 + 0.5f) * invsv - 0.5f;
    p0 = fminf(fmaxf(p0, 0.f), (float)(Ti - 1));
    const int jbase = (int)p0;
    float p1 = ((float)(t0 + 127) + 0.5f) * invsv - 0.5f;
    p1 = fminf(fmaxf(p1, 0.f), (float)(Ti - 1));
    const int him = min((int)p1 + 1, Ti - 1);
    const int jcount = him - jbase + 1;     // <= 66
    __syncthreads();
    const bh16* hcol = hb + (size_t)b * (TT * DD) + dbase;
    for (int e = tid; e < jcount * 64; e += 256) {
        int jl = e >> 6, d0 = e & 63;
        int j = jbase + jl;
        int tb = j * sv - (K - 1);
        float acc = 0.f;
        #pragma unroll 4
        for (int k = 0; k < K; ++k) {
            int t = tb + k;
            if (t >= 0)
                acc += b2f(*(const unsigned short*)(hcol + (size_t)t * DD + d0)) * ftile[k * 64 + d0];
        }
        dtile[jl * 64 + d0] = acc;
    }
    __syncthreads();
    for (int e = tid; e < 128 * 64; e += 256) {
        int tl = e >> 6, d0 = e & 63;
        int t = t0 + tl;
        float pos = ((float)t + 0.5f) * invsv - 0.5f;
        pos = fminf(fmaxf(pos, 0.f), (float)(Ti - 1));
        int lo = (int)pos;
        int hi = min(lo + 1, Ti - 1);
        float w = pos - (float)lo;
        float v = dtile[(lo - jbase) * 64 + d0] * (1.f - w) + dtile[(hi - jbase) * 64 + d0] * w;
        comb[((size_t)b * TT + t) * 2048 + i * 512 + dbase + d0] = __float2bfloat16(v);
    }
}

// ---------------- boundary loss: 32 blocks, one atomic per block ----------------
__global__ __launch_bounds__(256) void bd_loss_kernel(const float* __restrict__ tfb, const float* __restrict__ bdw,
                                                      const float* __restrict__ bdb, float* __restrict__ loss)
{
    __shared__ float wsum[4];
    int lane = threadIdx.x & 63, wid = threadIdx.x >> 6;
    float w = bdw[lane * 2] - bdw[lane * 2 + 1];
    float bconst = (bdb[0] - bdb[1]) + 0.1f;
    float acc = 0.f;
    for (int row = blockIdx.x * 4 + wid; row < BT; row += 128) {
        float vv = tfb[(size_t)row * PP + lane] * w;
        #pragma unroll
        for (int off = 32; off; off >>= 1) vv += __shfl_xor(vv, off);
        if (lane == 0) acc += fmaxf(vv + bconst, 0.f);
    }
    if (lane == 0) wsum[wid] = acc;
    __syncthreads();
    if (threadIdx.x == 0) {
        atomicAdd(loss, (wsum[0] + wsum[1] + wsum[2] + wsum[3]) * (1.f / 4096.f));
    }
}

// ---------------- h = layernorm(s0+s1+s2+s3 + h)*g + b, dual fp32+bf16 out ----------------
__global__ __launch_bounds__(256) void add_ln_kernel(const float* __restrict__ s0, const float* __restrict__ s1,
                                                     const float* __restrict__ s2, const float* __restrict__ s3,
                                                     float* __restrict__ h, bh16* __restrict__ hb,
                                                     const float* __restrict__ g, const float* __restrict__ be)
{
    int lane = threadIdx.x & 63, wid = threadIdx.x >> 6;
    size_t row = (size_t)blockIdx.x * 4 + wid;
    const float* sr0 = s0 + row * DD;
    const float* sr1 = s1 + row * DD;
    const float* sr2 = s2 + row * DD;
    const float* sr3 = s3 + row * DD;
    float* hr = h + row * DD;
    bh16* hbr = hb + row * DD;
    float xv[8]; float sum = 0.f;
    #pragma unroll
    for (int u = 0; u < 8; ++u) {
        int c = lane + u * 64;
        xv[u] = sr0[c] + sr1[c] + sr2[c] + sr3[c] + hr[c];
        sum += xv[u];
    }
    #pragma unroll
    for (int off = 32; off; off >>= 1) sum += __shfl_xor(sum, off);
    float mu = sum * (1.f / 512.f);
    float sq = 0.f;
    #pragma unroll
    for (int u = 0; u < 8; ++u) { float d = xv[u] - mu; sq += d * d; }
    #pragma unroll
    for (int off = 32; off; off >>= 1) sq += __shfl_xor(sq, off);
    float rstd = 1.f / sqrtf(sq * (1.f / 512.f) + 1e-5f);
    #pragma unroll
    for (int u = 0; u < 8; ++u) {
        int c = lane + u * 64;
        float v = (xv[u] - mu) * rstd * g[c] + be[c];
        hr[c] = v;
        hbr[c] = __float2bfloat16(v);
    }
}

// ---------------- weight transpose-convert ----------------
__global__ __launch_bounds__(256) void wtrans_kernel(const float* __restrict__ W, bh16* __restrict__ Wt,
                                                     int K, int N, long lstride)
{
    int l = blockIdx.z;
    const float* Wl = W + (size_t)l * K * N;
    bh16* Wo = Wt + (size_t)l * lstride;
    __shared__ float tile[32][33];
    int n0 = blockIdx.x * 32, k0 = blockIdx.y * 32;
    int lx = threadIdx.x & 31, ly = threadIdx.x >> 5;
    #pragma unroll
    for (int j = 0; j < 4; ++j) {
        int kk = ly + j * 8;
        tile[kk][lx] = Wl[(size_t)(k0 + kk) * N + n0 + lx];
    }
    __syncthreads();
    #pragma unroll
    for (int j = 0; j < 4; ++j) {
        int nr = ly + j * 8;
        Wo[(size_t)(n0 + nr) * K + k0 + lx] = __float2bfloat16(tile[lx][nr]);
    }
}

// ---------------- cc_w [L][O][I][3] f32 -> ccT [L][O][tap*512+I] bf16 ----------------
__global__ __launch_bounds__(256) void ccconv_kernel(const float* __restrict__ ccw, bh16* __restrict__ ccT)
{
    size_t idx = (size_t)blockIdx.x * 256 + threadIdx.x;   // 6*512*1536
    int i = idx & 511; size_t rem = idx >> 9;
    int tap = (int)(rem % 3); rem /= 3;
    int o = (int)(rem & 511); int l = (int)(rem >> 9);
    ccT[idx] = __float2bfloat16(ccw[(((size_t)l*512 + o)*512 + i)*3 + tap]);
}

// ---------------- qkv|te1 bias concat [L][1600] + fused-epilogue bias sum [L][512] ----------------
__global__ __launch_bounds__(256) void qkvbias_kernel(const float* __restrict__ qb_, const float* __restrict__ kb_,
                                                      const float* __restrict__ vb_, const float* __restrict__ t1b_,
                                                      float* __restrict__ ob,
                                                      const float* __restrict__ gob, const float* __restrict__ wrb,
                                                      const float* __restrict__ tdb, const float* __restrict__ ccb,
                                                      float* __restrict__ bsum)
{
    int idx = blockIdx.x * 256 + threadIdx.x;
    if (idx < 6 * 1600) {
        int l = idx / 1600, n = idx % 1600;
        float v = (n < 512) ? qb_[l*512 + n]
                : (n < 1024) ? kb_[l*512 + n - 512]
                : (n < 1536) ? vb_[l*512 + n - 1024]
                : t1b_[l*64 + n - 1536];
        ob[idx] = v;
    }
    if (idx < 6 * 512) {
        bsum[idx] = gob[idx] + wrb[idx] + tdb[idx] + ccb[idx];
    }
}

// ---------------- x f32 -> bf16 ----------------
__global__ __launch_bounds__(256) void convx_kernel(const float* __restrict__ x, bh16* __restrict__ xb)
{
    size_t idx = (size_t)blockIdx.x * 256 + threadIdx.x;
    xb[idx] = __float2bfloat16(x[idx]);
}

// ---------------- E matrix: row (t,b) = [sched[t]*noise[t,b,:] | temb[t]] ----------------
__global__ __launch_bounds__(256) void build_E_kernel(const float* __restrict__ noise, const float* __restrict__ sched,
                                                      bh16* __restrict__ E)
{
    int idx = blockIdx.x * 256 + threadIdx.x;   // 10*16*1024
    if (idx >= SS * BB * 1024) return;
    int k = idx & 1023; int rem = idx >> 10; int b = rem & 15; int t = rem >> 4;
    float v;
    if (k < 512) {
        v = sched[t] * noise[((size_t)t * BB + b) * 512 + k];
    } else {
        int j = k - 512;
        const float kfac = -9.210340371976184f / 255.f;
        v = (j < 256) ? sinf((float)t * expf((float)j * kfac))
                      : cosf((float)t * expf((float)(j - 256) * kfac));
    }
    E[idx] = __float2bfloat16(v);
}

// ---------------- head helpers ----------------
__global__ void init_kernel(bh16* zp, float* loss)
{
    int t = threadIdx.x;
    if (t < 64) zp[t] = __float2bfloat16(0.f);
    if (t == 64) *loss = 0.f;
}

__global__ __launch_bounds__(256) void build_cat16_kernel(const float* __restrict__ h, bh16* __restrict__ catb)
{
    int idx = blockIdx.x * 256 + threadIdx.x;   // 16*1024
    if (idx >= BB * 1024) return;
    int k = idx & 1023, b = idx >> 10;
    float v = (k < 512) ? h[((size_t)b * TT + 255) * DD + k]
                        : h[((size_t)b * TT + 254) * DD + (k - 512)];
    catb[idx] = __float2bfloat16(v);
}

__global__ __launch_bounds__(256) void cur_init2_kernel(const float* __restrict__ h, const float* __restrict__ mix,
                                                        float* __restrict__ curf, bh16* __restrict__ curb)
{
    int idx = blockIdx.x * 256 + threadIdx.x;   // 16*512
    if (idx >= BB * DD) return;
    int c = idx & 511, b = idx >> 9;
    float v = h[((size_t)b * TT + 255) * DD + c] + mix[idx];
    curf[idx] = v;
    curb[idx] = __float2bfloat16(v);
}

__global__ void fail_kernel(float* p) { p[0] = 1e30f; }

// =====================================================================================
extern "C" void kernel_launch(void* const* d_in, const int* in_sizes, int n_in,
                              void* d_out, int out_size, void* d_ws, size_t ws_size,
                              hipStream_t stream)
{
    const float* x      = (const float*)d_in[0];
    const float* in_w   = (const float*)d_in[1];
    const float* in_b   = (const float*)d_in[2];
    const float* gq_w   = (const float*)d_in[3];
    const float* gq_b   = (const float*)d_in[4];
    const float* gk_w   = (const float*)d_in[5];
    const float* gk_b   = (const float*)d_in[6];
    const float* gv_w   = (const float*)d_in[7];
    const float* gv_b   = (const float*)d_in[8];
    const float* go_w   = (const float*)d_in[9];
    const float* go_b   = (const float*)d_in[10];
    const float* curv   = (const float*)d_in[11];
    const float* wav0   = (const float*)d_in[12];
    const float* wav1   = (const float*)d_in[13];
    const float* wav2   = (const float*)d_in[14];
    const float* wav3   = (const float*)d_in[15];
    const float* wrec_w = (const float*)d_in[16];
    const float* wrec_b = (const float*)d_in[17];
    const float* te1_w  = (const float*)d_in[18];
    const float* te1_b  = (const float*)d_in[19];
    const float* te2_w  = (const float*)d_in[20];
    const float* te2_b  = (const float*)d_in[21];
    const float* td1_w  = (const float*)d_in[22];
    const float* td1_b  = (const float*)d_in[23];
    const float* td2_w  = (const float*)d_in[24];
    const float* td2_b  = (const float*)d_in[25];
    const float* bd_w   = (const float*)d_in[26];
    const float* bd_b   = (const float*)d_in[27];
    const float* cc_w   = (const float*)d_in[28];
    const float* cc_b   = (const float*)d_in[29];
    const float* ln_g   = (const float*)d_in[30];
    const float* ln_b   = (const float*)d_in[31];
    const float* mm1_w  = (const float*)d_in[32];
    const float* mm1_b  = (const float*)d_in[33];
    const float* mm2_w  = (const float*)d_in[34];
    const float* mm2_b  = (const float*)d_in[35];
    const float* dn1_w  = (const float*)d_in[36];
    const float* dn1_b  = (const float*)d_in[37];
    const float* dn2_w  = (const float*)d_in[38];
    const float* dn2_b  = (const float*)d_in[39];
    const float* dn3_w  = (const float*)d_in[40];
    const float* dn3_b  = (const float*)d_in[41];
    const float* out_w  = (const float*)d_in[42];
    const float* out_b  = (const float*)d_in[43];
    const float* nsched = (const float*)d_in[44];
    const float* noise  = (const float*)d_in[45];
    float* out = (float*)d_out;
    float* ws  = (float*)d_ws;

    // ---- fp32 workspace layout (float offsets) ----
    const size_t o_h   = 0;          // 2097152
    const size_t o_dec = 2097152;    // 2097152 (s2 partial; pre1 for head)
    const size_t o_s   = 4194304;    // 2097152
    const size_t o_tf  = 6291456;    // 262144
    const size_t o_qn  = 6553600;    // 32768 (unused now)
    const size_t o_kn  = 6586368;    // 32768 (unused now)
    const size_t o_at  = 6619136;    // 8388608: comb (bf16, first half) + s3/s4 partials (upper half)
    const size_t o_fl  = 15007744;   // 30720
    const size_t o_mix = 15038464;   // 8192
    const size_t o_cur = 15046656;   // 8192
    const size_t o_qkb = 15054848;   // 9600
    const size_t o_bs  = 15064448;   // 3072
    const size_t FP32_TOTAL = 15095808;
    // ---- bf16 region (element offsets from bp) ----
    const size_t b_xb   = 0;          // 1572864
    const size_t b_hb   = 1572864;    // 2097152
    const size_t b_qkv  = 3670016;    // 6553600: packed qkv|t1 [4096][1600]
    const size_t b_vt   = 10223616;   // 2097152 (unused now)
    const size_t b_pb   = 12320768;   // 8388608 (head scratch region)
    const size_t b_gmb  = 20709376;   // 2097152
    const size_t b_tdb  = 22806528;   // 2097152
    const size_t b_tfb  = 24903680;   // 262144
    const size_t b_zp   = 25165824;   // 512
    const size_t b_inwT = 25166336;   // 196608
    const size_t b_qkvT = 25362944;   // 4915200
    const size_t b_goT  = 30278144;   // 1572864
    const size_t b_wrT  = 31851008;   // 6291456
    const size_t b_td1T = 38142464;   // 196608
    const size_t b_td2T = 38339072;   // 1572864
    const size_t b_te2T = 39911936;   // 24576
    const size_t b_ccT  = 39936512;   // 4718592
    const size_t BF16_TOTAL = 44655104;
    const size_t TOTAL_BYTES = FP32_TOTAL * 4 + BF16_TOTAL * 2;
    if (ws_size < TOTAL_BYTES) { fail_kernel<<<1, 1, 0, stream>>>(out); return; }

    float* h_   = ws + o_h;
    float* s2_  = ws + o_dec;
    float* s_   = ws + o_s;
    float* tf_  = ws + o_tf;
    float* at_  = ws + o_at;
    float* s3_  = at_ + 4194304;   // upper half of at_ region
    float* s4_  = at_ + 6291456;
    float* fl_  = ws + o_fl;
    float* mixb = ws + o_mix;
    float* curf = ws + o_cur;
    float* qkvbias = ws + o_qkb;
    float* bsum = ws + o_bs;
    bh16* bp   = (bh16*)(ws + FP32_TOTAL);
    bh16* xb   = bp + b_xb;
    bh16* hb   = bp + b_hb;
    bh16* qkvb = bp + b_qkv;
    bh16* pb   = bp + b_pb;
    bh16* gmb  = bp + b_gmb;
    bh16* tdb  = bp + b_tdb;
    bh16* tfb  = bp + b_tfb;
    bh16* zp   = bp + b_zp;
    bh16* inwT = bp + b_inwT;
    bh16* qkvT = bp + b_qkvT;
    bh16* goT  = bp + b_goT;
    bh16* wrT  = bp + b_wrT;
    bh16* td1T = bp + b_td1T;
    bh16* td2T = bp + b_td2T;
    bh16* te2T = bp + b_te2T;
    bh16* ccT  = bp + b_ccT;
    bh16* combb = (bh16*)at_;   // comb: first 4194304 floats of at_ region

    // head bf16 scratch: aliased into pb region (dead during layers)
    bh16* dn1T  = pb;             // 524288
    bh16* dn2T  = pb + 524288;    // 262144
    bh16* dn3T  = pb + 786432;    // 262144
    bh16* mm1T  = pb + 1048576;   // 524288
    bh16* mm2T  = pb + 1572864;   // 262144
    bh16* outT  = pb + 1835008;   // 196608
    bh16* E16   = pb + 2031616;   // 163840
    bh16* cat16 = pb + 2195456;   // 16384
    bh16* tmb16 = pb + 2211840;   // 8192
    bh16* cur16 = pb + 2220032;   // 8192
    bh16* d1b16 = pb + 2228224;   // 8192
    bh16* d2b16 = pb + 2236416;   // 8192
    float* pre1 = s2_;            // 81920 f32, aliases s2 after layers

    auto mgp = [&](const bh16* A, int lda, const bh16* Bt, int ldb,
                   const float* bias, float* Cf, bh16* Cb, int ldc,
                   int M, int N, int K, int shift, int accum, int act) {
        dim3 g((N + 63) / 64, M / 128, 1);
        mgemm_kernel<<<g, 256, 0, stream>>>(A, lda, Bt, ldb, bias, Cf, Cb, ldc, N, K,
                                            shift, accum, act, 0, 0,
                                            0, 0, 0, 0, 0, 0, 0, zp);
    };
    auto hg = [&](const bh16* A, int lda, long aZ, const bh16* Bt, int ldb,
                  const float* bias, const float* pre, float* Of, bh16* Ob, long oZ,
                  int N, int K, int act, float* cf, bh16* cb, const float* sp, int nz) {
        hgemm16_kernel<<<dim3(N / 64, 1, nz), 256, 0, stream>>>(
            A, lda, aZ, Bt, ldb, bias, pre, Of, Ob, oZ, N, K, act, cf, cb, sp);
    };

    // ---- setup: zero page/loss, converts ----
    init_kernel<<<1, 128, 0, stream>>>(zp, out + BB * DIN);
    convx_kernel<<<BT * DIN / 256, 256, 0, stream>>>(x, xb);
    wtrans_kernel<<<dim3(DD/32, DIN/32, 1), 256, 0, stream>>>(in_w, inwT, DIN, DD, (long)DIN*DD);
    wtrans_kernel<<<dim3(16, 16, 6), 256, 0, stream>>>(gq_w, qkvT,          DD, DD, 819200L);
    wtrans_kernel<<<dim3(16, 16, 6), 256, 0, stream>>>(gk_w, qkvT + 262144, DD, DD, 819200L);
    wtrans_kernel<<<dim3(16, 16, 6), 256, 0, stream>>>(gv_w, qkvT + 524288, DD, DD, 819200L);
    wtrans_kernel<<<dim3(2, 16, 6), 256, 0, stream>>>(te1_w, qkvT + 786432, DD, PP, 819200L);
    qkvbias_kernel<<<38, 256, 0, stream>>>(gq_b, gk_b, gv_b, te1_b, qkvbias,
                                           go_b, wrec_b, td2_b, cc_b, bsum);
    wtrans_kernel<<<dim3(16, 16, 6), 256, 0, stream>>>(go_w, goT, DD, DD, (long)DD*DD);
    wtrans_kernel<<<dim3(16, 64, 6), 256, 0, stream>>>(wrec_w, wrT, 2048, DD, 2048L*DD);
    wtrans_kernel<<<dim3(16, 2, 6), 256, 0, stream>>>(td1_w, td1T, PP, DD, (long)PP*DD);
    wtrans_kernel<<<dim3(16, 16, 6), 256, 0, stream>>>(td2_w, td2T, DD, DD, (long)DD*DD);
    wtrans_kernel<<<dim3(2, 2, 6), 256, 0, stream>>>(te2_w, te2T, PP, PP, (long)PP*PP);
    ccconv_kernel<<<18432, 256, 0, stream>>>(cc_w, ccT);

    // h = x @ in_w + in_b  (fp32 + bf16)
    mgp(xb, DIN, inwT, DIN, in_b, h_, hb, DD, BT, DD, DIN, 0, 0, ACT_NONE);

    for (int l = 0; l < LL; ++l) {
        // fused q|k|v|te1 projection: N=1600, tail relu on te1
        mgp(hb, DD, qkvT + (size_t)l*819200, DD, qkvbias + (size_t)l*1600,
            nullptr, qkvb, 1600, BT, 1600, DD, 0, 0, ACT_RELU_TAIL);
        // attention: fully fused (norms + QK^T + softmax + V-transpose + PV)
        fattn_kernel<<<dim3(4, 128), 256, 0, stream>>>(qkvb, curv + (size_t)l*HH, gmb);
        // wavelet branch: dec+interp fused (comb occupies first half of at_)
        filt_softmax_kernel<<<8, 256, 0, stream>>>(wav0 + (size_t)l*DD*4, wav1 + (size_t)l*DD*8,
                                                   wav2 + (size_t)l*DD*16, wav3 + (size_t)l*DD*32, fl_);
        wave4_kernel<<<dim3(8, 8, 16), 256, 0, stream>>>(hb, fl_, combb);
        // topo branch: te2 from t1 (packed at qkvb+1536), bd loss, td1
        mgp(qkvb + 1536, 1600, te2T + (size_t)l*4096, PP, te2_b + (size_t)l*PP, tf_, tfb, PP, BT, PP, PP, 0, 0, ACT_NONE);
        bd_loss_kernel<<<32, 256, 0, stream>>>(tf_, bd_w + (size_t)l*PP*2, bd_b + (size_t)l*2, out + BB*DIN);
        mgp(tfb, PP, td1T + (size_t)l*32768, PP, td1_b + (size_t)l*DD, nullptr, tdb, DD, BT, DD, PP, 0, 0, ACT_RELU);
        // fused split-K(4) s = gmb@go + comb@wrec + tdb@td2 + cc(hb) + biassum
        fgemm_kernel<<<dim3(8, 32, 4), 256, 0, stream>>>(
            gmb, combb, tdb, hb,
            goT + (size_t)l*262144, wrT + (size_t)l*1048576,
            td2T + (size_t)l*262144, ccT + (size_t)l*786432,
            bsum + (size_t)l*512, s_, s2_, s3_, s4_, 1 << l, zp);
        // h = LN(s + s2 + s3 + s4 + h)
        add_ln_kernel<<<BT/4, 256, 0, stream>>>(s_, s2_, s3_, s4_, h_, hb, ln_g, ln_b);
    }

    // ---- head ----
    wtrans_kernel<<<dim3(16, 32, 1), 256, 0, stream>>>(dn1_w, dn1T, 1024, 512, 0L);
    wtrans_kernel<<<dim3(16, 16, 1), 256, 0, stream>>>(dn2_w, dn2T, 512, 512, 0L);
    wtrans_kernel<<<dim3(16, 16, 1), 256, 0, stream>>>(dn3_w, dn3T, 512, 512, 0L);
    wtrans_kernel<<<dim3(16, 32, 1), 256, 0, stream>>>(mm1_w, mm1T, 1024, 512, 0L);
    wtrans_kernel<<<dim3(16, 16, 1), 256, 0, stream>>>(mm2_w, mm2T, 512, 512, 0L);
    wtrans_kernel<<<dim3(12, 16, 1), 256, 0, stream>>>(out_w, outT, 512, 384, 0L);
    build_E_kernel<<<640, 256, 0, stream>>>(noise, nsched, E16);
    hg(E16, 1024, 16*1024, dn1T, 1024, dn1_b, nullptr, pre1, nullptr, 8192,
       512, 1024, ACT_NONE, nullptr, nullptr, nullptr, SS);
    build_cat16_kernel<<<64, 256, 0, stream>>>(h_, cat16);
    hg(cat16, 1024, 0, mm1T, 1024, mm1_b, nullptr, nullptr, tmb16, 0,
       512, 1024, ACT_TANH, nullptr, nullptr, nullptr, 1);
    hg(tmb16, 512, 0, mm2T, 512, mm2_b, nullptr, mixb, nullptr, 0,
       512, 512, ACT_NONE, nullptr, nullptr, nullptr, 1);
    cur_init2_kernel<<<32, 256, 0, stream>>>(h_, mixb, curf, cur16);
    for (int t = 0; t < SS; ++t) {
        hg(cur16, 512, 0, dn1T, 1024, nullptr, pre1 + (size_t)t*8192, nullptr, d1b16, 0,
           512, 512, ACT_SILU, nullptr, nullptr, nullptr, 1);
        hg(d1b16, 512, 0, dn2T, 512, dn2_b, nullptr, nullptr, d2b16, 0,
           512, 512, ACT_SILU, nullptr, nullptr, nullptr, 1);
        hg(d2b16, 512, 0, dn3T, 512, dn3_b, nullptr, nullptr, nullptr, 0,
           512, 512, ACT_NONE, curf, cur16, nsched + t, 1);
    }
    hg(cur16, 512, 0, outT, 512, out_b, nullptr, out, nullptr, 0,
       384, 512, ACT_NONE, nullptr, nullptr, nullptr, 1);
}

// Round 14
// 1015.460 us; speedup vs baseline: 2.1649x; 1.1894x over previous
//
#include <hip/hip_runtime.h>
#include <hip/hip_bf16.h>
#include <math.h>

#define BB 16
#define TT 256
#define DIN 384
#define DD 512
#define LL 6
#define HH 8
#define PP 64
#define SS 10
#define BT (BB*TT)   // 4096

enum { ACT_NONE=0, ACT_RELU=1, ACT_TANH=2, ACT_SILU=3, ACT_RELU_TAIL=4 };

typedef __attribute__((ext_vector_type(8))) short bf16x8;
typedef __attribute__((ext_vector_type(4))) float f32x4;
typedef __hip_bfloat16 bh16;

typedef const __attribute__((address_space(1))) void gvoid_t;
typedef __attribute__((address_space(3))) void lvoid_t;
__device__ __forceinline__ void gload16(const void* g, void* l) {
    __builtin_amdgcn_global_load_lds((gvoid_t*)g, (lvoid_t*)l, 16, 0, 0);
}

__device__ __forceinline__ float b2f(unsigned short u) {
    return __uint_as_float(((unsigned int)u) << 16);
}

// bijective chunked XCD swizzle (m204) within one z-plane.
__device__ __forceinline__ void xcd_swizzle_always(int& bx, int& by) {
    int gx = gridDim.x;
    int nwg = gx * gridDim.y;
    int lid = by * gx + bx;
    int q = nwg >> 3, r = nwg & 7;
    int xcd = lid & 7, idx = lid >> 3;
    int swz = (xcd < r) ? (xcd * (q + 1) + idx) : (r * (q + 1) + (xcd - r) * q + idx);
    bx = swz % gx;
    by = swz / gx;
}
__device__ __forceinline__ void xcd_swizzle(int& bx, int& by) {
    if (gridDim.z == 1) xcd_swizzle_always(bx, by);
}

// =====================================================================================
// Generic bf16 MFMA GEMM: C = act(A @ Bt^T + bias)  (Bt stored [N][K])
__global__ __launch_bounds__(256) void mgemm_kernel(
    const bh16* __restrict__ A, int lda,
    const bh16* __restrict__ Bt, int ldb,
    const float* __restrict__ bias,
    float* __restrict__ Cf, bh16* __restrict__ Cb, int ldc,
    int N, int K, int shift, int accum, int act,
    const bh16* __restrict__ zp)
{
    __shared__ bf16x8 As[128*8];
    __shared__ bf16x8 Bs[64*8];

    int bx = blockIdx.x, by = blockIdx.y;
    xcd_swizzle(bx, by);

    const int tid  = threadIdx.x;
    const int lane = tid & 63, w = tid >> 6;
    const int wm = w >> 1, wn = w & 1;
    const int row0 = by * 128, col0 = bx * 64;

    f32x4 acc[4][2];
    #pragma unroll
    for (int i = 0; i < 4; ++i)
        #pragma unroll
        for (int j = 0; j < 2; ++j) acc[i][j] = (f32x4){0.f,0.f,0.f,0.f};

    const int nkt = K >> 6;
    for (int kt = 0; kt < nkt; ++kt) {
        int k0 = kt << 6;
        #pragma unroll
        for (int j = 0; j < 4; ++j) {
            int c = ((w*4 + j) << 6) + lane;
            int row = c >> 3, chk = c & 7;
            int schk = chk ^ (row & 7);
            int grow = row0 + row;
            const bh16* src = ((grow & 255) >= shift)
                ? (A + (size_t)(grow - shift)*lda + k0 + schk*8) : zp;
            gload16(src, &As[(w*4 + j) * 64]);
        }
        #pragma unroll
        for (int j = 0; j < 2; ++j) {
            int c = ((w*2 + j) << 6) + lane;
            int row = c >> 3, chk = c & 7;
            int schk = chk ^ (row & 7);
            int gcol = col0 + row;
            const bh16* src = (gcol < N)
                ? (Bt + (size_t)gcol*ldb + k0 + schk*8) : zp;
            gload16(src, &Bs[(w*2 + j) * 64]);
        }
        asm volatile("s_waitcnt vmcnt(0)" ::: "memory");
        __syncthreads();

        bf16x8 a[4][2], b[2][2];
        #pragma unroll
        for (int fm = 0; fm < 4; ++fm) {
            int row = wm*64 + fm*16 + (lane & 15);
            #pragma unroll
            for (int ks = 0; ks < 2; ++ks)
                a[fm][ks] = As[row*8 + ((ks*4 + (lane>>4)) ^ (row & 7))];
        }
        #pragma unroll
        for (int fn = 0; fn < 2; ++fn) {
            int col = wn*32 + fn*16 + (lane & 15);
            #pragma unroll
            for (int ks = 0; ks < 2; ++ks)
                b[fn][ks] = Bs[col*8 + ((ks*4 + (lane>>4)) ^ (col & 7))];
        }
        #pragma unroll
        for (int ks = 0; ks < 2; ++ks)
            #pragma unroll
            for (int fm = 0; fm < 4; ++fm)
                #pragma unroll
                for (int fn = 0; fn < 2; ++fn)
                    acc[fm][fn] = __builtin_amdgcn_mfma_f32_16x16x32_bf16(
                        a[fm][ks], b[fn][ks], acc[fm][fn], 0, 0, 0);
        __syncthreads();
    }

    #pragma unroll
    for (int fm = 0; fm < 4; ++fm) {
        #pragma unroll
        for (int fn = 0; fn < 2; ++fn) {
            int gc = col0 + wn*32 + fn*16 + (lane & 15);
            float bs = bias ? bias[gc] : 0.f;
            #pragma unroll
            for (int r = 0; r < 4; ++r) {
                int gr = row0 + wm*64 + fm*16 + (lane>>4)*4 + r;
                float v = acc[fm][fn][r] + bs;
                if (act == ACT_RELU) v = fmaxf(v, 0.f);
                else if (act == ACT_RELU_TAIL && gc >= 1536) v = fmaxf(v, 0.f);
                size_t o = (size_t)gr*ldc + gc;
                if (Cf) { if (accum) Cf[o] += v; else Cf[o] = v; }
                if (Cb) Cb[o] = __float2bfloat16(v);
            }
        }
    }
}

// =====================================================================================
// Fused topo: tf = t1@te2 + b (fp32, full 64 cols, redundant per bx), bd loss (bx==0),
// tdb[:, bx*64..] = relu(tf_bf16 @ td1 + b). grid (8, 32).
__global__ __launch_bounds__(256) void topo_kernel(
    const bh16* __restrict__ t1,     // qkvb+1536, lda 1600
    const bh16* __restrict__ te2T,   // [64][64]
    const float* __restrict__ te2b,
    const bh16* __restrict__ td1T,   // [512][64]
    const float* __restrict__ td1b,
    const float* __restrict__ bdw, const float* __restrict__ bdb,
    float* __restrict__ loss,
    bh16* __restrict__ tdb)          // [4096][512]
{
    __shared__ bf16x8 As[128*8];     // t1 tile, then tf tile
    __shared__ bf16x8 Bs[64*8];      // te2, then td1 slice
    __shared__ float redT[2][128];
    __shared__ float bsumS;

    const int bx = blockIdx.x, by = blockIdx.y;
    const int lane = threadIdx.x & 63, w = threadIdx.x >> 6;
    const int wm = w >> 1, wn = w & 1;
    const int row0 = by * 128;

    // stage t1 (128 x 64) and te2T (64 x 64), swizzled
    #pragma unroll
    for (int j = 0; j < 4; ++j) {
        int c = ((w*4 + j) << 6) + lane;
        int row = c >> 3, chk = c & 7, schk = chk ^ (row & 7);
        gload16(t1 + (size_t)(row0 + row)*1600 + schk*8, &As[(w*4+j)*64]);
    }
    #pragma unroll
    for (int j = 0; j < 2; ++j) {
        int c = ((w*2 + j) << 6) + lane;
        int row = c >> 3, chk = c & 7, schk = chk ^ (row & 7);
        gload16(te2T + (size_t)row*64 + schk*8, &Bs[(w*2+j)*64]);
    }
    asm volatile("s_waitcnt vmcnt(0)" ::: "memory");
    __syncthreads();

    // tf = t1 @ te2 (K=64)
    f32x4 acc[4][2];
    #pragma unroll
    for (int i = 0; i < 4; ++i)
        #pragma unroll
        for (int j = 0; j < 2; ++j) acc[i][j] = (f32x4){0.f,0.f,0.f,0.f};
    {
        bf16x8 a[4][2], b[2][2];
        #pragma unroll
        for (int fm = 0; fm < 4; ++fm) {
            int row = wm*64 + fm*16 + (lane & 15);
            #pragma unroll
            for (int ks = 0; ks < 2; ++ks)
                a[fm][ks] = As[row*8 + ((ks*4 + (lane>>4)) ^ (row & 7))];
        }
        #pragma unroll
        for (int fn = 0; fn < 2; ++fn) {
            int col = wn*32 + fn*16 + (lane & 15);
            #pragma unroll
            for (int ks = 0; ks < 2; ++ks)
                b[fn][ks] = Bs[col*8 + ((ks*4 + (lane>>4)) ^ (col & 7))];
        }
        #pragma unroll
        for (int ks = 0; ks < 2; ++ks)
            #pragma unroll
            for (int fm = 0; fm < 4; ++fm)
                #pragma unroll
                for (int fn = 0; fn < 2; ++fn)
                    acc[fm][fn] = __builtin_amdgcn_mfma_f32_16x16x32_bf16(
                        a[fm][ks], b[fn][ks], acc[fm][fn], 0, 0, 0);
    }
    // add bias (tf fp32)
    #pragma unroll
    for (int fn = 0; fn < 2; ++fn) {
        int gc = wn*32 + fn*16 + (lane & 15);
        float bs = te2b[gc];
        #pragma unroll
        for (int fm = 0; fm < 4; ++fm)
            #pragma unroll
            for (int r = 0; r < 4; ++r) acc[fm][fn][r] += bs;
    }

    // bd loss (bx == 0 only; block-uniform branch)
    if (bx == 0) {
        float bconst = (bdb[0] - bdb[1]) + 0.1f;
        float wv[2];
        #pragma unroll
        for (int fn = 0; fn < 2; ++fn) {
            int gc = wn*32 + fn*16 + (lane & 15);
            wv[fn] = bdw[gc*2] - bdw[gc*2 + 1];
        }
        float dp[4][4];
        #pragma unroll
        for (int fm = 0; fm < 4; ++fm)
            #pragma unroll
            for (int r = 0; r < 4; ++r) {
                dp[fm][r] = acc[fm][0][r]*wv[0] + acc[fm][1][r]*wv[1];
                #pragma unroll
                for (int off = 1; off < 16; off <<= 1)
                    dp[fm][r] += __shfl_xor(dp[fm][r], off);
            }
        if ((lane & 15) == 0)
            #pragma unroll
            for (int fm = 0; fm < 4; ++fm)
                #pragma unroll
                for (int r = 0; r < 4; ++r)
                    redT[wn][wm*64 + fm*16 + (lane>>4)*4 + r] = dp[fm][r];
        if (threadIdx.x == 0) bsumS = 0.f;
        __syncthreads();
        if (wn == 0 && (lane & 15) == 0) {
            float ls = 0.f;
            #pragma unroll
            for (int fm = 0; fm < 4; ++fm)
                #pragma unroll
                for (int r = 0; r < 4; ++r) {
                    int rowl = wm*64 + fm*16 + (lane>>4)*4 + r;
                    ls += fmaxf(dp[fm][r] + redT[1][rowl] + bconst, 0.f);
                }
            atomicAdd(&bsumS, ls);
        }
        __syncthreads();
        if (threadIdx.x == 0) atomicAdd(loss, bsumS * (1.f / 4096.f));
    }

    __syncthreads();   // all frag reads of As/Bs done; safe to overwrite
    // restage tf (bf16) into As as swizzled A-tile
    #pragma unroll
    for (int fm = 0; fm < 4; ++fm)
        #pragma unroll
        for (int fn = 0; fn < 2; ++fn)
            #pragma unroll
            for (int r = 0; r < 4; ++r) {
                int rowl = wm*64 + fm*16 + (lane>>4)*4 + r;
                int gc = wn*32 + fn*16 + (lane & 15);
                ((bh16*)As)[(rowl*8 + ((gc >> 3) ^ (rowl & 7)))*8 + (gc & 7)] =
                    __float2bfloat16(acc[fm][fn][r]);
            }
    // stage td1 slice (cols bx*64..): rows = out cols
    #pragma unroll
    for (int j = 0; j < 2; ++j) {
        int c = ((w*2 + j) << 6) + lane;
        int row = c >> 3, chk = c & 7, schk = chk ^ (row & 7);
        gload16(td1T + (size_t)(bx*64 + row)*64 + schk*8, &Bs[(w*2+j)*64]);
    }
    asm volatile("s_waitcnt vmcnt(0)" ::: "memory");
    __syncthreads();

    // tdb = relu(tf @ td1 + b)
    f32x4 acc2[4][2];
    #pragma unroll
    for (int i = 0; i < 4; ++i)
        #pragma unroll
        for (int j = 0; j < 2; ++j) acc2[i][j] = (f32x4){0.f,0.f,0.f,0.f};
    {
        bf16x8 a[4][2], b[2][2];
        #pragma unroll
        for (int fm = 0; fm < 4; ++fm) {
            int row = wm*64 + fm*16 + (lane & 15);
            #pragma unroll
            for (int ks = 0; ks < 2; ++ks)
                a[fm][ks] = As[row*8 + ((ks*4 + (lane>>4)) ^ (row & 7))];
        }
        #pragma unroll
        for (int fn = 0; fn < 2; ++fn) {
            int col = wn*32 + fn*16 + (lane & 15);
            #pragma unroll
            for (int ks = 0; ks < 2; ++ks)
                b[fn][ks] = Bs[col*8 + ((ks*4 + (lane>>4)) ^ (col & 7))];
        }
        #pragma unroll
        for (int ks = 0; ks < 2; ++ks)
            #pragma unroll
            for (int fm = 0; fm < 4; ++fm)
                #pragma unroll
                for (int fn = 0; fn < 2; ++fn)
                    acc2[fm][fn] = __builtin_amdgcn_mfma_f32_16x16x32_bf16(
                        a[fm][ks], b[fn][ks], acc2[fm][fn], 0, 0, 0);
    }
    #pragma unroll
    for (int fm = 0; fm < 4; ++fm)
        #pragma unroll
        for (int fn = 0; fn < 2; ++fn) {
            int gcol = bx*64 + wn*32 + fn*16 + (lane & 15);
            float bs = td1b[gcol];
            #pragma unroll
            for (int r = 0; r < 4; ++r) {
                int gr = row0 + wm*64 + fm*16 + (lane>>4)*4 + r;
                tdb[(size_t)gr*512 + gcol] = __float2bfloat16(fmaxf(acc2[fm][fn][r] + bs, 0.f));
            }
        }
}

// =====================================================================================
// Fused attention: norms + QK^T + hyperbolic softmax + V-transpose + PV, one kernel.
__global__ __launch_bounds__(256) void fattn_kernel(
    const bh16* __restrict__ qkv,      // [4096][1600]: q@0, k@+512, v@+1024
    const float* __restrict__ curv,    // per-layer, 8 heads
    bh16* __restrict__ gmb)            // [4096][512]
{
    __shared__ bf16x8 Qs[64*8];
    __shared__ bf16x8 Ks[256*8];
    __shared__ __align__(16) bh16 Ps[64*64];
    __shared__ bf16x8 Bv[64*8];
    __shared__ unsigned short Vst[64*72];
    __shared__ float redA[2][64];
    __shared__ float redB[2][64];
    __shared__ float qnS[64];
    __shared__ float knS[256];

    const int rh = blockIdx.x;
    const int bh = blockIdx.y;
    const int b = bh >> 3, hh = bh & 7;
    const int lane = threadIdx.x & 63, w = threadIdx.x >> 6;
    const int wm = w >> 1, wn = w & 1;

    const bh16* qbase = qkv + hh * 64;
    const bh16* kbase = qkv + 512 + hh * 64;
    #pragma unroll
    for (int j = 0; j < 2; ++j) {
        int c = ((w*2 + j) << 6) + lane;
        int row = c >> 3, chk = c & 7, schk = chk ^ (row & 7);
        gload16(qbase + (size_t)(b*256 + rh*64 + row)*1600 + schk*8, &Qs[(w*2+j)*64]);
    }
    #pragma unroll
    for (int j = 0; j < 8; ++j) {
        int c = ((w*8 + j) << 6) + lane;
        int row = c >> 3, chk = c & 7, schk = chk ^ (row & 7);
        gload16(kbase + (size_t)(b*256 + row)*1600 + schk*8, &Ks[(w*8+j)*64]);
    }
    asm volatile("s_waitcnt vmcnt(0)" ::: "memory");
    __syncthreads();

    {
        int t = threadIdx.x;
        float s = 0.f;
        #pragma unroll
        for (int jj = 0; jj < 8; ++jj) {
            bf16x8 v = Ks[t*8 + ((t + jj) & 7)];
            #pragma unroll
            for (int e = 0; e < 8; ++e) { float f = b2f((unsigned short)v[e]); s += f * f; }
        }
        knS[t] = s;
        if (t < 64) {
            float sq = 0.f;
            #pragma unroll
            for (int jj = 0; jj < 8; ++jj) {
                bf16x8 v = Qs[t*8 + ((t + jj) & 7)];
                #pragma unroll
                for (int e = 0; e < 8; ++e) { float f = b2f((unsigned short)v[e]); sq += f * f; }
            }
            qnS[t] = sq;
        }
    }
    __syncthreads();

    f32x4 acc[2][8];
    #pragma unroll
    for (int i = 0; i < 2; ++i)
        #pragma unroll
        for (int j = 0; j < 8; ++j) acc[i][j] = (f32x4){0.f,0.f,0.f,0.f};

    bf16x8 af[2][2];
    #pragma unroll
    for (int fm = 0; fm < 2; ++fm) {
        int row = wm*32 + fm*16 + (lane & 15);
        #pragma unroll
        for (int ks = 0; ks < 2; ++ks)
            af[fm][ks] = Qs[row*8 + ((ks*4 + (lane>>4)) ^ (row & 7))];
    }
    #pragma unroll
    for (int fn = 0; fn < 8; ++fn) {
        int col = wn*128 + fn*16 + (lane & 15);
        #pragma unroll
        for (int ks = 0; ks < 2; ++ks) {
            bf16x8 bf = Ks[col*8 + ((ks*4 + (lane>>4)) ^ (col & 7))];
            #pragma unroll
            for (int fm = 0; fm < 2; ++fm)
                acc[fm][fn] = __builtin_amdgcn_mfma_f32_16x16x32_bf16(
                    af[fm][ks], bf, acc[fm][fn], 0, 0, 0);
        }
    }

    const float c_ = fabsf(curv[hh]) + 1e-8f;
    const float isc = 1.f / sqrtf(c_);
    float qnv[2][4], knv[8];
    #pragma unroll
    for (int fm = 0; fm < 2; ++fm)
        #pragma unroll
        for (int r = 0; r < 4; ++r)
            qnv[fm][r] = qnS[wm*32 + fm*16 + (lane>>4)*4 + r];
    #pragma unroll
    for (int fn = 0; fn < 8; ++fn)
        knv[fn] = knS[wn*128 + fn*16 + (lane & 15)];

    float rmax[2][4];
    #pragma unroll
    for (int fm = 0; fm < 2; ++fm)
        #pragma unroll
        for (int r = 0; r < 4; ++r) rmax[fm][r] = -1e30f;
    #pragma unroll
    for (int fm = 0; fm < 2; ++fm)
        #pragma unroll
        for (int fn = 0; fn < 8; ++fn)
            #pragma unroll
            for (int r = 0; r < 4; ++r) {
                float s = acc[fm][fn][r];
                float d2 = fmaxf(qnv[fm][r] + knv[fn] - 2.f * s, 0.f);
                float denom = fmaxf((1.f - c_ * qnv[fm][r]) * (1.f - c_ * knv[fn]), 1e-5f);
                float arg = fmaxf(1.f + (2.f * c_ * d2) / denom, 1.00001f);
                float dist = logf(arg + sqrtf((arg - 1.f) * (arg + 1.f))) * isc;
                float lg = -dist;
                acc[fm][fn][r] = lg;
                rmax[fm][r] = fmaxf(rmax[fm][r], lg);
            }
    #pragma unroll
    for (int off = 1; off < 16; off <<= 1)
        #pragma unroll
        for (int fm = 0; fm < 2; ++fm)
            #pragma unroll
            for (int r = 0; r < 4; ++r)
                rmax[fm][r] = fmaxf(rmax[fm][r], __shfl_xor(rmax[fm][r], off));
    if ((lane & 15) == 0)
        #pragma unroll
        for (int fm = 0; fm < 2; ++fm)
            #pragma unroll
            for (int r = 0; r < 4; ++r)
                redA[wn][wm*32 + fm*16 + (lane>>4)*4 + r] = rmax[fm][r];
    __syncthreads();
    #pragma unroll
    for (int fm = 0; fm < 2; ++fm)
        #pragma unroll
        for (int r = 0; r < 4; ++r)
            rmax[fm][r] = fmaxf(rmax[fm][r], redA[wn ^ 1][wm*32 + fm*16 + (lane>>4)*4 + r]);
    float rsum[2][4];
    #pragma unroll
    for (int fm = 0; fm < 2; ++fm)
        #pragma unroll
        for (int r = 0; r < 4; ++r) rsum[fm][r] = 0.f;
    #pragma unroll
    for (int fm = 0; fm < 2; ++fm)
        #pragma unroll
        for (int fn = 0; fn < 8; ++fn)
            #pragma unroll
            for (int r = 0; r < 4; ++r) {
                float e = expf(acc[fm][fn][r] - rmax[fm][r]);
                acc[fm][fn][r] = e;
                rsum[fm][r] += e;
            }
    #pragma unroll
    for (int off = 1; off < 16; off <<= 1)
        #pragma unroll
        for (int fm = 0; fm < 2; ++fm)
            #pragma unroll
            for (int r = 0; r < 4; ++r)
                rsum[fm][r] += __shfl_xor(rsum[fm][r], off);
    if ((lane & 15) == 0)
        #pragma unroll
        for (int fm = 0; fm < 2; ++fm)
            #pragma unroll
            for (int r = 0; r < 4; ++r)
                redB[wn][wm*32 + fm*16 + (lane>>4)*4 + r] = rsum[fm][r];
    __syncthreads();
    float pinv[2][4];
    #pragma unroll
    for (int fm = 0; fm < 2; ++fm)
        #pragma unroll
        for (int r = 0; r < 4; ++r)
            pinv[fm][r] = 1.f / (rsum[fm][r] + redB[wn ^ 1][wm*32 + fm*16 + (lane>>4)*4 + r]);

    f32x4 acc2[2][2];
    #pragma unroll
    for (int i = 0; i < 2; ++i)
        #pragma unroll
        for (int j = 0; j < 2; ++j) acc2[i][j] = (f32x4){0.f,0.f,0.f,0.f};

    const bh16* vbase = qkv + 1024 + hh * 64;
    for (int kt = 0; kt < 4; ++kt) {
        __syncthreads();
        if (wn == (kt >> 1)) {
            int fnb = (kt & 1) * 4;
            #pragma unroll
            for (int fm = 0; fm < 2; ++fm)
                #pragma unroll
                for (int fnl = 0; fnl < 4; ++fnl)
                    #pragma unroll
                    for (int r = 0; r < 4; ++r) {
                        int rowl = wm*32 + fm*16 + (lane>>4)*4 + r;
                        int kl = fnl*16 + (lane & 15);
                        float p = acc[fm][fnb + fnl][r] * pinv[fm][r];
                        Ps[(rowl*8 + ((kl >> 3) ^ (rowl & 7)))*8 + (kl & 7)] = __float2bfloat16(p);
                    }
        }
        #pragma unroll
        for (int j = 0; j < 2; ++j) {
            int c = threadIdx.x + j*256;
            int tr = c >> 3, chk = c & 7;
            bf16x8 v = *(const bf16x8*)(vbase + (size_t)(b*256 + kt*64 + tr)*1600 + chk*8);
            *(bf16x8*)(&Vst[tr*72 + chk*8]) = v;
        }
        __syncthreads();
        #pragma unroll
        for (int j = 0; j < 2; ++j) {
            int c = threadIdx.x + j*256;
            int col = c & 63, chk = c >> 6;
            bf16x8 v;
            #pragma unroll
            for (int e = 0; e < 8; ++e)
                v[e] = (short)Vst[(chk*8 + e)*72 + col];
            Bv[col*8 + (chk ^ (col & 7))] = v;
        }
        __syncthreads();

        bf16x8 pa[2][2], vb[2][2];
        #pragma unroll
        for (int fm = 0; fm < 2; ++fm) {
            int row = wm*32 + fm*16 + (lane & 15);
            #pragma unroll
            for (int ks = 0; ks < 2; ++ks)
                pa[fm][ks] = ((bf16x8*)Ps)[row*8 + ((ks*4 + (lane>>4)) ^ (row & 7))];
        }
        #pragma unroll
        for (int fn = 0; fn < 2; ++fn) {
            int col = wn*32 + fn*16 + (lane & 15);
            #pragma unroll
            for (int ks = 0; ks < 2; ++ks)
                vb[fn][ks] = Bv[col*8 + ((ks*4 + (lane>>4)) ^ (col & 7))];
        }
        #pragma unroll
        for (int ks = 0; ks < 2; ++ks)
            #pragma unroll
            for (int fm = 0; fm < 2; ++fm)
                #pragma unroll
                for (int fn = 0; fn < 2; ++fn)
                    acc2[fm][fn] = __builtin_amdgcn_mfma_f32_16x16x32_bf16(
                        pa[fm][ks], vb[fn][ks], acc2[fm][fn], 0, 0, 0);
    }

    #pragma unroll
    for (int fm = 0; fm < 2; ++fm)
        #pragma unroll
        for (int fn = 0; fn < 2; ++fn)
            #pragma unroll
            for (int r = 0; r < 4; ++r) {
                int rowl = wm*32 + fm*16 + (lane>>4)*4 + r;
                int col = wn*32 + fn*16 + (lane & 15);
                gmb[((size_t)(b*256 + rh*64 + rowl))*512 + hh*64 + col] =
                    __float2bfloat16(acc2[fm][fn][r]);
            }
}

// =====================================================================================
// Fused 4-segment GEMM, split-K=4 over blockIdx.z (18 kt each)
__global__ __launch_bounds__(256) void fgemm_kernel(
    const bh16* __restrict__ A0, const bh16* __restrict__ A1,
    const bh16* __restrict__ A2, const bh16* __restrict__ A3,
    const bh16* __restrict__ B0, const bh16* __restrict__ B1,
    const bh16* __restrict__ B2, const bh16* __restrict__ B3,
    const float* __restrict__ bias,
    float* __restrict__ Cf0, float* __restrict__ Cf1,
    float* __restrict__ Cf2, float* __restrict__ Cf3,
    int dil, const bh16* __restrict__ zp)
{
    __shared__ bf16x8 As[128*8];
    __shared__ bf16x8 Bs[64*8];

    int bx = blockIdx.x, by = blockIdx.y;
    xcd_swizzle_always(bx, by);
    const int zz = blockIdx.z;
    const int ktlo = zz * 18;
    const int kthi = ktlo + 18;

    const int tid  = threadIdx.x;
    const int lane = tid & 63, w = tid >> 6;
    const int wm = w >> 1, wn = w & 1;
    const int row0 = by * 128, col0 = bx * 64;

    f32x4 acc[4][2];
    #pragma unroll
    for (int i = 0; i < 4; ++i)
        #pragma unroll
        for (int j = 0; j < 2; ++j) acc[i][j] = (f32x4){0.f,0.f,0.f,0.f};

    for (int kt = ktlo; kt < kthi; ++kt) {
        const bh16* Aseg; const bh16* Bseg;
        int ldas, ldbs, k0, mask_sh, addr_sh;
        if (kt < 8) {
            Aseg = A0; Bseg = B0; ldas = 512; ldbs = 512;
            k0 = kt << 6; mask_sh = 0; addr_sh = 0;
        } else if (kt < 40) {
            Aseg = A1; Bseg = B1; ldas = 2048; ldbs = 2048;
            k0 = (kt - 8) << 6; mask_sh = 0; addr_sh = 0;
        } else if (kt < 48) {
            Aseg = A2; Bseg = B2; ldas = 512; ldbs = 512;
            k0 = (kt - 40) << 6; mask_sh = 0; addr_sh = 0;
        } else {
            int kl = kt - 48, tap = kl >> 3;
            Aseg = A3; Bseg = B3; ldas = 512; ldbs = 1536;
            k0 = kl << 6;
            mask_sh = (2 - tap) * dil;
            addr_sh = mask_sh + tap;
        }
        #pragma unroll
        for (int j = 0; j < 4; ++j) {
            int c = ((w*4 + j) << 6) + lane;
            int row = c >> 3, chk = c & 7;
            int schk = chk ^ (row & 7);
            int grow = row0 + row;
            const bh16* src = ((grow & 255) >= mask_sh)
                ? (Aseg + (size_t)(grow - addr_sh)*ldas + k0 + schk*8) : zp;
            gload16(src, &As[(w*4 + j) * 64]);
        }
        #pragma unroll
        for (int j = 0; j < 2; ++j) {
            int c = ((w*2 + j) << 6) + lane;
            int row = c >> 3, chk = c & 7;
            int schk = chk ^ (row & 7);
            int gcol = col0 + row;
            gload16(Bseg + (size_t)gcol*ldbs + k0 + schk*8, &Bs[(w*2 + j) * 64]);
        }
        asm volatile("s_waitcnt vmcnt(0)" ::: "memory");
        __syncthreads();

        bf16x8 a[4][2], b[2][2];
        #pragma unroll
        for (int fm = 0; fm < 4; ++fm) {
            int row = wm*64 + fm*16 + (lane & 15);
            #pragma unroll
            for (int ks = 0; ks < 2; ++ks)
                a[fm][ks] = As[row*8 + ((ks*4 + (lane>>4)) ^ (row & 7))];
        }
        #pragma unroll
        for (int fn = 0; fn < 2; ++fn) {
            int col = wn*32 + fn*16 + (lane & 15);
            #pragma unroll
            for (int ks = 0; ks < 2; ++ks)
                b[fn][ks] = Bs[col*8 + ((ks*4 + (lane>>4)) ^ (col & 7))];
        }
        #pragma unroll
        for (int ks = 0; ks < 2; ++ks)
            #pragma unroll
            for (int fm = 0; fm < 4; ++fm)
                #pragma unroll
                for (int fn = 0; fn < 2; ++fn)
                    acc[fm][fn] = __builtin_amdgcn_mfma_f32_16x16x32_bf16(
                        a[fm][ks], b[fn][ks], acc[fm][fn], 0, 0, 0);
        __syncthreads();
    }

    float* Cf = (zz == 0) ? Cf0 : (zz == 1) ? Cf1 : (zz == 2) ? Cf2 : Cf3;
    #pragma unroll
    for (int fm = 0; fm < 4; ++fm) {
        #pragma unroll
        for (int fn = 0; fn < 2; ++fn) {
            int gc = col0 + wn*32 + fn*16 + (lane & 15);
            float bs = (zz == 0) ? bias[gc] : 0.f;
            #pragma unroll
            for (int r = 0; r < 4; ++r) {
                int gr = row0 + wm*64 + fm*16 + (lane>>4)*4 + r;
                Cf[(size_t)gr*512 + gc] = acc[fm][fn][r] + bs;
            }
        }
    }
}

// =====================================================================================
// Small-M (M=16) MFMA GEMM, one wave = 16x16xK tile, no LDS.
__global__ __launch_bounds__(256) void hgemm16_kernel(
    const bh16* __restrict__ A, int lda, long aZ,
    const bh16* __restrict__ Bt, int ldb,
    const float* __restrict__ bias,
    const float* __restrict__ pre,
    float* __restrict__ Of, bh16* __restrict__ Ob, long oZ,
    int N, int K, int act,
    float* __restrict__ curf, bh16* __restrict__ curb,
    const float* __restrict__ scaleptr)
{
    const int z = blockIdx.z;
    A += (long)z * aZ;
    const int lane = threadIdx.x & 63, w = threadIdx.x >> 6;
    const int col0 = blockIdx.x * 64 + w * 16;
    const int ar = lane & 15;
    const int koff = (lane >> 4) * 8;
    const bh16* arow = A + (size_t)ar * lda + koff;
    const bh16* brow = Bt + (size_t)(col0 + ar) * ldb + koff;
    f32x4 acc = {0.f, 0.f, 0.f, 0.f};
    const int nkt = K >> 5;
    for (int kt0 = 0; kt0 < nkt; kt0 += 8) {
        bf16x8 av[8], bv[8];
        #pragma unroll
        for (int j = 0; j < 8; ++j) {
            av[j] = *(const bf16x8*)(arow + (size_t)(kt0 + j) * 32);
            bv[j] = *(const bf16x8*)(brow + (size_t)(kt0 + j) * 32);
        }
        #pragma unroll
        for (int j = 0; j < 8; ++j)
            acc = __builtin_amdgcn_mfma_f32_16x16x32_bf16(av[j], bv[j], acc, 0, 0, 0);
    }
    const int col = col0 + ar;
    float bs = bias ? bias[col] : 0.f;
    float sc = scaleptr ? *scaleptr : 0.f;
    #pragma unroll
    for (int r = 0; r < 4; ++r) {
        int row = (lane >> 4) * 4 + r;
        float v = acc[r] + bs;
        if (pre) v += pre[(size_t)row * N + col];
        if (act == ACT_SILU)      v = v / (1.f + expf(-v));
        else if (act == ACT_TANH) v = tanhf(v);
        if (curf) {
            size_t o = (size_t)row * 512 + col;
            float nc = curf[o] - v * sc;
            curf[o] = nc;
            curb[o] = __float2bfloat16(nc);
        } else {
            size_t o = (size_t)z * oZ + (size_t)row * N + col;
            if (Of) Of[o] = v;
            if (Ob) Ob[o] = __float2bfloat16(v);
        }
    }
}

// ---------------- wavelet: in-kernel filter softmax + dec (LDS tile) + interp ----------------
__global__ __launch_bounds__(256) void wave4_kernel(const bh16* __restrict__ hb,
                                                    const float* __restrict__ wav0,
                                                    const float* __restrict__ wav1,
                                                    const float* __restrict__ wav2,
                                                    const float* __restrict__ wav3,
                                                    int l,
                                                    bh16* __restrict__ comb)
{
    __shared__ float dtile[66 * 64];
    __shared__ float ftile[32 * 64];
    const int dblk = blockIdx.x;
    const int iy = blockIdx.y;
    const int b = blockIdx.z;
    const int i = iy >> 1, thalf = iy & 1;
    const int Karr[4] = {4, 8, 16, 32};
    const int K = Karr[i], sv = 2 << i, Ti = 128 >> i;
    const int tid = threadIdx.x;
    const int dbase = dblk * 64;
    // filter softmax for this block's 64 channels
    if (tid < 64) {
        const float* wsrc = (i == 0) ? wav0 : (i == 1) ? wav1 : (i == 2) ? wav2 : wav3;
        const float* row = wsrc + ((size_t)l * DD + dbase + tid) * K;
        float mx = -1e30f;
        for (int k = 0; k < K; ++k) mx = fmaxf(mx, row[k]);
        float s = 0.f;
        for (int k = 0; k < K; ++k) { float e = expf(row[k] - mx); ftile[k*64 + tid] = e; s += e; }
        float inv = 1.f / s;
        for (int k = 0; k < K; ++k) ftile[k*64 + tid] *= inv;
    }
    const float invsv = 1.f / (float)sv;
    const int t0 = thalf * 128;
    float p0 = ((float)t0 + 0.5f) * invsv - 0.5f;
    p0 = fminf(fmaxf(p0, 0.f), (float)(Ti - 1));
    const int jbase = (int)p0;
    float p1 = ((float)(t0 + 127) + 0.5f) * invsv - 0.5f;
    p1 = fminf(fmaxf(p1, 0.f), (float)(Ti - 1));
    const int him = min((int)p1 + 1, Ti - 1);
    const int jcount = him - jbase + 1;     // <= 66
    __syncthreads();
    const bh16* hcol = hb + (size_t)b * (TT * DD) + dbase;
    for (int e = tid; e < jcount * 64; e += 256) {
        int jl = e >> 6, d0 = e & 63;
        int j = jbase + jl;
        int tb = j * sv - (K - 1);
        float acc = 0.f;
        #pragma unroll 4
        for (int k = 0; k < K; ++k) {
            int t = tb + k;
            if (t >= 0)
                acc += b2f(*(const unsigned short*)(hcol + (size_t)t * DD + d0)) * ftile[k * 64 + d0];
        }
        dtile[jl * 64 + d0] = acc;
    }
    __syncthreads();
    for (int e = tid; e < 128 * 64; e += 256) {
        int tl = e >> 6, d0 = e & 63;
        int t = t0 + tl;
        float pos = ((float)t + 0.5f) * invsv - 0.5f;
        pos = fminf(fmaxf(pos, 0.f), (float)(Ti - 1));
        int lo = (int)pos;
        int hi = min(lo + 1, Ti - 1);
        float w = pos - (float)lo;
        float v = dtile[(lo - jbase) * 64 + d0] * (1.f - w) + dtile[(hi - jbase) * 64 + d0] * w;
        comb[((size_t)b * TT + t) * 2048 + i * 512 + dbase + d0] = __float2bfloat16(v);
    }
}

// ---------------- h = layernorm(s0+s1+s2+s3 + h)*g + b, dual fp32+bf16 out ----------------
__global__ __launch_bounds__(256) void add_ln_kernel(const float* __restrict__ s0, const float* __restrict__ s1,
                                                     const float* __restrict__ s2, const float* __restrict__ s3,
                                                     float* __restrict__ h, bh16* __restrict__ hb,
                                                     const float* __restrict__ g, const float* __restrict__ be)
{
    int lane = threadIdx.x & 63, wid = threadIdx.x >> 6;
    size_t row = (size_t)blockIdx.x * 4 + wid;
    const float* sr0 = s0 + row * DD;
    const float* sr1 = s1 + row * DD;
    const float* sr2 = s2 + row * DD;
    const float* sr3 = s3 + row * DD;
    float* hr = h + row * DD;
    bh16* hbr = hb + row * DD;
    float xv[8]; float sum = 0.f;
    #pragma unroll
    for (int u = 0; u < 8; ++u) {
        int c = lane + u * 64;
        xv[u] = sr0[c] + sr1[c] + sr2[c] + sr3[c] + hr[c];
        sum += xv[u];
    }
    #pragma unroll
    for (int off = 32; off; off >>= 1) sum += __shfl_xor(sum, off);
    float mu = sum * (1.f / 512.f);
    float sq = 0.f;
    #pragma unroll
    for (int u = 0; u < 8; ++u) { float d = xv[u] - mu; sq += d * d; }
    #pragma unroll
    for (int off = 32; off; off >>= 1) sq += __shfl_xor(sq, off);
    float rstd = 1.f / sqrtf(sq * (1.f / 512.f) + 1e-5f);
    #pragma unroll
    for (int u = 0; u < 8; ++u) {
        int c = lane + u * 64;
        float v = (xv[u] - mu) * rstd * g[c] + be[c];
        hr[c] = v;
        hbr[c] = __float2bfloat16(v);
    }
}

// ---------------- weight transpose-convert ----------------
__global__ __launch_bounds__(256) void wtrans_kernel(const float* __restrict__ W, bh16* __restrict__ Wt,
                                                     int K, int N, long lstride)
{
    int l = blockIdx.z;
    const float* Wl = W + (size_t)l * K * N;
    bh16* Wo = Wt + (size_t)l * lstride;
    __shared__ float tile[32][33];
    int n0 = blockIdx.x * 32, k0 = blockIdx.y * 32;
    int lx = threadIdx.x & 31, ly = threadIdx.x >> 5;
    #pragma unroll
    for (int j = 0; j < 4; ++j) {
        int kk = ly + j * 8;
        tile[kk][lx] = Wl[(size_t)(k0 + kk) * N + n0 + lx];
    }
    __syncthreads();
    #pragma unroll
    for (int j = 0; j < 4; ++j) {
        int nr = ly + j * 8;
        Wo[(size_t)(n0 + nr) * K + k0 + lx] = __float2bfloat16(tile[lx][nr]);
    }
}

// ---------------- fused qkv|te1 transpose: grid (50, 16, 6) ----------------
__global__ __launch_bounds__(256) void wtrans4_kernel(const float* __restrict__ gq, const float* __restrict__ gk,
                                                      const float* __restrict__ gv, const float* __restrict__ te1,
                                                      bh16* __restrict__ qkvT)
{
    int bxx = blockIdx.x, l = blockIdx.z;
    const float* W; long off; int N; int n0;
    if (bxx < 16)      { W = gq;  off = 0;      N = 512; n0 = bxx * 32; }
    else if (bxx < 32) { W = gk;  off = 262144; N = 512; n0 = (bxx - 16) * 32; }
    else if (bxx < 48) { W = gv;  off = 524288; N = 512; n0 = (bxx - 32) * 32; }
    else               { W = te1; off = 786432; N = 64;  n0 = (bxx - 48) * 32; }
    const float* Wl = W + (size_t)l * 512 * N;
    bh16* Wo = qkvT + (size_t)l * 819200 + off;
    __shared__ float tile[32][33];
    int k0 = blockIdx.y * 32;
    int lx = threadIdx.x & 31, ly = threadIdx.x >> 5;
    #pragma unroll
    for (int j = 0; j < 4; ++j) {
        int kk = ly + j * 8;
        tile[kk][lx] = Wl[(size_t)(k0 + kk) * N + n0 + lx];
    }
    __syncthreads();
    #pragma unroll
    for (int j = 0; j < 4; ++j) {
        int nr = ly + j * 8;
        Wo[(size_t)(n0 + nr) * 512 + k0 + lx] = __float2bfloat16(tile[lx][nr]);
    }
}

// ---------------- cc_w [L][O][I][3] f32 -> ccT [L][O][tap*512+I] bf16 ----------------
__global__ __launch_bounds__(256) void ccconv_kernel(const float* __restrict__ ccw, bh16* __restrict__ ccT)
{
    size_t idx = (size_t)blockIdx.x * 256 + threadIdx.x;   // 6*512*1536
    int i = idx & 511; size_t rem = idx >> 9;
    int tap = (int)(rem % 3); rem /= 3;
    int o = (int)(rem & 511); int l = (int)(rem >> 9);
    ccT[idx] = __float2bfloat16(ccw[(((size_t)l*512 + o)*512 + i)*3 + tap]);
}

// ---------------- qkv|te1 bias concat [L][1600] + fused-epilogue bias sum [L][512] ----------------
__global__ __launch_bounds__(256) void qkvbias_kernel(const float* __restrict__ qb_, const float* __restrict__ kb_,
                                                      const float* __restrict__ vb_, const float* __restrict__ t1b_,
                                                      float* __restrict__ ob,
                                                      const float* __restrict__ gob, const float* __restrict__ wrb,
                                                      const float* __restrict__ tdb, const float* __restrict__ ccb,
                                                      float* __restrict__ bsum)
{
    int idx = blockIdx.x * 256 + threadIdx.x;
    if (idx < 6 * 1600) {
        int l = idx / 1600, n = idx % 1600;
        float v = (n < 512) ? qb_[l*512 + n]
                : (n < 1024) ? kb_[l*512 + n - 512]
                : (n < 1536) ? vb_[l*512 + n - 1024]
                : t1b_[l*64 + n - 1536];
        ob[idx] = v;
    }
    if (idx < 6 * 512) {
        bsum[idx] = gob[idx] + wrb[idx] + tdb[idx] + ccb[idx];
    }
}

// ---------------- x f32 -> bf16 ----------------
__global__ __launch_bounds__(256) void convx_kernel(const float* __restrict__ x, bh16* __restrict__ xb)
{
    size_t idx = (size_t)blockIdx.x * 256 + threadIdx.x;
    xb[idx] = __float2bfloat16(x[idx]);
}

// ---------------- E matrix: row (t,b) = [sched[t]*noise[t,b,:] | temb[t]] ----------------
__global__ __launch_bounds__(256) void build_E_kernel(const float* __restrict__ noise, const float* __restrict__ sched,
                                                      bh16* __restrict__ E)
{
    int idx = blockIdx.x * 256 + threadIdx.x;   // 10*16*1024
    if (idx >= SS * BB * 1024) return;
    int k = idx & 1023; int rem = idx >> 10; int b = rem & 15; int t = rem >> 4;
    float v;
    if (k < 512) {
        v = sched[t] * noise[((size_t)t * BB + b) * 512 + k];
    } else {
        int j = k - 512;
        const float kfac = -9.210340371976184f / 255.f;
        v = (j < 256) ? sinf((float)t * expf((float)j * kfac))
                      : cosf((float)t * expf((float)(j - 256) * kfac));
    }
    E[idx] = __float2bfloat16(v);
}

// ---------------- head helpers ----------------
__global__ void init_kernel(bh16* zp, float* loss)
{
    int t = threadIdx.x;
    if (t < 64) zp[t] = __float2bfloat16(0.f);
    if (t == 64) *loss = 0.f;
}

__global__ __launch_bounds__(256) void build_cat16_kernel(const float* __restrict__ h, bh16* __restrict__ catb)
{
    int idx = blockIdx.x * 256 + threadIdx.x;   // 16*1024
    if (idx >= BB * 1024) return;
    int k = idx & 1023, b = idx >> 10;
    float v = (k < 512) ? h[((size_t)b * TT + 255) * DD + k]
                        : h[((size_t)b * TT + 254) * DD + (k - 512)];
    catb[idx] = __float2bfloat16(v);
}

__global__ __launch_bounds__(256) void cur_init2_kernel(const float* __restrict__ h, const float* __restrict__ mix,
                                                        float* __restrict__ curf, bh16* __restrict__ curb)
{
    int idx = blockIdx.x * 256 + threadIdx.x;   // 16*512
    if (idx >= BB * DD) return;
    int c = idx & 511, b = idx >> 9;
    float v = h[((size_t)b * TT + 255) * DD + c] + mix[idx];
    curf[idx] = v;
    curb[idx] = __float2bfloat16(v);
}

__global__ void fail_kernel(float* p) { p[0] = 1e30f; }

// =====================================================================================
extern "C" void kernel_launch(void* const* d_in, const int* in_sizes, int n_in,
                              void* d_out, int out_size, void* d_ws, size_t ws_size,
                              hipStream_t stream)
{
    const float* x      = (const float*)d_in[0];
    const float* in_w   = (const float*)d_in[1];
    const float* in_b   = (const float*)d_in[2];
    const float* gq_w   = (const float*)d_in[3];
    const float* gq_b   = (const float*)d_in[4];
    const float* gk_w   = (const float*)d_in[5];
    const float* gk_b   = (const float*)d_in[6];
    const float* gv_w   = (const float*)d_in[7];
    const float* gv_b   = (const float*)d_in[8];
    const float* go_w   = (const float*)d_in[9];
    const float* go_b   = (const float*)d_in[10];
    const float* curv   = (const float*)d_in[11];
    const float* wav0   = (const float*)d_in[12];
    const float* wav1   = (const float*)d_in[13];
    const float* wav2   = (const float*)d_in[14];
    const float* wav3   = (const float*)d_in[15];
    const float* wrec_w = (const float*)d_in[16];
    const float* wrec_b = (const float*)d_in[17];
    const float* te1_w  = (const float*)d_in[18];
    const float* te1_b  = (const float*)d_in[19];
    const float* te2_w  = (const float*)d_in[20];
    const float* te2_b  = (const float*)d_in[21];
    const float* td1_w  = (const float*)d_in[22];
    const float* td1_b  = (const float*)d_in[23];
    const float* td2_w  = (const float*)d_in[24];
    const float* td2_b  = (const float*)d_in[25];
    const float* bd_w   = (const float*)d_in[26];
    const float* bd_b   = (const float*)d_in[27];
    const float* cc_w   = (const float*)d_in[28];
    const float* cc_b   = (const float*)d_in[29];
    const float* ln_g   = (const float*)d_in[30];
    const float* ln_b   = (const float*)d_in[31];
    const float* mm1_w  = (const float*)d_in[32];
    const float* mm1_b  = (const float*)d_in[33];
    const float* mm2_w  = (const float*)d_in[34];
    const float* mm2_b  = (const float*)d_in[35];
    const float* dn1_w  = (const float*)d_in[36];
    const float* dn1_b  = (const float*)d_in[37];
    const float* dn2_w  = (const float*)d_in[38];
    const float* dn2_b  = (const float*)d_in[39];
    const float* dn3_w  = (const float*)d_in[40];
    const float* dn3_b  = (const float*)d_in[41];
    const float* out_w  = (const float*)d_in[42];
    const float* out_b  = (const float*)d_in[43];
    const float* nsched = (const float*)d_in[44];
    const float* noise  = (const float*)d_in[45];
    float* out = (float*)d_out;
    float* ws  = (float*)d_ws;

    // ---- fp32 workspace layout (float offsets) ----
    const size_t o_h   = 0;          // 2097152
    const size_t o_dec = 2097152;    // 2097152 (s2 partial; pre1 for head)
    const size_t o_s   = 4194304;    // 2097152
    const size_t o_tf  = 6291456;    // 262144 (unused)
    const size_t o_at  = 6619136;    // 8388608: comb (bf16, first half) + s3/s4 partials
    const size_t o_mix = 15038464;   // 8192
    const size_t o_cur = 15046656;   // 8192
    const size_t o_qkb = 15054848;   // 9600
    const size_t o_bs  = 15064448;   // 3072
    const size_t FP32_TOTAL = 15095808;
    // ---- bf16 region (element offsets from bp) ----
    const size_t b_xb   = 0;          // 1572864
    const size_t b_hb   = 1572864;    // 2097152
    const size_t b_qkv  = 3670016;    // 6553600: packed qkv|t1 [4096][1600]
    const size_t b_pb   = 12320768;   // 8388608 (head scratch region)
    const size_t b_gmb  = 20709376;   // 2097152
    const size_t b_tdb  = 22806528;   // 2097152
    const size_t b_zp   = 25165824;   // 512
    const size_t b_inwT = 25166336;   // 196608
    const size_t b_qkvT = 25362944;   // 4915200
    const size_t b_goT  = 30278144;   // 1572864
    const size_t b_wrT  = 31851008;   // 6291456
    const size_t b_td1T = 38142464;   // 196608
    const size_t b_td2T = 38339072;   // 1572864
    const size_t b_te2T = 39911936;   // 24576
    const size_t b_ccT  = 39936512;   // 4718592
    const size_t BF16_TOTAL = 44655104;
    const size_t TOTAL_BYTES = FP32_TOTAL * 4 + BF16_TOTAL * 2;
    if (ws_size < TOTAL_BYTES) { fail_kernel<<<1, 1, 0, stream>>>(out); return; }

    float* h_   = ws + o_h;
    float* s2_  = ws + o_dec;
    float* s_   = ws + o_s;
    float* at_  = ws + o_at;
    float* s3_  = at_ + 4194304;
    float* s4_  = at_ + 6291456;
    float* mixb = ws + o_mix;
    float* curf = ws + o_cur;
    float* qkvbias = ws + o_qkb;
    float* bsum = ws + o_bs;
    bh16* bp   = (bh16*)(ws + FP32_TOTAL);
    bh16* xb   = bp + b_xb;
    bh16* hb   = bp + b_hb;
    bh16* qkvb = bp + b_qkv;
    bh16* pb   = bp + b_pb;
    bh16* gmb  = bp + b_gmb;
    bh16* tdb  = bp + b_tdb;
    bh16* zp   = bp + b_zp;
    bh16* inwT = bp + b_inwT;
    bh16* qkvT = bp + b_qkvT;
    bh16* goT  = bp + b_goT;
    bh16* wrT  = bp + b_wrT;
    bh16* td1T = bp + b_td1T;
    bh16* td2T = bp + b_td2T;
    bh16* te2T = bp + b_te2T;
    bh16* ccT  = bp + b_ccT;
    bh16* combb = (bh16*)at_;

    // head bf16 scratch: aliased into pb region (dead during layers)
    bh16* dn1T  = pb;             // 524288
    bh16* dn2T  = pb + 524288;    // 262144
    bh16* dn3T  = pb + 786432;    // 262144
    bh16* mm1T  = pb + 1048576;   // 524288
    bh16* mm2T  = pb + 1572864;   // 262144
    bh16* outT  = pb + 1835008;   // 196608
    bh16* E16   = pb + 2031616;   // 163840
    bh16* cat16 = pb + 2195456;   // 16384
    bh16* tmb16 = pb + 2211840;   // 8192
    bh16* cur16 = pb + 2220032;   // 8192
    bh16* d1b16 = pb + 2228224;   // 8192
    bh16* d2b16 = pb + 2236416;   // 8192
    float* pre1 = s2_;            // 81920 f32, aliases s2 after layers

    auto mgp = [&](const bh16* A, int lda, const bh16* Bt, int ldb,
                   const float* bias, float* Cf, bh16* Cb, int ldc,
                   int M, int N, int K, int shift, int accum, int act) {
        dim3 g((N + 63) / 64, M / 128, 1);
        mgemm_kernel<<<g, 256, 0, stream>>>(A, lda, Bt, ldb, bias, Cf, Cb, ldc, N, K,
                                            shift, accum, act, zp);
    };
    auto hg = [&](const bh16* A, int lda, long aZ, const bh16* Bt, int ldb,
                  const float* bias, const float* pre, float* Of, bh16* Ob, long oZ,
                  int N, int K, int act, float* cf, bh16* cb, const float* sp, int nz) {
        hgemm16_kernel<<<dim3(N / 64, 1, nz), 256, 0, stream>>>(
            A, lda, aZ, Bt, ldb, bias, pre, Of, Ob, oZ, N, K, act, cf, cb, sp);
    };

    // ---- setup: zero page/loss, converts ----
    init_kernel<<<1, 128, 0, stream>>>(zp, out + BB * DIN);
    convx_kernel<<<BT * DIN / 256, 256, 0, stream>>>(x, xb);
    wtrans_kernel<<<dim3(DD/32, DIN/32, 1), 256, 0, stream>>>(in_w, inwT, DIN, DD, (long)DIN*DD);
    wtrans4_kernel<<<dim3(50, 16, 6), 256, 0, stream>>>(gq_w, gk_w, gv_w, te1_w, qkvT);
    qkvbias_kernel<<<38, 256, 0, stream>>>(gq_b, gk_b, gv_b, te1_b, qkvbias,
                                           go_b, wrec_b, td2_b, cc_b, bsum);
    wtrans_kernel<<<dim3(16, 16, 6), 256, 0, stream>>>(go_w, goT, DD, DD, (long)DD*DD);
    wtrans_kernel<<<dim3(16, 64, 6), 256, 0, stream>>>(wrec_w, wrT, 2048, DD, 2048L*DD);
    wtrans_kernel<<<dim3(16, 2, 6), 256, 0, stream>>>(td1_w, td1T, PP, DD, (long)PP*DD);
    wtrans_kernel<<<dim3(16, 16, 6), 256, 0, stream>>>(td2_w, td2T, DD, DD, (long)DD*DD);
    wtrans_kernel<<<dim3(2, 2, 6), 256, 0, stream>>>(te2_w, te2T, PP, PP, (long)PP*PP);
    ccconv_kernel<<<18432, 256, 0, stream>>>(cc_w, ccT);

    // h = x @ in_w + in_b  (fp32 + bf16)
    mgp(xb, DIN, inwT, DIN, in_b, h_, hb, DD, BT, DD, DIN, 0, 0, ACT_NONE);

    for (int l = 0; l < LL; ++l) {
        // fused q|k|v|te1 projection: N=1600, tail relu on te1
        mgp(hb, DD, qkvT + (size_t)l*819200, DD, qkvbias + (size_t)l*1600,
            nullptr, qkvb, 1600, BT, 1600, DD, 0, 0, ACT_RELU_TAIL);
        // attention: fully fused
        fattn_kernel<<<dim3(4, 128), 256, 0, stream>>>(qkvb, curv + (size_t)l*HH, gmb);
        // wavelet: in-kernel softmax + dec + interp
        wave4_kernel<<<dim3(8, 8, 16), 256, 0, stream>>>(hb, wav0, wav1, wav2, wav3, l, combb);
        // topo: te2 + bd loss + td1 fused
        topo_kernel<<<dim3(8, 32), 256, 0, stream>>>(
            qkvb + 1536, te2T + (size_t)l*4096, te2_b + (size_t)l*PP,
            td1T + (size_t)l*32768, td1_b + (size_t)l*DD,
            bd_w + (size_t)l*PP*2, bd_b + (size_t)l*2, out + BB*DIN, tdb);
        // fused split-K(4) s = gmb@go + comb@wrec + tdb@td2 + cc(hb) + biassum
        fgemm_kernel<<<dim3(8, 32, 4), 256, 0, stream>>>(
            gmb, combb, tdb, hb,
            goT + (size_t)l*262144, wrT + (size_t)l*1048576,
            td2T + (size_t)l*262144, ccT + (size_t)l*786432,
            bsum + (size_t)l*512, s_, s2_, s3_, s4_, 1 << l, zp);
        // h = LN(s + s2 + s3 + s4 + h)
        add_ln_kernel<<<BT/4, 256, 0, stream>>>(s_, s2_, s3_, s4_, h_, hb, ln_g, ln_b);
    }

    // ---- head ----
    wtrans_kernel<<<dim3(16, 32, 1), 256, 0, stream>>>(dn1_w, dn1T, 1024, 512, 0L);
    wtrans_kernel<<<dim3(16, 16, 1), 256, 0, stream>>>(dn2_w, dn2T, 512, 512, 0L);
    wtrans_kernel<<<dim3(16, 16, 1), 256, 0, stream>>>(dn3_w, dn3T, 512, 512, 0L);
    wtrans_kernel<<<dim3(16, 32, 1), 256, 0, stream>>>(mm1_w, mm1T, 1024, 512, 0L);
    wtrans_kernel<<<dim3(16, 16, 1), 256, 0, stream>>>(mm2_w, mm2T, 512, 512, 0L);
    wtrans_kernel<<<dim3(12, 16, 1), 256, 0, stream>>>(out_w, outT, 512, 384, 0L);
    build_E_kernel<<<640, 256, 0, stream>>>(noise, nsched, E16);
    hg(E16, 1024, 16*1024, dn1T, 1024, dn1_b, nullptr, pre1, nullptr, 8192,
       512, 1024, ACT_NONE, nullptr, nullptr, nullptr, SS);
    build_cat16_kernel<<<64, 256, 0, stream>>>(h_, cat16);
    hg(cat16, 1024, 0, mm1T, 1024, mm1_b, nullptr, nullptr, tmb16, 0,
       512, 1024, ACT_TANH, nullptr, nullptr, nullptr, 1);
    hg(tmb16, 512, 0, mm2T, 512, mm2_b, nullptr, mixb, nullptr, 0,
       512, 512, ACT_NONE, nullptr, nullptr, nullptr, 1);
    cur_init2_kernel<<<32, 256, 0, stream>>>(h_, mixb, curf, cur16);
    for (int t = 0; t < SS; ++t) {
        hg(cur16, 512, 0, dn1T, 1024, nullptr, pre1 + (size_t)t*8192, nullptr, d1b16, 0,
           512, 512, ACT_SILU, nullptr, nullptr, nullptr, 1);
        hg(d1b16, 512, 0, dn2T, 512, dn2_b, nullptr, nullptr, d2b16, 0,
           512, 512, ACT_SILU, nullptr, nullptr, nullptr, 1);
        hg(d2b16, 512, 0, dn3T, 512, dn3_b, nullptr, nullptr, nullptr, 0,
           512, 512, ACT_NONE, curf, cur16, nsched + t, 1);
    }
    hg(cur16, 512, 0, outT, 512, out_b, nullptr, out, nullptr, 0,
       384, 512, ACT_NONE, nullptr, nullptr, nullptr, 1);
}